// Round 4
// baseline (822.861 us; speedup 1.0000x reference)
//
#include <hip/hip_runtime.h>
#include <hip/hip_bf16.h>

// ---------------- problem constants ----------------
constexpr int U_  = 51200;
constexpr int I_  = 25600;
constexpr int N_  = U_ + I_;             // 76800 combined rows
constexpr int E_  = 1000000;
constexpr int EP_ = 100000;
constexpr int CB_ = 256;                 // contrastive chunk size
constexpr int NCHUNK_ = U_ / CB_;        // 200
constexpr size_t UD_ = (size_t)U_ * 64;
constexpr size_t ID_ = (size_t)I_ * 64;
constexpr int NB_ = N_ / 1024;           // 75 scan blocks
constexpr int NBK_ = 100;                // coarse buckets per side
constexpr int TILE_ = 4096;              // edges per Phase-A block
constexpr int NBA_ = (E_ + TILE_ - 1) / TILE_;  // 245
constexpr int DIRCAP_ = NBA_ * NBK_;     // 24500 entries max

// ---------------- workspace layout (4-byte element offsets) ----------------
constexpr size_t OFF_LOSS  = 0;
constexpr size_t OFF_FLAG  = 1;
// counters: 4=gallocU 5=dcntU 6=gallocI 7=dcntI
constexpr size_t OFF_WA    = 64;
constexpr size_t OFF_CNT   = 128;                    // N_ ints (fine histogram)
constexpr size_t MEMSET_BYTES = (OFF_CNT + N_) * 4;  // zero loss/counters/cnt
constexpr size_t OFF_RTMP  = OFF_CNT + N_;           // N_ ints
constexpr size_t OFF_BSUM  = OFF_RTMP + N_;          // 128
constexpr size_t OFF_BOFF  = OFF_BSUM + 128;         // 128
constexpr size_t OFF_ROWU  = OFF_BOFF + 128;         // U_+1
constexpr size_t OFF_ROWI  = OFF_ROWU + U_ + 1;      // I_+1
constexpr size_t OFF_DIRU  = ((OFF_ROWI + I_ + 1 + 63) / 64) * 64;  // 4*DIRCAP_
constexpr size_t OFF_DIRI  = ((OFF_DIRU + 4 * DIRCAP_ + 63) / 64) * 64;
constexpr size_t OFF_CSRU  = ((OFF_DIRI + 4 * DIRCAP_ + 63) / 64) * 64;  // E_
constexpr size_t OFF_CSRI  = OFF_CSRU + E_;          // E_
constexpr size_t OFF_U1    = ((OFF_CSRI + E_ + 63) / 64) * 64;
constexpr size_t OFF_I1    = OFF_U1 + UD_;
constexpr size_t OFF_HU    = OFF_I1 + ID_;           // bufU aliases here (2M elts, 8MB)
constexpr size_t OFF_HI    = OFF_HU + UD_;           // bufI aliases here (spills into anc)
constexpr size_t OFF_ANC   = OFF_HI + ID_;
// total ≈ 62.1 MB (< the 72.4 MB used successfully in round 2)

#define DEVI static __device__ __forceinline__

typedef _Float16 h2v __attribute__((ext_vector_type(2)));

DEVI float b2f(__hip_bfloat16 x) { return __bfloat162float(x); }

DEVI float ldf(const void* p, size_t i, int isf32) {
  if (isf32) return ((const float*)p)[i];
  return b2f(((const __hip_bfloat16*)p)[i]);
}

DEVI float fdot2f(h2v a, h2v b, float c) {
#if __has_builtin(__builtin_amdgcn_fdot2)
  return __builtin_amdgcn_fdot2(a, b, c, false);
#else
  return (float)a[0] * (float)b[0] + (float)a[1] * (float)b[1] + c;
#endif
}
DEVI unsigned h2u(h2v h) { unsigned u; __builtin_memcpy(&u, &h, 4); return u; }
DEVI h2v u2h(unsigned u) { h2v h; __builtin_memcpy(&h, &u, 4); return h; }
DEVI float frcp(float x) { return __builtin_amdgcn_rcpf(x); }

DEVI int waveInclScan(int v, int lane) {
  #pragma unroll
  for (int off = 1; off < 64; off <<= 1) {
    int t = __shfl_up(v, off, 64);
    if (lane >= off) v += t;
  }
  return v;
}

// ---------------- 0. dtype detection ----------------
__global__ void detect_kernel(const unsigned short* __restrict__ p,
                              float* __restrict__ flag) {
  int cnt = 0;
  for (int i = 0; i < 256; i++) {
    int e = (p[i] >> 7) & 0xFF;
    if (e >= 130) cnt++;
  }
  *flag = (cnt >= 8) ? 1.0f : 0.0f;
}

// ---------------- 1a. Phase A: bucket edges into chunked record buffer ----------
// key/payload are the edge endpoint arrays (key determines bucket).
// Emits 8B records (key<<32 | payload) grouped in per-(block,bucket) chunks,
// recorded in a directory. Optionally folds in the fine per-node histogram.
__global__ __launch_bounds__(256) void bucketA_kernel(
    const int* __restrict__ key, const int* __restrict__ payload,
    unsigned long long* __restrict__ buf, int* __restrict__ galloc,
    int* __restrict__ dir, int* __restrict__ dcnt,
    int shift, int* __restrict__ fineCnt, int doFine) {
  __shared__ int hist[NBK_], loff[NBK_ + 1], cbase[NBK_], lcur[NBK_];
  __shared__ unsigned long long recs[TILE_];
  int tid = threadIdx.x;
  int base = blockIdx.x * TILE_;
  for (int i = tid; i < NBK_; i += 256) hist[i] = 0;
  __syncthreads();
  int kk[16], pp[16];
  #pragma unroll
  for (int t = 0; t < 16; t++) {
    int e = base + t * 256 + tid;
    bool v = e < E_;
    kk[t] = v ? key[e] : -1;
    pp[t] = v ? payload[e] : 0;
    if (v) {
      atomicAdd(&hist[kk[t] >> shift], 1);
      if (doFine) {  // U pass: key=src, payload=dst
        atomicAdd(&fineCnt[kk[t]], 1);
        atomicAdd(&fineCnt[U_ + pp[t]], 1);
      }
    }
  }
  __syncthreads();
  if (tid < NBK_) {
    int c = hist[tid];
    int gb = 0;
    if (c > 0) {
      gb = atomicAdd(galloc, c);
      int di = atomicAdd(dcnt, 1);
      dir[di * 4]     = tid;
      dir[di * 4 + 1] = gb;
      dir[di * 4 + 2] = c;
    }
    cbase[tid] = gb;
  }
  __syncthreads();
  if (tid == 0) {
    int run = 0;
    for (int b = 0; b < NBK_; b++) { loff[b] = run; run += hist[b]; }
    loff[NBK_] = run;
  }
  __syncthreads();
  if (tid < NBK_) lcur[tid] = loff[tid];
  __syncthreads();
  #pragma unroll
  for (int t = 0; t < 16; t++) {
    if (kk[t] >= 0) {
      int b = kk[t] >> shift;
      int p = atomicAdd(&lcur[b], 1);
      recs[p] = ((unsigned long long)(unsigned)kk[t] << 32) | (unsigned)pp[t];
    }
  }
  __syncthreads();
  int total = loff[NBK_];
  for (int p = tid; p < total; p += 256) {
    int lo = 0, hi = NBK_;
    while (hi - lo > 1) { int mid = (lo + hi) >> 1; if (loff[mid] <= p) lo = mid; else hi = mid; }
    buf[cbase[lo] + (p - loff[lo])] = recs[p];
  }
}

// ---------------- 1b. Phase B: per-bucket CSR fill via LDS staging -------------
__global__ __launch_bounds__(256) void bucketB_kernel(
    const unsigned long long* __restrict__ buf,
    const int* __restrict__ dir, const int* __restrict__ dcnt,
    const int* __restrict__ rowptr, int* __restrict__ csr,
    int keysPerBucket) {
  __shared__ int stage[16384];      // 64 KB
  __shared__ int kcur[512];
  __shared__ int est[512], eln[512], epre[513];
  __shared__ int lcnt;
  int tid = threadIdx.x, b = blockIdx.x;
  if (tid == 0) lcnt = 0;
  int keyBase = b * keysPerBucket;
  int regionBase = rowptr[keyBase];
  int size = rowptr[keyBase + keysPerBucket] - regionBase;
  for (int k = tid; k < keysPerBucket; k += 256)
    kcur[k] = rowptr[keyBase + k] - regionBase;
  __syncthreads();
  int nd = *dcnt;
  for (int i = tid; i < nd; i += 256) {
    if (dir[i * 4] == b) {
      int li = atomicAdd(&lcnt, 1);
      est[li] = dir[i * 4 + 1];
      eln[li] = dir[i * 4 + 2];
    }
  }
  __syncthreads();
  if (tid == 0) {
    int run = 0;
    for (int i = 0; i < lcnt; i++) { epre[i] = run; run += eln[i]; }
    epre[lcnt] = run;
  }
  __syncthreads();
  int ne = lcnt;
  int total = epre[ne];
  for (int r = tid; r < total; r += 256) {
    int lo = 0, hi = ne;
    while (hi - lo > 1) { int mid = (lo + hi) >> 1; if (epre[mid] <= r) lo = mid; else hi = mid; }
    unsigned long long rec = buf[(size_t)est[lo] + (r - epre[lo])];
    int keyv = (int)(rec >> 32);
    int pay  = (int)(unsigned)(rec & 0xffffffffULL);
    int slot = atomicAdd(&kcur[keyv - keyBase], 1);
    if (slot < 16384) stage[slot] = pay;   // cap: statistically unreachable (+64 sigma)
  }
  __syncthreads();
  for (int s = tid; s < size; s += 256) csr[regionBase + s] = stage[s];
}

// ---------------- 1c. row-pointer scan (fine hist -> rowU/rowI) ----------------
__global__ __launch_bounds__(256) void scanA_kernel(
    const int* __restrict__ cnt, int* __restrict__ rtmp, int* __restrict__ bsum) {
  __shared__ int wsum[4];
  int tid = threadIdx.x, lane = tid & 63, wv = tid >> 6;
  int gid = blockIdx.x * 256 + tid;
  int4 v = ((const int4*)cnt)[gid];
  int s = v.x + v.y + v.z + v.w;
  int inc = waveInclScan(s, lane);
  if (lane == 63) wsum[wv] = inc;
  __syncthreads();
  int wvoff = 0;
  for (int w = 0; w < wv; w++) wvoff += wsum[w];
  int excl = wvoff + inc - s;
  int base = gid * 4;
  rtmp[base]     = excl;
  rtmp[base + 1] = excl + v.x;
  rtmp[base + 2] = excl + v.x + v.y;
  rtmp[base + 3] = excl + v.x + v.y + v.z;
  if (tid == 255) bsum[blockIdx.x] = wvoff + wsum[3];
}

__global__ void scanB_kernel(const int* __restrict__ bsum, int* __restrict__ boff) {
  if (threadIdx.x == 0) {
    int run = 0;
    for (int i = 0; i < NB_; i++) { boff[i] = run; run += bsum[i]; }
  }
}

__global__ __launch_bounds__(256) void scanC_kernel(
    const int* __restrict__ rtmp, const int* __restrict__ boff,
    int* __restrict__ rowU, int* __restrict__ rowI) {
  int gid = blockIdx.x * 256 + threadIdx.x;
  int off = boff[blockIdx.x];
  int4 v = ((const int4*)rtmp)[gid];
  int vals[4] = {v.x, v.y, v.z, v.w};
  int base = gid * 4;
  #pragma unroll
  for (int k = 0; k < 4; k++) {
    int i = base + k;
    int val = vals[k] + off;
    if (i < U_) rowU[i] = val;
    else        rowI[i - U_] = val - E_;
  }
  if (gid == 0) { rowU[U_] = E_; rowI[I_] = E_; }
}

// ---------------- 2. layer-1 aggregation (gather, normalized) ----------------
__global__ __launch_bounds__(256) void agg1_kernel(
    const void* __restrict__ src, const int* __restrict__ row,
    const int* __restrict__ csr, float* __restrict__ out,
    const float* __restrict__ flag) {
  int isf32 = *flag > 0.5f;
  int wv = threadIdx.x >> 6, lane = threadIdx.x & 63;
  int r = blockIdx.x * 4 + wv;
  int s0 = row[r], s1 = row[r + 1];
  float acc = 0.f;
  int j = s0;
  for (; j + 4 <= s1; j += 4) {
    int a = csr[j], b = csr[j + 1], c = csr[j + 2], d = csr[j + 3];
    float va = ldf(src, (size_t)a * 64 + lane, isf32);
    float vb = ldf(src, (size_t)b * 64 + lane, isf32);
    float vc = ldf(src, (size_t)c * 64 + lane, isf32);
    float vd = ldf(src, (size_t)d * 64 + lane, isf32);
    acc += (va + vb) + (vc + vd);
  }
  for (; j < s1; j++) acc += ldf(src, (size_t)csr[j] * 64 + lane, isf32);
  out[(size_t)r * 64 + lane] = acc / fmaxf((float)(s1 - s0), 1.0f);
}

// ---------------- 3. layer-2 aggregation + fused layer attention ----------------
__global__ __launch_bounds__(256) void agg2attn_kernel(
    const float* __restrict__ opp1, const void* __restrict__ base,
    const float* __restrict__ own1,
    const int* __restrict__ row, const int* __restrict__ csr,
    const float* __restrict__ Wa, float* __restrict__ h,
    const float* __restrict__ flag) {
  int isf32 = *flag > 0.5f;
  int wv = threadIdx.x >> 6, lane = threadIdx.x & 63;
  int r = blockIdx.x * 4 + wv;
  int s0 = row[r], s1 = row[r + 1];
  float acc = 0.f;
  int j = s0;
  for (; j + 4 <= s1; j += 4) {
    int a = csr[j], b = csr[j + 1], c = csr[j + 2], d = csr[j + 3];
    float va = opp1[(size_t)a * 64 + lane];
    float vb = opp1[(size_t)b * 64 + lane];
    float vc = opp1[(size_t)c * 64 + lane];
    float vd = opp1[(size_t)d * 64 + lane];
    acc += (va + vb) + (vc + vd);
  }
  for (; j < s1; j++) acc += opp1[(size_t)csr[j] * 64 + lane];
  size_t idx = (size_t)r * 64 + lane;
  float t2 = acc / fmaxf((float)(s1 - s0), 1.0f);
  float t0 = ldf(base, idx, isf32);
  float t1 = own1[idx];
  float w = Wa[lane];
  float p0 = t0 * w, p1 = t1 * w, p2 = t2 * w;
  #pragma unroll
  for (int off = 32; off; off >>= 1) {
    p0 += __shfl_xor(p0, off, 64);
    p1 += __shfl_xor(p1, off, 64);
    p2 += __shfl_xor(p2, off, 64);
  }
  float m = fmaxf(p0, fmaxf(p1, p2));
  float e0 = __expf(p0 - m), e1 = __expf(p1 - m), e2 = __expf(p2 - m);
  float inv = 1.0f / (e0 + e1 + e2);
  h[idx] = (t0 * e0 + t1 * e1 + t2 * e2) * inv;
}

// ---------------- Wa = W @ a ----------------
__global__ void wa_kernel(const void* __restrict__ W, const void* __restrict__ a,
                          float* __restrict__ Wa, const float* __restrict__ flag) {
  int isf32 = *flag > 0.5f;
  int d = threadIdx.x;
  float s = 0.f;
  for (int e = 0; e < 64; e++) s += ldf(W, d * 64 + e, isf32) * ldf(a, e, isf32);
  Wa[d] = s;
}

// ---------------- 4. anchor user embed (FFT filter + attention) ----------------
__global__ __launch_bounds__(256) void anchor_kernel(
    const void* __restrict__ ue, const void* __restrict__ WU,
    const void* __restrict__ aU, const void* __restrict__ cw,
    const int* __restrict__ nbr, float* __restrict__ out,
    const float* __restrict__ flag) {
  int isf32 = *flag > 0.5f;
  __shared__ __align__(16) float sf[4][8][64];
  __shared__ __align__(16) float urow[4][64];
  int wv = threadIdx.x >> 6, lane = threadIdx.x & 63;
  int u = blockIdx.x * 4 + wv;

  float x[8];
  #pragma unroll
  for (int k = 0; k < 8; k++) {
    int nb = nbr[u * 8 + k];
    x[k] = ldf(ue, (size_t)nb * 64 + lane, isf32);
  }
  const float c1 = 0.70710678118654752440f;
  float sA = x[1] - x[3] - x[5] + x[7];
  float sB = x[1] + x[3] - x[5] - x[7];
  float ev = (x[0] + x[4]) + (x[2] + x[6]);
  float od = (x[1] + x[5]) + (x[3] + x[7]);
  float d04 = x[0] - x[4], d26 = x[2] - x[6];
  float X0r = ev + od;
  float X1r = d04 + c1 * sA;
  float X1i = -d26 - c1 * sB;
  float X2r = (x[0] + x[4]) - (x[2] + x[6]);
  float X2i = -(x[1] - x[3] + x[5] - x[7]);
  float X3r = d04 - c1 * sA;
  float X3i = d26 - c1 * sB;
  float X4r = ev - od;
  float Zr0 = X0r * ldf(cw, (0 * 64 + lane) * 2, isf32);
  float w1r = ldf(cw, (1 * 64 + lane) * 2, isf32), w1i = ldf(cw, (1 * 64 + lane) * 2 + 1, isf32);
  float Zr1 = X1r * w1r - X1i * w1i, Zi1 = X1r * w1i + X1i * w1r;
  float w2r = ldf(cw, (2 * 64 + lane) * 2, isf32), w2i = ldf(cw, (2 * 64 + lane) * 2 + 1, isf32);
  float Zr2 = X2r * w2r - X2i * w2i, Zi2 = X2r * w2i + X2i * w2r;
  float w3r = ldf(cw, (3 * 64 + lane) * 2, isf32), w3i = ldf(cw, (3 * 64 + lane) * 2 + 1, isf32);
  float Zr3 = X3r * w3r - X3i * w3i, Zi3 = X3r * w3i + X3i * w3r;
  float Zr4 = X4r * ldf(cw, (4 * 64 + lane) * 2, isf32);
  float eP = Zr0 + Zr4, eM = Zr0 - Zr4;
  float t1 = c1 * (Zr1 - Zr3), t2 = c1 * (Zi1 + Zi3);
  float y[8];
  y[0] = eP + 2.f * (Zr1 + Zr2 + Zr3);
  y[1] = eM + 2.f * (t1 - t2 - Zi2);
  y[2] = eP + 2.f * (-Zi1 - Zr2 + Zi3);
  y[3] = eM + 2.f * (-t1 - t2 + Zi2);
  y[4] = eP + 2.f * (-Zr1 + Zr2 - Zr3);
  y[5] = eM + 2.f * (-t1 + t2 - Zi2);
  y[6] = eP + 2.f * (Zi1 - Zr2 - Zi3);
  y[7] = eM + 2.f * (t1 + t2 + Zi2);
  #pragma unroll
  for (int k = 0; k < 8; k++) sf[wv][k][lane] = y[k] * 0.125f;
  urow[wv][lane] = ldf(ue, (size_t)u * 64 + lane, isf32);
  __syncthreads();

  float acc[8] = {0, 0, 0, 0, 0, 0, 0, 0};
  float wu = 0.f;
  for (int eg = 0; eg < 16; eg++) {
    float4 uq4 = ((const float4*)urow[wv])[eg];
    float uq[4] = {uq4.x, uq4.y, uq4.z, uq4.w};
    float sq[8][4];
    #pragma unroll
    for (int k = 0; k < 8; k++) {
      float4 q = ((const float4*)sf[wv][k])[eg];
      sq[k][0] = q.x; sq[k][1] = q.y; sq[k][2] = q.z; sq[k][3] = q.w;
    }
    #pragma unroll
    for (int j = 0; j < 4; j++) {
      float wval = ldf(WU, (eg * 4 + j) * 64 + lane, isf32);
      wu += uq[j] * wval;
      #pragma unroll
      for (int k = 0; k < 8; k++) acc[k] += sq[k][j] * wval;
    }
  }
  float aU1 = ldf(aU, lane, isf32), aU2 = ldf(aU, 64 + lane, isf32);
  float ek[8];
  #pragma unroll
  for (int k = 0; k < 8; k++) ek[k] = acc[k] * aU1;
  float q = wu * aU2;
  #pragma unroll
  for (int off = 32; off; off >>= 1) {
    #pragma unroll
    for (int k = 0; k < 8; k++) ek[k] += __shfl_xor(ek[k], off, 64);
    q += __shfl_xor(q, off, 64);
  }
  float m = -1e30f;
  #pragma unroll
  for (int k = 0; k < 8; k++) {
    float v = ek[k] + q;
    v = v > 0.f ? v : 0.1f * v;
    ek[k] = v;
    m = fmaxf(m, v);
  }
  float se = 0.f, wexp[8];
  #pragma unroll
  for (int k = 0; k < 8; k++) { wexp[k] = __expf(ek[k] - m); se += wexp[k]; }
  float o = 0.f;
  #pragma unroll
  for (int k = 0; k < 8; k++) o += wexp[k] * acc[k];
  out[(size_t)u * 64 + lane] = o / se;
}

// ---------------- 5. contrastive loss (per 256-row chunk) ----------------
__global__ __launch_bounds__(256) void contrast_kernel(
    const float* __restrict__ hu, const float* __restrict__ an,
    float* __restrict__ loss_acc) {
  __shared__ uint4 L1[CB_ * 8];
  __shared__ uint4 L2[CB_ * 8];
  __shared__ float N1[CB_], N2[CB_];
  int tid = threadIdx.x, c = blockIdx.x;
  const float* r1 = hu + ((size_t)c * CB_ + tid) * 64;
  const float* r2 = an + ((size_t)c * CB_ + tid) * 64;
  float s1 = 0.f, s2 = 0.f;
  #pragma unroll
  for (int t = 0; t < 16; t++) {
    float4 a = ((const float4*)r1)[t];
    s1 += a.x * a.x + a.y * a.y + a.z * a.z + a.w * a.w;
    float4 b = ((const float4*)r2)[t];
    s2 += b.x * b.x + b.y * b.y + b.z * b.z + b.w * b.w;
  }
  float n1 = sqrtf(s1), n2 = sqrtf(s2);
  float inv1 = frcp(n1), inv2 = frcp(n2);
  N1[tid] = n1; N2[tid] = n2;
  h2v h1[32], g2[32];
  #pragma unroll
  for (int t = 0; t < 16; t++) {
    float4 a = ((const float4*)r1)[t];
    h2v p; p[0] = (_Float16)(a.x * inv1); p[1] = (_Float16)(a.y * inv1); h1[2 * t] = p;
    h2v q; q[0] = (_Float16)(a.z * inv1); q[1] = (_Float16)(a.w * inv1); h1[2 * t + 1] = q;
    float4 b = ((const float4*)r2)[t];
    h2v r; r[0] = (_Float16)(b.x * inv2); r[1] = (_Float16)(b.y * inv2); g2[2 * t] = r;
    h2v s; s[0] = (_Float16)(b.z * inv2); s[1] = (_Float16)(b.w * inv2); g2[2 * t + 1] = s;
  }
  #pragma unroll
  for (int t = 0; t < 8; t++) {
    uint4 p = {h2u(h1[4 * t]), h2u(h1[4 * t + 1]), h2u(h1[4 * t + 2]), h2u(h1[4 * t + 3])};
    L1[tid * 8 + t] = p;
    uint4 q = {h2u(g2[4 * t]), h2u(g2[4 * t + 1]), h2u(g2[4 * t + 2]), h2u(g2[4 * t + 3])};
    L2[tid * 8 + t] = q;
  }
  __syncthreads();

  float sum_t = 0.f, sum_b = 0.f, labT = 0.f, labB = 0.f;
  for (int j = 0; j < CB_; j++) {
    float d11 = 0.f, d12 = 0.f, d21 = 0.f, d22 = 0.f;
    #pragma unroll
    for (int t = 0; t < 8; t++) {
      uint4 a1 = L1[j * 8 + t];
      uint4 a2 = L2[j * 8 + t];
      h2v b;
      b = u2h(a1.x); d11 = fdot2f(h1[4 * t + 0], b, d11); d21 = fdot2f(g2[4 * t + 0], b, d21);
      b = u2h(a1.y); d11 = fdot2f(h1[4 * t + 1], b, d11); d21 = fdot2f(g2[4 * t + 1], b, d21);
      b = u2h(a1.z); d11 = fdot2f(h1[4 * t + 2], b, d11); d21 = fdot2f(g2[4 * t + 2], b, d21);
      b = u2h(a1.w); d11 = fdot2f(h1[4 * t + 3], b, d11); d21 = fdot2f(g2[4 * t + 3], b, d21);
      b = u2h(a2.x); d12 = fdot2f(h1[4 * t + 0], b, d12); d22 = fdot2f(g2[4 * t + 0], b, d22);
      b = u2h(a2.y); d12 = fdot2f(h1[4 * t + 1], b, d12); d22 = fdot2f(g2[4 * t + 1], b, d22);
      b = u2h(a2.z); d12 = fdot2f(h1[4 * t + 2], b, d12); d22 = fdot2f(g2[4 * t + 2], b, d22);
      b = u2h(a2.w); d12 = fdot2f(h1[4 * t + 3], b, d12); d22 = fdot2f(g2[4 * t + 3], b, d22);
    }
    float m1 = N1[j], m2 = N2[j];
    float p11 = n1 * m1, p12 = n1 * m2, p21 = n2 * m1, p22 = n2 * m2;
    d11 *= 5.0f * p11 * frcp(p11 + 1e-6f);
    d12 *= 5.0f * p12 * frcp(p12 + 1e-6f);
    d21 *= 5.0f * p21 * frcp(p21 + 1e-6f);
    d22 *= 5.0f * p22 * frcp(p22 + 1e-6f);
    float e12 = __expf(d12), e21 = __expf(d21);
    if (j == tid) {
      labT = d12; labB = d21;
      sum_t += e12; sum_b += e21;
    } else {
      sum_t += __expf(d11) + e12;
      sum_b += __expf(d22) + e21;
    }
  }
  float loss = (__logf(sum_t) - labT) + (__logf(sum_b) - labB);
  #pragma unroll
  for (int off = 32; off; off >>= 1) loss += __shfl_xor(loss, off, 64);
  if ((tid & 63) == 0) atomicAdd(loss_acc, loss);
}

// ---------------- 6. scores ----------------
__global__ __launch_bounds__(256) void score_kernel(
    const float* __restrict__ hu, const float* __restrict__ hi,
    const int* __restrict__ pu, const int* __restrict__ pi,
    const int* __restrict__ nu, const int* __restrict__ ni,
    void* __restrict__ out, const float* __restrict__ flag) {
  int isf32 = *flag > 0.5f;
  int w = (blockIdx.x * 256 + threadIdx.x) >> 6;
  int lane = threadIdx.x & 63;
  int uu, ii;
  if (w < EP_) { uu = pu[w]; ii = pi[w]; }
  else         { uu = nu[w - EP_]; ii = ni[w - EP_]; }
  float p = hu[(size_t)uu * 64 + lane] * hi[(size_t)ii * 64 + lane];
  #pragma unroll
  for (int off = 32; off; off >>= 1) p += __shfl_xor(p, off, 64);
  if (lane == 0) {
    if (isf32) ((float*)out)[w] = p;
    else       ((__hip_bfloat16*)out)[w] = __float2bfloat16(p);
  }
}

__global__ void finalize_kernel(const float* __restrict__ loss_acc,
                                void* __restrict__ out,
                                const float* __restrict__ flag) {
  float v = loss_acc[0] * (1.0f / (float)(2 * CB_ * NCHUNK_));
  if (*flag > 0.5f) ((float*)out)[2 * EP_] = v;
  else              ((__hip_bfloat16*)out)[2 * EP_] = __float2bfloat16(v);
}

// ---------------- launch ----------------
extern "C" void kernel_launch(void* const* d_in, const int* in_sizes, int n_in,
                              void* d_out, int out_size, void* d_ws, size_t ws_size,
                              hipStream_t stream) {
  const void* ue  = d_in[0];
  const void* ie  = d_in[1];
  const void* W   = d_in[2];
  const void* a   = d_in[3];
  const void* WU  = d_in[4];
  const void* aU  = d_in[5];
  const void* cw  = d_in[6];
  const int* rs  = (const int*)d_in[7];
  const int* rd  = (const int*)d_in[8];
  const int* pu  = (const int*)d_in[9];
  const int* pi  = (const int*)d_in[10];
  const int* nu  = (const int*)d_in[11];
  const int* ni  = (const int*)d_in[12];
  const int* nbr = (const int*)d_in[13];

  float* wsf  = (float*)d_ws;
  int*   wsi  = (int*)d_ws;
  float* loss = wsf + OFF_LOSS;
  float* flag = wsf + OFF_FLAG;
  int* gallocU = wsi + 4;
  int* dcntU   = wsi + 5;
  int* gallocI = wsi + 6;
  int* dcntI   = wsi + 7;
  float* Wa   = wsf + OFF_WA;
  int*   cnt  = wsi + OFF_CNT;
  int*   rtmp = wsi + OFF_RTMP;
  int*   bsum = wsi + OFF_BSUM;
  int*   boff = wsi + OFF_BOFF;
  int*   rowU = wsi + OFF_ROWU;
  int*   rowI = wsi + OFF_ROWI;
  int*   dirU = wsi + OFF_DIRU;
  int*   dirI = wsi + OFF_DIRI;
  int*   csrU = wsi + OFF_CSRU;
  int*   csrI = wsi + OFF_CSRI;
  float* u1   = wsf + OFF_U1;
  float* i1   = wsf + OFF_I1;
  float* hu   = wsf + OFF_HU;
  float* hi   = wsf + OFF_HI;
  float* anc  = wsf + OFF_ANC;
  // record buffers alias hu/hi+anc (dead once Phase B completes)
  unsigned long long* bufU = (unsigned long long*)(wsf + OFF_HU);
  unsigned long long* bufI = (unsigned long long*)(wsf + OFF_HI);

  hipMemsetAsync(d_ws, 0, MEMSET_BYTES, stream);
  detect_kernel<<<1, 1, 0, stream>>>((const unsigned short*)ue, flag);
  wa_kernel<<<1, 64, 0, stream>>>(W, a, Wa, flag);

  // CSR build: Phase A (bucket scatter, + fine hist on U pass), scans, Phase B
  bucketA_kernel<<<NBA_, 256, 0, stream>>>(rs, rd, bufU, gallocU, dirU, dcntU, 9, cnt, 1);
  bucketA_kernel<<<NBA_, 256, 0, stream>>>(rd, rs, bufI, gallocI, dirI, dcntI, 8, cnt, 0);
  scanA_kernel<<<NB_, 256, 0, stream>>>(cnt, rtmp, bsum);
  scanB_kernel<<<1, 64, 0, stream>>>(bsum, boff);
  scanC_kernel<<<NB_, 256, 0, stream>>>(rtmp, boff, rowU, rowI);
  bucketB_kernel<<<NBK_, 256, 0, stream>>>(bufU, dirU, dcntU, rowU, csrU, 512);
  bucketB_kernel<<<NBK_, 256, 0, stream>>>(bufI, dirI, dcntI, rowI, csrI, 256);

  // layer-1 aggregation (gather)
  agg1_kernel<<<I_ / 4, 256, 0, stream>>>(ue, rowI, csrI, i1, flag);
  agg1_kernel<<<U_ / 4, 256, 0, stream>>>(ie, rowU, csrU, u1, flag);

  // layer-2 aggregation + fused layer attention (overwrites buf aliases - safe)
  agg2attn_kernel<<<I_ / 4, 256, 0, stream>>>(u1, ie, i1, rowI, csrI, Wa, hi, flag);
  agg2attn_kernel<<<U_ / 4, 256, 0, stream>>>(i1, ue, u1, rowU, csrU, Wa, hu, flag);

  // anchor path
  anchor_kernel<<<U_ / 4, 256, 0, stream>>>(ue, WU, aU, cw, nbr, anc, flag);

  // contrastive loss
  contrast_kernel<<<NCHUNK_, 256, 0, stream>>>(hu, anc, loss);

  // scores
  score_kernel<<<(2 * EP_ * 64) / 256, 256, 0, stream>>>(hu, hi, pu, pi, nu, ni, d_out, flag);
  finalize_kernel<<<1, 1, 0, stream>>>(loss, d_out, flag);
}

// Round 5
// 797.509 us; speedup vs baseline: 1.0318x; 1.0318x over previous
//
#include <hip/hip_runtime.h>
#include <hip/hip_bf16.h>

// ---------------- problem constants ----------------
constexpr int U_  = 51200;
constexpr int I_  = 25600;
constexpr int N_  = U_ + I_;             // 76800 combined rows
constexpr int E_  = 1000000;
constexpr int EP_ = 100000;
constexpr int CB_ = 256;                 // contrastive chunk size
constexpr int NCHUNK_ = U_ / CB_;        // 200
constexpr size_t UD_ = (size_t)U_ * 64;
constexpr size_t ID_ = (size_t)I_ * 64;
constexpr int NB_ = N_ / 1024;           // 75 scan blocks
constexpr int NBK_ = 100;                // coarse buckets per side
constexpr int TILE_ = 4096;              // edges per Phase-A block
constexpr int NBA_ = (E_ + TILE_ - 1) / TILE_;  // 245
constexpr int DIRCAP_ = NBA_ * NBK_;     // 24500 entries max

// ---------------- workspace layout (4-byte element offsets) ----------------
constexpr size_t OFF_LOSS  = 0;
constexpr size_t OFF_FLAG  = 1;
// counters: 4=gallocU 5=dcntU 6=gallocI 7=dcntI
constexpr size_t OFF_WA    = 64;
constexpr size_t OFF_CNT   = 128;                    // N_ ints (fine histogram)
constexpr size_t MEMSET_BYTES = (OFF_CNT + N_) * 4;  // zero loss/counters/cnt
constexpr size_t OFF_RTMP  = OFF_CNT + N_;           // N_ ints
constexpr size_t OFF_BSUM  = OFF_RTMP + N_;          // 128
constexpr size_t OFF_BOFF  = OFF_BSUM + 128;         // 128
constexpr size_t OFF_ROWU  = OFF_BOFF + 128;         // U_+1
constexpr size_t OFF_ROWI  = OFF_ROWU + U_ + 1;      // I_+1
constexpr size_t OFF_DIRU  = ((OFF_ROWI + I_ + 1 + 63) / 64) * 64;  // 4*DIRCAP_
constexpr size_t OFF_DIRI  = ((OFF_DIRU + 4 * DIRCAP_ + 63) / 64) * 64;
constexpr size_t OFF_CSRU  = ((OFF_DIRI + 4 * DIRCAP_ + 63) / 64) * 64;  // E_
constexpr size_t OFF_CSRI  = OFF_CSRU + E_;          // E_
constexpr size_t OFF_U1    = ((OFF_CSRI + E_ + 63) / 64) * 64;
constexpr size_t OFF_I1    = OFF_U1 + UD_;
constexpr size_t OFF_HU    = OFF_I1 + ID_;           // bufU aliases here
constexpr size_t OFF_HI    = OFF_HU + UD_;           // bufI aliases here
constexpr size_t OFF_ANC   = OFF_HI + ID_;
// total ≈ 62.1 MB

#define DEVI static __device__ __forceinline__

typedef _Float16 h2v __attribute__((ext_vector_type(2)));

DEVI float b2f(__hip_bfloat16 x) { return __bfloat162float(x); }

DEVI float ldf(const void* p, size_t i, int isf32) {
  if (isf32) return ((const float*)p)[i];
  return b2f(((const __hip_bfloat16*)p)[i]);
}

DEVI float fdot2f(h2v a, h2v b, float c) {
#if __has_builtin(__builtin_amdgcn_fdot2)
  return __builtin_amdgcn_fdot2(a, b, c, false);
#else
  return (float)a[0] * (float)b[0] + (float)a[1] * (float)b[1] + c;
#endif
}
DEVI unsigned h2u(h2v h) { unsigned u; __builtin_memcpy(&u, &h, 4); return u; }
DEVI h2v u2h(unsigned u) { h2v h; __builtin_memcpy(&h, &u, 4); return h; }
DEVI float frcp(float x) { return __builtin_amdgcn_rcpf(x); }

DEVI int waveInclScan(int v, int lane) {
  #pragma unroll
  for (int off = 1; off < 64; off <<= 1) {
    int t = __shfl_up(v, off, 64);
    if (lane >= off) v += t;
  }
  return v;
}

// ---------------- 0. dtype detection ----------------
__global__ void detect_kernel(const unsigned short* __restrict__ p,
                              float* __restrict__ flag) {
  int cnt = 0;
  for (int i = 0; i < 256; i++) {
    int e = (p[i] >> 7) & 0xFF;
    if (e >= 130) cnt++;
  }
  *flag = (cnt >= 8) ? 1.0f : 0.0f;
}

// ---------------- 1a. Phase A: bucket edges into chunked record buffer ----------
__global__ __launch_bounds__(256) void bucketA_kernel(
    const int* __restrict__ key, const int* __restrict__ payload,
    unsigned long long* __restrict__ buf, int* __restrict__ galloc,
    int* __restrict__ dir, int* __restrict__ dcnt,
    int shift, int* __restrict__ fineCnt, int doFine) {
  __shared__ int hist[NBK_], loff[NBK_ + 1], cbase[NBK_], lcur[NBK_];
  __shared__ unsigned long long recs[TILE_];
  int tid = threadIdx.x;
  int base = blockIdx.x * TILE_;
  for (int i = tid; i < NBK_; i += 256) hist[i] = 0;
  __syncthreads();
  int kk[16], pp[16];
  #pragma unroll
  for (int t = 0; t < 16; t++) {
    int e = base + t * 256 + tid;
    bool v = e < E_;
    kk[t] = v ? key[e] : -1;
    pp[t] = v ? payload[e] : 0;
    if (v) {
      atomicAdd(&hist[kk[t] >> shift], 1);
      if (doFine) {
        atomicAdd(&fineCnt[kk[t]], 1);
        atomicAdd(&fineCnt[U_ + pp[t]], 1);
      }
    }
  }
  __syncthreads();
  if (tid < NBK_) {
    int c = hist[tid];
    int gb = 0;
    if (c > 0) {
      gb = atomicAdd(galloc, c);
      int di = atomicAdd(dcnt, 1);
      dir[di * 4]     = tid;
      dir[di * 4 + 1] = gb;
      dir[di * 4 + 2] = c;
    }
    cbase[tid] = gb;
  }
  __syncthreads();
  if (tid == 0) {
    int run = 0;
    for (int b = 0; b < NBK_; b++) { loff[b] = run; run += hist[b]; }
    loff[NBK_] = run;
  }
  __syncthreads();
  if (tid < NBK_) lcur[tid] = loff[tid];
  __syncthreads();
  #pragma unroll
  for (int t = 0; t < 16; t++) {
    if (kk[t] >= 0) {
      int b = kk[t] >> shift;
      int p = atomicAdd(&lcur[b], 1);
      recs[p] = ((unsigned long long)(unsigned)kk[t] << 32) | (unsigned)pp[t];
    }
  }
  __syncthreads();
  int total = loff[NBK_];
  for (int p = tid; p < total; p += 256) {
    int lo = 0, hi = NBK_;
    while (hi - lo > 1) { int mid = (lo + hi) >> 1; if (loff[mid] <= p) lo = mid; else hi = mid; }
    buf[cbase[lo] + (p - loff[lo])] = recs[p];
  }
}

// ---------------- 1b. Phase B: per-bucket CSR fill via LDS staging -------------
__global__ __launch_bounds__(256) void bucketB_kernel(
    const unsigned long long* __restrict__ buf,
    const int* __restrict__ dir, const int* __restrict__ dcnt,
    const int* __restrict__ rowptr, int* __restrict__ csr,
    int keysPerBucket) {
  __shared__ int stage[16384];
  __shared__ int kcur[512];
  __shared__ int est[512], eln[512], epre[513];
  __shared__ int lcnt;
  int tid = threadIdx.x, b = blockIdx.x;
  if (tid == 0) lcnt = 0;
  int keyBase = b * keysPerBucket;
  int regionBase = rowptr[keyBase];
  int size = rowptr[keyBase + keysPerBucket] - regionBase;
  for (int k = tid; k < keysPerBucket; k += 256)
    kcur[k] = rowptr[keyBase + k] - regionBase;
  __syncthreads();
  int nd = *dcnt;
  for (int i = tid; i < nd; i += 256) {
    if (dir[i * 4] == b) {
      int li = atomicAdd(&lcnt, 1);
      est[li] = dir[i * 4 + 1];
      eln[li] = dir[i * 4 + 2];
    }
  }
  __syncthreads();
  if (tid == 0) {
    int run = 0;
    for (int i = 0; i < lcnt; i++) { epre[i] = run; run += eln[i]; }
    epre[lcnt] = run;
  }
  __syncthreads();
  int ne = lcnt;
  int total = epre[ne];
  for (int r = tid; r < total; r += 256) {
    int lo = 0, hi = ne;
    while (hi - lo > 1) { int mid = (lo + hi) >> 1; if (epre[mid] <= r) lo = mid; else hi = mid; }
    unsigned long long rec = buf[(size_t)est[lo] + (r - epre[lo])];
    int keyv = (int)(rec >> 32);
    int pay  = (int)(unsigned)(rec & 0xffffffffULL);
    int slot = atomicAdd(&kcur[keyv - keyBase], 1);
    if (slot < 16384) stage[slot] = pay;
  }
  __syncthreads();
  for (int s = tid; s < size; s += 256) csr[regionBase + s] = stage[s];
}

// ---------------- 1c. row-pointer scan ----------------
__global__ __launch_bounds__(256) void scanA_kernel(
    const int* __restrict__ cnt, int* __restrict__ rtmp, int* __restrict__ bsum) {
  __shared__ int wsum[4];
  int tid = threadIdx.x, lane = tid & 63, wv = tid >> 6;
  int gid = blockIdx.x * 256 + tid;
  int4 v = ((const int4*)cnt)[gid];
  int s = v.x + v.y + v.z + v.w;
  int inc = waveInclScan(s, lane);
  if (lane == 63) wsum[wv] = inc;
  __syncthreads();
  int wvoff = 0;
  for (int w = 0; w < wv; w++) wvoff += wsum[w];
  int excl = wvoff + inc - s;
  int base = gid * 4;
  rtmp[base]     = excl;
  rtmp[base + 1] = excl + v.x;
  rtmp[base + 2] = excl + v.x + v.y;
  rtmp[base + 3] = excl + v.x + v.y + v.z;
  if (tid == 255) bsum[blockIdx.x] = wvoff + wsum[3];
}

__global__ void scanB_kernel(const int* __restrict__ bsum, int* __restrict__ boff) {
  if (threadIdx.x == 0) {
    int run = 0;
    for (int i = 0; i < NB_; i++) { boff[i] = run; run += bsum[i]; }
  }
}

__global__ __launch_bounds__(256) void scanC_kernel(
    const int* __restrict__ rtmp, const int* __restrict__ boff,
    int* __restrict__ rowU, int* __restrict__ rowI) {
  int gid = blockIdx.x * 256 + threadIdx.x;
  int off = boff[blockIdx.x];
  int4 v = ((const int4*)rtmp)[gid];
  int vals[4] = {v.x, v.y, v.z, v.w};
  int base = gid * 4;
  #pragma unroll
  for (int k = 0; k < 4; k++) {
    int i = base + k;
    int val = vals[k] + off;
    if (i < U_) rowU[i] = val;
    else        rowI[i - U_] = val - E_;
  }
  if (gid == 0) { rowU[U_] = E_; rowI[I_] = E_; }
}

// ---------------- 2. layer-1 aggregation ----------------
__global__ __launch_bounds__(256) void agg1_kernel(
    const void* __restrict__ src, const int* __restrict__ row,
    const int* __restrict__ csr, float* __restrict__ out,
    const float* __restrict__ flag) {
  int isf32 = *flag > 0.5f;
  int wv = threadIdx.x >> 6, lane = threadIdx.x & 63;
  int r = blockIdx.x * 4 + wv;
  int s0 = row[r], s1 = row[r + 1];
  float acc = 0.f;
  int j = s0;
  for (; j + 4 <= s1; j += 4) {
    int a = csr[j], b = csr[j + 1], c = csr[j + 2], d = csr[j + 3];
    float va = ldf(src, (size_t)a * 64 + lane, isf32);
    float vb = ldf(src, (size_t)b * 64 + lane, isf32);
    float vc = ldf(src, (size_t)c * 64 + lane, isf32);
    float vd = ldf(src, (size_t)d * 64 + lane, isf32);
    acc += (va + vb) + (vc + vd);
  }
  for (; j < s1; j++) acc += ldf(src, (size_t)csr[j] * 64 + lane, isf32);
  out[(size_t)r * 64 + lane] = acc / fmaxf((float)(s1 - s0), 1.0f);
}

// ---------------- 3. layer-2 aggregation + fused layer attention ----------------
__global__ __launch_bounds__(256) void agg2attn_kernel(
    const float* __restrict__ opp1, const void* __restrict__ base,
    const float* __restrict__ own1,
    const int* __restrict__ row, const int* __restrict__ csr,
    const float* __restrict__ Wa, float* __restrict__ h,
    const float* __restrict__ flag) {
  int isf32 = *flag > 0.5f;
  int wv = threadIdx.x >> 6, lane = threadIdx.x & 63;
  int r = blockIdx.x * 4 + wv;
  int s0 = row[r], s1 = row[r + 1];
  float acc = 0.f;
  int j = s0;
  for (; j + 4 <= s1; j += 4) {
    int a = csr[j], b = csr[j + 1], c = csr[j + 2], d = csr[j + 3];
    float va = opp1[(size_t)a * 64 + lane];
    float vb = opp1[(size_t)b * 64 + lane];
    float vc = opp1[(size_t)c * 64 + lane];
    float vd = opp1[(size_t)d * 64 + lane];
    acc += (va + vb) + (vc + vd);
  }
  for (; j < s1; j++) acc += opp1[(size_t)csr[j] * 64 + lane];
  size_t idx = (size_t)r * 64 + lane;
  float t2 = acc / fmaxf((float)(s1 - s0), 1.0f);
  float t0 = ldf(base, idx, isf32);
  float t1 = own1[idx];
  float w = Wa[lane];
  float p0 = t0 * w, p1 = t1 * w, p2 = t2 * w;
  #pragma unroll
  for (int off = 32; off; off >>= 1) {
    p0 += __shfl_xor(p0, off, 64);
    p1 += __shfl_xor(p1, off, 64);
    p2 += __shfl_xor(p2, off, 64);
  }
  float m = fmaxf(p0, fmaxf(p1, p2));
  float e0 = __expf(p0 - m), e1 = __expf(p1 - m), e2 = __expf(p2 - m);
  float inv = 1.0f / (e0 + e1 + e2);
  h[idx] = (t0 * e0 + t1 * e1 + t2 * e2) * inv;
}

// ---------------- Wa = W @ a ----------------
__global__ void wa_kernel(const void* __restrict__ W, const void* __restrict__ a,
                          float* __restrict__ Wa, const float* __restrict__ flag) {
  int isf32 = *flag > 0.5f;
  int d = threadIdx.x;
  float s = 0.f;
  for (int e = 0; e < 64; e++) s += ldf(W, d * 64 + e, isf32) * ldf(a, e, isf32);
  Wa[d] = s;
}

// ---------------- 4. anchor user embed ----------------
__global__ __launch_bounds__(256) void anchor_kernel(
    const void* __restrict__ ue, const void* __restrict__ WU,
    const void* __restrict__ aU, const void* __restrict__ cw,
    const int* __restrict__ nbr, float* __restrict__ out,
    const float* __restrict__ flag) {
  int isf32 = *flag > 0.5f;
  __shared__ __align__(16) float sf[4][8][64];
  __shared__ __align__(16) float urow[4][64];
  int wv = threadIdx.x >> 6, lane = threadIdx.x & 63;
  int u = blockIdx.x * 4 + wv;

  float x[8];
  #pragma unroll
  for (int k = 0; k < 8; k++) {
    int nb = nbr[u * 8 + k];
    x[k] = ldf(ue, (size_t)nb * 64 + lane, isf32);
  }
  const float c1 = 0.70710678118654752440f;
  float sA = x[1] - x[3] - x[5] + x[7];
  float sB = x[1] + x[3] - x[5] - x[7];
  float ev = (x[0] + x[4]) + (x[2] + x[6]);
  float od = (x[1] + x[5]) + (x[3] + x[7]);
  float d04 = x[0] - x[4], d26 = x[2] - x[6];
  float X0r = ev + od;
  float X1r = d04 + c1 * sA;
  float X1i = -d26 - c1 * sB;
  float X2r = (x[0] + x[4]) - (x[2] + x[6]);
  float X2i = -(x[1] - x[3] + x[5] - x[7]);
  float X3r = d04 - c1 * sA;
  float X3i = d26 - c1 * sB;
  float X4r = ev - od;
  float Zr0 = X0r * ldf(cw, (0 * 64 + lane) * 2, isf32);
  float w1r = ldf(cw, (1 * 64 + lane) * 2, isf32), w1i = ldf(cw, (1 * 64 + lane) * 2 + 1, isf32);
  float Zr1 = X1r * w1r - X1i * w1i, Zi1 = X1r * w1i + X1i * w1r;
  float w2r = ldf(cw, (2 * 64 + lane) * 2, isf32), w2i = ldf(cw, (2 * 64 + lane) * 2 + 1, isf32);
  float Zr2 = X2r * w2r - X2i * w2i, Zi2 = X2r * w2i + X2i * w2r;
  float w3r = ldf(cw, (3 * 64 + lane) * 2, isf32), w3i = ldf(cw, (3 * 64 + lane) * 2 + 1, isf32);
  float Zr3 = X3r * w3r - X3i * w3i, Zi3 = X3r * w3i + X3i * w3r;
  float Zr4 = X4r * ldf(cw, (4 * 64 + lane) * 2, isf32);
  float eP = Zr0 + Zr4, eM = Zr0 - Zr4;
  float t1 = c1 * (Zr1 - Zr3), t2 = c1 * (Zi1 + Zi3);
  float y[8];
  y[0] = eP + 2.f * (Zr1 + Zr2 + Zr3);
  y[1] = eM + 2.f * (t1 - t2 - Zi2);
  y[2] = eP + 2.f * (-Zi1 - Zr2 + Zi3);
  y[3] = eM + 2.f * (-t1 - t2 + Zi2);
  y[4] = eP + 2.f * (-Zr1 + Zr2 - Zr3);
  y[5] = eM + 2.f * (-t1 + t2 - Zi2);
  y[6] = eP + 2.f * (Zi1 - Zr2 - Zi3);
  y[7] = eM + 2.f * (t1 + t2 + Zi2);
  #pragma unroll
  for (int k = 0; k < 8; k++) sf[wv][k][lane] = y[k] * 0.125f;
  urow[wv][lane] = ldf(ue, (size_t)u * 64 + lane, isf32);
  __syncthreads();

  float acc[8] = {0, 0, 0, 0, 0, 0, 0, 0};
  float wu = 0.f;
  for (int eg = 0; eg < 16; eg++) {
    float4 uq4 = ((const float4*)urow[wv])[eg];
    float uq[4] = {uq4.x, uq4.y, uq4.z, uq4.w};
    float sq[8][4];
    #pragma unroll
    for (int k = 0; k < 8; k++) {
      float4 q = ((const float4*)sf[wv][k])[eg];
      sq[k][0] = q.x; sq[k][1] = q.y; sq[k][2] = q.z; sq[k][3] = q.w;
    }
    #pragma unroll
    for (int j = 0; j < 4; j++) {
      float wval = ldf(WU, (eg * 4 + j) * 64 + lane, isf32);
      wu += uq[j] * wval;
      #pragma unroll
      for (int k = 0; k < 8; k++) acc[k] += sq[k][j] * wval;
    }
  }
  float aU1 = ldf(aU, lane, isf32), aU2 = ldf(aU, 64 + lane, isf32);
  float ek[8];
  #pragma unroll
  for (int k = 0; k < 8; k++) ek[k] = acc[k] * aU1;
  float q = wu * aU2;
  #pragma unroll
  for (int off = 32; off; off >>= 1) {
    #pragma unroll
    for (int k = 0; k < 8; k++) ek[k] += __shfl_xor(ek[k], off, 64);
    q += __shfl_xor(q, off, 64);
  }
  float m = -1e30f;
  #pragma unroll
  for (int k = 0; k < 8; k++) {
    float v = ek[k] + q;
    v = v > 0.f ? v : 0.1f * v;
    ek[k] = v;
    m = fmaxf(m, v);
  }
  float se = 0.f, wexp[8];
  #pragma unroll
  for (int k = 0; k < 8; k++) { wexp[k] = __expf(ek[k] - m); se += wexp[k]; }
  float o = 0.f;
  #pragma unroll
  for (int k = 0; k < 8; k++) o += wexp[k] * acc[k];
  out[(size_t)u * 64 + lane] = o / se;
}

// ---------------- 5. contrastive loss: 4 row-slices per chunk ----------------
// Block b: chunk c = b>>2, slice s = b&3. LDS holds the full chunk (transposed
// [t][row] so stores/reloads are conflict-free; j-loop reads are broadcasts).
// Thread (jq,ti): partial Sexp for row i=s*64+ti over j in [jq*64,(jq+1)*64).
__global__ __launch_bounds__(256) void contrast_kernel(
    const float* __restrict__ hu, const float* __restrict__ an,
    float* __restrict__ loss_acc) {
  __shared__ uint4 L1[8 * CB_];  // 32KB, [t][row]
  __shared__ uint4 L2[8 * CB_];  // 32KB
  __shared__ float N1[CB_], N2[CB_];
  __shared__ float psT[4][64], psB[4][64], labT[64], labB[64];
  int tid = threadIdx.x;
  int c = blockIdx.x >> 2, s = blockIdx.x & 3;

  // --- load + normalize row `tid` of both sides ---
  const float* r1 = hu + ((size_t)c * CB_ + tid) * 64;
  const float* r2 = an + ((size_t)c * CB_ + tid) * 64;
  float s1 = 0.f, s2 = 0.f;
  float4 a4[16], b4[16];
  #pragma unroll
  for (int t = 0; t < 16; t++) {
    a4[t] = ((const float4*)r1)[t];
    s1 += a4[t].x * a4[t].x + a4[t].y * a4[t].y + a4[t].z * a4[t].z + a4[t].w * a4[t].w;
    b4[t] = ((const float4*)r2)[t];
    s2 += b4[t].x * b4[t].x + b4[t].y * b4[t].y + b4[t].z * b4[t].z + b4[t].w * b4[t].w;
  }
  float n1 = sqrtf(s1), n2 = sqrtf(s2);
  float inv1 = frcp(n1), inv2 = frcp(n2);
  N1[tid] = n1; N2[tid] = n2;
  #pragma unroll
  for (int t = 0; t < 8; t++) {
    h2v p0; p0[0] = (_Float16)(a4[2*t].x * inv1); p0[1] = (_Float16)(a4[2*t].y * inv1);
    h2v p1; p1[0] = (_Float16)(a4[2*t].z * inv1); p1[1] = (_Float16)(a4[2*t].w * inv1);
    h2v p2; p2[0] = (_Float16)(a4[2*t+1].x * inv1); p2[1] = (_Float16)(a4[2*t+1].y * inv1);
    h2v p3; p3[0] = (_Float16)(a4[2*t+1].z * inv1); p3[1] = (_Float16)(a4[2*t+1].w * inv1);
    uint4 pk = {h2u(p0), h2u(p1), h2u(p2), h2u(p3)};
    L1[t * CB_ + tid] = pk;
    h2v q0; q0[0] = (_Float16)(b4[2*t].x * inv2); q0[1] = (_Float16)(b4[2*t].y * inv2);
    h2v q1; q1[0] = (_Float16)(b4[2*t].z * inv2); q1[1] = (_Float16)(b4[2*t].w * inv2);
    h2v q2; q2[0] = (_Float16)(b4[2*t+1].x * inv2); q2[1] = (_Float16)(b4[2*t+1].y * inv2);
    h2v q3; q3[0] = (_Float16)(b4[2*t+1].z * inv2); q3[1] = (_Float16)(b4[2*t+1].w * inv2);
    uint4 qk = {h2u(q0), h2u(q1), h2u(q2), h2u(q3)};
    L2[t * CB_ + tid] = qk;
  }
  __syncthreads();

  // --- compute: row i = s*64+ti, j over [jq*64, jq*64+64) ---
  int ti = tid & 63, jq = tid >> 6;
  int i = s * 64 + ti;
  uint4 a1r[8], a2r[8];
  #pragma unroll
  for (int t = 0; t < 8; t++) { a1r[t] = L1[t * CB_ + i]; a2r[t] = L2[t * CB_ + i]; }
  float n1i = N1[i], n2i = N2[i];
  float sum_t = 0.f, sum_b = 0.f, lT = 0.f, lB = 0.f;
  int j0 = jq * 64;
  for (int jj = 0; jj < 64; jj++) {
    int j = j0 + jj;
    float d11 = 0.f, d12 = 0.f, d21 = 0.f, d22 = 0.f;
    #pragma unroll
    for (int t = 0; t < 8; t++) {
      uint4 c1v = L1[t * CB_ + j];
      uint4 c2v = L2[t * CB_ + j];
      h2v b;
      b = u2h(c1v.x); d11 = fdot2f(u2h(a1r[t].x), b, d11); d21 = fdot2f(u2h(a2r[t].x), b, d21);
      b = u2h(c1v.y); d11 = fdot2f(u2h(a1r[t].y), b, d11); d21 = fdot2f(u2h(a2r[t].y), b, d21);
      b = u2h(c1v.z); d11 = fdot2f(u2h(a1r[t].z), b, d11); d21 = fdot2f(u2h(a2r[t].z), b, d21);
      b = u2h(c1v.w); d11 = fdot2f(u2h(a1r[t].w), b, d11); d21 = fdot2f(u2h(a2r[t].w), b, d21);
      b = u2h(c2v.x); d12 = fdot2f(u2h(a1r[t].x), b, d12); d22 = fdot2f(u2h(a2r[t].x), b, d22);
      b = u2h(c2v.y); d12 = fdot2f(u2h(a1r[t].y), b, d12); d22 = fdot2f(u2h(a2r[t].y), b, d22);
      b = u2h(c2v.z); d12 = fdot2f(u2h(a1r[t].z), b, d12); d22 = fdot2f(u2h(a2r[t].z), b, d22);
      b = u2h(c2v.w); d12 = fdot2f(u2h(a1r[t].w), b, d12); d22 = fdot2f(u2h(a2r[t].w), b, d22);
    }
    // reference semantics: s = dot/(n_i*n_j + 1e-6)/TEMP, dot = cos*n_i*n_j
    float m1 = N1[j], m2 = N2[j];
    float p11 = n1i * m1, p12 = n1i * m2, p21 = n2i * m1, p22 = n2i * m2;
    d11 *= 5.0f * p11 * frcp(p11 + 1e-6f);
    d12 *= 5.0f * p12 * frcp(p12 + 1e-6f);
    d21 *= 5.0f * p21 * frcp(p21 + 1e-6f);
    d22 *= 5.0f * p22 * frcp(p22 + 1e-6f);
    float e12 = __expf(d12), e21 = __expf(d21);
    if (j == i) {  // diag of s-terms masked; labels = c12/c21 diag
      lT = d12; lB = d21;
      sum_t += e12; sum_b += e21;
    } else {
      sum_t += __expf(d11) + e12;
      sum_b += __expf(d22) + e21;
    }
  }
  psT[jq][ti] = sum_t;
  psB[jq][ti] = sum_b;
  if (jq == s) { labT[ti] = lT; labB[ti] = lB; }
  __syncthreads();

  if (tid < 64) {
    float st = psT[0][tid] + psT[1][tid] + psT[2][tid] + psT[3][tid];
    float sb = psB[0][tid] + psB[1][tid] + psB[2][tid] + psB[3][tid];
    float loss = (__logf(st) - labT[tid]) + (__logf(sb) - labB[tid]);
    #pragma unroll
    for (int off = 32; off; off >>= 1) loss += __shfl_xor(loss, off, 64);
    if (tid == 0) atomicAdd(loss_acc, loss);
  }
}

// ---------------- 6. scores ----------------
__global__ __launch_bounds__(256) void score_kernel(
    const float* __restrict__ hu, const float* __restrict__ hi,
    const int* __restrict__ pu, const int* __restrict__ pi,
    const int* __restrict__ nu, const int* __restrict__ ni,
    void* __restrict__ out, const float* __restrict__ flag) {
  int isf32 = *flag > 0.5f;
  int w = (blockIdx.x * 256 + threadIdx.x) >> 6;
  int lane = threadIdx.x & 63;
  int uu, ii;
  if (w < EP_) { uu = pu[w]; ii = pi[w]; }
  else         { uu = nu[w - EP_]; ii = ni[w - EP_]; }
  float p = hu[(size_t)uu * 64 + lane] * hi[(size_t)ii * 64 + lane];
  #pragma unroll
  for (int off = 32; off; off >>= 1) p += __shfl_xor(p, off, 64);
  if (lane == 0) {
    if (isf32) ((float*)out)[w] = p;
    else       ((__hip_bfloat16*)out)[w] = __float2bfloat16(p);
  }
}

__global__ void finalize_kernel(const float* __restrict__ loss_acc,
                                void* __restrict__ out,
                                const float* __restrict__ flag) {
  float v = loss_acc[0] * (1.0f / (float)(2 * CB_ * NCHUNK_));
  if (*flag > 0.5f) ((float*)out)[2 * EP_] = v;
  else              ((__hip_bfloat16*)out)[2 * EP_] = __float2bfloat16(v);
}

// ---------------- launch ----------------
extern "C" void kernel_launch(void* const* d_in, const int* in_sizes, int n_in,
                              void* d_out, int out_size, void* d_ws, size_t ws_size,
                              hipStream_t stream) {
  const void* ue  = d_in[0];
  const void* ie  = d_in[1];
  const void* W   = d_in[2];
  const void* a   = d_in[3];
  const void* WU  = d_in[4];
  const void* aU  = d_in[5];
  const void* cw  = d_in[6];
  const int* rs  = (const int*)d_in[7];
  const int* rd  = (const int*)d_in[8];
  const int* pu  = (const int*)d_in[9];
  const int* pi  = (const int*)d_in[10];
  const int* nu  = (const int*)d_in[11];
  const int* ni  = (const int*)d_in[12];
  const int* nbr = (const int*)d_in[13];

  float* wsf  = (float*)d_ws;
  int*   wsi  = (int*)d_ws;
  float* loss = wsf + OFF_LOSS;
  float* flag = wsf + OFF_FLAG;
  int* gallocU = wsi + 4;
  int* dcntU   = wsi + 5;
  int* gallocI = wsi + 6;
  int* dcntI   = wsi + 7;
  float* Wa   = wsf + OFF_WA;
  int*   cnt  = wsi + OFF_CNT;
  int*   rtmp = wsi + OFF_RTMP;
  int*   bsum = wsi + OFF_BSUM;
  int*   boff = wsi + OFF_BOFF;
  int*   rowU = wsi + OFF_ROWU;
  int*   rowI = wsi + OFF_ROWI;
  int*   dirU = wsi + OFF_DIRU;
  int*   dirI = wsi + OFF_DIRI;
  int*   csrU = wsi + OFF_CSRU;
  int*   csrI = wsi + OFF_CSRI;
  float* u1   = wsf + OFF_U1;
  float* i1   = wsf + OFF_I1;
  float* hu   = wsf + OFF_HU;
  float* hi   = wsf + OFF_HI;
  float* anc  = wsf + OFF_ANC;
  unsigned long long* bufU = (unsigned long long*)(wsf + OFF_HU);
  unsigned long long* bufI = (unsigned long long*)(wsf + OFF_HI);

  hipMemsetAsync(d_ws, 0, MEMSET_BYTES, stream);
  detect_kernel<<<1, 1, 0, stream>>>((const unsigned short*)ue, flag);
  wa_kernel<<<1, 64, 0, stream>>>(W, a, Wa, flag);

  // CSR build
  bucketA_kernel<<<NBA_, 256, 0, stream>>>(rs, rd, bufU, gallocU, dirU, dcntU, 9, cnt, 1);
  bucketA_kernel<<<NBA_, 256, 0, stream>>>(rd, rs, bufI, gallocI, dirI, dcntI, 8, cnt, 0);
  scanA_kernel<<<NB_, 256, 0, stream>>>(cnt, rtmp, bsum);
  scanB_kernel<<<1, 64, 0, stream>>>(bsum, boff);
  scanC_kernel<<<NB_, 256, 0, stream>>>(rtmp, boff, rowU, rowI);
  bucketB_kernel<<<NBK_, 256, 0, stream>>>(bufU, dirU, dcntU, rowU, csrU, 512);
  bucketB_kernel<<<NBK_, 256, 0, stream>>>(bufI, dirI, dcntI, rowI, csrI, 256);

  // layer-1 aggregation (gather)
  agg1_kernel<<<I_ / 4, 256, 0, stream>>>(ue, rowI, csrI, i1, flag);
  agg1_kernel<<<U_ / 4, 256, 0, stream>>>(ie, rowU, csrU, u1, flag);

  // layer-2 aggregation + fused layer attention
  agg2attn_kernel<<<I_ / 4, 256, 0, stream>>>(u1, ie, i1, rowI, csrI, Wa, hi, flag);
  agg2attn_kernel<<<U_ / 4, 256, 0, stream>>>(i1, ue, u1, rowU, csrU, Wa, hu, flag);

  // anchor path
  anchor_kernel<<<U_ / 4, 256, 0, stream>>>(ue, WU, aU, cw, nbr, anc, flag);

  // contrastive loss (4 slices per chunk)
  contrast_kernel<<<NCHUNK_ * 4, 256, 0, stream>>>(hu, anc, loss);

  // scores
  score_kernel<<<(2 * EP_ * 64) / 256, 256, 0, stream>>>(hu, hi, pu, pi, nu, ni, d_out, flag);
  finalize_kernel<<<1, 1, 0, stream>>>(loss, d_out, flag);
}

// Round 6
// 766.853 us; speedup vs baseline: 1.0730x; 1.0400x over previous
//
#include <hip/hip_runtime.h>
#include <hip/hip_bf16.h>

// ---------------- problem constants ----------------
constexpr int U_  = 51200;
constexpr int I_  = 25600;
constexpr int N_  = U_ + I_;             // 76800 combined rows
constexpr int E_  = 1000000;
constexpr int EP_ = 100000;
constexpr int CB_ = 256;                 // contrastive chunk size
constexpr int NCHUNK_ = U_ / CB_;        // 200
constexpr size_t UD_ = (size_t)U_ * 64;
constexpr size_t ID_ = (size_t)I_ * 64;
constexpr int NB_ = N_ / 1024;           // 75 scan blocks
constexpr int NBK_ = 100;                // coarse buckets per side
constexpr int TILE_ = 4096;              // edges per Phase-A block
constexpr int NBA_ = (E_ + TILE_ - 1) / TILE_;  // 245
constexpr int DIRCAP_ = NBA_ * NBK_;     // 24500 entries max

// ---------------- workspace layout (4-byte element offsets) ----------------
constexpr size_t OFF_LOSS  = 0;
constexpr size_t OFF_FLAG  = 1;
// counters: 4=gallocU 5=dcntU 6=gallocI 7=dcntI
constexpr size_t OFF_VEC   = 64;                     // 192 floats: Wa | vU1 | vU2
constexpr size_t OFF_CNT   = 256;                    // N_ ints (fine histogram)
constexpr size_t MEMSET_BYTES = (OFF_CNT + N_) * 4;  // zero loss/counters/cnt
constexpr size_t OFF_RTMP  = OFF_CNT + N_;           // N_ ints
constexpr size_t OFF_BSUM  = OFF_RTMP + N_;          // 128
constexpr size_t OFF_BOFF  = OFF_BSUM + 128;         // 128
constexpr size_t OFF_ROWU  = OFF_BOFF + 128;         // U_+1
constexpr size_t OFF_ROWI  = OFF_ROWU + U_ + 1;      // I_+1
constexpr size_t OFF_DIRU  = ((OFF_ROWI + I_ + 1 + 63) / 64) * 64;  // 4*DIRCAP_
constexpr size_t OFF_DIRI  = ((OFF_DIRU + 4 * DIRCAP_ + 63) / 64) * 64;
constexpr size_t OFF_CSRU  = ((OFF_DIRI + 4 * DIRCAP_ + 63) / 64) * 64;  // E_
constexpr size_t OFF_CSRI  = OFF_CSRU + E_;          // E_
constexpr size_t OFF_U1    = ((OFF_CSRI + E_ + 63) / 64) * 64;
constexpr size_t OFF_I1    = OFF_U1 + UD_;
constexpr size_t OFF_HU    = OFF_I1 + ID_;           // bufU aliases here
constexpr size_t OFF_HI    = OFF_HU + UD_;           // bufI aliases here
constexpr size_t OFF_ANC   = OFF_HI + ID_;
// total ≈ 62.1 MB

#define DEVI static __device__ __forceinline__

typedef _Float16 h2v __attribute__((ext_vector_type(2)));

DEVI float b2f(__hip_bfloat16 x) { return __bfloat162float(x); }

DEVI float ldf(const void* p, size_t i, int isf32) {
  if (isf32) return ((const float*)p)[i];
  return b2f(((const __hip_bfloat16*)p)[i]);
}

DEVI float fdot2f(h2v a, h2v b, float c) {
#if __has_builtin(__builtin_amdgcn_fdot2)
  return __builtin_amdgcn_fdot2(a, b, c, false);
#else
  return (float)a[0] * (float)b[0] + (float)a[1] * (float)b[1] + c;
#endif
}
DEVI unsigned h2u(h2v h) { unsigned u; __builtin_memcpy(&u, &h, 4); return u; }
DEVI h2v u2h(unsigned u) { h2v h; __builtin_memcpy(&h, &u, 4); return h; }
DEVI float frcp(float x) { return __builtin_amdgcn_rcpf(x); }

DEVI int waveInclScan(int v, int lane) {
  #pragma unroll
  for (int off = 1; off < 64; off <<= 1) {
    int t = __shfl_up(v, off, 64);
    if (lane >= off) v += t;
  }
  return v;
}

// ---------------- 0. prep: dtype detection + Wa/vU1/vU2 precompute ----------------
// vU1 = WU @ aU[:64], vU2 = WU @ aU[64:] make the anchor GEMM collapsible:
//   e[u,k] = leaky(sf_u[k]·vU1 + ue_u·vU2);  out_u = (sum_k alpha_k sf_u[k]) @ WU
__global__ void prep_kernel(const unsigned short* __restrict__ ueu,
                            const void* __restrict__ W, const void* __restrict__ a,
                            const void* __restrict__ WU, const void* __restrict__ aU,
                            float* __restrict__ vecs, float* __restrict__ flag) {
  int cnt = 0;
  for (int i = 0; i < 256; i++) {
    int e = (ueu[i] >> 7) & 0xFF;
    if (e >= 130) cnt++;
  }
  int isf32 = (cnt >= 8);
  if (threadIdx.x == 0) *flag = isf32 ? 1.0f : 0.0f;
  int d = threadIdx.x;  // 64 threads
  float s = 0.f, t1 = 0.f, t2 = 0.f;
  for (int e = 0; e < 64; e++) {
    s += ldf(W, d * 64 + e, isf32) * ldf(a, e, isf32);
    float wue = ldf(WU, d * 64 + e, isf32);
    t1 += wue * ldf(aU, e, isf32);
    t2 += wue * ldf(aU, 64 + e, isf32);
  }
  vecs[d] = s;          // Wa
  vecs[64 + d] = t1;    // vU1
  vecs[128 + d] = t2;   // vU2
}

// ---------------- 1a. Phase A: bucket edges into chunked record buffer ----------
__global__ __launch_bounds__(256) void bucketA_kernel(
    const int* __restrict__ key, const int* __restrict__ payload,
    unsigned long long* __restrict__ buf, int* __restrict__ galloc,
    int* __restrict__ dir, int* __restrict__ dcnt,
    int shift, int* __restrict__ fineCnt, int doFine) {
  __shared__ int hist[NBK_], loff[NBK_ + 1], cbase[NBK_], lcur[NBK_];
  __shared__ unsigned long long recs[TILE_];
  int tid = threadIdx.x;
  int base = blockIdx.x * TILE_;
  for (int i = tid; i < NBK_; i += 256) hist[i] = 0;
  __syncthreads();
  int kk[16], pp[16];
  #pragma unroll
  for (int t = 0; t < 16; t++) {
    int e = base + t * 256 + tid;
    bool v = e < E_;
    kk[t] = v ? key[e] : -1;
    pp[t] = v ? payload[e] : 0;
    if (v) {
      atomicAdd(&hist[kk[t] >> shift], 1);
      if (doFine) {
        atomicAdd(&fineCnt[kk[t]], 1);
        atomicAdd(&fineCnt[U_ + pp[t]], 1);
      }
    }
  }
  __syncthreads();
  if (tid < NBK_) {
    int c = hist[tid];
    int gb = 0;
    if (c > 0) {
      gb = atomicAdd(galloc, c);
      int di = atomicAdd(dcnt, 1);
      dir[di * 4]     = tid;
      dir[di * 4 + 1] = gb;
      dir[di * 4 + 2] = c;
    }
    cbase[tid] = gb;
  }
  __syncthreads();
  if (tid == 0) {
    int run = 0;
    for (int b = 0; b < NBK_; b++) { loff[b] = run; run += hist[b]; }
    loff[NBK_] = run;
  }
  __syncthreads();
  if (tid < NBK_) lcur[tid] = loff[tid];
  __syncthreads();
  #pragma unroll
  for (int t = 0; t < 16; t++) {
    if (kk[t] >= 0) {
      int b = kk[t] >> shift;
      int p = atomicAdd(&lcur[b], 1);
      recs[p] = ((unsigned long long)(unsigned)kk[t] << 32) | (unsigned)pp[t];
    }
  }
  __syncthreads();
  int total = loff[NBK_];
  for (int p = tid; p < total; p += 256) {
    int lo = 0, hi = NBK_;
    while (hi - lo > 1) { int mid = (lo + hi) >> 1; if (loff[mid] <= p) lo = mid; else hi = mid; }
    buf[cbase[lo] + (p - loff[lo])] = recs[p];
  }
}

// ---------------- 1b. Phase B: per-bucket CSR fill via LDS staging -------------
__global__ __launch_bounds__(256) void bucketB_kernel(
    const unsigned long long* __restrict__ buf,
    const int* __restrict__ dir, const int* __restrict__ dcnt,
    const int* __restrict__ rowptr, int* __restrict__ csr,
    int keysPerBucket) {
  __shared__ int stage[16384];
  __shared__ int kcur[512];
  __shared__ int est[512], eln[512], epre[513];
  __shared__ int lcnt;
  int tid = threadIdx.x, b = blockIdx.x;
  if (tid == 0) lcnt = 0;
  int keyBase = b * keysPerBucket;
  int regionBase = rowptr[keyBase];
  int size = rowptr[keyBase + keysPerBucket] - regionBase;
  for (int k = tid; k < keysPerBucket; k += 256)
    kcur[k] = rowptr[keyBase + k] - regionBase;
  __syncthreads();
  int nd = *dcnt;
  for (int i = tid; i < nd; i += 256) {
    if (dir[i * 4] == b) {
      int li = atomicAdd(&lcnt, 1);
      est[li] = dir[i * 4 + 1];
      eln[li] = dir[i * 4 + 2];
    }
  }
  __syncthreads();
  if (tid == 0) {
    int run = 0;
    for (int i = 0; i < lcnt; i++) { epre[i] = run; run += eln[i]; }
    epre[lcnt] = run;
  }
  __syncthreads();
  int ne = lcnt;
  int total = epre[ne];
  for (int r = tid; r < total; r += 256) {
    int lo = 0, hi = ne;
    while (hi - lo > 1) { int mid = (lo + hi) >> 1; if (epre[mid] <= r) lo = mid; else hi = mid; }
    unsigned long long rec = buf[(size_t)est[lo] + (r - epre[lo])];
    int keyv = (int)(rec >> 32);
    int pay  = (int)(unsigned)(rec & 0xffffffffULL);
    int slot = atomicAdd(&kcur[keyv - keyBase], 1);
    if (slot < 16384) stage[slot] = pay;
  }
  __syncthreads();
  for (int s = tid; s < size; s += 256) csr[regionBase + s] = stage[s];
}

// ---------------- 1c. row-pointer scan ----------------
__global__ __launch_bounds__(256) void scanA_kernel(
    const int* __restrict__ cnt, int* __restrict__ rtmp, int* __restrict__ bsum) {
  __shared__ int wsum[4];
  int tid = threadIdx.x, lane = tid & 63, wv = tid >> 6;
  int gid = blockIdx.x * 256 + tid;
  int4 v = ((const int4*)cnt)[gid];
  int s = v.x + v.y + v.z + v.w;
  int inc = waveInclScan(s, lane);
  if (lane == 63) wsum[wv] = inc;
  __syncthreads();
  int wvoff = 0;
  for (int w = 0; w < wv; w++) wvoff += wsum[w];
  int excl = wvoff + inc - s;
  int base = gid * 4;
  rtmp[base]     = excl;
  rtmp[base + 1] = excl + v.x;
  rtmp[base + 2] = excl + v.x + v.y;
  rtmp[base + 3] = excl + v.x + v.y + v.z;
  if (tid == 255) bsum[blockIdx.x] = wvoff + wsum[3];
}

__global__ void scanB_kernel(const int* __restrict__ bsum, int* __restrict__ boff) {
  if (threadIdx.x == 0) {
    int run = 0;
    for (int i = 0; i < NB_; i++) { boff[i] = run; run += bsum[i]; }
  }
}

__global__ __launch_bounds__(256) void scanC_kernel(
    const int* __restrict__ rtmp, const int* __restrict__ boff,
    int* __restrict__ rowU, int* __restrict__ rowI) {
  int gid = blockIdx.x * 256 + threadIdx.x;
  int off = boff[blockIdx.x];
  int4 v = ((const int4*)rtmp)[gid];
  int vals[4] = {v.x, v.y, v.z, v.w};
  int base = gid * 4;
  #pragma unroll
  for (int k = 0; k < 4; k++) {
    int i = base + k;
    int val = vals[k] + off;
    if (i < U_) rowU[i] = val;
    else        rowI[i - U_] = val - E_;
  }
  if (gid == 0) { rowU[U_] = E_; rowI[I_] = E_; }
}

// ---------------- 2. layer-1 aggregation ----------------
__global__ __launch_bounds__(256) void agg1_kernel(
    const void* __restrict__ src, const int* __restrict__ row,
    const int* __restrict__ csr, float* __restrict__ out,
    const float* __restrict__ flag) {
  int isf32 = *flag > 0.5f;
  int wv = threadIdx.x >> 6, lane = threadIdx.x & 63;
  int r = blockIdx.x * 4 + wv;
  int s0 = row[r], s1 = row[r + 1];
  float acc = 0.f;
  int j = s0;
  for (; j + 4 <= s1; j += 4) {
    int a = csr[j], b = csr[j + 1], c = csr[j + 2], d = csr[j + 3];
    float va = ldf(src, (size_t)a * 64 + lane, isf32);
    float vb = ldf(src, (size_t)b * 64 + lane, isf32);
    float vc = ldf(src, (size_t)c * 64 + lane, isf32);
    float vd = ldf(src, (size_t)d * 64 + lane, isf32);
    acc += (va + vb) + (vc + vd);
  }
  for (; j < s1; j++) acc += ldf(src, (size_t)csr[j] * 64 + lane, isf32);
  out[(size_t)r * 64 + lane] = acc / fmaxf((float)(s1 - s0), 1.0f);
}

// ---------------- 3. layer-2 aggregation + fused layer attention ----------------
__global__ __launch_bounds__(256) void agg2attn_kernel(
    const float* __restrict__ opp1, const void* __restrict__ base,
    const float* __restrict__ own1,
    const int* __restrict__ row, const int* __restrict__ csr,
    const float* __restrict__ Wa, float* __restrict__ h,
    const float* __restrict__ flag) {
  int isf32 = *flag > 0.5f;
  int wv = threadIdx.x >> 6, lane = threadIdx.x & 63;
  int r = blockIdx.x * 4 + wv;
  int s0 = row[r], s1 = row[r + 1];
  float acc = 0.f;
  int j = s0;
  for (; j + 4 <= s1; j += 4) {
    int a = csr[j], b = csr[j + 1], c = csr[j + 2], d = csr[j + 3];
    float va = opp1[(size_t)a * 64 + lane];
    float vb = opp1[(size_t)b * 64 + lane];
    float vc = opp1[(size_t)c * 64 + lane];
    float vd = opp1[(size_t)d * 64 + lane];
    acc += (va + vb) + (vc + vd);
  }
  for (; j < s1; j++) acc += opp1[(size_t)csr[j] * 64 + lane];
  size_t idx = (size_t)r * 64 + lane;
  float t2 = acc / fmaxf((float)(s1 - s0), 1.0f);
  float t0 = ldf(base, idx, isf32);
  float t1 = own1[idx];
  float w = Wa[lane];
  float p0 = t0 * w, p1 = t1 * w, p2 = t2 * w;
  #pragma unroll
  for (int off = 32; off; off >>= 1) {
    p0 += __shfl_xor(p0, off, 64);
    p1 += __shfl_xor(p1, off, 64);
    p2 += __shfl_xor(p2, off, 64);
  }
  float m = fmaxf(p0, fmaxf(p1, p2));
  float e0 = __expf(p0 - m), e1 = __expf(p1 - m), e2 = __expf(p2 - m);
  float inv = 1.0f / (e0 + e1 + e2);
  h[idx] = (t0 * e0 + t1 * e1 + t2 * e2) * inv;
}

// ---------------- 4. anchor user embed (FFT filter + collapsed attention) -------
// Per wave = 1 user. y[k] (filtered simu, column d=lane) stays in registers.
// e[k] = leaky(y[k]·vU1 + ue·vU2) via shuffle-reduce; softmax over k;
// mix = sum_k wexp[k]*y[k]; out = (mix @ WU) / se  — ONE matvec per user.
__global__ __launch_bounds__(256) void anchor_kernel(
    const void* __restrict__ ue, const void* __restrict__ WU,
    const void* __restrict__ cw, const float* __restrict__ vecs,
    const int* __restrict__ nbr, float* __restrict__ out,
    const float* __restrict__ flag) {
  int isf32 = *flag > 0.5f;
  __shared__ __align__(16) float2 wu2[32][64];  // 16KB: (WU[2dp][n], WU[2dp+1][n])
  __shared__ __align__(16) float mixS[4][64];
  int tid = threadIdx.x;
  int wv = tid >> 6, lane = tid & 63;
  int u = blockIdx.x * 4 + wv;

  // stage WU (f32) into LDS, packed in d-pairs
  for (int idx = tid; idx < 2048; idx += 256) {
    int dp = idx >> 6, n = idx & 63;
    wu2[dp][n] = make_float2(ldf(WU, (size_t)(2 * dp) * 64 + n, isf32),
                             ldf(WU, (size_t)(2 * dp + 1) * 64 + n, isf32));
  }

  // gather neighbor rows (FFT axis k in registers)
  float x[8];
  #pragma unroll
  for (int k = 0; k < 8; k++) {
    int nb = nbr[u * 8 + k];
    x[k] = ldf(ue, (size_t)nb * 64 + lane, isf32);
  }
  // 8-point rfft (unscaled); 'ortho' fwd+inv scaling folded into final 1/8
  const float c1 = 0.70710678118654752440f;
  float sA = x[1] - x[3] - x[5] + x[7];
  float sB = x[1] + x[3] - x[5] - x[7];
  float ev = (x[0] + x[4]) + (x[2] + x[6]);
  float od = (x[1] + x[5]) + (x[3] + x[7]);
  float d04 = x[0] - x[4], d26 = x[2] - x[6];
  float X0r = ev + od;
  float X1r = d04 + c1 * sA;
  float X1i = -d26 - c1 * sB;
  float X2r = (x[0] + x[4]) - (x[2] + x[6]);
  float X2i = -(x[1] - x[3] + x[5] - x[7]);
  float X3r = d04 - c1 * sA;
  float X3i = d26 - c1 * sB;
  float X4r = ev - od;
  float Zr0 = X0r * ldf(cw, (0 * 64 + lane) * 2, isf32);
  float w1r = ldf(cw, (1 * 64 + lane) * 2, isf32), w1i = ldf(cw, (1 * 64 + lane) * 2 + 1, isf32);
  float Zr1 = X1r * w1r - X1i * w1i, Zi1 = X1r * w1i + X1i * w1r;
  float w2r = ldf(cw, (2 * 64 + lane) * 2, isf32), w2i = ldf(cw, (2 * 64 + lane) * 2 + 1, isf32);
  float Zr2 = X2r * w2r - X2i * w2i, Zi2 = X2r * w2i + X2i * w2r;
  float w3r = ldf(cw, (3 * 64 + lane) * 2, isf32), w3i = ldf(cw, (3 * 64 + lane) * 2 + 1, isf32);
  float Zr3 = X3r * w3r - X3i * w3i, Zi3 = X3r * w3i + X3i * w3r;
  float Zr4 = X4r * ldf(cw, (4 * 64 + lane) * 2, isf32);
  float eP = Zr0 + Zr4, eM = Zr0 - Zr4;
  float t1 = c1 * (Zr1 - Zr3), t2 = c1 * (Zi1 + Zi3);
  float y[8];
  y[0] = eP + 2.f * (Zr1 + Zr2 + Zr3);
  y[1] = eM + 2.f * (t1 - t2 - Zi2);
  y[2] = eP + 2.f * (-Zi1 - Zr2 + Zi3);
  y[3] = eM + 2.f * (-t1 - t2 + Zi2);
  y[4] = eP + 2.f * (-Zr1 + Zr2 - Zr3);
  y[5] = eM + 2.f * (-t1 + t2 - Zi2);
  y[6] = eP + 2.f * (Zi1 - Zr2 - Zi3);
  y[7] = eM + 2.f * (t1 + t2 + Zi2);
  #pragma unroll
  for (int k = 0; k < 8; k++) y[k] *= 0.125f;

  // attention scores via collapsed vectors
  float v1 = vecs[64 + lane], v2 = vecs[128 + lane];
  float ek[8];
  #pragma unroll
  for (int k = 0; k < 8; k++) ek[k] = y[k] * v1;
  float q = ldf(ue, (size_t)u * 64 + lane, isf32) * v2;
  #pragma unroll
  for (int off = 32; off; off >>= 1) {
    #pragma unroll
    for (int k = 0; k < 8; k++) ek[k] += __shfl_xor(ek[k], off, 64);
    q += __shfl_xor(q, off, 64);
  }
  float m = -1e30f;
  #pragma unroll
  for (int k = 0; k < 8; k++) {
    float v = ek[k] + q;
    v = v > 0.f ? v : 0.1f * v;  // LeakyReLU(0.1)
    ek[k] = v;
    m = fmaxf(m, v);
  }
  float se = 0.f, wexp[8];
  #pragma unroll
  for (int k = 0; k < 8; k++) { wexp[k] = __expf(ek[k] - m); se += wexp[k]; }
  float mix = 0.f;
  #pragma unroll
  for (int k = 0; k < 8; k++) mix += wexp[k] * y[k];
  mixS[wv][lane] = mix;
  __syncthreads();  // covers wu2 staging + mixS writes

  // out[lane] = (mix @ WU)[lane] / se
  float acc = 0.f;
  const float4* mrow = (const float4*)mixS[wv];
  #pragma unroll
  for (int it = 0; it < 16; it++) {
    float4 m4 = mrow[it];              // wave-uniform broadcast
    float2 w0 = wu2[2 * it][lane];     // lane-consecutive
    float2 w1 = wu2[2 * it + 1][lane];
    acc += m4.x * w0.x + m4.y * w0.y + m4.z * w1.x + m4.w * w1.y;
  }
  out[(size_t)u * 64 + lane] = acc / se;
}

// ---------------- 5. contrastive loss: 4 row-slices per chunk ----------------
__global__ __launch_bounds__(256) void contrast_kernel(
    const float* __restrict__ hu, const float* __restrict__ an,
    float* __restrict__ loss_acc) {
  __shared__ uint4 L1[8 * CB_];  // 32KB, [t][row]
  __shared__ uint4 L2[8 * CB_];  // 32KB
  __shared__ float N1[CB_], N2[CB_];
  __shared__ float psT[4][64], psB[4][64], labT[64], labB[64];
  int tid = threadIdx.x;
  int c = blockIdx.x >> 2, s = blockIdx.x & 3;

  const float* r1 = hu + ((size_t)c * CB_ + tid) * 64;
  const float* r2 = an + ((size_t)c * CB_ + tid) * 64;
  float s1 = 0.f, s2 = 0.f;
  float4 a4[16], b4[16];
  #pragma unroll
  for (int t = 0; t < 16; t++) {
    a4[t] = ((const float4*)r1)[t];
    s1 += a4[t].x * a4[t].x + a4[t].y * a4[t].y + a4[t].z * a4[t].z + a4[t].w * a4[t].w;
    b4[t] = ((const float4*)r2)[t];
    s2 += b4[t].x * b4[t].x + b4[t].y * b4[t].y + b4[t].z * b4[t].z + b4[t].w * b4[t].w;
  }
  float n1 = sqrtf(s1), n2 = sqrtf(s2);
  float inv1 = frcp(n1), inv2 = frcp(n2);
  N1[tid] = n1; N2[tid] = n2;
  #pragma unroll
  for (int t = 0; t < 8; t++) {
    h2v p0; p0[0] = (_Float16)(a4[2*t].x * inv1); p0[1] = (_Float16)(a4[2*t].y * inv1);
    h2v p1; p1[0] = (_Float16)(a4[2*t].z * inv1); p1[1] = (_Float16)(a4[2*t].w * inv1);
    h2v p2; p2[0] = (_Float16)(a4[2*t+1].x * inv1); p2[1] = (_Float16)(a4[2*t+1].y * inv1);
    h2v p3; p3[0] = (_Float16)(a4[2*t+1].z * inv1); p3[1] = (_Float16)(a4[2*t+1].w * inv1);
    uint4 pk = {h2u(p0), h2u(p1), h2u(p2), h2u(p3)};
    L1[t * CB_ + tid] = pk;
    h2v q0; q0[0] = (_Float16)(b4[2*t].x * inv2); q0[1] = (_Float16)(b4[2*t].y * inv2);
    h2v q1; q1[0] = (_Float16)(b4[2*t].z * inv2); q1[1] = (_Float16)(b4[2*t].w * inv2);
    h2v q2; q2[0] = (_Float16)(b4[2*t+1].x * inv2); q2[1] = (_Float16)(b4[2*t+1].y * inv2);
    h2v q3; q3[0] = (_Float16)(b4[2*t+1].z * inv2); q3[1] = (_Float16)(b4[2*t+1].w * inv2);
    uint4 qk = {h2u(q0), h2u(q1), h2u(q2), h2u(q3)};
    L2[t * CB_ + tid] = qk;
  }
  __syncthreads();

  int ti = tid & 63, jq = tid >> 6;
  int i = s * 64 + ti;
  uint4 a1r[8], a2r[8];
  #pragma unroll
  for (int t = 0; t < 8; t++) { a1r[t] = L1[t * CB_ + i]; a2r[t] = L2[t * CB_ + i]; }
  float n1i = N1[i], n2i = N2[i];
  float sum_t = 0.f, sum_b = 0.f, lT = 0.f, lB = 0.f;
  int j0 = jq * 64;
  for (int jj = 0; jj < 64; jj++) {
    int j = j0 + jj;
    float d11 = 0.f, d12 = 0.f, d21 = 0.f, d22 = 0.f;
    #pragma unroll
    for (int t = 0; t < 8; t++) {
      uint4 c1v = L1[t * CB_ + j];
      uint4 c2v = L2[t * CB_ + j];
      h2v b;
      b = u2h(c1v.x); d11 = fdot2f(u2h(a1r[t].x), b, d11); d21 = fdot2f(u2h(a2r[t].x), b, d21);
      b = u2h(c1v.y); d11 = fdot2f(u2h(a1r[t].y), b, d11); d21 = fdot2f(u2h(a2r[t].y), b, d21);
      b = u2h(c1v.z); d11 = fdot2f(u2h(a1r[t].z), b, d11); d21 = fdot2f(u2h(a2r[t].z), b, d21);
      b = u2h(c1v.w); d11 = fdot2f(u2h(a1r[t].w), b, d11); d21 = fdot2f(u2h(a2r[t].w), b, d21);
      b = u2h(c2v.x); d12 = fdot2f(u2h(a1r[t].x), b, d12); d22 = fdot2f(u2h(a2r[t].x), b, d22);
      b = u2h(c2v.y); d12 = fdot2f(u2h(a1r[t].y), b, d12); d22 = fdot2f(u2h(a2r[t].y), b, d22);
      b = u2h(c2v.z); d12 = fdot2f(u2h(a1r[t].z), b, d12); d22 = fdot2f(u2h(a2r[t].z), b, d22);
      b = u2h(c2v.w); d12 = fdot2f(u2h(a1r[t].w), b, d12); d22 = fdot2f(u2h(a2r[t].w), b, d22);
    }
    float m1 = N1[j], m2 = N2[j];
    float p11 = n1i * m1, p12 = n1i * m2, p21 = n2i * m1, p22 = n2i * m2;
    d11 *= 5.0f * p11 * frcp(p11 + 1e-6f);
    d12 *= 5.0f * p12 * frcp(p12 + 1e-6f);
    d21 *= 5.0f * p21 * frcp(p21 + 1e-6f);
    d22 *= 5.0f * p22 * frcp(p22 + 1e-6f);
    float e12 = __expf(d12), e21 = __expf(d21);
    if (j == i) {
      lT = d12; lB = d21;
      sum_t += e12; sum_b += e21;
    } else {
      sum_t += __expf(d11) + e12;
      sum_b += __expf(d22) + e21;
    }
  }
  psT[jq][ti] = sum_t;
  psB[jq][ti] = sum_b;
  if (jq == s) { labT[ti] = lT; labB[ti] = lB; }
  __syncthreads();

  if (tid < 64) {
    float st = psT[0][tid] + psT[1][tid] + psT[2][tid] + psT[3][tid];
    float sb = psB[0][tid] + psB[1][tid] + psB[2][tid] + psB[3][tid];
    float loss = (__logf(st) - labT[tid]) + (__logf(sb) - labB[tid]);
    #pragma unroll
    for (int off = 32; off; off >>= 1) loss += __shfl_xor(loss, off, 64);
    if (tid == 0) atomicAdd(loss_acc, loss);
  }
}

// ---------------- 6. scores ----------------
__global__ __launch_bounds__(256) void score_kernel(
    const float* __restrict__ hu, const float* __restrict__ hi,
    const int* __restrict__ pu, const int* __restrict__ pi,
    const int* __restrict__ nu, const int* __restrict__ ni,
    void* __restrict__ out, const float* __restrict__ flag) {
  int isf32 = *flag > 0.5f;
  int w = (blockIdx.x * 256 + threadIdx.x) >> 6;
  int lane = threadIdx.x & 63;
  int uu, ii;
  if (w < EP_) { uu = pu[w]; ii = pi[w]; }
  else         { uu = nu[w - EP_]; ii = ni[w - EP_]; }
  float p = hu[(size_t)uu * 64 + lane] * hi[(size_t)ii * 64 + lane];
  #pragma unroll
  for (int off = 32; off; off >>= 1) p += __shfl_xor(p, off, 64);
  if (lane == 0) {
    if (isf32) ((float*)out)[w] = p;
    else       ((__hip_bfloat16*)out)[w] = __float2bfloat16(p);
  }
}

__global__ void finalize_kernel(const float* __restrict__ loss_acc,
                                void* __restrict__ out,
                                const float* __restrict__ flag) {
  float v = loss_acc[0] * (1.0f / (float)(2 * CB_ * NCHUNK_));
  if (*flag > 0.5f) ((float*)out)[2 * EP_] = v;
  else              ((__hip_bfloat16*)out)[2 * EP_] = __float2bfloat16(v);
}

// ---------------- launch ----------------
extern "C" void kernel_launch(void* const* d_in, const int* in_sizes, int n_in,
                              void* d_out, int out_size, void* d_ws, size_t ws_size,
                              hipStream_t stream) {
  const void* ue  = d_in[0];
  const void* ie  = d_in[1];
  const void* W   = d_in[2];
  const void* a   = d_in[3];
  const void* WU  = d_in[4];
  const void* aU  = d_in[5];
  const void* cw  = d_in[6];
  const int* rs  = (const int*)d_in[7];
  const int* rd  = (const int*)d_in[8];
  const int* pu  = (const int*)d_in[9];
  const int* pi  = (const int*)d_in[10];
  const int* nu  = (const int*)d_in[11];
  const int* ni  = (const int*)d_in[12];
  const int* nbr = (const int*)d_in[13];

  float* wsf  = (float*)d_ws;
  int*   wsi  = (int*)d_ws;
  float* loss = wsf + OFF_LOSS;
  float* flag = wsf + OFF_FLAG;
  int* gallocU = wsi + 4;
  int* dcntU   = wsi + 5;
  int* gallocI = wsi + 6;
  int* dcntI   = wsi + 7;
  float* vecs = wsf + OFF_VEC;   // Wa | vU1 | vU2
  int*   cnt  = wsi + OFF_CNT;
  int*   rtmp = wsi + OFF_RTMP;
  int*   bsum = wsi + OFF_BSUM;
  int*   boff = wsi + OFF_BOFF;
  int*   rowU = wsi + OFF_ROWU;
  int*   rowI = wsi + OFF_ROWI;
  int*   dirU = wsi + OFF_DIRU;
  int*   dirI = wsi + OFF_DIRI;
  int*   csrU = wsi + OFF_CSRU;
  int*   csrI = wsi + OFF_CSRI;
  float* u1   = wsf + OFF_U1;
  float* i1   = wsf + OFF_I1;
  float* hu   = wsf + OFF_HU;
  float* hi   = wsf + OFF_HI;
  float* anc  = wsf + OFF_ANC;
  unsigned long long* bufU = (unsigned long long*)(wsf + OFF_HU);
  unsigned long long* bufI = (unsigned long long*)(wsf + OFF_HI);

  hipMemsetAsync(d_ws, 0, MEMSET_BYTES, stream);
  prep_kernel<<<1, 64, 0, stream>>>((const unsigned short*)ue, W, a, WU, aU, vecs, flag);

  // CSR build
  bucketA_kernel<<<NBA_, 256, 0, stream>>>(rs, rd, bufU, gallocU, dirU, dcntU, 9, cnt, 1);
  bucketA_kernel<<<NBA_, 256, 0, stream>>>(rd, rs, bufI, gallocI, dirI, dcntI, 8, cnt, 0);
  scanA_kernel<<<NB_, 256, 0, stream>>>(cnt, rtmp, bsum);
  scanB_kernel<<<1, 64, 0, stream>>>(bsum, boff);
  scanC_kernel<<<NB_, 256, 0, stream>>>(rtmp, boff, rowU, rowI);
  bucketB_kernel<<<NBK_, 256, 0, stream>>>(bufU, dirU, dcntU, rowU, csrU, 512);
  bucketB_kernel<<<NBK_, 256, 0, stream>>>(bufI, dirI, dcntI, rowI, csrI, 256);

  // layer-1 aggregation (gather)
  agg1_kernel<<<I_ / 4, 256, 0, stream>>>(ue, rowI, csrI, i1, flag);
  agg1_kernel<<<U_ / 4, 256, 0, stream>>>(ie, rowU, csrU, u1, flag);

  // layer-2 aggregation + fused layer attention
  agg2attn_kernel<<<I_ / 4, 256, 0, stream>>>(u1, ie, i1, rowI, csrI, vecs, hi, flag);
  agg2attn_kernel<<<U_ / 4, 256, 0, stream>>>(i1, ue, u1, rowU, csrU, vecs, hu, flag);

  // anchor path (collapsed attention)
  anchor_kernel<<<U_ / 4, 256, 0, stream>>>(ue, WU, cw, vecs, nbr, anc, flag);

  // contrastive loss (4 slices per chunk)
  contrast_kernel<<<NCHUNK_ * 4, 256, 0, stream>>>(hu, anc, loss);

  // scores
  score_kernel<<<(2 * EP_ * 64) / 256, 256, 0, stream>>>(hu, hi, pu, pi, nu, ni, d_out, flag);
  finalize_kernel<<<1, 1, 0, stream>>>(loss, d_out, flag);
}

// Round 7
// 731.489 us; speedup vs baseline: 1.1249x; 1.0483x over previous
//
#include <hip/hip_runtime.h>
#include <hip/hip_bf16.h>

// ---------------- problem constants ----------------
constexpr int U_  = 51200;
constexpr int I_  = 25600;
constexpr int N_  = U_ + I_;             // 76800 combined rows
constexpr int E_  = 1000000;
constexpr int EP_ = 100000;
constexpr int CB_ = 256;                 // contrastive chunk size
constexpr int NCHUNK_ = U_ / CB_;        // 200
constexpr size_t UD_ = (size_t)U_ * 64;
constexpr size_t ID_ = (size_t)I_ * 64;
constexpr int NB_ = N_ / 1024;           // 75 scan blocks
constexpr int NBK_ = 100;                // coarse buckets per side
constexpr int TILE_ = 4096;              // edges per Phase-A block
constexpr int NBA_ = (E_ + TILE_ - 1) / TILE_;  // 245
constexpr int DIRCAP_ = NBA_ * NBK_;     // 24500 entries max

// ---------------- workspace layout (4-byte element offsets) ----------------
constexpr size_t OFF_LOSS  = 0;
constexpr size_t OFF_FLAG  = 1;
// counters: 4=gallocU 5=dcntU 6=gallocI 7=dcntI
constexpr size_t OFF_VEC   = 64;                     // 192 floats: Wa | vU1 | vU2
constexpr size_t OFF_CNT   = 256;                    // N_ ints (fine histogram)
constexpr size_t MEMSET_BYTES = (OFF_CNT + N_) * 4;  // zero loss/counters/cnt
constexpr size_t OFF_RTMP  = OFF_CNT + N_;           // N_ ints
constexpr size_t OFF_BSUM  = OFF_RTMP + N_;          // 128
constexpr size_t OFF_BOFF  = OFF_BSUM + 128;         // 128
constexpr size_t OFF_ROWU  = OFF_BOFF + 128;         // U_+1
constexpr size_t OFF_ROWI  = OFF_ROWU + U_ + 1;      // I_+1
constexpr size_t OFF_DIRU  = ((OFF_ROWI + I_ + 1 + 63) / 64) * 64;  // 4*DIRCAP_
constexpr size_t OFF_DIRI  = ((OFF_DIRU + 4 * DIRCAP_ + 63) / 64) * 64;
constexpr size_t OFF_CSRU  = ((OFF_DIRI + 4 * DIRCAP_ + 63) / 64) * 64;  // E_
constexpr size_t OFF_CSRI  = OFF_CSRU + E_;          // E_
constexpr size_t OFF_U1    = ((OFF_CSRI + E_ + 63) / 64) * 64;
constexpr size_t OFF_I1    = OFF_U1 + UD_;
constexpr size_t OFF_HU    = OFF_I1 + ID_;           // bufU aliases here
constexpr size_t OFF_HI    = OFF_HU + UD_;           // bufI aliases here
constexpr size_t OFF_ANC   = OFF_HI + ID_;
// total ≈ 62.1 MB

#define DEVI static __device__ __forceinline__

typedef _Float16 h2v __attribute__((ext_vector_type(2)));
typedef _Float16 f16x8 __attribute__((ext_vector_type(8)));
typedef float floatx4 __attribute__((ext_vector_type(4)));

DEVI float b2f(__hip_bfloat16 x) { return __bfloat162float(x); }

DEVI float ldf(const void* p, size_t i, int isf32) {
  if (isf32) return ((const float*)p)[i];
  return b2f(((const __hip_bfloat16*)p)[i]);
}

DEVI float frcp(float x) { return __builtin_amdgcn_rcpf(x); }

DEVI int waveInclScan(int v, int lane) {
  #pragma unroll
  for (int off = 1; off < 64; off <<= 1) {
    int t = __shfl_up(v, off, 64);
    if (lane >= off) v += t;
  }
  return v;
}

// ---------------- 0. prep: dtype detection + Wa/vU1/vU2 precompute ----------------
__global__ void prep_kernel(const unsigned short* __restrict__ ueu,
                            const void* __restrict__ W, const void* __restrict__ a,
                            const void* __restrict__ WU, const void* __restrict__ aU,
                            float* __restrict__ vecs, float* __restrict__ flag) {
  int cnt = 0;
  for (int i = 0; i < 256; i++) {
    int e = (ueu[i] >> 7) & 0xFF;
    if (e >= 130) cnt++;
  }
  int isf32 = (cnt >= 8);
  if (threadIdx.x == 0) *flag = isf32 ? 1.0f : 0.0f;
  int d = threadIdx.x;  // 64 threads
  float s = 0.f, t1 = 0.f, t2 = 0.f;
  for (int e = 0; e < 64; e++) {
    s += ldf(W, d * 64 + e, isf32) * ldf(a, e, isf32);
    float wue = ldf(WU, d * 64 + e, isf32);
    t1 += wue * ldf(aU, e, isf32);
    t2 += wue * ldf(aU, 64 + e, isf32);
  }
  vecs[d] = s;          // Wa
  vecs[64 + d] = t1;    // vU1
  vecs[128 + d] = t2;   // vU2
}

// ---------------- 1a. Phase A: bucket edges into chunked record buffer ----------
__global__ __launch_bounds__(256) void bucketA_kernel(
    const int* __restrict__ key, const int* __restrict__ payload,
    unsigned long long* __restrict__ buf, int* __restrict__ galloc,
    int* __restrict__ dir, int* __restrict__ dcnt,
    int shift, int* __restrict__ fineCnt, int doFine) {
  __shared__ int hist[NBK_], loff[NBK_ + 1], cbase[NBK_], lcur[NBK_];
  __shared__ unsigned long long recs[TILE_];
  int tid = threadIdx.x;
  int base = blockIdx.x * TILE_;
  for (int i = tid; i < NBK_; i += 256) hist[i] = 0;
  __syncthreads();
  int kk[16], pp[16];
  #pragma unroll
  for (int t = 0; t < 16; t++) {
    int e = base + t * 256 + tid;
    bool v = e < E_;
    kk[t] = v ? key[e] : -1;
    pp[t] = v ? payload[e] : 0;
    if (v) {
      atomicAdd(&hist[kk[t] >> shift], 1);
      if (doFine) {
        atomicAdd(&fineCnt[kk[t]], 1);
        atomicAdd(&fineCnt[U_ + pp[t]], 1);
      }
    }
  }
  __syncthreads();
  if (tid < NBK_) {
    int c = hist[tid];
    int gb = 0;
    if (c > 0) {
      gb = atomicAdd(galloc, c);
      int di = atomicAdd(dcnt, 1);
      dir[di * 4]     = tid;
      dir[di * 4 + 1] = gb;
      dir[di * 4 + 2] = c;
    }
    cbase[tid] = gb;
  }
  __syncthreads();
  if (tid == 0) {
    int run = 0;
    for (int b = 0; b < NBK_; b++) { loff[b] = run; run += hist[b]; }
    loff[NBK_] = run;
  }
  __syncthreads();
  if (tid < NBK_) lcur[tid] = loff[tid];
  __syncthreads();
  #pragma unroll
  for (int t = 0; t < 16; t++) {
    if (kk[t] >= 0) {
      int b = kk[t] >> shift;
      int p = atomicAdd(&lcur[b], 1);
      recs[p] = ((unsigned long long)(unsigned)kk[t] << 32) | (unsigned)pp[t];
    }
  }
  __syncthreads();
  int total = loff[NBK_];
  for (int p = tid; p < total; p += 256) {
    int lo = 0, hi = NBK_;
    while (hi - lo > 1) { int mid = (lo + hi) >> 1; if (loff[mid] <= p) lo = mid; else hi = mid; }
    buf[cbase[lo] + (p - loff[lo])] = recs[p];
  }
}

// ---------------- 1b. Phase B: per-bucket CSR fill via LDS staging -------------
__global__ __launch_bounds__(256) void bucketB_kernel(
    const unsigned long long* __restrict__ buf,
    const int* __restrict__ dir, const int* __restrict__ dcnt,
    const int* __restrict__ rowptr, int* __restrict__ csr,
    int keysPerBucket) {
  __shared__ int stage[16384];
  __shared__ int kcur[512];
  __shared__ int est[512], eln[512], epre[513];
  __shared__ int lcnt;
  int tid = threadIdx.x, b = blockIdx.x;
  if (tid == 0) lcnt = 0;
  int keyBase = b * keysPerBucket;
  int regionBase = rowptr[keyBase];
  int size = rowptr[keyBase + keysPerBucket] - regionBase;
  for (int k = tid; k < keysPerBucket; k += 256)
    kcur[k] = rowptr[keyBase + k] - regionBase;
  __syncthreads();
  int nd = *dcnt;
  for (int i = tid; i < nd; i += 256) {
    if (dir[i * 4] == b) {
      int li = atomicAdd(&lcnt, 1);
      est[li] = dir[i * 4 + 1];
      eln[li] = dir[i * 4 + 2];
    }
  }
  __syncthreads();
  if (tid == 0) {
    int run = 0;
    for (int i = 0; i < lcnt; i++) { epre[i] = run; run += eln[i]; }
    epre[lcnt] = run;
  }
  __syncthreads();
  int ne = lcnt;
  int total = epre[ne];
  for (int r = tid; r < total; r += 256) {
    int lo = 0, hi = ne;
    while (hi - lo > 1) { int mid = (lo + hi) >> 1; if (epre[mid] <= r) lo = mid; else hi = mid; }
    unsigned long long rec = buf[(size_t)est[lo] + (r - epre[lo])];
    int keyv = (int)(rec >> 32);
    int pay  = (int)(unsigned)(rec & 0xffffffffULL);
    int slot = atomicAdd(&kcur[keyv - keyBase], 1);
    if (slot < 16384) stage[slot] = pay;
  }
  __syncthreads();
  for (int s = tid; s < size; s += 256) csr[regionBase + s] = stage[s];
}

// ---------------- 1c. row-pointer scan ----------------
__global__ __launch_bounds__(256) void scanA_kernel(
    const int* __restrict__ cnt, int* __restrict__ rtmp, int* __restrict__ bsum) {
  __shared__ int wsum[4];
  int tid = threadIdx.x, lane = tid & 63, wv = tid >> 6;
  int gid = blockIdx.x * 256 + tid;
  int4 v = ((const int4*)cnt)[gid];
  int s = v.x + v.y + v.z + v.w;
  int inc = waveInclScan(s, lane);
  if (lane == 63) wsum[wv] = inc;
  __syncthreads();
  int wvoff = 0;
  for (int w = 0; w < wv; w++) wvoff += wsum[w];
  int excl = wvoff + inc - s;
  int base = gid * 4;
  rtmp[base]     = excl;
  rtmp[base + 1] = excl + v.x;
  rtmp[base + 2] = excl + v.x + v.y;
  rtmp[base + 3] = excl + v.x + v.y + v.z;
  if (tid == 255) bsum[blockIdx.x] = wvoff + wsum[3];
}

__global__ void scanB_kernel(const int* __restrict__ bsum, int* __restrict__ boff) {
  if (threadIdx.x == 0) {
    int run = 0;
    for (int i = 0; i < NB_; i++) { boff[i] = run; run += bsum[i]; }
  }
}

__global__ __launch_bounds__(256) void scanC_kernel(
    const int* __restrict__ rtmp, const int* __restrict__ boff,
    int* __restrict__ rowU, int* __restrict__ rowI) {
  int gid = blockIdx.x * 256 + threadIdx.x;
  int off = boff[blockIdx.x];
  int4 v = ((const int4*)rtmp)[gid];
  int vals[4] = {v.x, v.y, v.z, v.w};
  int base = gid * 4;
  #pragma unroll
  for (int k = 0; k < 4; k++) {
    int i = base + k;
    int val = vals[k] + off;
    if (i < U_) rowU[i] = val;
    else        rowI[i - U_] = val - E_;
  }
  if (gid == 0) { rowU[U_] = E_; rowI[I_] = E_; }
}

// ---------------- 2. layer-1 aggregation ----------------
__global__ __launch_bounds__(256) void agg1_kernel(
    const void* __restrict__ src, const int* __restrict__ row,
    const int* __restrict__ csr, float* __restrict__ out,
    const float* __restrict__ flag) {
  int isf32 = *flag > 0.5f;
  int wv = threadIdx.x >> 6, lane = threadIdx.x & 63;
  int r = blockIdx.x * 4 + wv;
  int s0 = row[r], s1 = row[r + 1];
  float acc = 0.f;
  int j = s0;
  for (; j + 4 <= s1; j += 4) {
    int a = csr[j], b = csr[j + 1], c = csr[j + 2], d = csr[j + 3];
    float va = ldf(src, (size_t)a * 64 + lane, isf32);
    float vb = ldf(src, (size_t)b * 64 + lane, isf32);
    float vc = ldf(src, (size_t)c * 64 + lane, isf32);
    float vd = ldf(src, (size_t)d * 64 + lane, isf32);
    acc += (va + vb) + (vc + vd);
  }
  for (; j < s1; j++) acc += ldf(src, (size_t)csr[j] * 64 + lane, isf32);
  out[(size_t)r * 64 + lane] = acc / fmaxf((float)(s1 - s0), 1.0f);
}

// ---------------- 3. layer-2 aggregation + fused layer attention ----------------
__global__ __launch_bounds__(256) void agg2attn_kernel(
    const float* __restrict__ opp1, const void* __restrict__ base,
    const float* __restrict__ own1,
    const int* __restrict__ row, const int* __restrict__ csr,
    const float* __restrict__ Wa, float* __restrict__ h,
    const float* __restrict__ flag) {
  int isf32 = *flag > 0.5f;
  int wv = threadIdx.x >> 6, lane = threadIdx.x & 63;
  int r = blockIdx.x * 4 + wv;
  int s0 = row[r], s1 = row[r + 1];
  float acc = 0.f;
  int j = s0;
  for (; j + 4 <= s1; j += 4) {
    int a = csr[j], b = csr[j + 1], c = csr[j + 2], d = csr[j + 3];
    float va = opp1[(size_t)a * 64 + lane];
    float vb = opp1[(size_t)b * 64 + lane];
    float vc = opp1[(size_t)c * 64 + lane];
    float vd = opp1[(size_t)d * 64 + lane];
    acc += (va + vb) + (vc + vd);
  }
  for (; j < s1; j++) acc += opp1[(size_t)csr[j] * 64 + lane];
  size_t idx = (size_t)r * 64 + lane;
  float t2 = acc / fmaxf((float)(s1 - s0), 1.0f);
  float t0 = ldf(base, idx, isf32);
  float t1 = own1[idx];
  float w = Wa[lane];
  float p0 = t0 * w, p1 = t1 * w, p2 = t2 * w;
  #pragma unroll
  for (int off = 32; off; off >>= 1) {
    p0 += __shfl_xor(p0, off, 64);
    p1 += __shfl_xor(p1, off, 64);
    p2 += __shfl_xor(p2, off, 64);
  }
  float m = fmaxf(p0, fmaxf(p1, p2));
  float e0 = __expf(p0 - m), e1 = __expf(p1 - m), e2 = __expf(p2 - m);
  float inv = 1.0f / (e0 + e1 + e2);
  h[idx] = (t0 * e0 + t1 * e1 + t2 * e2) * inv;
}

// ---------------- 4. anchor user embed (FFT filter + collapsed attention) -------
__global__ __launch_bounds__(256) void anchor_kernel(
    const void* __restrict__ ue, const void* __restrict__ WU,
    const void* __restrict__ cw, const float* __restrict__ vecs,
    const int* __restrict__ nbr, float* __restrict__ out,
    const float* __restrict__ flag) {
  int isf32 = *flag > 0.5f;
  __shared__ __align__(16) float2 wu2[32][64];  // 16KB
  __shared__ __align__(16) float mixS[4][64];
  int tid = threadIdx.x;
  int wv = tid >> 6, lane = tid & 63;
  int u = blockIdx.x * 4 + wv;

  for (int idx = tid; idx < 2048; idx += 256) {
    int dp = idx >> 6, n = idx & 63;
    wu2[dp][n] = make_float2(ldf(WU, (size_t)(2 * dp) * 64 + n, isf32),
                             ldf(WU, (size_t)(2 * dp + 1) * 64 + n, isf32));
  }

  float x[8];
  #pragma unroll
  for (int k = 0; k < 8; k++) {
    int nb = nbr[u * 8 + k];
    x[k] = ldf(ue, (size_t)nb * 64 + lane, isf32);
  }
  const float c1 = 0.70710678118654752440f;
  float sA = x[1] - x[3] - x[5] + x[7];
  float sB = x[1] + x[3] - x[5] - x[7];
  float ev = (x[0] + x[4]) + (x[2] + x[6]);
  float od = (x[1] + x[5]) + (x[3] + x[7]);
  float d04 = x[0] - x[4], d26 = x[2] - x[6];
  float X0r = ev + od;
  float X1r = d04 + c1 * sA;
  float X1i = -d26 - c1 * sB;
  float X2r = (x[0] + x[4]) - (x[2] + x[6]);
  float X2i = -(x[1] - x[3] + x[5] - x[7]);
  float X3r = d04 - c1 * sA;
  float X3i = d26 - c1 * sB;
  float X4r = ev - od;
  float Zr0 = X0r * ldf(cw, (0 * 64 + lane) * 2, isf32);
  float w1r = ldf(cw, (1 * 64 + lane) * 2, isf32), w1i = ldf(cw, (1 * 64 + lane) * 2 + 1, isf32);
  float Zr1 = X1r * w1r - X1i * w1i, Zi1 = X1r * w1i + X1i * w1r;
  float w2r = ldf(cw, (2 * 64 + lane) * 2, isf32), w2i = ldf(cw, (2 * 64 + lane) * 2 + 1, isf32);
  float Zr2 = X2r * w2r - X2i * w2i, Zi2 = X2r * w2i + X2i * w2r;
  float w3r = ldf(cw, (3 * 64 + lane) * 2, isf32), w3i = ldf(cw, (3 * 64 + lane) * 2 + 1, isf32);
  float Zr3 = X3r * w3r - X3i * w3i, Zi3 = X3r * w3i + X3i * w3r;
  float Zr4 = X4r * ldf(cw, (4 * 64 + lane) * 2, isf32);
  float eP = Zr0 + Zr4, eM = Zr0 - Zr4;
  float t1 = c1 * (Zr1 - Zr3), t2 = c1 * (Zi1 + Zi3);
  float y[8];
  y[0] = eP + 2.f * (Zr1 + Zr2 + Zr3);
  y[1] = eM + 2.f * (t1 - t2 - Zi2);
  y[2] = eP + 2.f * (-Zi1 - Zr2 + Zi3);
  y[3] = eM + 2.f * (-t1 - t2 + Zi2);
  y[4] = eP + 2.f * (-Zr1 + Zr2 - Zr3);
  y[5] = eM + 2.f * (-t1 + t2 - Zi2);
  y[6] = eP + 2.f * (Zi1 - Zr2 - Zi3);
  y[7] = eM + 2.f * (t1 + t2 + Zi2);
  #pragma unroll
  for (int k = 0; k < 8; k++) y[k] *= 0.125f;

  float v1 = vecs[64 + lane], v2 = vecs[128 + lane];
  float ek[8];
  #pragma unroll
  for (int k = 0; k < 8; k++) ek[k] = y[k] * v1;
  float q = ldf(ue, (size_t)u * 64 + lane, isf32) * v2;
  #pragma unroll
  for (int off = 32; off; off >>= 1) {
    #pragma unroll
    for (int k = 0; k < 8; k++) ek[k] += __shfl_xor(ek[k], off, 64);
    q += __shfl_xor(q, off, 64);
  }
  float m = -1e30f;
  #pragma unroll
  for (int k = 0; k < 8; k++) {
    float v = ek[k] + q;
    v = v > 0.f ? v : 0.1f * v;
    ek[k] = v;
    m = fmaxf(m, v);
  }
  float se = 0.f, wexp[8];
  #pragma unroll
  for (int k = 0; k < 8; k++) { wexp[k] = __expf(ek[k] - m); se += wexp[k]; }
  float mix = 0.f;
  #pragma unroll
  for (int k = 0; k < 8; k++) mix += wexp[k] * y[k];
  mixS[wv][lane] = mix;
  __syncthreads();

  float acc = 0.f;
  const float4* mrow = (const float4*)mixS[wv];
  #pragma unroll
  for (int it = 0; it < 16; it++) {
    float4 m4 = mrow[it];
    float2 w0 = wu2[2 * it][lane];
    float2 w1 = wu2[2 * it + 1][lane];
    acc += m4.x * w0.x + m4.y * w0.y + m4.z * w1.x + m4.w * w1.y;
  }
  out[(size_t)u * 64 + lane] = acc / se;
}

// ---------------- 5. contrastive loss via MFMA Gram matrix ----------------
// Block b: chunk c=b>>2, row-slice sl=b&3 (128 of the 512 stacked rows
// X = [r1n (256); r2n (256)]). G = X@X^T gives all 4 quadrants; mask at j==i,
// label at j==i^256. Wave owns 2 row-tiles; loops 32 col-tiles with
// mfma_f32_16x16x32_f16 (K=64 in 2 steps), applies scale+exp inline.
constexpr int XS_ = 72;  // f16 row stride (144 B: 16B-aligned, uniform banks)
__global__ __launch_bounds__(256) void contrast_kernel(
    const float* __restrict__ hu, const float* __restrict__ an,
    float* __restrict__ loss_acc) {
  __shared__ __align__(16) _Float16 Xh[512 * XS_];  // 72 KB
  __shared__ float Nn[512];
  int tid = threadIdx.x;
  int c = blockIdx.x >> 2, sl = blockIdx.x & 3;

  // --- stage: thread tid normalizes hu row tid and anc row tid ---
  const float* r1 = hu + ((size_t)c * CB_ + tid) * 64;
  const float* r2 = an + ((size_t)c * CB_ + tid) * 64;
  float4 a4[16], b4[16];
  float s1 = 0.f, s2 = 0.f;
  #pragma unroll
  for (int t = 0; t < 16; t++) {
    a4[t] = ((const float4*)r1)[t];
    s1 += a4[t].x * a4[t].x + a4[t].y * a4[t].y + a4[t].z * a4[t].z + a4[t].w * a4[t].w;
    b4[t] = ((const float4*)r2)[t];
    s2 += b4[t].x * b4[t].x + b4[t].y * b4[t].y + b4[t].z * b4[t].z + b4[t].w * b4[t].w;
  }
  float n1 = sqrtf(s1), n2 = sqrtf(s2);
  float inv1 = frcp(n1), inv2 = frcp(n2);
  Nn[tid] = n1; Nn[256 + tid] = n2;
  #pragma unroll
  for (int t = 0; t < 8; t++) {
    f16x8 v;
    v[0] = (_Float16)(a4[2*t].x * inv1);   v[1] = (_Float16)(a4[2*t].y * inv1);
    v[2] = (_Float16)(a4[2*t].z * inv1);   v[3] = (_Float16)(a4[2*t].w * inv1);
    v[4] = (_Float16)(a4[2*t+1].x * inv1); v[5] = (_Float16)(a4[2*t+1].y * inv1);
    v[6] = (_Float16)(a4[2*t+1].z * inv1); v[7] = (_Float16)(a4[2*t+1].w * inv1);
    *(f16x8*)&Xh[tid * XS_ + t * 8] = v;
    f16x8 w;
    w[0] = (_Float16)(b4[2*t].x * inv2);   w[1] = (_Float16)(b4[2*t].y * inv2);
    w[2] = (_Float16)(b4[2*t].z * inv2);   w[3] = (_Float16)(b4[2*t].w * inv2);
    w[4] = (_Float16)(b4[2*t+1].x * inv2); w[5] = (_Float16)(b4[2*t+1].y * inv2);
    w[6] = (_Float16)(b4[2*t+1].z * inv2); w[7] = (_Float16)(b4[2*t+1].w * inv2);
    *(f16x8*)&Xh[(256 + tid) * XS_ + t * 8] = w;
  }
  __syncthreads();

  // --- compute ---
  int l = tid & 63, w = tid >> 6;
  int n = l & 15, q = l >> 4;
  int rb = sl * 128 + w * 32;  // wave's 2 row-tiles: rb, rb+16
  f16x8 A[2][2];
  #pragma unroll
  for (int t = 0; t < 2; t++)
    #pragma unroll
    for (int h = 0; h < 2; h++)
      A[t][h] = *(const f16x8*)&Xh[(rb + t * 16 + n) * XS_ + h * 32 + q * 8];
  float NiR[2][4];
  #pragma unroll
  for (int t = 0; t < 2; t++)
    #pragma unroll
    for (int r = 0; r < 4; r++)
      NiR[t][r] = Nn[rb + t * 16 + q * 4 + r];
  float sums[2][4] = {{0,0,0,0},{0,0,0,0}};
  float labs[2][4] = {{0,0,0,0},{0,0,0,0}};
  const floatx4 zero = {0.f, 0.f, 0.f, 0.f};
  for (int ct = 0; ct < 32; ct++) {
    int cb = ct * 16;
    f16x8 B0 = *(const f16x8*)&Xh[(cb + n) * XS_ + q * 8];
    f16x8 B1 = *(const f16x8*)&Xh[(cb + n) * XS_ + 32 + q * 8];
    floatx4 acc0 = __builtin_amdgcn_mfma_f32_16x16x32_f16(A[0][0], B0, zero, 0, 0, 0);
    acc0 = __builtin_amdgcn_mfma_f32_16x16x32_f16(A[0][1], B1, acc0, 0, 0, 0);
    floatx4 acc1 = __builtin_amdgcn_mfma_f32_16x16x32_f16(A[1][0], B0, zero, 0, 0, 0);
    acc1 = __builtin_amdgcn_mfma_f32_16x16x32_f16(A[1][1], B1, acc1, 0, 0, 0);
    int j = cb + n;
    float Nj = Nn[j];
    #pragma unroll
    for (int t = 0; t < 2; t++) {
      #pragma unroll
      for (int r = 0; r < 4; r++) {
        int i = rb + t * 16 + q * 4 + r;
        float G = (t == 0) ? acc0[r] : acc1[r];
        float p = NiR[t][r] * Nj;
        float s = 5.0f * G * p * frcp(p + 1e-6f);
        float e = (j == i) ? 0.f : __expf(s);
        sums[t][r] += e;
        labs[t][r] += (j == (i ^ 256)) ? s : 0.f;
      }
    }
  }
  // reduce over n-group (16 lanes: xor 1,2,4,8 stay in-group)
  #pragma unroll
  for (int off = 1; off <= 8; off <<= 1) {
    #pragma unroll
    for (int t = 0; t < 2; t++)
      #pragma unroll
      for (int r = 0; r < 4; r++) {
        sums[t][r] += __shfl_xor(sums[t][r], off, 64);
        labs[t][r] += __shfl_xor(labs[t][r], off, 64);
      }
  }
  float part = 0.f;
  if (n == 0) {
    #pragma unroll
    for (int t = 0; t < 2; t++)
      #pragma unroll
      for (int r = 0; r < 4; r++)
        part += __logf(sums[t][r]) - labs[t][r];
  }
  #pragma unroll
  for (int off = 1; off < 64; off <<= 1) part += __shfl_xor(part, off, 64);
  if (l == 0) atomicAdd(loss_acc, part);
}

// ---------------- 6. scores ----------------
__global__ __launch_bounds__(256) void score_kernel(
    const float* __restrict__ hu, const float* __restrict__ hi,
    const int* __restrict__ pu, const int* __restrict__ pi,
    const int* __restrict__ nu, const int* __restrict__ ni,
    void* __restrict__ out, const float* __restrict__ flag) {
  int isf32 = *flag > 0.5f;
  int w = (blockIdx.x * 256 + threadIdx.x) >> 6;
  int lane = threadIdx.x & 63;
  int uu, ii;
  if (w < EP_) { uu = pu[w]; ii = pi[w]; }
  else         { uu = nu[w - EP_]; ii = ni[w - EP_]; }
  float p = hu[(size_t)uu * 64 + lane] * hi[(size_t)ii * 64 + lane];
  #pragma unroll
  for (int off = 32; off; off >>= 1) p += __shfl_xor(p, off, 64);
  if (lane == 0) {
    if (isf32) ((float*)out)[w] = p;
    else       ((__hip_bfloat16*)out)[w] = __float2bfloat16(p);
  }
}

__global__ void finalize_kernel(const float* __restrict__ loss_acc,
                                void* __restrict__ out,
                                const float* __restrict__ flag) {
  float v = loss_acc[0] * (1.0f / (float)(2 * CB_ * NCHUNK_));
  if (*flag > 0.5f) ((float*)out)[2 * EP_] = v;
  else              ((__hip_bfloat16*)out)[2 * EP_] = __float2bfloat16(v);
}

// ---------------- launch ----------------
extern "C" void kernel_launch(void* const* d_in, const int* in_sizes, int n_in,
                              void* d_out, int out_size, void* d_ws, size_t ws_size,
                              hipStream_t stream) {
  const void* ue  = d_in[0];
  const void* ie  = d_in[1];
  const void* W   = d_in[2];
  const void* a   = d_in[3];
  const void* WU  = d_in[4];
  const void* aU  = d_in[5];
  const void* cw  = d_in[6];
  const int* rs  = (const int*)d_in[7];
  const int* rd  = (const int*)d_in[8];
  const int* pu  = (const int*)d_in[9];
  const int* pi  = (const int*)d_in[10];
  const int* nu  = (const int*)d_in[11];
  const int* ni  = (const int*)d_in[12];
  const int* nbr = (const int*)d_in[13];

  float* wsf  = (float*)d_ws;
  int*   wsi  = (int*)d_ws;
  float* loss = wsf + OFF_LOSS;
  float* flag = wsf + OFF_FLAG;
  int* gallocU = wsi + 4;
  int* dcntU   = wsi + 5;
  int* gallocI = wsi + 6;
  int* dcntI   = wsi + 7;
  float* vecs = wsf + OFF_VEC;
  int*   cnt  = wsi + OFF_CNT;
  int*   rtmp = wsi + OFF_RTMP;
  int*   bsum = wsi + OFF_BSUM;
  int*   boff = wsi + OFF_BOFF;
  int*   rowU = wsi + OFF_ROWU;
  int*   rowI = wsi + OFF_ROWI;
  int*   dirU = wsi + OFF_DIRU;
  int*   dirI = wsi + OFF_DIRI;
  int*   csrU = wsi + OFF_CSRU;
  int*   csrI = wsi + OFF_CSRI;
  float* u1   = wsf + OFF_U1;
  float* i1   = wsf + OFF_I1;
  float* hu   = wsf + OFF_HU;
  float* hi   = wsf + OFF_HI;
  float* anc  = wsf + OFF_ANC;
  unsigned long long* bufU = (unsigned long long*)(wsf + OFF_HU);
  unsigned long long* bufI = (unsigned long long*)(wsf + OFF_HI);

  hipMemsetAsync(d_ws, 0, MEMSET_BYTES, stream);
  prep_kernel<<<1, 64, 0, stream>>>((const unsigned short*)ue, W, a, WU, aU, vecs, flag);

  // CSR build
  bucketA_kernel<<<NBA_, 256, 0, stream>>>(rs, rd, bufU, gallocU, dirU, dcntU, 9, cnt, 1);
  bucketA_kernel<<<NBA_, 256, 0, stream>>>(rd, rs, bufI, gallocI, dirI, dcntI, 8, cnt, 0);
  scanA_kernel<<<NB_, 256, 0, stream>>>(cnt, rtmp, bsum);
  scanB_kernel<<<1, 64, 0, stream>>>(bsum, boff);
  scanC_kernel<<<NB_, 256, 0, stream>>>(rtmp, boff, rowU, rowI);
  bucketB_kernel<<<NBK_, 256, 0, stream>>>(bufU, dirU, dcntU, rowU, csrU, 512);
  bucketB_kernel<<<NBK_, 256, 0, stream>>>(bufI, dirI, dcntI, rowI, csrI, 256);

  // layer-1 aggregation (gather)
  agg1_kernel<<<I_ / 4, 256, 0, stream>>>(ue, rowI, csrI, i1, flag);
  agg1_kernel<<<U_ / 4, 256, 0, stream>>>(ie, rowU, csrU, u1, flag);

  // layer-2 aggregation + fused layer attention
  agg2attn_kernel<<<I_ / 4, 256, 0, stream>>>(u1, ie, i1, rowI, csrI, vecs, hi, flag);
  agg2attn_kernel<<<U_ / 4, 256, 0, stream>>>(i1, ue, u1, rowU, csrU, vecs, hu, flag);

  // anchor path
  anchor_kernel<<<U_ / 4, 256, 0, stream>>>(ue, WU, cw, vecs, nbr, anc, flag);

  // contrastive loss (MFMA Gram)
  contrast_kernel<<<NCHUNK_ * 4, 256, 0, stream>>>(hu, anc, loss);

  // scores
  score_kernel<<<(2 * EP_ * 64) / 256, 256, 0, stream>>>(hu, hi, pu, pi, nu, ni, d_out, flag);
  finalize_kernel<<<1, 1, 0, stream>>>(loss, d_out, flag);
}

// Round 8
// 715.300 us; speedup vs baseline: 1.1504x; 1.0226x over previous
//
#include <hip/hip_runtime.h>
#include <hip/hip_bf16.h>

// ---------------- problem constants ----------------
constexpr int U_  = 51200;
constexpr int I_  = 25600;
constexpr int E_  = 1000000;
constexpr int EP_ = 100000;
constexpr int CB_ = 256;                 // contrastive chunk size
constexpr int NCHUNK_ = U_ / CB_;        // 200
constexpr size_t UD_ = (size_t)U_ * 64;
constexpr size_t ID_ = (size_t)I_ * 64;
constexpr int NBK_ = 100;                // coarse buckets per side
constexpr int TILE_ = 4096;              // edges per Phase-A block
constexpr int NBA_ = (E_ + TILE_ - 1) / TILE_;  // 245
constexpr int DIRCAP_ = NBA_ * NBK_;     // 24500 entries max

// ---------------- workspace layout (4-byte element offsets) ----------------
constexpr size_t OFF_LOSS  = 0;
constexpr size_t OFF_FLAG  = 1;
// counters: 4=gallocU 5=dcntU 6=gallocI 7=dcntI
constexpr size_t OFF_BTOTU = 8;                      // 100 ints (bucket totals U)
constexpr size_t OFF_BTOTI = 108;                    // 100 ints (bucket totals I)
constexpr size_t MEMSET_BYTES = 208 * 4;             // zero loss/flag/counters/btot
constexpr size_t OFF_VEC   = 256;                    // 192 floats: Wa | vU1 | vU2
constexpr size_t OFF_BBASEU= 512;                    // 101 ints
constexpr size_t OFF_BBASEI= 640;                    // 101 ints
constexpr size_t OFF_ROWU  = 768;                    // U_+1
constexpr size_t OFF_ROWI  = ((OFF_ROWU + U_ + 1 + 63) / 64) * 64;   // I_+1
constexpr size_t OFF_DIRU  = ((OFF_ROWI + I_ + 1 + 63) / 64) * 64;   // 4*DIRCAP_
constexpr size_t OFF_DIRI  = ((OFF_DIRU + 4 * DIRCAP_ + 63) / 64) * 64;
constexpr size_t OFF_CSRU  = ((OFF_DIRI + 4 * DIRCAP_ + 63) / 64) * 64;  // E_
constexpr size_t OFF_CSRI  = OFF_CSRU + E_;          // E_
constexpr size_t OFF_U1    = ((OFF_CSRI + E_ + 63) / 64) * 64;
constexpr size_t OFF_I1    = OFF_U1 + UD_;
constexpr size_t OFF_HU    = OFF_I1 + ID_;           // bufU (E_ uints) aliases here
constexpr size_t OFF_HI    = OFF_HU + UD_;           // bufI aliases here
constexpr size_t OFF_ANC   = OFF_HI + ID_;
// total ≈ 61.5 MB

#define DEVI static __device__ __forceinline__

typedef _Float16 h2v __attribute__((ext_vector_type(2)));
typedef _Float16 f16x8 __attribute__((ext_vector_type(8)));
typedef float floatx4 __attribute__((ext_vector_type(4)));

DEVI float b2f(__hip_bfloat16 x) { return __bfloat162float(x); }

DEVI float ldf(const void* p, size_t i, int isf32) {
  if (isf32) return ((const float*)p)[i];
  return b2f(((const __hip_bfloat16*)p)[i]);
}

DEVI float frcp(float x) { return __builtin_amdgcn_rcpf(x); }

DEVI int waveInclScan(int v, int lane) {
  #pragma unroll
  for (int off = 1; off < 64; off <<= 1) {
    int t = __shfl_up(v, off, 64);
    if (lane >= off) v += t;
  }
  return v;
}

// ---------------- 0. prep: dtype detection + Wa/vU1/vU2 precompute ----------------
__global__ void prep_kernel(const unsigned short* __restrict__ ueu,
                            const void* __restrict__ W, const void* __restrict__ a,
                            const void* __restrict__ WU, const void* __restrict__ aU,
                            float* __restrict__ vecs, float* __restrict__ flag) {
  int cnt = 0;
  for (int i = 0; i < 256; i++) {
    int e = (ueu[i] >> 7) & 0xFF;
    if (e >= 130) cnt++;
  }
  int isf32 = (cnt >= 8);
  if (threadIdx.x == 0) *flag = isf32 ? 1.0f : 0.0f;
  int d = threadIdx.x;  // 64 threads
  float s = 0.f, t1 = 0.f, t2 = 0.f;
  for (int e = 0; e < 64; e++) {
    s += ldf(W, d * 64 + e, isf32) * ldf(a, e, isf32);
    float wue = ldf(WU, d * 64 + e, isf32);
    t1 += wue * ldf(aU, e, isf32);
    t2 += wue * ldf(aU, 64 + e, isf32);
  }
  vecs[d] = s;          // Wa
  vecs[64 + d] = t1;    // vU1
  vecs[128 + d] = t2;   // vU2
}

// ---------------- 1a. Phase A: bucket edges into chunked 32-bit record buffer ----
// rec = (localKey << 17) | payload.  localKey = key & (kpb-1), bucket = key>>shift.
// Per-(block,bucket) chunks recorded in a directory; bucket totals accumulated.
__global__ __launch_bounds__(256) void bucketA_kernel(
    const int* __restrict__ key, const int* __restrict__ payload,
    unsigned* __restrict__ buf, int* __restrict__ galloc,
    int* __restrict__ dir, int* __restrict__ dcnt, int* __restrict__ btot,
    int shift) {
  __shared__ int hist[NBK_], loff[NBK_ + 1], cbase[NBK_], lcur[NBK_];
  __shared__ unsigned recs[TILE_];
  int tid = threadIdx.x;
  int base = blockIdx.x * TILE_;
  int lmask = (1 << shift) - 1;
  for (int i = tid; i < NBK_; i += 256) hist[i] = 0;
  __syncthreads();
  int kk[16], pp[16];
  #pragma unroll
  for (int t = 0; t < 16; t++) {
    int e = base + t * 256 + tid;
    bool v = e < E_;
    kk[t] = v ? key[e] : -1;
    pp[t] = v ? payload[e] : 0;
    if (v) atomicAdd(&hist[kk[t] >> shift], 1);
  }
  __syncthreads();
  if (tid < NBK_) {
    int c = hist[tid];
    int gb = 0;
    if (c > 0) {
      gb = atomicAdd(galloc, c);
      int di = atomicAdd(dcnt, 1);
      dir[di * 4]     = tid;
      dir[di * 4 + 1] = gb;
      dir[di * 4 + 2] = c;
      atomicAdd(&btot[tid], c);
    }
    cbase[tid] = gb;
  }
  __syncthreads();
  if (tid == 0) {
    int run = 0;
    for (int b = 0; b < NBK_; b++) { loff[b] = run; run += hist[b]; }
    loff[NBK_] = run;
  }
  __syncthreads();
  if (tid < NBK_) lcur[tid] = loff[tid];
  __syncthreads();
  #pragma unroll
  for (int t = 0; t < 16; t++) {
    if (kk[t] >= 0) {
      int b = kk[t] >> shift;
      int p = atomicAdd(&lcur[b], 1);
      recs[p] = ((unsigned)(kk[t] & lmask) << 17) | (unsigned)pp[t];
    }
  }
  __syncthreads();
  int total = loff[NBK_];
  for (int p = tid; p < total; p += 256) {
    int lo = 0, hi = NBK_;
    while (hi - lo > 1) { int mid = (lo + hi) >> 1; if (loff[mid] <= p) lo = mid; else hi = mid; }
    buf[cbase[lo] + (p - loff[lo])] = recs[p];
  }
}

// ---------------- 1b. tiny scan of bucket totals -> bucket bases + sentinels ----
__global__ void scanBuckets_kernel(const int* __restrict__ btotU,
                                   const int* __restrict__ btotI,
                                   int* __restrict__ bbaseU, int* __restrict__ bbaseI,
                                   int* __restrict__ rowU, int* __restrict__ rowI) {
  if (threadIdx.x == 0) {
    int run = 0;
    for (int i = 0; i < NBK_; i++) { bbaseU[i] = run; run += btotU[i]; }
    bbaseU[NBK_] = run;
    run = 0;
    for (int i = 0; i < NBK_; i++) { bbaseI[i] = run; run += btotI[i]; }
    bbaseI[NBK_] = run;
    rowU[U_] = E_;
    rowI[I_] = E_;
  }
}

// ---------------- 1c. Phase B: local hist+scan -> rowptr slice + CSR fill -------
__global__ __launch_bounds__(256) void bucketB_kernel(
    const unsigned* __restrict__ buf,
    const int* __restrict__ dir, const int* __restrict__ dcnt,
    const int* __restrict__ bbase, int* __restrict__ rowptr, int* __restrict__ csr,
    int kpb) {                     // keys per bucket: 512 (U) or 256 (I)
  __shared__ int stage[16384];     // 64 KB payload staging
  __shared__ int cntk[512], offk[512];
  __shared__ int est[512], eln[512], epre[513];
  __shared__ int lcnt, wsum[4];
  int tid = threadIdx.x, b = blockIdx.x;
  if (tid == 0) lcnt = 0;
  for (int k = tid; k < kpb; k += 256) cntk[k] = 0;
  __syncthreads();
  // gather this bucket's chunk directory entries
  int nd = *dcnt;
  for (int i = tid; i < nd; i += 256) {
    if (dir[i * 4] == b) {
      int li = atomicAdd(&lcnt, 1);
      est[li] = dir[i * 4 + 1];
      eln[li] = dir[i * 4 + 2];
    }
  }
  __syncthreads();
  if (tid == 0) {
    int run = 0;
    for (int i = 0; i < lcnt; i++) { epre[i] = run; run += eln[i]; }
    epre[lcnt] = run;
  }
  __syncthreads();
  int ne = lcnt, total = epre[ne];
  // pass 1: local key histogram
  for (int r = tid; r < total; r += 256) {
    int lo = 0, hi = ne;
    while (hi - lo > 1) { int mid = (lo + hi) >> 1; if (epre[mid] <= r) lo = mid; else hi = mid; }
    unsigned rec = buf[(size_t)est[lo] + (r - epre[lo])];
    atomicAdd(&cntk[rec >> 17], 1);
  }
  __syncthreads();
  // exclusive scan over kpb keys (kpt = 1 or 2 keys/thread)
  int kpt = kpb >> 8;
  int lane = tid & 63, wv = tid >> 6;
  int c0 = cntk[tid * kpt];
  int c1 = (kpt == 2) ? cntk[tid * kpt + 1] : 0;
  int s = c0 + c1;
  int incl = waveInclScan(s, lane);
  if (lane == 63) wsum[wv] = incl;
  __syncthreads();
  int wvoff = 0;
  for (int w = 0; w < wv; w++) wvoff += wsum[w];
  int excl = wvoff + incl - s;
  int bb = bbase[b];
  offk[tid * kpt] = excl;
  rowptr[b * kpb + tid * kpt] = bb + excl;
  if (kpt == 2) {
    offk[tid * kpt + 1] = excl + c0;
    rowptr[b * kpb + tid * kpt + 1] = bb + excl + c0;
  }
  __syncthreads();
  // pass 2: place payloads into LDS stage at exact slots
  for (int r = tid; r < total; r += 256) {
    int lo = 0, hi = ne;
    while (hi - lo > 1) { int mid = (lo + hi) >> 1; if (epre[mid] <= r) lo = mid; else hi = mid; }
    unsigned rec = buf[(size_t)est[lo] + (r - epre[lo])];
    int slot = atomicAdd(&offk[rec >> 17], 1);
    if (slot < 16384) stage[slot] = (int)(rec & 0x1FFFFu);
  }
  __syncthreads();
  // contiguous coalesced CSR write
  for (int s2 = tid; s2 < total; s2 += 256) csr[bb + s2] = stage[s2];
}

// ---------------- 2. layer-1 aggregation ----------------
__global__ __launch_bounds__(256) void agg1_kernel(
    const void* __restrict__ src, const int* __restrict__ row,
    const int* __restrict__ csr, float* __restrict__ out,
    const float* __restrict__ flag) {
  int isf32 = *flag > 0.5f;
  int wv = threadIdx.x >> 6, lane = threadIdx.x & 63;
  int r = blockIdx.x * 4 + wv;
  int s0 = row[r], s1 = row[r + 1];
  float acc = 0.f;
  int j = s0;
  for (; j + 4 <= s1; j += 4) {
    int a = csr[j], b = csr[j + 1], c = csr[j + 2], d = csr[j + 3];
    float va = ldf(src, (size_t)a * 64 + lane, isf32);
    float vb = ldf(src, (size_t)b * 64 + lane, isf32);
    float vc = ldf(src, (size_t)c * 64 + lane, isf32);
    float vd = ldf(src, (size_t)d * 64 + lane, isf32);
    acc += (va + vb) + (vc + vd);
  }
  for (; j < s1; j++) acc += ldf(src, (size_t)csr[j] * 64 + lane, isf32);
  out[(size_t)r * 64 + lane] = acc / fmaxf((float)(s1 - s0), 1.0f);
}

// ---------------- 3. layer-2 aggregation + fused layer attention ----------------
__global__ __launch_bounds__(256) void agg2attn_kernel(
    const float* __restrict__ opp1, const void* __restrict__ base,
    const float* __restrict__ own1,
    const int* __restrict__ row, const int* __restrict__ csr,
    const float* __restrict__ Wa, float* __restrict__ h,
    const float* __restrict__ flag) {
  int isf32 = *flag > 0.5f;
  int wv = threadIdx.x >> 6, lane = threadIdx.x & 63;
  int r = blockIdx.x * 4 + wv;
  int s0 = row[r], s1 = row[r + 1];
  float acc = 0.f;
  int j = s0;
  for (; j + 4 <= s1; j += 4) {
    int a = csr[j], b = csr[j + 1], c = csr[j + 2], d = csr[j + 3];
    float va = opp1[(size_t)a * 64 + lane];
    float vb = opp1[(size_t)b * 64 + lane];
    float vc = opp1[(size_t)c * 64 + lane];
    float vd = opp1[(size_t)d * 64 + lane];
    acc += (va + vb) + (vc + vd);
  }
  for (; j < s1; j++) acc += opp1[(size_t)csr[j] * 64 + lane];
  size_t idx = (size_t)r * 64 + lane;
  float t2 = acc / fmaxf((float)(s1 - s0), 1.0f);
  float t0 = ldf(base, idx, isf32);
  float t1 = own1[idx];
  float w = Wa[lane];
  float p0 = t0 * w, p1 = t1 * w, p2 = t2 * w;
  #pragma unroll
  for (int off = 32; off; off >>= 1) {
    p0 += __shfl_xor(p0, off, 64);
    p1 += __shfl_xor(p1, off, 64);
    p2 += __shfl_xor(p2, off, 64);
  }
  float m = fmaxf(p0, fmaxf(p1, p2));
  float e0 = __expf(p0 - m), e1 = __expf(p1 - m), e2 = __expf(p2 - m);
  float inv = 1.0f / (e0 + e1 + e2);
  h[idx] = (t0 * e0 + t1 * e1 + t2 * e2) * inv;
}

// ---------------- 4. anchor user embed (FFT filter + collapsed attention) -------
__global__ __launch_bounds__(256) void anchor_kernel(
    const void* __restrict__ ue, const void* __restrict__ WU,
    const void* __restrict__ cw, const float* __restrict__ vecs,
    const int* __restrict__ nbr, float* __restrict__ out,
    const float* __restrict__ flag) {
  int isf32 = *flag > 0.5f;
  __shared__ __align__(16) float2 wu2[32][64];  // 16KB
  __shared__ __align__(16) float mixS[4][64];
  int tid = threadIdx.x;
  int wv = tid >> 6, lane = tid & 63;
  int u = blockIdx.x * 4 + wv;

  for (int idx = tid; idx < 2048; idx += 256) {
    int dp = idx >> 6, n = idx & 63;
    wu2[dp][n] = make_float2(ldf(WU, (size_t)(2 * dp) * 64 + n, isf32),
                             ldf(WU, (size_t)(2 * dp + 1) * 64 + n, isf32));
  }

  float x[8];
  #pragma unroll
  for (int k = 0; k < 8; k++) {
    int nb = nbr[u * 8 + k];
    x[k] = ldf(ue, (size_t)nb * 64 + lane, isf32);
  }
  const float c1 = 0.70710678118654752440f;
  float sA = x[1] - x[3] - x[5] + x[7];
  float sB = x[1] + x[3] - x[5] - x[7];
  float ev = (x[0] + x[4]) + (x[2] + x[6]);
  float od = (x[1] + x[5]) + (x[3] + x[7]);
  float d04 = x[0] - x[4], d26 = x[2] - x[6];
  float X0r = ev + od;
  float X1r = d04 + c1 * sA;
  float X1i = -d26 - c1 * sB;
  float X2r = (x[0] + x[4]) - (x[2] + x[6]);
  float X2i = -(x[1] - x[3] + x[5] - x[7]);
  float X3r = d04 - c1 * sA;
  float X3i = d26 - c1 * sB;
  float X4r = ev - od;
  float Zr0 = X0r * ldf(cw, (0 * 64 + lane) * 2, isf32);
  float w1r = ldf(cw, (1 * 64 + lane) * 2, isf32), w1i = ldf(cw, (1 * 64 + lane) * 2 + 1, isf32);
  float Zr1 = X1r * w1r - X1i * w1i, Zi1 = X1r * w1i + X1i * w1r;
  float w2r = ldf(cw, (2 * 64 + lane) * 2, isf32), w2i = ldf(cw, (2 * 64 + lane) * 2 + 1, isf32);
  float Zr2 = X2r * w2r - X2i * w2i, Zi2 = X2r * w2i + X2i * w2r;
  float w3r = ldf(cw, (3 * 64 + lane) * 2, isf32), w3i = ldf(cw, (3 * 64 + lane) * 2 + 1, isf32);
  float Zr3 = X3r * w3r - X3i * w3i, Zi3 = X3r * w3i + X3i * w3r;
  float Zr4 = X4r * ldf(cw, (4 * 64 + lane) * 2, isf32);
  float eP = Zr0 + Zr4, eM = Zr0 - Zr4;
  float t1 = c1 * (Zr1 - Zr3), t2 = c1 * (Zi1 + Zi3);
  float y[8];
  y[0] = eP + 2.f * (Zr1 + Zr2 + Zr3);
  y[1] = eM + 2.f * (t1 - t2 - Zi2);
  y[2] = eP + 2.f * (-Zi1 - Zr2 + Zi3);
  y[3] = eM + 2.f * (-t1 - t2 + Zi2);
  y[4] = eP + 2.f * (-Zr1 + Zr2 - Zr3);
  y[5] = eM + 2.f * (-t1 + t2 - Zi2);
  y[6] = eP + 2.f * (Zi1 - Zr2 - Zi3);
  y[7] = eM + 2.f * (t1 + t2 + Zi2);
  #pragma unroll
  for (int k = 0; k < 8; k++) y[k] *= 0.125f;

  float v1 = vecs[64 + lane], v2 = vecs[128 + lane];
  float ek[8];
  #pragma unroll
  for (int k = 0; k < 8; k++) ek[k] = y[k] * v1;
  float q = ldf(ue, (size_t)u * 64 + lane, isf32) * v2;
  #pragma unroll
  for (int off = 32; off; off >>= 1) {
    #pragma unroll
    for (int k = 0; k < 8; k++) ek[k] += __shfl_xor(ek[k], off, 64);
    q += __shfl_xor(q, off, 64);
  }
  float m = -1e30f;
  #pragma unroll
  for (int k = 0; k < 8; k++) {
    float v = ek[k] + q;
    v = v > 0.f ? v : 0.1f * v;
    ek[k] = v;
    m = fmaxf(m, v);
  }
  float se = 0.f, wexp[8];
  #pragma unroll
  for (int k = 0; k < 8; k++) { wexp[k] = __expf(ek[k] - m); se += wexp[k]; }
  float mix = 0.f;
  #pragma unroll
  for (int k = 0; k < 8; k++) mix += wexp[k] * y[k];
  mixS[wv][lane] = mix;
  __syncthreads();

  float acc = 0.f;
  const float4* mrow = (const float4*)mixS[wv];
  #pragma unroll
  for (int it = 0; it < 16; it++) {
    float4 m4 = mrow[it];
    float2 w0 = wu2[2 * it][lane];
    float2 w1 = wu2[2 * it + 1][lane];
    acc += m4.x * w0.x + m4.y * w0.y + m4.z * w1.x + m4.w * w1.y;
  }
  out[(size_t)u * 64 + lane] = acc / se;
}

// ---------------- 5. contrastive loss via MFMA Gram matrix ----------------
constexpr int XS_ = 72;  // f16 row stride (144 B: 16B-aligned, uniform banks)
__global__ __launch_bounds__(256) void contrast_kernel(
    const float* __restrict__ hu, const float* __restrict__ an,
    float* __restrict__ loss_acc) {
  __shared__ __align__(16) _Float16 Xh[512 * XS_];  // 72 KB
  __shared__ float Nn[512];
  int tid = threadIdx.x;
  int c = blockIdx.x >> 2, sl = blockIdx.x & 3;

  const float* r1 = hu + ((size_t)c * CB_ + tid) * 64;
  const float* r2 = an + ((size_t)c * CB_ + tid) * 64;
  float4 a4[16], b4[16];
  float s1 = 0.f, s2 = 0.f;
  #pragma unroll
  for (int t = 0; t < 16; t++) {
    a4[t] = ((const float4*)r1)[t];
    s1 += a4[t].x * a4[t].x + a4[t].y * a4[t].y + a4[t].z * a4[t].z + a4[t].w * a4[t].w;
    b4[t] = ((const float4*)r2)[t];
    s2 += b4[t].x * b4[t].x + b4[t].y * b4[t].y + b4[t].z * b4[t].z + b4[t].w * b4[t].w;
  }
  float n1 = sqrtf(s1), n2 = sqrtf(s2);
  float inv1 = frcp(n1), inv2 = frcp(n2);
  Nn[tid] = n1; Nn[256 + tid] = n2;
  #pragma unroll
  for (int t = 0; t < 8; t++) {
    f16x8 v;
    v[0] = (_Float16)(a4[2*t].x * inv1);   v[1] = (_Float16)(a4[2*t].y * inv1);
    v[2] = (_Float16)(a4[2*t].z * inv1);   v[3] = (_Float16)(a4[2*t].w * inv1);
    v[4] = (_Float16)(a4[2*t+1].x * inv1); v[5] = (_Float16)(a4[2*t+1].y * inv1);
    v[6] = (_Float16)(a4[2*t+1].z * inv1); v[7] = (_Float16)(a4[2*t+1].w * inv1);
    *(f16x8*)&Xh[tid * XS_ + t * 8] = v;
    f16x8 w;
    w[0] = (_Float16)(b4[2*t].x * inv2);   w[1] = (_Float16)(b4[2*t].y * inv2);
    w[2] = (_Float16)(b4[2*t].z * inv2);   w[3] = (_Float16)(b4[2*t].w * inv2);
    w[4] = (_Float16)(b4[2*t+1].x * inv2); w[5] = (_Float16)(b4[2*t+1].y * inv2);
    w[6] = (_Float16)(b4[2*t+1].z * inv2); w[7] = (_Float16)(b4[2*t+1].w * inv2);
    *(f16x8*)&Xh[(256 + tid) * XS_ + t * 8] = w;
  }
  __syncthreads();

  int l = tid & 63, w = tid >> 6;
  int n = l & 15, q = l >> 4;
  int rb = sl * 128 + w * 32;
  f16x8 A[2][2];
  #pragma unroll
  for (int t = 0; t < 2; t++)
    #pragma unroll
    for (int h = 0; h < 2; h++)
      A[t][h] = *(const f16x8*)&Xh[(rb + t * 16 + n) * XS_ + h * 32 + q * 8];
  float NiR[2][4];
  #pragma unroll
  for (int t = 0; t < 2; t++)
    #pragma unroll
    for (int r = 0; r < 4; r++)
      NiR[t][r] = Nn[rb + t * 16 + q * 4 + r];
  float sums[2][4] = {{0,0,0,0},{0,0,0,0}};
  float labs[2][4] = {{0,0,0,0},{0,0,0,0}};
  const floatx4 zero = {0.f, 0.f, 0.f, 0.f};
  for (int ct = 0; ct < 32; ct++) {
    int cb = ct * 16;
    f16x8 B0 = *(const f16x8*)&Xh[(cb + n) * XS_ + q * 8];
    f16x8 B1 = *(const f16x8*)&Xh[(cb + n) * XS_ + 32 + q * 8];
    floatx4 acc0 = __builtin_amdgcn_mfma_f32_16x16x32_f16(A[0][0], B0, zero, 0, 0, 0);
    acc0 = __builtin_amdgcn_mfma_f32_16x16x32_f16(A[0][1], B1, acc0, 0, 0, 0);
    floatx4 acc1 = __builtin_amdgcn_mfma_f32_16x16x32_f16(A[1][0], B0, zero, 0, 0, 0);
    acc1 = __builtin_amdgcn_mfma_f32_16x16x32_f16(A[1][1], B1, acc1, 0, 0, 0);
    int j = cb + n;
    float Nj = Nn[j];
    #pragma unroll
    for (int t = 0; t < 2; t++) {
      #pragma unroll
      for (int r = 0; r < 4; r++) {
        int i = rb + t * 16 + q * 4 + r;
        float G = (t == 0) ? acc0[r] : acc1[r];
        float p = NiR[t][r] * Nj;
        float s = 5.0f * G * p * frcp(p + 1e-6f);
        float e = (j == i) ? 0.f : __expf(s);
        sums[t][r] += e;
        labs[t][r] += (j == (i ^ 256)) ? s : 0.f;
      }
    }
  }
  #pragma unroll
  for (int off = 1; off <= 8; off <<= 1) {
    #pragma unroll
    for (int t = 0; t < 2; t++)
      #pragma unroll
      for (int r = 0; r < 4; r++) {
        sums[t][r] += __shfl_xor(sums[t][r], off, 64);
        labs[t][r] += __shfl_xor(labs[t][r], off, 64);
      }
  }
  float part = 0.f;
  if (n == 0) {
    #pragma unroll
    for (int t = 0; t < 2; t++)
      #pragma unroll
      for (int r = 0; r < 4; r++)
        part += __logf(sums[t][r]) - labs[t][r];
  }
  #pragma unroll
  for (int off = 1; off < 64; off <<= 1) part += __shfl_xor(part, off, 64);
  if (l == 0) atomicAdd(loss_acc, part);
}

// ---------------- 6. scores ----------------
__global__ __launch_bounds__(256) void score_kernel(
    const float* __restrict__ hu, const float* __restrict__ hi,
    const int* __restrict__ pu, const int* __restrict__ pi,
    const int* __restrict__ nu, const int* __restrict__ ni,
    void* __restrict__ out, const float* __restrict__ flag) {
  int isf32 = *flag > 0.5f;
  int w = (blockIdx.x * 256 + threadIdx.x) >> 6;
  int lane = threadIdx.x & 63;
  int uu, ii;
  if (w < EP_) { uu = pu[w]; ii = pi[w]; }
  else         { uu = nu[w - EP_]; ii = ni[w - EP_]; }
  float p = hu[(size_t)uu * 64 + lane] * hi[(size_t)ii * 64 + lane];
  #pragma unroll
  for (int off = 32; off; off >>= 1) p += __shfl_xor(p, off, 64);
  if (lane == 0) {
    if (isf32) ((float*)out)[w] = p;
    else       ((__hip_bfloat16*)out)[w] = __float2bfloat16(p);
  }
}

__global__ void finalize_kernel(const float* __restrict__ loss_acc,
                                void* __restrict__ out,
                                const float* __restrict__ flag) {
  float v = loss_acc[0] * (1.0f / (float)(2 * CB_ * NCHUNK_));
  if (*flag > 0.5f) ((float*)out)[2 * EP_] = v;
  else              ((__hip_bfloat16*)out)[2 * EP_] = __float2bfloat16(v);
}

// ---------------- launch ----------------
extern "C" void kernel_launch(void* const* d_in, const int* in_sizes, int n_in,
                              void* d_out, int out_size, void* d_ws, size_t ws_size,
                              hipStream_t stream) {
  const void* ue  = d_in[0];
  const void* ie  = d_in[1];
  const void* W   = d_in[2];
  const void* a   = d_in[3];
  const void* WU  = d_in[4];
  const void* aU  = d_in[5];
  const void* cw  = d_in[6];
  const int* rs  = (const int*)d_in[7];
  const int* rd  = (const int*)d_in[8];
  const int* pu  = (const int*)d_in[9];
  const int* pi  = (const int*)d_in[10];
  const int* nu  = (const int*)d_in[11];
  const int* ni  = (const int*)d_in[12];
  const int* nbr = (const int*)d_in[13];

  float* wsf  = (float*)d_ws;
  int*   wsi  = (int*)d_ws;
  float* loss = wsf + OFF_LOSS;
  float* flag = wsf + OFF_FLAG;
  int* gallocU = wsi + 4;
  int* dcntU   = wsi + 5;
  int* gallocI = wsi + 6;
  int* dcntI   = wsi + 7;
  int* btotU   = wsi + OFF_BTOTU;
  int* btotI   = wsi + OFF_BTOTI;
  float* vecs  = wsf + OFF_VEC;
  int* bbaseU  = wsi + OFF_BBASEU;
  int* bbaseI  = wsi + OFF_BBASEI;
  int* rowU    = wsi + OFF_ROWU;
  int* rowI    = wsi + OFF_ROWI;
  int* dirU    = wsi + OFF_DIRU;
  int* dirI    = wsi + OFF_DIRI;
  int* csrU    = wsi + OFF_CSRU;
  int* csrI    = wsi + OFF_CSRI;
  float* u1    = wsf + OFF_U1;
  float* i1    = wsf + OFF_I1;
  float* hu    = wsf + OFF_HU;
  float* hi    = wsf + OFF_HI;
  float* anc   = wsf + OFF_ANC;
  unsigned* bufU = (unsigned*)(wsf + OFF_HU);
  unsigned* bufI = (unsigned*)(wsf + OFF_HI);

  hipMemsetAsync(d_ws, 0, MEMSET_BYTES, stream);
  prep_kernel<<<1, 64, 0, stream>>>((const unsigned short*)ue, W, a, WU, aU, vecs, flag);

  // CSR build (bucket sort, no global fine histogram)
  bucketA_kernel<<<NBA_, 256, 0, stream>>>(rs, rd, bufU, gallocU, dirU, dcntU, btotU, 9);
  bucketA_kernel<<<NBA_, 256, 0, stream>>>(rd, rs, bufI, gallocI, dirI, dcntI, btotI, 8);
  scanBuckets_kernel<<<1, 64, 0, stream>>>(btotU, btotI, bbaseU, bbaseI, rowU, rowI);
  bucketB_kernel<<<NBK_, 256, 0, stream>>>(bufU, dirU, dcntU, bbaseU, rowU, csrU, 512);
  bucketB_kernel<<<NBK_, 256, 0, stream>>>(bufI, dirI, dcntI, bbaseI, rowI, csrI, 256);

  // layer-1 aggregation (gather)
  agg1_kernel<<<I_ / 4, 256, 0, stream>>>(ue, rowI, csrI, i1, flag);
  agg1_kernel<<<U_ / 4, 256, 0, stream>>>(ie, rowU, csrU, u1, flag);

  // layer-2 aggregation + fused layer attention
  agg2attn_kernel<<<I_ / 4, 256, 0, stream>>>(u1, ie, i1, rowI, csrI, vecs, hi, flag);
  agg2attn_kernel<<<U_ / 4, 256, 0, stream>>>(i1, ue, u1, rowU, csrU, vecs, hu, flag);

  // anchor path
  anchor_kernel<<<U_ / 4, 256, 0, stream>>>(ue, WU, cw, vecs, nbr, anc, flag);

  // contrastive loss (MFMA Gram)
  contrast_kernel<<<NCHUNK_ * 4, 256, 0, stream>>>(hu, anc, loss);

  // scores
  score_kernel<<<(2 * EP_ * 64) / 256, 256, 0, stream>>>(hu, hi, pu, pi, nu, ni, d_out, flag);
  finalize_kernel<<<1, 1, 0, stream>>>(loss, d_out, flag);
}

// Round 9
// 504.704 us; speedup vs baseline: 1.6304x; 1.4173x over previous
//
#include <hip/hip_runtime.h>
#include <hip/hip_bf16.h>

// ---------------- problem constants ----------------
constexpr int U_  = 51200;
constexpr int I_  = 25600;
constexpr int E_  = 1000000;
constexpr int EP_ = 100000;
constexpr int CB_ = 256;                 // contrastive chunk size
constexpr int NCHUNK_ = U_ / CB_;        // 200
constexpr size_t UD_ = (size_t)U_ * 64;
constexpr size_t ID_ = (size_t)I_ * 64;
constexpr int NBK_ = 200;                // buckets per side
constexpr int CAP_ = 8192;               // record slots per bucket (+45 sigma)
constexpr int TILE_ = 4096;              // edges per Phase-A block
constexpr int NBA_ = (E_ + TILE_ - 1) / TILE_;  // 245

// ---------------- workspace layout (4-byte element offsets) ----------------
constexpr size_t OFF_LOSS  = 0;
constexpr size_t OFF_FLAG  = 1;
constexpr size_t OFF_CURU  = 8;                      // 200 ints (bucket cursors U)
constexpr size_t OFF_CURI  = 208;                    // 200 ints (bucket cursors I)
constexpr size_t MEMSET_BYTES = 408 * 4;             // zero loss/flag/cursors
constexpr size_t OFF_VEC   = 448;                    // 192 floats: Wa | vU1 | vU2
constexpr size_t OFF_BBU   = 640;                    // 201 ints (bucket bases U)
constexpr size_t OFF_BBI   = 848;                    // 201 ints (bucket bases I)
constexpr size_t OFF_ROWU  = 1088;                   // U_+1
constexpr size_t OFF_ROWI  = ((OFF_ROWU + U_ + 1 + 63) / 64) * 64;   // I_+1
constexpr size_t OFF_CSRU  = ((OFF_ROWI + I_ + 1 + 63) / 64) * 64;   // E_
constexpr size_t OFF_CSRI  = OFF_CSRU + E_;          // E_
constexpr size_t OFF_U1    = ((OFF_CSRI + E_ + 63) / 64) * 64;
constexpr size_t OFF_I1    = OFF_U1 + UD_;
constexpr size_t OFF_HU    = OFF_I1 + ID_;           // bufU (NBK_*CAP_ uints) aliases
constexpr size_t OFF_HI    = OFF_HU + UD_;           // bufI aliases (exactly ID_)
constexpr size_t OFF_ANC   = OFF_HI + ID_;
// total ≈ 60.7 MB

#define DEVI static __device__ __forceinline__

typedef _Float16 h2v __attribute__((ext_vector_type(2)));
typedef _Float16 f16x8 __attribute__((ext_vector_type(8)));
typedef float floatx4 __attribute__((ext_vector_type(4)));

DEVI float b2f(__hip_bfloat16 x) { return __bfloat162float(x); }

DEVI float ldf(const void* p, size_t i, int isf32) {
  if (isf32) return ((const float*)p)[i];
  return b2f(((const __hip_bfloat16*)p)[i]);
}

DEVI float frcp(float x) { return __builtin_amdgcn_rcpf(x); }

DEVI int waveInclScan(int v, int lane) {
  #pragma unroll
  for (int off = 1; off < 64; off <<= 1) {
    int t = __shfl_up(v, off, 64);
    if (lane >= off) v += t;
  }
  return v;
}

// ---------------- 0. prep: dtype detection + Wa/vU1/vU2 precompute ----------------
__global__ void prep_kernel(const unsigned short* __restrict__ ueu,
                            const void* __restrict__ W, const void* __restrict__ a,
                            const void* __restrict__ WU, const void* __restrict__ aU,
                            float* __restrict__ vecs, float* __restrict__ flag) {
  int cnt = 0;
  for (int i = 0; i < 256; i++) {
    int e = (ueu[i] >> 7) & 0xFF;
    if (e >= 130) cnt++;
  }
  int isf32 = (cnt >= 8);
  if (threadIdx.x == 0) *flag = isf32 ? 1.0f : 0.0f;
  int d = threadIdx.x;  // 64 threads
  float s = 0.f, t1 = 0.f, t2 = 0.f;
  for (int e = 0; e < 64; e++) {
    s += ldf(W, d * 64 + e, isf32) * ldf(a, e, isf32);
    float wue = ldf(WU, d * 64 + e, isf32);
    t1 += wue * ldf(aU, e, isf32);
    t2 += wue * ldf(aU, 64 + e, isf32);
  }
  vecs[d] = s;          // Wa
  vecs[64 + d] = t1;    // vU1
  vecs[128 + d] = t2;   // vU2
}

// ---------------- 1a. Phase A: both sides, per-bucket contiguous chunks ---------
// U: key=src (bucket=key>>8, local 8b), payload=dst. I: key=dst (>>7, 7b), payload=src.
// rec = (local<<17)|payload. Chunk base = bucket*CAP_ + atomicAdd(cur[bucket], c).
__global__ __launch_bounds__(256) void bucketA_kernel(
    const int* __restrict__ rs, const int* __restrict__ rd,
    unsigned* __restrict__ bufU, unsigned* __restrict__ bufI,
    int* __restrict__ curU, int* __restrict__ curI) {
  __shared__ int histU[NBK_], histI[NBK_];
  __shared__ int loffU[NBK_ + 1], loffI[NBK_ + 1];
  __shared__ int cbU[NBK_], cbI[NBK_];
  __shared__ int lcU[NBK_], lcI[NBK_];
  __shared__ int wsU[4], wsI[4];
  __shared__ unsigned recsU[TILE_], recsI[TILE_];
  int tid = threadIdx.x;
  int base = blockIdx.x * TILE_;
  for (int i = tid; i < NBK_; i += 256) { histU[i] = 0; histI[i] = 0; }
  __syncthreads();
  int ss[16], dd[16];
  #pragma unroll
  for (int t = 0; t < 16; t++) {
    int e = base + t * 256 + tid;
    bool v = e < E_;
    ss[t] = v ? rs[e] : -1;
    dd[t] = v ? rd[e] : 0;
    if (v) {
      atomicAdd(&histU[ss[t] >> 8], 1);
      atomicAdd(&histI[dd[t] >> 7], 1);
    }
  }
  __syncthreads();
  // reserve per-bucket chunks in global record buffers
  if (tid < NBK_) {
    int cU = histU[tid];
    cbU[tid] = tid * CAP_ + (cU ? atomicAdd(&curU[tid], cU) : 0);
    int cI = histI[tid];
    cbI[tid] = tid * CAP_ + (cI ? atomicAdd(&curI[tid], cI) : 0);
  }
  // parallel exclusive scans of both local histograms
  int lane = tid & 63, wv = tid >> 6;
  int cvU = (tid < NBK_) ? histU[tid] : 0;
  int cvI = (tid < NBK_) ? histI[tid] : 0;
  int inU = waveInclScan(cvU, lane);
  int inI = waveInclScan(cvI, lane);
  if (lane == 63) { wsU[wv] = inU; wsI[wv] = inI; }
  __syncthreads();
  int woU = 0, woI = 0;
  for (int w = 0; w < wv; w++) { woU += wsU[w]; woI += wsI[w]; }
  if (tid < NBK_) {
    loffU[tid] = woU + inU - cvU;
    loffI[tid] = woI + inI - cvI;
  }
  if (tid == NBK_ - 1) {
    loffU[NBK_] = woU + inU;
    loffI[NBK_] = woI + inI;
  }
  __syncthreads();
  if (tid < NBK_) { lcU[tid] = loffU[tid]; lcI[tid] = loffI[tid]; }
  __syncthreads();
  // local counting sort into LDS
  #pragma unroll
  for (int t = 0; t < 16; t++) {
    if (ss[t] >= 0) {
      int b = ss[t] >> 8;
      int p = atomicAdd(&lcU[b], 1);
      recsU[p] = ((unsigned)(ss[t] & 255) << 17) | (unsigned)dd[t];
      b = dd[t] >> 7;
      p = atomicAdd(&lcI[b], 1);
      recsI[p] = ((unsigned)(dd[t] & 127) << 17) | (unsigned)ss[t];
    }
  }
  __syncthreads();
  // stream out chunk-contiguous
  int totU = loffU[NBK_];
  for (int p = tid; p < totU; p += 256) {
    int lo = 0, hi = NBK_;
    while (hi - lo > 1) { int mid = (lo + hi) >> 1; if (loffU[mid] <= p) lo = mid; else hi = mid; }
    bufU[cbU[lo] + (p - loffU[lo])] = recsU[p];
  }
  int totI = loffI[NBK_];
  for (int p = tid; p < totI; p += 256) {
    int lo = 0, hi = NBK_;
    while (hi - lo > 1) { int mid = (lo + hi) >> 1; if (loffI[mid] <= p) lo = mid; else hi = mid; }
    bufI[cbI[lo] + (p - loffI[lo])] = recsI[p];
  }
}

// ---------------- 1b. tiny scan: bucket totals -> bucket bases + sentinels ------
__global__ void scanBuckets_kernel(const int* __restrict__ curU,
                                   const int* __restrict__ curI,
                                   int* __restrict__ bbU, int* __restrict__ bbI,
                                   int* __restrict__ rowU, int* __restrict__ rowI) {
  if (threadIdx.x == 0) {
    int run = 0;
    for (int i = 0; i < NBK_; i++) { bbU[i] = run; run += curU[i]; }
    bbU[NBK_] = run;
    run = 0;
    for (int i = 0; i < NBK_; i++) { bbI[i] = run; run += curI[i]; }
    bbI[NBK_] = run;
    rowU[U_] = E_;
    rowI[I_] = E_;
  }
}

// ---------------- 1c. Phase B: contiguous bucket -> rowptr slice + CSR ----------
// 400 blocks: b<200 = U bucket b (256 keys), else I bucket b-200 (128 keys).
__global__ __launch_bounds__(256) void bucketB_kernel(
    const unsigned* __restrict__ bufU, const unsigned* __restrict__ bufI,
    const int* __restrict__ curU, const int* __restrict__ curI,
    const int* __restrict__ bbU, const int* __restrict__ bbI,
    int* __restrict__ rowU, int* __restrict__ rowI,
    int* __restrict__ csrU, int* __restrict__ csrI) {
  __shared__ int stage[CAP_];   // 32 KB
  __shared__ int cntk[256], offk[256];
  __shared__ int wsum[4];
  int tid = threadIdx.x, b = blockIdx.x;
  int side = b >= NBK_;
  int bb = side ? b - NBK_ : b;
  const unsigned* src = (side ? bufI : bufU) + (size_t)bb * CAP_;
  int total = side ? curI[bb] : curU[bb];
  int gbase = side ? bbI[bb] : bbU[bb];
  int kpb   = side ? 128 : 256;
  int* rowptr = side ? rowI : rowU;
  int* csr    = side ? csrI : csrU;
  cntk[tid] = 0;
  __syncthreads();
  // pass 1: key histogram (coalesced reads)
  for (int r = tid; r < total; r += 256) atomicAdd(&cntk[src[r] >> 17], 1);
  __syncthreads();
  // exclusive scan over kpb keys
  int lane = tid & 63, wv = tid >> 6;
  int cv = (tid < kpb) ? cntk[tid] : 0;
  int incl = waveInclScan(cv, lane);
  if (lane == 63) wsum[wv] = incl;
  __syncthreads();
  int wvoff = 0;
  for (int w = 0; w < wv; w++) wvoff += wsum[w];
  int excl = wvoff + incl - cv;
  if (tid < kpb) {
    offk[tid] = excl;
    rowptr[bb * kpb + tid] = gbase + excl;
  }
  __syncthreads();
  // pass 2: place payloads at exact slots in LDS
  for (int r = tid; r < total; r += 256) {
    unsigned rec = src[r];
    int slot = atomicAdd(&offk[rec >> 17], 1);
    if (slot < CAP_) stage[slot] = (int)(rec & 0x1FFFFu);
  }
  __syncthreads();
  // coalesced CSR write
  for (int s = tid; s < total; s += 256) csr[gbase + s] = stage[s];
}

// ---------------- 2. layer-1 aggregation ----------------
__global__ __launch_bounds__(256) void agg1_kernel(
    const void* __restrict__ src, const int* __restrict__ row,
    const int* __restrict__ csr, float* __restrict__ out,
    const float* __restrict__ flag) {
  int isf32 = *flag > 0.5f;
  int wv = threadIdx.x >> 6, lane = threadIdx.x & 63;
  int r = blockIdx.x * 4 + wv;
  int s0 = row[r], s1 = row[r + 1];
  float acc = 0.f;
  int j = s0;
  for (; j + 4 <= s1; j += 4) {
    int a = csr[j], b = csr[j + 1], c = csr[j + 2], d = csr[j + 3];
    float va = ldf(src, (size_t)a * 64 + lane, isf32);
    float vb = ldf(src, (size_t)b * 64 + lane, isf32);
    float vc = ldf(src, (size_t)c * 64 + lane, isf32);
    float vd = ldf(src, (size_t)d * 64 + lane, isf32);
    acc += (va + vb) + (vc + vd);
  }
  for (; j < s1; j++) acc += ldf(src, (size_t)csr[j] * 64 + lane, isf32);
  out[(size_t)r * 64 + lane] = acc / fmaxf((float)(s1 - s0), 1.0f);
}

// ---------------- 3. layer-2 aggregation + fused layer attention ----------------
__global__ __launch_bounds__(256) void agg2attn_kernel(
    const float* __restrict__ opp1, const void* __restrict__ base,
    const float* __restrict__ own1,
    const int* __restrict__ row, const int* __restrict__ csr,
    const float* __restrict__ Wa, float* __restrict__ h,
    const float* __restrict__ flag) {
  int isf32 = *flag > 0.5f;
  int wv = threadIdx.x >> 6, lane = threadIdx.x & 63;
  int r = blockIdx.x * 4 + wv;
  int s0 = row[r], s1 = row[r + 1];
  float acc = 0.f;
  int j = s0;
  for (; j + 4 <= s1; j += 4) {
    int a = csr[j], b = csr[j + 1], c = csr[j + 2], d = csr[j + 3];
    float va = opp1[(size_t)a * 64 + lane];
    float vb = opp1[(size_t)b * 64 + lane];
    float vc = opp1[(size_t)c * 64 + lane];
    float vd = opp1[(size_t)d * 64 + lane];
    acc += (va + vb) + (vc + vd);
  }
  for (; j < s1; j++) acc += opp1[(size_t)csr[j] * 64 + lane];
  size_t idx = (size_t)r * 64 + lane;
  float t2 = acc / fmaxf((float)(s1 - s0), 1.0f);
  float t0 = ldf(base, idx, isf32);
  float t1 = own1[idx];
  float w = Wa[lane];
  float p0 = t0 * w, p1 = t1 * w, p2 = t2 * w;
  #pragma unroll
  for (int off = 32; off; off >>= 1) {
    p0 += __shfl_xor(p0, off, 64);
    p1 += __shfl_xor(p1, off, 64);
    p2 += __shfl_xor(p2, off, 64);
  }
  float m = fmaxf(p0, fmaxf(p1, p2));
  float e0 = __expf(p0 - m), e1 = __expf(p1 - m), e2 = __expf(p2 - m);
  float inv = 1.0f / (e0 + e1 + e2);
  h[idx] = (t0 * e0 + t1 * e1 + t2 * e2) * inv;
}

// ---------------- 4. anchor user embed (FFT filter + collapsed attention) -------
__global__ __launch_bounds__(256) void anchor_kernel(
    const void* __restrict__ ue, const void* __restrict__ WU,
    const void* __restrict__ cw, const float* __restrict__ vecs,
    const int* __restrict__ nbr, float* __restrict__ out,
    const float* __restrict__ flag) {
  int isf32 = *flag > 0.5f;
  __shared__ __align__(16) float2 wu2[32][64];  // 16KB
  __shared__ __align__(16) float mixS[4][64];
  int tid = threadIdx.x;
  int wv = tid >> 6, lane = tid & 63;
  int u = blockIdx.x * 4 + wv;

  for (int idx = tid; idx < 2048; idx += 256) {
    int dp = idx >> 6, n = idx & 63;
    wu2[dp][n] = make_float2(ldf(WU, (size_t)(2 * dp) * 64 + n, isf32),
                             ldf(WU, (size_t)(2 * dp + 1) * 64 + n, isf32));
  }

  float x[8];
  #pragma unroll
  for (int k = 0; k < 8; k++) {
    int nb = nbr[u * 8 + k];
    x[k] = ldf(ue, (size_t)nb * 64 + lane, isf32);
  }
  const float c1 = 0.70710678118654752440f;
  float sA = x[1] - x[3] - x[5] + x[7];
  float sB = x[1] + x[3] - x[5] - x[7];
  float ev = (x[0] + x[4]) + (x[2] + x[6]);
  float od = (x[1] + x[5]) + (x[3] + x[7]);
  float d04 = x[0] - x[4], d26 = x[2] - x[6];
  float X0r = ev + od;
  float X1r = d04 + c1 * sA;
  float X1i = -d26 - c1 * sB;
  float X2r = (x[0] + x[4]) - (x[2] + x[6]);
  float X2i = -(x[1] - x[3] + x[5] - x[7]);
  float X3r = d04 - c1 * sA;
  float X3i = d26 - c1 * sB;
  float X4r = ev - od;
  float Zr0 = X0r * ldf(cw, (0 * 64 + lane) * 2, isf32);
  float w1r = ldf(cw, (1 * 64 + lane) * 2, isf32), w1i = ldf(cw, (1 * 64 + lane) * 2 + 1, isf32);
  float Zr1 = X1r * w1r - X1i * w1i, Zi1 = X1r * w1i + X1i * w1r;
  float w2r = ldf(cw, (2 * 64 + lane) * 2, isf32), w2i = ldf(cw, (2 * 64 + lane) * 2 + 1, isf32);
  float Zr2 = X2r * w2r - X2i * w2i, Zi2 = X2r * w2i + X2i * w2r;
  float w3r = ldf(cw, (3 * 64 + lane) * 2, isf32), w3i = ldf(cw, (3 * 64 + lane) * 2 + 1, isf32);
  float Zr3 = X3r * w3r - X3i * w3i, Zi3 = X3r * w3i + X3i * w3r;
  float Zr4 = X4r * ldf(cw, (4 * 64 + lane) * 2, isf32);
  float eP = Zr0 + Zr4, eM = Zr0 - Zr4;
  float t1 = c1 * (Zr1 - Zr3), t2 = c1 * (Zi1 + Zi3);
  float y[8];
  y[0] = eP + 2.f * (Zr1 + Zr2 + Zr3);
  y[1] = eM + 2.f * (t1 - t2 - Zi2);
  y[2] = eP + 2.f * (-Zi1 - Zr2 + Zi3);
  y[3] = eM + 2.f * (-t1 - t2 + Zi2);
  y[4] = eP + 2.f * (-Zr1 + Zr2 - Zr3);
  y[5] = eM + 2.f * (-t1 + t2 - Zi2);
  y[6] = eP + 2.f * (Zi1 - Zr2 - Zi3);
  y[7] = eM + 2.f * (t1 + t2 + Zi2);
  #pragma unroll
  for (int k = 0; k < 8; k++) y[k] *= 0.125f;

  float v1 = vecs[64 + lane], v2 = vecs[128 + lane];
  float ek[8];
  #pragma unroll
  for (int k = 0; k < 8; k++) ek[k] = y[k] * v1;
  float q = ldf(ue, (size_t)u * 64 + lane, isf32) * v2;
  #pragma unroll
  for (int off = 32; off; off >>= 1) {
    #pragma unroll
    for (int k = 0; k < 8; k++) ek[k] += __shfl_xor(ek[k], off, 64);
    q += __shfl_xor(q, off, 64);
  }
  float m = -1e30f;
  #pragma unroll
  for (int k = 0; k < 8; k++) {
    float v = ek[k] + q;
    v = v > 0.f ? v : 0.1f * v;
    ek[k] = v;
    m = fmaxf(m, v);
  }
  float se = 0.f, wexp[8];
  #pragma unroll
  for (int k = 0; k < 8; k++) { wexp[k] = __expf(ek[k] - m); se += wexp[k]; }
  float mix = 0.f;
  #pragma unroll
  for (int k = 0; k < 8; k++) mix += wexp[k] * y[k];
  mixS[wv][lane] = mix;
  __syncthreads();

  float acc = 0.f;
  const float4* mrow = (const float4*)mixS[wv];
  #pragma unroll
  for (int it = 0; it < 16; it++) {
    float4 m4 = mrow[it];
    float2 w0 = wu2[2 * it][lane];
    float2 w1 = wu2[2 * it + 1][lane];
    acc += m4.x * w0.x + m4.y * w0.y + m4.z * w1.x + m4.w * w1.y;
  }
  out[(size_t)u * 64 + lane] = acc / se;
}

// ---------------- 5. contrastive loss via MFMA Gram matrix ----------------
constexpr int XS_ = 72;  // f16 row stride (144 B: 16B-aligned, uniform banks)
__global__ __launch_bounds__(256) void contrast_kernel(
    const float* __restrict__ hu, const float* __restrict__ an,
    float* __restrict__ loss_acc) {
  __shared__ __align__(16) _Float16 Xh[512 * XS_];  // 72 KB
  __shared__ float Nn[512];
  int tid = threadIdx.x;
  int c = blockIdx.x >> 2, sl = blockIdx.x & 3;

  const float* r1 = hu + ((size_t)c * CB_ + tid) * 64;
  const float* r2 = an + ((size_t)c * CB_ + tid) * 64;
  float4 a4[16], b4[16];
  float s1 = 0.f, s2 = 0.f;
  #pragma unroll
  for (int t = 0; t < 16; t++) {
    a4[t] = ((const float4*)r1)[t];
    s1 += a4[t].x * a4[t].x + a4[t].y * a4[t].y + a4[t].z * a4[t].z + a4[t].w * a4[t].w;
    b4[t] = ((const float4*)r2)[t];
    s2 += b4[t].x * b4[t].x + b4[t].y * b4[t].y + b4[t].z * b4[t].z + b4[t].w * b4[t].w;
  }
  float n1 = sqrtf(s1), n2 = sqrtf(s2);
  float inv1 = frcp(n1), inv2 = frcp(n2);
  Nn[tid] = n1; Nn[256 + tid] = n2;
  #pragma unroll
  for (int t = 0; t < 8; t++) {
    f16x8 v;
    v[0] = (_Float16)(a4[2*t].x * inv1);   v[1] = (_Float16)(a4[2*t].y * inv1);
    v[2] = (_Float16)(a4[2*t].z * inv1);   v[3] = (_Float16)(a4[2*t].w * inv1);
    v[4] = (_Float16)(a4[2*t+1].x * inv1); v[5] = (_Float16)(a4[2*t+1].y * inv1);
    v[6] = (_Float16)(a4[2*t+1].z * inv1); v[7] = (_Float16)(a4[2*t+1].w * inv1);
    *(f16x8*)&Xh[tid * XS_ + t * 8] = v;
    f16x8 w;
    w[0] = (_Float16)(b4[2*t].x * inv2);   w[1] = (_Float16)(b4[2*t].y * inv2);
    w[2] = (_Float16)(b4[2*t].z * inv2);   w[3] = (_Float16)(b4[2*t].w * inv2);
    w[4] = (_Float16)(b4[2*t+1].x * inv2); w[5] = (_Float16)(b4[2*t+1].y * inv2);
    w[6] = (_Float16)(b4[2*t+1].z * inv2); w[7] = (_Float16)(b4[2*t+1].w * inv2);
    *(f16x8*)&Xh[(256 + tid) * XS_ + t * 8] = w;
  }
  __syncthreads();

  int l = tid & 63, w = tid >> 6;
  int n = l & 15, q = l >> 4;
  int rb = sl * 128 + w * 32;
  f16x8 A[2][2];
  #pragma unroll
  for (int t = 0; t < 2; t++)
    #pragma unroll
    for (int h = 0; h < 2; h++)
      A[t][h] = *(const f16x8*)&Xh[(rb + t * 16 + n) * XS_ + h * 32 + q * 8];
  float NiR[2][4];
  #pragma unroll
  for (int t = 0; t < 2; t++)
    #pragma unroll
    for (int r = 0; r < 4; r++)
      NiR[t][r] = Nn[rb + t * 16 + q * 4 + r];
  float sums[2][4] = {{0,0,0,0},{0,0,0,0}};
  float labs[2][4] = {{0,0,0,0},{0,0,0,0}};
  const floatx4 zero = {0.f, 0.f, 0.f, 0.f};
  for (int ct = 0; ct < 32; ct++) {
    int cb = ct * 16;
    f16x8 B0 = *(const f16x8*)&Xh[(cb + n) * XS_ + q * 8];
    f16x8 B1 = *(const f16x8*)&Xh[(cb + n) * XS_ + 32 + q * 8];
    floatx4 acc0 = __builtin_amdgcn_mfma_f32_16x16x32_f16(A[0][0], B0, zero, 0, 0, 0);
    acc0 = __builtin_amdgcn_mfma_f32_16x16x32_f16(A[0][1], B1, acc0, 0, 0, 0);
    floatx4 acc1 = __builtin_amdgcn_mfma_f32_16x16x32_f16(A[1][0], B0, zero, 0, 0, 0);
    acc1 = __builtin_amdgcn_mfma_f32_16x16x32_f16(A[1][1], B1, acc1, 0, 0, 0);
    int j = cb + n;
    float Nj = Nn[j];
    #pragma unroll
    for (int t = 0; t < 2; t++) {
      #pragma unroll
      for (int r = 0; r < 4; r++) {
        int i = rb + t * 16 + q * 4 + r;
        float G = (t == 0) ? acc0[r] : acc1[r];
        float p = NiR[t][r] * Nj;
        float s = 5.0f * G * p * frcp(p + 1e-6f);
        float e = (j == i) ? 0.f : __expf(s);
        sums[t][r] += e;
        labs[t][r] += (j == (i ^ 256)) ? s : 0.f;
      }
    }
  }
  #pragma unroll
  for (int off = 1; off <= 8; off <<= 1) {
    #pragma unroll
    for (int t = 0; t < 2; t++)
      #pragma unroll
      for (int r = 0; r < 4; r++) {
        sums[t][r] += __shfl_xor(sums[t][r], off, 64);
        labs[t][r] += __shfl_xor(labs[t][r], off, 64);
      }
  }
  float part = 0.f;
  if (n == 0) {
    #pragma unroll
    for (int t = 0; t < 2; t++)
      #pragma unroll
      for (int r = 0; r < 4; r++)
        part += __logf(sums[t][r]) - labs[t][r];
  }
  #pragma unroll
  for (int off = 1; off < 64; off <<= 1) part += __shfl_xor(part, off, 64);
  if (l == 0) atomicAdd(loss_acc, part);
}

// ---------------- 6. scores ----------------
__global__ __launch_bounds__(256) void score_kernel(
    const float* __restrict__ hu, const float* __restrict__ hi,
    const int* __restrict__ pu, const int* __restrict__ pi,
    const int* __restrict__ nu, const int* __restrict__ ni,
    void* __restrict__ out, const float* __restrict__ flag) {
  int isf32 = *flag > 0.5f;
  int w = (blockIdx.x * 256 + threadIdx.x) >> 6;
  int lane = threadIdx.x & 63;
  int uu, ii;
  if (w < EP_) { uu = pu[w]; ii = pi[w]; }
  else         { uu = nu[w - EP_]; ii = ni[w - EP_]; }
  float p = hu[(size_t)uu * 64 + lane] * hi[(size_t)ii * 64 + lane];
  #pragma unroll
  for (int off = 32; off; off >>= 1) p += __shfl_xor(p, off, 64);
  if (lane == 0) {
    if (isf32) ((float*)out)[w] = p;
    else       ((__hip_bfloat16*)out)[w] = __float2bfloat16(p);
  }
}

__global__ void finalize_kernel(const float* __restrict__ loss_acc,
                                void* __restrict__ out,
                                const float* __restrict__ flag) {
  float v = loss_acc[0] * (1.0f / (float)(2 * CB_ * NCHUNK_));
  if (*flag > 0.5f) ((float*)out)[2 * EP_] = v;
  else              ((__hip_bfloat16*)out)[2 * EP_] = __float2bfloat16(v);
}

// ---------------- launch ----------------
extern "C" void kernel_launch(void* const* d_in, const int* in_sizes, int n_in,
                              void* d_out, int out_size, void* d_ws, size_t ws_size,
                              hipStream_t stream) {
  const void* ue  = d_in[0];
  const void* ie  = d_in[1];
  const void* W   = d_in[2];
  const void* a   = d_in[3];
  const void* WU  = d_in[4];
  const void* aU  = d_in[5];
  const void* cw  = d_in[6];
  const int* rs  = (const int*)d_in[7];
  const int* rd  = (const int*)d_in[8];
  const int* pu  = (const int*)d_in[9];
  const int* pi  = (const int*)d_in[10];
  const int* nu  = (const int*)d_in[11];
  const int* ni  = (const int*)d_in[12];
  const int* nbr = (const int*)d_in[13];

  float* wsf  = (float*)d_ws;
  int*   wsi  = (int*)d_ws;
  float* loss = wsf + OFF_LOSS;
  float* flag = wsf + OFF_FLAG;
  int* curU   = wsi + OFF_CURU;
  int* curI   = wsi + OFF_CURI;
  float* vecs = wsf + OFF_VEC;
  int* bbU    = wsi + OFF_BBU;
  int* bbI    = wsi + OFF_BBI;
  int* rowU   = wsi + OFF_ROWU;
  int* rowI   = wsi + OFF_ROWI;
  int* csrU   = wsi + OFF_CSRU;
  int* csrI   = wsi + OFF_CSRI;
  float* u1   = wsf + OFF_U1;
  float* i1   = wsf + OFF_I1;
  float* hu   = wsf + OFF_HU;
  float* hi   = wsf + OFF_HI;
  float* anc  = wsf + OFF_ANC;
  unsigned* bufU = (unsigned*)(wsf + OFF_HU);
  unsigned* bufI = (unsigned*)(wsf + OFF_HI);

  hipMemsetAsync(d_ws, 0, MEMSET_BYTES, stream);
  prep_kernel<<<1, 64, 0, stream>>>((const unsigned short*)ue, W, a, WU, aU, vecs, flag);

  // CSR build: fused Phase A, tiny scan, fused Phase B
  bucketA_kernel<<<NBA_, 256, 0, stream>>>(rs, rd, bufU, bufI, curU, curI);
  scanBuckets_kernel<<<1, 64, 0, stream>>>(curU, curI, bbU, bbI, rowU, rowI);
  bucketB_kernel<<<2 * NBK_, 256, 0, stream>>>(bufU, bufI, curU, curI, bbU, bbI,
                                               rowU, rowI, csrU, csrI);

  // layer-1 aggregation (gather)
  agg1_kernel<<<I_ / 4, 256, 0, stream>>>(ue, rowI, csrI, i1, flag);
  agg1_kernel<<<U_ / 4, 256, 0, stream>>>(ie, rowU, csrU, u1, flag);

  // layer-2 aggregation + fused layer attention
  agg2attn_kernel<<<I_ / 4, 256, 0, stream>>>(u1, ie, i1, rowI, csrI, vecs, hi, flag);
  agg2attn_kernel<<<U_ / 4, 256, 0, stream>>>(i1, ue, u1, rowU, csrU, vecs, hu, flag);

  // anchor path
  anchor_kernel<<<U_ / 4, 256, 0, stream>>>(ue, WU, cw, vecs, nbr, anc, flag);

  // contrastive loss (MFMA Gram)
  contrast_kernel<<<NCHUNK_ * 4, 256, 0, stream>>>(hu, anc, loss);

  // scores
  score_kernel<<<(2 * EP_ * 64) / 256, 256, 0, stream>>>(hu, hi, pu, pi, nu, ni, d_out, flag);
  finalize_kernel<<<1, 1, 0, stream>>>(loss, d_out, flag);
}

// Round 10
// 484.913 us; speedup vs baseline: 1.6969x; 1.0408x over previous
//
#include <hip/hip_runtime.h>
#include <hip/hip_bf16.h>

// ---------------- problem constants ----------------
constexpr int U_  = 51200;
constexpr int I_  = 25600;
constexpr int E_  = 1000000;
constexpr int EP_ = 100000;
constexpr int CB_ = 256;                 // contrastive chunk size
constexpr int NCHUNK_ = U_ / CB_;        // 200
constexpr size_t UD_ = (size_t)U_ * 64;
constexpr size_t ID_ = (size_t)I_ * 64;
constexpr int NBK_ = 200;                // buckets per side
constexpr int CAP_ = 8192;               // record slots per bucket (+45 sigma)
constexpr int TILE_ = 4096;              // edges per Phase-A block
constexpr int NBA_ = (E_ + TILE_ - 1) / TILE_;  // 245

// ---------------- workspace layout (4-byte element offsets) ----------------
constexpr size_t OFF_LOSS  = 0;
constexpr size_t OFF_FLAG  = 1;
constexpr size_t OFF_CURU  = 8;                      // 200 ints (bucket cursors U)
constexpr size_t OFF_CURI  = 208;                    // 200 ints (bucket cursors I)
constexpr size_t MEMSET_BYTES = 408 * 4;             // zero loss/flag/cursors
constexpr size_t OFF_VEC   = 448;                    // 192 floats: Wa | vU1 | vU2
constexpr size_t OFF_BBU   = 640;                    // 201 ints (bucket bases U)
constexpr size_t OFF_BBI   = 848;                    // 201 ints (bucket bases I)
constexpr size_t OFF_ROWU  = 1088;                   // U_+1
constexpr size_t OFF_ROWI  = ((OFF_ROWU + U_ + 1 + 63) / 64) * 64;   // I_+1
constexpr size_t OFF_CSRU  = ((OFF_ROWI + I_ + 1 + 63) / 64) * 64;   // E_
constexpr size_t OFF_CSRI  = OFF_CSRU + E_;          // E_
constexpr size_t OFF_U1    = ((OFF_CSRI + E_ + 63) / 64) * 64;
constexpr size_t OFF_I1    = OFF_U1 + UD_;
constexpr size_t OFF_HU    = OFF_I1 + ID_;           // bufU (NBK_*CAP_ uints) aliases
constexpr size_t OFF_HI    = OFF_HU + UD_;           // bufI aliases (exactly ID_)
constexpr size_t OFF_ANC   = OFF_HI + ID_;
// total ≈ 60.7 MB

#define DEVI static __device__ __forceinline__

typedef _Float16 h2v __attribute__((ext_vector_type(2)));
typedef _Float16 f16x8 __attribute__((ext_vector_type(8)));
typedef float floatx4 __attribute__((ext_vector_type(4)));

DEVI float b2f(__hip_bfloat16 x) { return __bfloat162float(x); }

DEVI float ldf(const void* p, size_t i, int isf32) {
  if (isf32) return ((const float*)p)[i];
  return b2f(((const __hip_bfloat16*)p)[i]);
}

DEVI float frcp(float x) { return __builtin_amdgcn_rcpf(x); }

DEVI int waveInclScan(int v, int lane) {
  #pragma unroll
  for (int off = 1; off < 64; off <<= 1) {
    int t = __shfl_up(v, off, 64);
    if (lane >= off) v += t;
  }
  return v;
}

// ---------------- 0. prep: dtype detection + Wa/vU1/vU2 precompute ----------------
__global__ void prep_kernel(const unsigned short* __restrict__ ueu,
                            const void* __restrict__ W, const void* __restrict__ a,
                            const void* __restrict__ WU, const void* __restrict__ aU,
                            float* __restrict__ vecs, float* __restrict__ flag) {
  int cnt = 0;
  for (int i = 0; i < 256; i++) {
    int e = (ueu[i] >> 7) & 0xFF;
    if (e >= 130) cnt++;
  }
  int isf32 = (cnt >= 8);
  if (threadIdx.x == 0) *flag = isf32 ? 1.0f : 0.0f;
  int d = threadIdx.x;  // 64 threads
  float s = 0.f, t1 = 0.f, t2 = 0.f;
  for (int e = 0; e < 64; e++) {
    s += ldf(W, d * 64 + e, isf32) * ldf(a, e, isf32);
    float wue = ldf(WU, d * 64 + e, isf32);
    t1 += wue * ldf(aU, e, isf32);
    t2 += wue * ldf(aU, 64 + e, isf32);
  }
  vecs[d] = s;          // Wa
  vecs[64 + d] = t1;    // vU1
  vecs[128 + d] = t2;   // vU2
}

// ---------------- 1a. Phase A: both sides, per-bucket contiguous chunks ---------
__global__ __launch_bounds__(256) void bucketA_kernel(
    const int* __restrict__ rs, const int* __restrict__ rd,
    unsigned* __restrict__ bufU, unsigned* __restrict__ bufI,
    int* __restrict__ curU, int* __restrict__ curI) {
  __shared__ int histU[NBK_], histI[NBK_];
  __shared__ int loffU[NBK_ + 1], loffI[NBK_ + 1];
  __shared__ int cbU[NBK_], cbI[NBK_];
  __shared__ int lcU[NBK_], lcI[NBK_];
  __shared__ int wsU[4], wsI[4];
  __shared__ unsigned recsU[TILE_], recsI[TILE_];
  int tid = threadIdx.x;
  int base = blockIdx.x * TILE_;
  for (int i = tid; i < NBK_; i += 256) { histU[i] = 0; histI[i] = 0; }
  __syncthreads();
  int ss[16], dd[16];
  #pragma unroll
  for (int t = 0; t < 16; t++) {
    int e = base + t * 256 + tid;
    bool v = e < E_;
    ss[t] = v ? rs[e] : -1;
    dd[t] = v ? rd[e] : 0;
    if (v) {
      atomicAdd(&histU[ss[t] >> 8], 1);
      atomicAdd(&histI[dd[t] >> 7], 1);
    }
  }
  __syncthreads();
  if (tid < NBK_) {
    int cU = histU[tid];
    cbU[tid] = tid * CAP_ + (cU ? atomicAdd(&curU[tid], cU) : 0);
    int cI = histI[tid];
    cbI[tid] = tid * CAP_ + (cI ? atomicAdd(&curI[tid], cI) : 0);
  }
  int lane = tid & 63, wv = tid >> 6;
  int cvU = (tid < NBK_) ? histU[tid] : 0;
  int cvI = (tid < NBK_) ? histI[tid] : 0;
  int inU = waveInclScan(cvU, lane);
  int inI = waveInclScan(cvI, lane);
  if (lane == 63) { wsU[wv] = inU; wsI[wv] = inI; }
  __syncthreads();
  int woU = 0, woI = 0;
  for (int w = 0; w < wv; w++) { woU += wsU[w]; woI += wsI[w]; }
  if (tid < NBK_) {
    loffU[tid] = woU + inU - cvU;
    loffI[tid] = woI + inI - cvI;
  }
  if (tid == NBK_ - 1) {
    loffU[NBK_] = woU + inU;
    loffI[NBK_] = woI + inI;
  }
  __syncthreads();
  if (tid < NBK_) { lcU[tid] = loffU[tid]; lcI[tid] = loffI[tid]; }
  __syncthreads();
  #pragma unroll
  for (int t = 0; t < 16; t++) {
    if (ss[t] >= 0) {
      int b = ss[t] >> 8;
      int p = atomicAdd(&lcU[b], 1);
      recsU[p] = ((unsigned)(ss[t] & 255) << 17) | (unsigned)dd[t];
      b = dd[t] >> 7;
      p = atomicAdd(&lcI[b], 1);
      recsI[p] = ((unsigned)(dd[t] & 127) << 17) | (unsigned)ss[t];
    }
  }
  __syncthreads();
  int totU = loffU[NBK_];
  for (int p = tid; p < totU; p += 256) {
    int lo = 0, hi = NBK_;
    while (hi - lo > 1) { int mid = (lo + hi) >> 1; if (loffU[mid] <= p) lo = mid; else hi = mid; }
    bufU[cbU[lo] + (p - loffU[lo])] = recsU[p];
  }
  int totI = loffI[NBK_];
  for (int p = tid; p < totI; p += 256) {
    int lo = 0, hi = NBK_;
    while (hi - lo > 1) { int mid = (lo + hi) >> 1; if (loffI[mid] <= p) lo = mid; else hi = mid; }
    bufI[cbI[lo] + (p - loffI[lo])] = recsI[p];
  }
}

// ---------------- 1b. tiny scan: bucket totals -> bucket bases + sentinels ------
__global__ void scanBuckets_kernel(const int* __restrict__ curU,
                                   const int* __restrict__ curI,
                                   int* __restrict__ bbU, int* __restrict__ bbI,
                                   int* __restrict__ rowU, int* __restrict__ rowI) {
  if (threadIdx.x == 0) {
    int run = 0;
    for (int i = 0; i < NBK_; i++) { bbU[i] = run; run += curU[i]; }
    bbU[NBK_] = run;
    run = 0;
    for (int i = 0; i < NBK_; i++) { bbI[i] = run; run += curI[i]; }
    bbI[NBK_] = run;
    rowU[U_] = E_;
    rowI[I_] = E_;
  }
}

// ---------------- 1c. Phase B: contiguous bucket -> rowptr slice + CSR ----------
__global__ __launch_bounds__(256) void bucketB_kernel(
    const unsigned* __restrict__ bufU, const unsigned* __restrict__ bufI,
    const int* __restrict__ curU, const int* __restrict__ curI,
    const int* __restrict__ bbU, const int* __restrict__ bbI,
    int* __restrict__ rowU, int* __restrict__ rowI,
    int* __restrict__ csrU, int* __restrict__ csrI) {
  __shared__ int stage[CAP_];   // 32 KB
  __shared__ int cntk[256], offk[256];
  __shared__ int wsum[4];
  int tid = threadIdx.x, b = blockIdx.x;
  int side = b >= NBK_;
  int bb = side ? b - NBK_ : b;
  const unsigned* src = (side ? bufI : bufU) + (size_t)bb * CAP_;
  int total = side ? curI[bb] : curU[bb];
  int gbase = side ? bbI[bb] : bbU[bb];
  int kpb   = side ? 128 : 256;
  int* rowptr = side ? rowI : rowU;
  int* csr    = side ? csrI : csrU;
  cntk[tid] = 0;
  __syncthreads();
  for (int r = tid; r < total; r += 256) atomicAdd(&cntk[src[r] >> 17], 1);
  __syncthreads();
  int lane = tid & 63, wv = tid >> 6;
  int cv = (tid < kpb) ? cntk[tid] : 0;
  int incl = waveInclScan(cv, lane);
  if (lane == 63) wsum[wv] = incl;
  __syncthreads();
  int wvoff = 0;
  for (int w = 0; w < wv; w++) wvoff += wsum[w];
  int excl = wvoff + incl - cv;
  if (tid < kpb) {
    offk[tid] = excl;
    rowptr[bb * kpb + tid] = gbase + excl;
  }
  __syncthreads();
  for (int r = tid; r < total; r += 256) {
    unsigned rec = src[r];
    int slot = atomicAdd(&offk[rec >> 17], 1);
    if (slot < CAP_) stage[slot] = (int)(rec & 0x1FFFFu);
  }
  __syncthreads();
  for (int s = tid; s < total; s += 256) csr[gbase + s] = stage[s];
}

// ---------------- 2. layer-1 aggregation ----------------
__global__ __launch_bounds__(256) void agg1_kernel(
    const void* __restrict__ src, const int* __restrict__ row,
    const int* __restrict__ csr, float* __restrict__ out,
    const float* __restrict__ flag) {
  int isf32 = *flag > 0.5f;
  int wv = threadIdx.x >> 6, lane = threadIdx.x & 63;
  int r = blockIdx.x * 4 + wv;
  int s0 = row[r], s1 = row[r + 1];
  float acc = 0.f;
  int j = s0;
  for (; j + 4 <= s1; j += 4) {
    int a = csr[j], b = csr[j + 1], c = csr[j + 2], d = csr[j + 3];
    float va = ldf(src, (size_t)a * 64 + lane, isf32);
    float vb = ldf(src, (size_t)b * 64 + lane, isf32);
    float vc = ldf(src, (size_t)c * 64 + lane, isf32);
    float vd = ldf(src, (size_t)d * 64 + lane, isf32);
    acc += (va + vb) + (vc + vd);
  }
  for (; j < s1; j++) acc += ldf(src, (size_t)csr[j] * 64 + lane, isf32);
  out[(size_t)r * 64 + lane] = acc / fmaxf((float)(s1 - s0), 1.0f);
}

// ---------------- 3. layer-2 aggregation + fused layer attention ----------------
__global__ __launch_bounds__(256) void agg2attn_kernel(
    const float* __restrict__ opp1, const void* __restrict__ base,
    const float* __restrict__ own1,
    const int* __restrict__ row, const int* __restrict__ csr,
    const float* __restrict__ Wa, float* __restrict__ h,
    const float* __restrict__ flag) {
  int isf32 = *flag > 0.5f;
  int wv = threadIdx.x >> 6, lane = threadIdx.x & 63;
  int r = blockIdx.x * 4 + wv;
  int s0 = row[r], s1 = row[r + 1];
  float acc = 0.f;
  int j = s0;
  for (; j + 4 <= s1; j += 4) {
    int a = csr[j], b = csr[j + 1], c = csr[j + 2], d = csr[j + 3];
    float va = opp1[(size_t)a * 64 + lane];
    float vb = opp1[(size_t)b * 64 + lane];
    float vc = opp1[(size_t)c * 64 + lane];
    float vd = opp1[(size_t)d * 64 + lane];
    acc += (va + vb) + (vc + vd);
  }
  for (; j < s1; j++) acc += opp1[(size_t)csr[j] * 64 + lane];
  size_t idx = (size_t)r * 64 + lane;
  float t2 = acc / fmaxf((float)(s1 - s0), 1.0f);
  float t0 = ldf(base, idx, isf32);
  float t1 = own1[idx];
  float w = Wa[lane];
  float p0 = t0 * w, p1 = t1 * w, p2 = t2 * w;
  #pragma unroll
  for (int off = 32; off; off >>= 1) {
    p0 += __shfl_xor(p0, off, 64);
    p1 += __shfl_xor(p1, off, 64);
    p2 += __shfl_xor(p2, off, 64);
  }
  float m = fmaxf(p0, fmaxf(p1, p2));
  float e0 = __expf(p0 - m), e1 = __expf(p1 - m), e2 = __expf(p2 - m);
  float inv = 1.0f / (e0 + e1 + e2);
  h[idx] = (t0 * e0 + t1 * e1 + t2 * e2) * inv;
}

// ---------------- 4. anchor: 16 users/block, FFT per wave + batched MFMA matvec --
// Wave wv computes FFT filter + softmax for users wv*4..wv*4+3, writing mix (f16)
// + 1/se to LDS. Then one 16x64 @ 64x64 matvec via mfma_16x16x32_f16: wave wv
// owns N-tile wv (cols wv*16..+16), 2 MFMAs (K=64). WU^T staged as f16 once.
constexpr int WS_ = 72;  // f16 row stride for WUt/mixS
__global__ __launch_bounds__(256) void anchor_kernel(
    const void* __restrict__ ue, const void* __restrict__ WU,
    const void* __restrict__ cw, const float* __restrict__ vecs,
    const int* __restrict__ nbr, float* __restrict__ out,
    const float* __restrict__ flag) {
  int isf32 = *flag > 0.5f;
  __shared__ __align__(16) _Float16 WUt[64 * WS_];   // 9 KB: WUt[n][k] = WU[k][n]
  __shared__ __align__(16) _Float16 mixS[16 * WS_];  // 2.25 KB
  __shared__ float invSe[16];
  __shared__ int nbrS[128];
  int tid = threadIdx.x;
  int wv = tid >> 6, lane = tid & 63;
  int ublk = blockIdx.x * 16;

  // stage WU^T (f16) + neighbor indices
  #pragma unroll
  for (int it = 0; it < 16; it++) {
    int k = it * 4 + wv;                       // row of WU
    WUt[lane * WS_ + k] = (_Float16)ldf(WU, (size_t)k * 64 + lane, isf32);
  }
  if (tid < 128) nbrS[tid] = nbr[ublk * 8 + tid];
  __syncthreads();

  // complex filter weights (shared across the wave's 4 users)
  float cw0 = ldf(cw, (0 * 64 + lane) * 2, isf32);
  float w1r = ldf(cw, (1 * 64 + lane) * 2, isf32), w1i = ldf(cw, (1 * 64 + lane) * 2 + 1, isf32);
  float w2r = ldf(cw, (2 * 64 + lane) * 2, isf32), w2i = ldf(cw, (2 * 64 + lane) * 2 + 1, isf32);
  float w3r = ldf(cw, (3 * 64 + lane) * 2, isf32), w3i = ldf(cw, (3 * 64 + lane) * 2 + 1, isf32);
  float cw4 = ldf(cw, (4 * 64 + lane) * 2, isf32);
  float v1 = vecs[64 + lane], v2 = vecs[128 + lane];
  const float c1 = 0.70710678118654752440f;

  // prefetch user 0's neighbor rows
  float xc[8], xn[8];
  #pragma unroll
  for (int k = 0; k < 8; k++)
    xc[k] = ldf(ue, (size_t)nbrS[wv * 32 + k] * 64 + lane, isf32);

  for (int u4 = 0; u4 < 4; u4++) {
    int uL = wv * 4 + u4;          // local user 0..15
    int u = ublk + uL;
    if (u4 < 3) {
      #pragma unroll
      for (int k = 0; k < 8; k++)
        xn[k] = ldf(ue, (size_t)nbrS[wv * 32 + (u4 + 1) * 8 + k] * 64 + lane, isf32);
    }
    // 8-point rfft (unscaled); ortho fwd+inv folded into 1/8
    float sA = xc[1] - xc[3] - xc[5] + xc[7];
    float sB = xc[1] + xc[3] - xc[5] - xc[7];
    float ev = (xc[0] + xc[4]) + (xc[2] + xc[6]);
    float od = (xc[1] + xc[5]) + (xc[3] + xc[7]);
    float d04 = xc[0] - xc[4], d26 = xc[2] - xc[6];
    float X0r = ev + od;
    float X1r = d04 + c1 * sA;
    float X1i = -d26 - c1 * sB;
    float X2r = (xc[0] + xc[4]) - (xc[2] + xc[6]);
    float X2i = -(xc[1] - xc[3] + xc[5] - xc[7]);
    float X3r = d04 - c1 * sA;
    float X3i = d26 - c1 * sB;
    float X4r = ev - od;
    float Zr0 = X0r * cw0;
    float Zr1 = X1r * w1r - X1i * w1i, Zi1 = X1r * w1i + X1i * w1r;
    float Zr2 = X2r * w2r - X2i * w2i, Zi2 = X2r * w2i + X2i * w2r;
    float Zr3 = X3r * w3r - X3i * w3i, Zi3 = X3r * w3i + X3i * w3r;
    float Zr4 = X4r * cw4;
    float eP = Zr0 + Zr4, eM = Zr0 - Zr4;
    float t1 = c1 * (Zr1 - Zr3), t2 = c1 * (Zi1 + Zi3);
    float y[8];
    y[0] = eP + 2.f * (Zr1 + Zr2 + Zr3);
    y[1] = eM + 2.f * (t1 - t2 - Zi2);
    y[2] = eP + 2.f * (-Zi1 - Zr2 + Zi3);
    y[3] = eM + 2.f * (-t1 - t2 + Zi2);
    y[4] = eP + 2.f * (-Zr1 + Zr2 - Zr3);
    y[5] = eM + 2.f * (-t1 + t2 - Zi2);
    y[6] = eP + 2.f * (Zi1 - Zr2 - Zi3);
    y[7] = eM + 2.f * (t1 + t2 + Zi2);
    #pragma unroll
    for (int k = 0; k < 8; k++) y[k] *= 0.125f;

    // attention scores via collapsed vectors
    float ek[8];
    #pragma unroll
    for (int k = 0; k < 8; k++) ek[k] = y[k] * v1;
    float q = ldf(ue, (size_t)u * 64 + lane, isf32) * v2;
    #pragma unroll
    for (int off = 32; off; off >>= 1) {
      #pragma unroll
      for (int k = 0; k < 8; k++) ek[k] += __shfl_xor(ek[k], off, 64);
      q += __shfl_xor(q, off, 64);
    }
    float m = -1e30f;
    #pragma unroll
    for (int k = 0; k < 8; k++) {
      float v = ek[k] + q;
      v = v > 0.f ? v : 0.1f * v;  // LeakyReLU(0.1)
      ek[k] = v;
      m = fmaxf(m, v);
    }
    float se = 0.f, wexp[8];
    #pragma unroll
    for (int k = 0; k < 8; k++) { wexp[k] = __expf(ek[k] - m); se += wexp[k]; }
    float mix = 0.f;
    #pragma unroll
    for (int k = 0; k < 8; k++) mix += wexp[k] * y[k];
    mixS[uL * WS_ + lane] = (_Float16)mix;
    if (lane == 0) invSe[uL] = frcp(se);
    #pragma unroll
    for (int k = 0; k < 8; k++) xc[k] = xn[k];
  }
  __syncthreads();

  // batched matvec: out16x64 = Mix @ WU  (wave wv -> N-tile wv)
  int n = lane & 15, qd = lane >> 4;
  // A[m][k]: lane m=n? No: A frag lane = (m = lane&15, k = qd*8 + j)
  f16x8 A0 = *(const f16x8*)&mixS[(lane & 15) * WS_ + qd * 8];
  f16x8 A1 = *(const f16x8*)&mixS[(lane & 15) * WS_ + 32 + qd * 8];
  // B[k][col]: lane col=n, k=qd*8+j  ->  WUt[wv*16 + n][qd*8 + j]
  f16x8 B0 = *(const f16x8*)&WUt[(wv * 16 + n) * WS_ + qd * 8];
  f16x8 B1 = *(const f16x8*)&WUt[(wv * 16 + n) * WS_ + 32 + qd * 8];
  const floatx4 zero = {0.f, 0.f, 0.f, 0.f};
  floatx4 acc = __builtin_amdgcn_mfma_f32_16x16x32_f16(A0, B0, zero, 0, 0, 0);
  acc = __builtin_amdgcn_mfma_f32_16x16x32_f16(A1, B1, acc, 0, 0, 0);
  // C: col = lane&15 (n), row m = qd*4 + r
  #pragma unroll
  for (int r = 0; r < 4; r++) {
    int m = qd * 4 + r;
    out[(size_t)(ublk + m) * 64 + wv * 16 + n] = acc[r] * invSe[m];
  }
}

// ---------------- 5. contrastive loss via MFMA Gram matrix ----------------
constexpr int XS_ = 72;  // f16 row stride (144 B: 16B-aligned, uniform banks)
__global__ __launch_bounds__(256) void contrast_kernel(
    const float* __restrict__ hu, const float* __restrict__ an,
    float* __restrict__ loss_acc) {
  __shared__ __align__(16) _Float16 Xh[512 * XS_];  // 72 KB
  __shared__ float Nn[512];
  int tid = threadIdx.x;
  int c = blockIdx.x >> 2, sl = blockIdx.x & 3;

  const float* r1 = hu + ((size_t)c * CB_ + tid) * 64;
  const float* r2 = an + ((size_t)c * CB_ + tid) * 64;
  float4 a4[16], b4[16];
  float s1 = 0.f, s2 = 0.f;
  #pragma unroll
  for (int t = 0; t < 16; t++) {
    a4[t] = ((const float4*)r1)[t];
    s1 += a4[t].x * a4[t].x + a4[t].y * a4[t].y + a4[t].z * a4[t].z + a4[t].w * a4[t].w;
    b4[t] = ((const float4*)r2)[t];
    s2 += b4[t].x * b4[t].x + b4[t].y * b4[t].y + b4[t].z * b4[t].z + b4[t].w * b4[t].w;
  }
  float n1 = sqrtf(s1), n2 = sqrtf(s2);
  float inv1 = frcp(n1), inv2 = frcp(n2);
  Nn[tid] = n1; Nn[256 + tid] = n2;
  #pragma unroll
  for (int t = 0; t < 8; t++) {
    f16x8 v;
    v[0] = (_Float16)(a4[2*t].x * inv1);   v[1] = (_Float16)(a4[2*t].y * inv1);
    v[2] = (_Float16)(a4[2*t].z * inv1);   v[3] = (_Float16)(a4[2*t].w * inv1);
    v[4] = (_Float16)(a4[2*t+1].x * inv1); v[5] = (_Float16)(a4[2*t+1].y * inv1);
    v[6] = (_Float16)(a4[2*t+1].z * inv1); v[7] = (_Float16)(a4[2*t+1].w * inv1);
    *(f16x8*)&Xh[tid * XS_ + t * 8] = v;
    f16x8 w;
    w[0] = (_Float16)(b4[2*t].x * inv2);   w[1] = (_Float16)(b4[2*t].y * inv2);
    w[2] = (_Float16)(b4[2*t].z * inv2);   w[3] = (_Float16)(b4[2*t].w * inv2);
    w[4] = (_Float16)(b4[2*t+1].x * inv2); w[5] = (_Float16)(b4[2*t+1].y * inv2);
    w[6] = (_Float16)(b4[2*t+1].z * inv2); w[7] = (_Float16)(b4[2*t+1].w * inv2);
    *(f16x8*)&Xh[(256 + tid) * XS_ + t * 8] = w;
  }
  __syncthreads();

  int l = tid & 63, w = tid >> 6;
  int n = l & 15, q = l >> 4;
  int rb = sl * 128 + w * 32;
  f16x8 A[2][2];
  #pragma unroll
  for (int t = 0; t < 2; t++)
    #pragma unroll
    for (int h = 0; h < 2; h++)
      A[t][h] = *(const f16x8*)&Xh[(rb + t * 16 + n) * XS_ + h * 32 + q * 8];
  float NiR[2][4];
  #pragma unroll
  for (int t = 0; t < 2; t++)
    #pragma unroll
    for (int r = 0; r < 4; r++)
      NiR[t][r] = Nn[rb + t * 16 + q * 4 + r];
  float sums[2][4] = {{0,0,0,0},{0,0,0,0}};
  float labs[2][4] = {{0,0,0,0},{0,0,0,0}};
  const floatx4 zero = {0.f, 0.f, 0.f, 0.f};
  for (int ct = 0; ct < 32; ct++) {
    int cb = ct * 16;
    f16x8 B0 = *(const f16x8*)&Xh[(cb + n) * XS_ + q * 8];
    f16x8 B1 = *(const f16x8*)&Xh[(cb + n) * XS_ + 32 + q * 8];
    floatx4 acc0 = __builtin_amdgcn_mfma_f32_16x16x32_f16(A[0][0], B0, zero, 0, 0, 0);
    acc0 = __builtin_amdgcn_mfma_f32_16x16x32_f16(A[0][1], B1, acc0, 0, 0, 0);
    floatx4 acc1 = __builtin_amdgcn_mfma_f32_16x16x32_f16(A[1][0], B0, zero, 0, 0, 0);
    acc1 = __builtin_amdgcn_mfma_f32_16x16x32_f16(A[1][1], B1, acc1, 0, 0, 0);
    int j = cb + n;
    float Nj = Nn[j];
    #pragma unroll
    for (int t = 0; t < 2; t++) {
      #pragma unroll
      for (int r = 0; r < 4; r++) {
        int i = rb + t * 16 + q * 4 + r;
        float G = (t == 0) ? acc0[r] : acc1[r];
        float p = NiR[t][r] * Nj;
        float s = 5.0f * G * p * frcp(p + 1e-6f);
        float e = (j == i) ? 0.f : __expf(s);
        sums[t][r] += e;
        labs[t][r] += (j == (i ^ 256)) ? s : 0.f;
      }
    }
  }
  #pragma unroll
  for (int off = 1; off <= 8; off <<= 1) {
    #pragma unroll
    for (int t = 0; t < 2; t++)
      #pragma unroll
      for (int r = 0; r < 4; r++) {
        sums[t][r] += __shfl_xor(sums[t][r], off, 64);
        labs[t][r] += __shfl_xor(labs[t][r], off, 64);
      }
  }
  float part = 0.f;
  if (n == 0) {
    #pragma unroll
    for (int t = 0; t < 2; t++)
      #pragma unroll
      for (int r = 0; r < 4; r++)
        part += __logf(sums[t][r]) - labs[t][r];
  }
  #pragma unroll
  for (int off = 1; off < 64; off <<= 1) part += __shfl_xor(part, off, 64);
  if (l == 0) atomicAdd(loss_acc, part);
}

// ---------------- 6. scores ----------------
__global__ __launch_bounds__(256) void score_kernel(
    const float* __restrict__ hu, const float* __restrict__ hi,
    const int* __restrict__ pu, const int* __restrict__ pi,
    const int* __restrict__ nu, const int* __restrict__ ni,
    void* __restrict__ out, const float* __restrict__ flag) {
  int isf32 = *flag > 0.5f;
  int w = (blockIdx.x * 256 + threadIdx.x) >> 6;
  int lane = threadIdx.x & 63;
  int uu, ii;
  if (w < EP_) { uu = pu[w]; ii = pi[w]; }
  else         { uu = nu[w - EP_]; ii = ni[w - EP_]; }
  float p = hu[(size_t)uu * 64 + lane] * hi[(size_t)ii * 64 + lane];
  #pragma unroll
  for (int off = 32; off; off >>= 1) p += __shfl_xor(p, off, 64);
  if (lane == 0) {
    if (isf32) ((float*)out)[w] = p;
    else       ((__hip_bfloat16*)out)[w] = __float2bfloat16(p);
  }
}

__global__ void finalize_kernel(const float* __restrict__ loss_acc,
                                void* __restrict__ out,
                                const float* __restrict__ flag) {
  float v = loss_acc[0] * (1.0f / (float)(2 * CB_ * NCHUNK_));
  if (*flag > 0.5f) ((float*)out)[2 * EP_] = v;
  else              ((__hip_bfloat16*)out)[2 * EP_] = __float2bfloat16(v);
}

// ---------------- launch ----------------
extern "C" void kernel_launch(void* const* d_in, const int* in_sizes, int n_in,
                              void* d_out, int out_size, void* d_ws, size_t ws_size,
                              hipStream_t stream) {
  const void* ue  = d_in[0];
  const void* ie  = d_in[1];
  const void* W   = d_in[2];
  const void* a   = d_in[3];
  const void* WU  = d_in[4];
  const void* aU  = d_in[5];
  const void* cw  = d_in[6];
  const int* rs  = (const int*)d_in[7];
  const int* rd  = (const int*)d_in[8];
  const int* pu  = (const int*)d_in[9];
  const int* pi  = (const int*)d_in[10];
  const int* nu  = (const int*)d_in[11];
  const int* ni  = (const int*)d_in[12];
  const int* nbr = (const int*)d_in[13];

  float* wsf  = (float*)d_ws;
  int*   wsi  = (int*)d_ws;
  float* loss = wsf + OFF_LOSS;
  float* flag = wsf + OFF_FLAG;
  int* curU   = wsi + OFF_CURU;
  int* curI   = wsi + OFF_CURI;
  float* vecs = wsf + OFF_VEC;
  int* bbU    = wsi + OFF_BBU;
  int* bbI    = wsi + OFF_BBI;
  int* rowU   = wsi + OFF_ROWU;
  int* rowI   = wsi + OFF_ROWI;
  int* csrU   = wsi + OFF_CSRU;
  int* csrI   = wsi + OFF_CSRI;
  float* u1   = wsf + OFF_U1;
  float* i1   = wsf + OFF_I1;
  float* hu   = wsf + OFF_HU;
  float* hi   = wsf + OFF_HI;
  float* anc  = wsf + OFF_ANC;
  unsigned* bufU = (unsigned*)(wsf + OFF_HU);
  unsigned* bufI = (unsigned*)(wsf + OFF_HI);

  hipMemsetAsync(d_ws, 0, MEMSET_BYTES, stream);
  prep_kernel<<<1, 64, 0, stream>>>((const unsigned short*)ue, W, a, WU, aU, vecs, flag);

  // CSR build: fused Phase A, tiny scan, fused Phase B
  bucketA_kernel<<<NBA_, 256, 0, stream>>>(rs, rd, bufU, bufI, curU, curI);
  scanBuckets_kernel<<<1, 64, 0, stream>>>(curU, curI, bbU, bbI, rowU, rowI);
  bucketB_kernel<<<2 * NBK_, 256, 0, stream>>>(bufU, bufI, curU, curI, bbU, bbI,
                                               rowU, rowI, csrU, csrI);

  // layer-1 aggregation (gather)
  agg1_kernel<<<I_ / 4, 256, 0, stream>>>(ue, rowI, csrI, i1, flag);
  agg1_kernel<<<U_ / 4, 256, 0, stream>>>(ie, rowU, csrU, u1, flag);

  // layer-2 aggregation + fused layer attention
  agg2attn_kernel<<<I_ / 4, 256, 0, stream>>>(u1, ie, i1, rowI, csrI, vecs, hi, flag);
  agg2attn_kernel<<<U_ / 4, 256, 0, stream>>>(i1, ue, u1, rowU, csrU, vecs, hu, flag);

  // anchor path (16 users/block, MFMA matvec)
  anchor_kernel<<<U_ / 16, 256, 0, stream>>>(ue, WU, cw, vecs, nbr, anc, flag);

  // contrastive loss (MFMA Gram)
  contrast_kernel<<<NCHUNK_ * 4, 256, 0, stream>>>(hu, anc, loss);

  // scores
  score_kernel<<<(2 * EP_ * 64) / 256, 256, 0, stream>>>(hu, hi, pu, pi, nu, ni, d_out, flag);
  finalize_kernel<<<1, 1, 0, stream>>>(loss, d_out, flag);
}

// Round 11
// 475.498 us; speedup vs baseline: 1.7305x; 1.0198x over previous
//
#include <hip/hip_runtime.h>
#include <hip/hip_bf16.h>

// ---------------- problem constants ----------------
constexpr int U_  = 51200;
constexpr int I_  = 25600;
constexpr int E_  = 1000000;
constexpr int EP_ = 100000;
constexpr int CB_ = 256;                 // contrastive chunk size
constexpr int NCHUNK_ = U_ / CB_;        // 200
constexpr size_t UD_ = (size_t)U_ * 64;
constexpr size_t ID_ = (size_t)I_ * 64;
constexpr int NBK_ = 200;                // buckets per side
constexpr int CAP_ = 8192;               // record slots per bucket (+45 sigma)
constexpr int TILE_ = 4096;              // edges per Phase-A block
constexpr int NBA_ = (E_ + TILE_ - 1) / TILE_;  // 245

// ---------------- workspace layout (4-byte element offsets) ----------------
constexpr size_t OFF_LOSS  = 0;
constexpr size_t OFF_FLAG  = 1;
constexpr size_t OFF_CURU  = 8;                      // 200 ints (bucket cursors U)
constexpr size_t OFF_CURI  = 208;                    // 200 ints (bucket cursors I)
constexpr size_t MEMSET_BYTES = 408 * 4;             // zero loss/flag/cursors
constexpr size_t OFF_VEC   = 448;                    // 192 floats: Wa | vU1 | vU2
constexpr size_t OFF_BBU   = 640;                    // 201 ints (bucket bases U)
constexpr size_t OFF_BBI   = 848;                    // 201 ints (bucket bases I)
constexpr size_t OFF_ROWU  = 1088;                   // U_+1
constexpr size_t OFF_ROWI  = ((OFF_ROWU + U_ + 1 + 63) / 64) * 64;   // I_+1
constexpr size_t OFF_CSRU  = ((OFF_ROWI + I_ + 1 + 63) / 64) * 64;   // E_
constexpr size_t OFF_CSRI  = OFF_CSRU + E_;          // E_
constexpr size_t OFF_U1    = ((OFF_CSRI + E_ + 63) / 64) * 64;
constexpr size_t OFF_I1    = OFF_U1 + UD_;
constexpr size_t OFF_HU    = OFF_I1 + ID_;           // bufU (NBK_*CAP_ uints) aliases
constexpr size_t OFF_HI    = OFF_HU + UD_;           // bufI aliases (exactly ID_)
constexpr size_t OFF_ANC   = OFF_HI + ID_;
// total ≈ 60.7 MB

#define DEVI static __device__ __forceinline__

typedef _Float16 h2v __attribute__((ext_vector_type(2)));
typedef _Float16 f16x8 __attribute__((ext_vector_type(8)));
typedef float floatx4 __attribute__((ext_vector_type(4)));

DEVI float b2f(__hip_bfloat16 x) { return __bfloat162float(x); }

DEVI float ldf(const void* p, size_t i, int isf32) {
  if (isf32) return ((const float*)p)[i];
  return b2f(((const __hip_bfloat16*)p)[i]);
}

DEVI float frcp(float x) { return __builtin_amdgcn_rcpf(x); }

DEVI int waveInclScan(int v, int lane) {
  #pragma unroll
  for (int off = 1; off < 64; off <<= 1) {
    int t = __shfl_up(v, off, 64);
    if (lane >= off) v += t;
  }
  return v;
}

// ---------------- 0. prep: dtype detection + Wa/vU1/vU2 precompute ----------------
__global__ void prep_kernel(const unsigned short* __restrict__ ueu,
                            const void* __restrict__ W, const void* __restrict__ a,
                            const void* __restrict__ WU, const void* __restrict__ aU,
                            float* __restrict__ vecs, float* __restrict__ flag) {
  int cnt = 0;
  for (int i = 0; i < 256; i++) {
    int e = (ueu[i] >> 7) & 0xFF;
    if (e >= 130) cnt++;
  }
  int isf32 = (cnt >= 8);
  if (threadIdx.x == 0) *flag = isf32 ? 1.0f : 0.0f;
  int d = threadIdx.x;  // 64 threads
  float s = 0.f, t1 = 0.f, t2 = 0.f;
  for (int e = 0; e < 64; e++) {
    s += ldf(W, d * 64 + e, isf32) * ldf(a, e, isf32);
    float wue = ldf(WU, d * 64 + e, isf32);
    t1 += wue * ldf(aU, e, isf32);
    t2 += wue * ldf(aU, 64 + e, isf32);
  }
  vecs[d] = s;          // Wa
  vecs[64 + d] = t1;    // vU1
  vecs[128 + d] = t2;   // vU2
}

// ---------------- 1a. Phase A: both sides, per-bucket contiguous chunks ---------
__global__ __launch_bounds__(256) void bucketA_kernel(
    const int* __restrict__ rs, const int* __restrict__ rd,
    unsigned* __restrict__ bufU, unsigned* __restrict__ bufI,
    int* __restrict__ curU, int* __restrict__ curI) {
  __shared__ int histU[NBK_], histI[NBK_];
  __shared__ int loffU[NBK_ + 1], loffI[NBK_ + 1];
  __shared__ int cbU[NBK_], cbI[NBK_];
  __shared__ int lcU[NBK_], lcI[NBK_];
  __shared__ int wsU[4], wsI[4];
  __shared__ unsigned recsU[TILE_], recsI[TILE_];
  int tid = threadIdx.x;
  int base = blockIdx.x * TILE_;
  for (int i = tid; i < NBK_; i += 256) { histU[i] = 0; histI[i] = 0; }
  __syncthreads();
  int ss[16], dd[16];
  #pragma unroll
  for (int t = 0; t < 16; t++) {
    int e = base + t * 256 + tid;
    bool v = e < E_;
    ss[t] = v ? rs[e] : -1;
    dd[t] = v ? rd[e] : 0;
    if (v) {
      atomicAdd(&histU[ss[t] >> 8], 1);
      atomicAdd(&histI[dd[t] >> 7], 1);
    }
  }
  __syncthreads();
  if (tid < NBK_) {
    int cU = histU[tid];
    cbU[tid] = tid * CAP_ + (cU ? atomicAdd(&curU[tid], cU) : 0);
    int cI = histI[tid];
    cbI[tid] = tid * CAP_ + (cI ? atomicAdd(&curI[tid], cI) : 0);
  }
  int lane = tid & 63, wv = tid >> 6;
  int cvU = (tid < NBK_) ? histU[tid] : 0;
  int cvI = (tid < NBK_) ? histI[tid] : 0;
  int inU = waveInclScan(cvU, lane);
  int inI = waveInclScan(cvI, lane);
  if (lane == 63) { wsU[wv] = inU; wsI[wv] = inI; }
  __syncthreads();
  int woU = 0, woI = 0;
  for (int w = 0; w < wv; w++) { woU += wsU[w]; woI += wsI[w]; }
  if (tid < NBK_) {
    loffU[tid] = woU + inU - cvU;
    loffI[tid] = woI + inI - cvI;
  }
  if (tid == NBK_ - 1) {
    loffU[NBK_] = woU + inU;
    loffI[NBK_] = woI + inI;
  }
  __syncthreads();
  if (tid < NBK_) { lcU[tid] = loffU[tid]; lcI[tid] = loffI[tid]; }
  __syncthreads();
  #pragma unroll
  for (int t = 0; t < 16; t++) {
    if (ss[t] >= 0) {
      int b = ss[t] >> 8;
      int p = atomicAdd(&lcU[b], 1);
      recsU[p] = ((unsigned)(ss[t] & 255) << 17) | (unsigned)dd[t];
      b = dd[t] >> 7;
      p = atomicAdd(&lcI[b], 1);
      recsI[p] = ((unsigned)(dd[t] & 127) << 17) | (unsigned)ss[t];
    }
  }
  __syncthreads();
  int totU = loffU[NBK_];
  for (int p = tid; p < totU; p += 256) {
    int lo = 0, hi = NBK_;
    while (hi - lo > 1) { int mid = (lo + hi) >> 1; if (loffU[mid] <= p) lo = mid; else hi = mid; }
    bufU[cbU[lo] + (p - loffU[lo])] = recsU[p];
  }
  int totI = loffI[NBK_];
  for (int p = tid; p < totI; p += 256) {
    int lo = 0, hi = NBK_;
    while (hi - lo > 1) { int mid = (lo + hi) >> 1; if (loffI[mid] <= p) lo = mid; else hi = mid; }
    bufI[cbI[lo] + (p - loffI[lo])] = recsI[p];
  }
}

// ---------------- 1b. tiny scan: bucket totals -> bucket bases + sentinels ------
__global__ void scanBuckets_kernel(const int* __restrict__ curU,
                                   const int* __restrict__ curI,
                                   int* __restrict__ bbU, int* __restrict__ bbI,
                                   int* __restrict__ rowU, int* __restrict__ rowI) {
  if (threadIdx.x == 0) {
    int run = 0;
    for (int i = 0; i < NBK_; i++) { bbU[i] = run; run += curU[i]; }
    bbU[NBK_] = run;
    run = 0;
    for (int i = 0; i < NBK_; i++) { bbI[i] = run; run += curI[i]; }
    bbI[NBK_] = run;
    rowU[U_] = E_;
    rowI[I_] = E_;
  }
}

// ---------------- 1c. Phase B: contiguous bucket -> rowptr slice + CSR ----------
__global__ __launch_bounds__(256) void bucketB_kernel(
    const unsigned* __restrict__ bufU, const unsigned* __restrict__ bufI,
    const int* __restrict__ curU, const int* __restrict__ curI,
    const int* __restrict__ bbU, const int* __restrict__ bbI,
    int* __restrict__ rowU, int* __restrict__ rowI,
    int* __restrict__ csrU, int* __restrict__ csrI) {
  __shared__ int stage[CAP_];   // 32 KB
  __shared__ int cntk[256], offk[256];
  __shared__ int wsum[4];
  int tid = threadIdx.x, b = blockIdx.x;
  int side = b >= NBK_;
  int bb = side ? b - NBK_ : b;
  const unsigned* src = (side ? bufI : bufU) + (size_t)bb * CAP_;
  int total = side ? curI[bb] : curU[bb];
  int gbase = side ? bbI[bb] : bbU[bb];
  int kpb   = side ? 128 : 256;
  int* rowptr = side ? rowI : rowU;
  int* csr    = side ? csrI : csrU;
  cntk[tid] = 0;
  __syncthreads();
  for (int r = tid; r < total; r += 256) atomicAdd(&cntk[src[r] >> 17], 1);
  __syncthreads();
  int lane = tid & 63, wv = tid >> 6;
  int cv = (tid < kpb) ? cntk[tid] : 0;
  int incl = waveInclScan(cv, lane);
  if (lane == 63) wsum[wv] = incl;
  __syncthreads();
  int wvoff = 0;
  for (int w = 0; w < wv; w++) wvoff += wsum[w];
  int excl = wvoff + incl - cv;
  if (tid < kpb) {
    offk[tid] = excl;
    rowptr[bb * kpb + tid] = gbase + excl;
  }
  __syncthreads();
  for (int r = tid; r < total; r += 256) {
    unsigned rec = src[r];
    int slot = atomicAdd(&offk[rec >> 17], 1);
    if (slot < CAP_) stage[slot] = (int)(rec & 0x1FFFFu);
  }
  __syncthreads();
  for (int s = tid; s < total; s += 256) csr[gbase + s] = stage[s];
}

// ---------------- 2. layer-1 aggregation ----------------
__global__ __launch_bounds__(256) void agg1_kernel(
    const void* __restrict__ src, const int* __restrict__ row,
    const int* __restrict__ csr, float* __restrict__ out,
    const float* __restrict__ flag) {
  int isf32 = *flag > 0.5f;
  int wv = threadIdx.x >> 6, lane = threadIdx.x & 63;
  int r = blockIdx.x * 4 + wv;
  int s0 = row[r], s1 = row[r + 1];
  float acc = 0.f;
  int j = s0;
  for (; j + 4 <= s1; j += 4) {
    int a = csr[j], b = csr[j + 1], c = csr[j + 2], d = csr[j + 3];
    float va = ldf(src, (size_t)a * 64 + lane, isf32);
    float vb = ldf(src, (size_t)b * 64 + lane, isf32);
    float vc = ldf(src, (size_t)c * 64 + lane, isf32);
    float vd = ldf(src, (size_t)d * 64 + lane, isf32);
    acc += (va + vb) + (vc + vd);
  }
  for (; j < s1; j++) acc += ldf(src, (size_t)csr[j] * 64 + lane, isf32);
  out[(size_t)r * 64 + lane] = acc / fmaxf((float)(s1 - s0), 1.0f);
}

// ---------------- 3. layer-2 aggregation + fused layer attention ----------------
__global__ __launch_bounds__(256) void agg2attn_kernel(
    const float* __restrict__ opp1, const void* __restrict__ base,
    const float* __restrict__ own1,
    const int* __restrict__ row, const int* __restrict__ csr,
    const float* __restrict__ Wa, float* __restrict__ h,
    const float* __restrict__ flag) {
  int isf32 = *flag > 0.5f;
  int wv = threadIdx.x >> 6, lane = threadIdx.x & 63;
  int r = blockIdx.x * 4 + wv;
  int s0 = row[r], s1 = row[r + 1];
  float acc = 0.f;
  int j = s0;
  for (; j + 4 <= s1; j += 4) {
    int a = csr[j], b = csr[j + 1], c = csr[j + 2], d = csr[j + 3];
    float va = opp1[(size_t)a * 64 + lane];
    float vb = opp1[(size_t)b * 64 + lane];
    float vc = opp1[(size_t)c * 64 + lane];
    float vd = opp1[(size_t)d * 64 + lane];
    acc += (va + vb) + (vc + vd);
  }
  for (; j < s1; j++) acc += opp1[(size_t)csr[j] * 64 + lane];
  size_t idx = (size_t)r * 64 + lane;
  float t2 = acc / fmaxf((float)(s1 - s0), 1.0f);
  float t0 = ldf(base, idx, isf32);
  float t1 = own1[idx];
  float w = Wa[lane];
  float p0 = t0 * w, p1 = t1 * w, p2 = t2 * w;
  #pragma unroll
  for (int off = 32; off; off >>= 1) {
    p0 += __shfl_xor(p0, off, 64);
    p1 += __shfl_xor(p1, off, 64);
    p2 += __shfl_xor(p2, off, 64);
  }
  float m = fmaxf(p0, fmaxf(p1, p2));
  float e0 = __expf(p0 - m), e1 = __expf(p1 - m), e2 = __expf(p2 - m);
  float inv = 1.0f / (e0 + e1 + e2);
  h[idx] = (t0 * e0 + t1 * e1 + t2 * e2) * inv;
}

// ---------------- 4. anchor: 16 users/block, FFT per wave + batched MFMA matvec --
constexpr int WS_ = 72;  // f16 row stride for WUt/mixS
__global__ __launch_bounds__(256) void anchor_kernel(
    const void* __restrict__ ue, const void* __restrict__ WU,
    const void* __restrict__ cw, const float* __restrict__ vecs,
    const int* __restrict__ nbr, float* __restrict__ out,
    const float* __restrict__ flag) {
  int isf32 = *flag > 0.5f;
  __shared__ __align__(16) _Float16 WUt[64 * WS_];   // 9 KB: WUt[n][k] = WU[k][n]
  __shared__ __align__(16) _Float16 mixS[16 * WS_];  // 2.25 KB
  __shared__ float invSe[16];
  __shared__ int nbrS[128];
  int tid = threadIdx.x;
  int wv = tid >> 6, lane = tid & 63;
  int ublk = blockIdx.x * 16;

  #pragma unroll
  for (int it = 0; it < 16; it++) {
    int k = it * 4 + wv;
    WUt[lane * WS_ + k] = (_Float16)ldf(WU, (size_t)k * 64 + lane, isf32);
  }
  if (tid < 128) nbrS[tid] = nbr[ublk * 8 + tid];
  __syncthreads();

  float cw0 = ldf(cw, (0 * 64 + lane) * 2, isf32);
  float w1r = ldf(cw, (1 * 64 + lane) * 2, isf32), w1i = ldf(cw, (1 * 64 + lane) * 2 + 1, isf32);
  float w2r = ldf(cw, (2 * 64 + lane) * 2, isf32), w2i = ldf(cw, (2 * 64 + lane) * 2 + 1, isf32);
  float w3r = ldf(cw, (3 * 64 + lane) * 2, isf32), w3i = ldf(cw, (3 * 64 + lane) * 2 + 1, isf32);
  float cw4 = ldf(cw, (4 * 64 + lane) * 2, isf32);
  float v1 = vecs[64 + lane], v2 = vecs[128 + lane];
  const float c1 = 0.70710678118654752440f;

  float xc[8], xn[8];
  #pragma unroll
  for (int k = 0; k < 8; k++)
    xc[k] = ldf(ue, (size_t)nbrS[wv * 32 + k] * 64 + lane, isf32);

  for (int u4 = 0; u4 < 4; u4++) {
    int uL = wv * 4 + u4;
    int u = ublk + uL;
    if (u4 < 3) {
      #pragma unroll
      for (int k = 0; k < 8; k++)
        xn[k] = ldf(ue, (size_t)nbrS[wv * 32 + (u4 + 1) * 8 + k] * 64 + lane, isf32);
    }
    float sA = xc[1] - xc[3] - xc[5] + xc[7];
    float sB = xc[1] + xc[3] - xc[5] - xc[7];
    float ev = (xc[0] + xc[4]) + (xc[2] + xc[6]);
    float od = (xc[1] + xc[5]) + (xc[3] + xc[7]);
    float d04 = xc[0] - xc[4], d26 = xc[2] - xc[6];
    float X0r = ev + od;
    float X1r = d04 + c1 * sA;
    float X1i = -d26 - c1 * sB;
    float X2r = (xc[0] + xc[4]) - (xc[2] + xc[6]);
    float X2i = -(xc[1] - xc[3] + xc[5] - xc[7]);
    float X3r = d04 - c1 * sA;
    float X3i = d26 - c1 * sB;
    float X4r = ev - od;
    float Zr0 = X0r * cw0;
    float Zr1 = X1r * w1r - X1i * w1i, Zi1 = X1r * w1i + X1i * w1r;
    float Zr2 = X2r * w2r - X2i * w2i, Zi2 = X2r * w2i + X2i * w2r;
    float Zr3 = X3r * w3r - X3i * w3i, Zi3 = X3r * w3i + X3i * w3r;
    float Zr4 = X4r * cw4;
    float eP = Zr0 + Zr4, eM = Zr0 - Zr4;
    float t1 = c1 * (Zr1 - Zr3), t2 = c1 * (Zi1 + Zi3);
    float y[8];
    y[0] = eP + 2.f * (Zr1 + Zr2 + Zr3);
    y[1] = eM + 2.f * (t1 - t2 - Zi2);
    y[2] = eP + 2.f * (-Zi1 - Zr2 + Zi3);
    y[3] = eM + 2.f * (-t1 - t2 + Zi2);
    y[4] = eP + 2.f * (-Zr1 + Zr2 - Zr3);
    y[5] = eM + 2.f * (-t1 + t2 - Zi2);
    y[6] = eP + 2.f * (Zi1 - Zr2 - Zi3);
    y[7] = eM + 2.f * (t1 + t2 + Zi2);
    #pragma unroll
    for (int k = 0; k < 8; k++) y[k] *= 0.125f;

    float ek[8];
    #pragma unroll
    for (int k = 0; k < 8; k++) ek[k] = y[k] * v1;
    float q = ldf(ue, (size_t)u * 64 + lane, isf32) * v2;
    #pragma unroll
    for (int off = 32; off; off >>= 1) {
      #pragma unroll
      for (int k = 0; k < 8; k++) ek[k] += __shfl_xor(ek[k], off, 64);
      q += __shfl_xor(q, off, 64);
    }
    float m = -1e30f;
    #pragma unroll
    for (int k = 0; k < 8; k++) {
      float v = ek[k] + q;
      v = v > 0.f ? v : 0.1f * v;  // LeakyReLU(0.1)
      ek[k] = v;
      m = fmaxf(m, v);
    }
    float se = 0.f, wexp[8];
    #pragma unroll
    for (int k = 0; k < 8; k++) { wexp[k] = __expf(ek[k] - m); se += wexp[k]; }
    float mix = 0.f;
    #pragma unroll
    for (int k = 0; k < 8; k++) mix += wexp[k] * y[k];
    mixS[uL * WS_ + lane] = (_Float16)mix;
    if (lane == 0) invSe[uL] = frcp(se);
    #pragma unroll
    for (int k = 0; k < 8; k++) xc[k] = xn[k];
  }
  __syncthreads();

  int n = lane & 15, qd = lane >> 4;
  f16x8 A0 = *(const f16x8*)&mixS[(lane & 15) * WS_ + qd * 8];
  f16x8 A1 = *(const f16x8*)&mixS[(lane & 15) * WS_ + 32 + qd * 8];
  f16x8 B0 = *(const f16x8*)&WUt[(wv * 16 + n) * WS_ + qd * 8];
  f16x8 B1 = *(const f16x8*)&WUt[(wv * 16 + n) * WS_ + 32 + qd * 8];
  const floatx4 zero = {0.f, 0.f, 0.f, 0.f};
  floatx4 acc = __builtin_amdgcn_mfma_f32_16x16x32_f16(A0, B0, zero, 0, 0, 0);
  acc = __builtin_amdgcn_mfma_f32_16x16x32_f16(A1, B1, acc, 0, 0, 0);
  #pragma unroll
  for (int r = 0; r < 4; r++) {
    int m = qd * 4 + r;
    out[(size_t)(ublk + m) * 64 + wv * 16 + n] = acc[r] * invSe[m];
  }
}

// ---------------- 5. contrastive loss: 1 block per chunk, MFMA Gram ----------
// Wave wv owns 8 row-tiles (rows wv*128..wv*128+127) x 32 col-tiles.
// Diag mask only in ct==rtg; label only in ct==rtg^16 (wave-uniform branches).
constexpr int XS_ = 72;  // f16 row stride (144 B: 16B-aligned)
__global__ __launch_bounds__(256) void contrast_kernel(
    const float* __restrict__ hu, const float* __restrict__ an,
    float* __restrict__ loss_acc) {
  __shared__ __align__(16) _Float16 Xh[512 * XS_];  // 72 KB
  __shared__ float Nn[512];
  int tid = threadIdx.x;
  int c = blockIdx.x;

  // --- stage: thread tid normalizes hu row tid and anc row tid ---
  const float* r1 = hu + ((size_t)c * CB_ + tid) * 64;
  const float* r2 = an + ((size_t)c * CB_ + tid) * 64;
  float4 a4[16], b4[16];
  float s1 = 0.f, s2 = 0.f;
  #pragma unroll
  for (int t = 0; t < 16; t++) {
    a4[t] = ((const float4*)r1)[t];
    s1 += a4[t].x * a4[t].x + a4[t].y * a4[t].y + a4[t].z * a4[t].z + a4[t].w * a4[t].w;
    b4[t] = ((const float4*)r2)[t];
    s2 += b4[t].x * b4[t].x + b4[t].y * b4[t].y + b4[t].z * b4[t].z + b4[t].w * b4[t].w;
  }
  float n1 = sqrtf(s1), n2 = sqrtf(s2);
  float inv1 = frcp(n1), inv2 = frcp(n2);
  Nn[tid] = n1; Nn[256 + tid] = n2;
  #pragma unroll
  for (int t = 0; t < 8; t++) {
    f16x8 v;
    v[0] = (_Float16)(a4[2*t].x * inv1);   v[1] = (_Float16)(a4[2*t].y * inv1);
    v[2] = (_Float16)(a4[2*t].z * inv1);   v[3] = (_Float16)(a4[2*t].w * inv1);
    v[4] = (_Float16)(a4[2*t+1].x * inv1); v[5] = (_Float16)(a4[2*t+1].y * inv1);
    v[6] = (_Float16)(a4[2*t+1].z * inv1); v[7] = (_Float16)(a4[2*t+1].w * inv1);
    *(f16x8*)&Xh[tid * XS_ + t * 8] = v;
    f16x8 w;
    w[0] = (_Float16)(b4[2*t].x * inv2);   w[1] = (_Float16)(b4[2*t].y * inv2);
    w[2] = (_Float16)(b4[2*t].z * inv2);   w[3] = (_Float16)(b4[2*t].w * inv2);
    w[4] = (_Float16)(b4[2*t+1].x * inv2); w[5] = (_Float16)(b4[2*t+1].y * inv2);
    w[6] = (_Float16)(b4[2*t+1].z * inv2); w[7] = (_Float16)(b4[2*t+1].w * inv2);
    *(f16x8*)&Xh[(256 + tid) * XS_ + t * 8] = w;
  }
  __syncthreads();

  // --- compute: wave wv -> 8 row-tiles ---
  int l = tid & 63, wv = tid >> 6;
  int n = l & 15, q = l >> 4;
  int rb = wv * 128;
  f16x8 A[8][2];
  #pragma unroll
  for (int t = 0; t < 8; t++) {
    A[t][0] = *(const f16x8*)&Xh[(rb + t * 16 + n) * XS_ + q * 8];
    A[t][1] = *(const f16x8*)&Xh[(rb + t * 16 + n) * XS_ + 32 + q * 8];
  }
  float NiR[8][4];
  #pragma unroll
  for (int t = 0; t < 8; t++)
    #pragma unroll
    for (int r = 0; r < 4; r++)
      NiR[t][r] = Nn[rb + t * 16 + q * 4 + r];
  float sums[8][4] = {{0,0,0,0},{0,0,0,0},{0,0,0,0},{0,0,0,0},
                      {0,0,0,0},{0,0,0,0},{0,0,0,0},{0,0,0,0}};
  float labs8[8] = {0,0,0,0,0,0,0,0};
  int selfn = q * 4;  // lane's slot base: rows q*4+r; label/diag hits when n==q*4+r
  const floatx4 zero = {0.f, 0.f, 0.f, 0.f};
  for (int ct = 0; ct < 32; ct++) {
    f16x8 B0 = *(const f16x8*)&Xh[(ct * 16 + n) * XS_ + q * 8];
    f16x8 B1 = *(const f16x8*)&Xh[(ct * 16 + n) * XS_ + 32 + q * 8];
    float Nj = Nn[ct * 16 + n];
    #pragma unroll
    for (int t = 0; t < 8; t++) {
      floatx4 acc = __builtin_amdgcn_mfma_f32_16x16x32_f16(A[t][0], B0, zero, 0, 0, 0);
      acc = __builtin_amdgcn_mfma_f32_16x16x32_f16(A[t][1], B1, acc, 0, 0, 0);
      int rtg = wv * 8 + t;
      if (ct == (rtg ^ 16)) {
        // label tile: also accumulate s at n == q*4+r (plus normal sum path)
        #pragma unroll
        for (int r = 0; r < 4; r++) {
          float p = NiR[t][r] * Nj;
          float s = 5.0f * acc[r] * p * frcp(p + 1e-6f);
          sums[t][r] += __expf(s);
          if (n == selfn + r) labs8[t] += s;
        }
      } else if (ct == rtg) {
        // diag tile: mask j==i
        #pragma unroll
        for (int r = 0; r < 4; r++) {
          float p = NiR[t][r] * Nj;
          float s = 5.0f * acc[r] * p * frcp(p + 1e-6f);
          float e = (n == selfn + r) ? 0.f : __expf(s);
          sums[t][r] += e;
        }
      } else {
        #pragma unroll
        for (int r = 0; r < 4; r++) {
          float p = NiR[t][r] * Nj;
          float s = 5.0f * acc[r] * p * frcp(p + 1e-6f);
          sums[t][r] += __expf(s);
        }
      }
    }
  }
  // reduce over n-group (xor 1,2,4,8 stay within the 16-lane group)
  #pragma unroll
  for (int off = 1; off <= 8; off <<= 1) {
    #pragma unroll
    for (int t = 0; t < 8; t++) {
      #pragma unroll
      for (int r = 0; r < 4; r++) sums[t][r] += __shfl_xor(sums[t][r], off, 64);
      labs8[t] += __shfl_xor(labs8[t], off, 64);
    }
  }
  float part = 0.f;
  if (n == 0) {
    #pragma unroll
    for (int t = 0; t < 8; t++) {
      float lt = 0.f;
      #pragma unroll
      for (int r = 0; r < 4; r++) lt += __logf(sums[t][r]);
      part += lt - labs8[t];
    }
  }
  #pragma unroll
  for (int off = 1; off < 64; off <<= 1) part += __shfl_xor(part, off, 64);
  if (l == 0) atomicAdd(loss_acc, part);
}

// ---------------- 6. scores ----------------
__global__ __launch_bounds__(256) void score_kernel(
    const float* __restrict__ hu, const float* __restrict__ hi,
    const int* __restrict__ pu, const int* __restrict__ pi,
    const int* __restrict__ nu, const int* __restrict__ ni,
    void* __restrict__ out, const float* __restrict__ flag) {
  int isf32 = *flag > 0.5f;
  int w = (blockIdx.x * 256 + threadIdx.x) >> 6;
  int lane = threadIdx.x & 63;
  int uu, ii;
  if (w < EP_) { uu = pu[w]; ii = pi[w]; }
  else         { uu = nu[w - EP_]; ii = ni[w - EP_]; }
  float p = hu[(size_t)uu * 64 + lane] * hi[(size_t)ii * 64 + lane];
  #pragma unroll
  for (int off = 32; off; off >>= 1) p += __shfl_xor(p, off, 64);
  if (lane == 0) {
    if (isf32) ((float*)out)[w] = p;
    else       ((__hip_bfloat16*)out)[w] = __float2bfloat16(p);
  }
}

__global__ void finalize_kernel(const float* __restrict__ loss_acc,
                                void* __restrict__ out,
                                const float* __restrict__ flag) {
  float v = loss_acc[0] * (1.0f / (float)(2 * CB_ * NCHUNK_));
  if (*flag > 0.5f) ((float*)out)[2 * EP_] = v;
  else              ((__hip_bfloat16*)out)[2 * EP_] = __float2bfloat16(v);
}

// ---------------- launch ----------------
extern "C" void kernel_launch(void* const* d_in, const int* in_sizes, int n_in,
                              void* d_out, int out_size, void* d_ws, size_t ws_size,
                              hipStream_t stream) {
  const void* ue  = d_in[0];
  const void* ie  = d_in[1];
  const void* W   = d_in[2];
  const void* a   = d_in[3];
  const void* WU  = d_in[4];
  const void* aU  = d_in[5];
  const void* cw  = d_in[6];
  const int* rs  = (const int*)d_in[7];
  const int* rd  = (const int*)d_in[8];
  const int* pu  = (const int*)d_in[9];
  const int* pi  = (const int*)d_in[10];
  const int* nu  = (const int*)d_in[11];
  const int* ni  = (const int*)d_in[12];
  const int* nbr = (const int*)d_in[13];

  float* wsf  = (float*)d_ws;
  int*   wsi  = (int*)d_ws;
  float* loss = wsf + OFF_LOSS;
  float* flag = wsf + OFF_FLAG;
  int* curU   = wsi + OFF_CURU;
  int* curI   = wsi + OFF_CURI;
  float* vecs = wsf + OFF_VEC;
  int* bbU    = wsi + OFF_BBU;
  int* bbI    = wsi + OFF_BBI;
  int* rowU   = wsi + OFF_ROWU;
  int* rowI   = wsi + OFF_ROWI;
  int* csrU   = wsi + OFF_CSRU;
  int* csrI   = wsi + OFF_CSRI;
  float* u1   = wsf + OFF_U1;
  float* i1   = wsf + OFF_I1;
  float* hu   = wsf + OFF_HU;
  float* hi   = wsf + OFF_HI;
  float* anc  = wsf + OFF_ANC;
  unsigned* bufU = (unsigned*)(wsf + OFF_HU);
  unsigned* bufI = (unsigned*)(wsf + OFF_HI);

  hipMemsetAsync(d_ws, 0, MEMSET_BYTES, stream);
  prep_kernel<<<1, 64, 0, stream>>>((const unsigned short*)ue, W, a, WU, aU, vecs, flag);

  // CSR build: fused Phase A, tiny scan, fused Phase B
  bucketA_kernel<<<NBA_, 256, 0, stream>>>(rs, rd, bufU, bufI, curU, curI);
  scanBuckets_kernel<<<1, 64, 0, stream>>>(curU, curI, bbU, bbI, rowU, rowI);
  bucketB_kernel<<<2 * NBK_, 256, 0, stream>>>(bufU, bufI, curU, curI, bbU, bbI,
                                               rowU, rowI, csrU, csrI);

  // layer-1 aggregation (gather)
  agg1_kernel<<<I_ / 4, 256, 0, stream>>>(ue, rowI, csrI, i1, flag);
  agg1_kernel<<<U_ / 4, 256, 0, stream>>>(ie, rowU, csrU, u1, flag);

  // layer-2 aggregation + fused layer attention
  agg2attn_kernel<<<I_ / 4, 256, 0, stream>>>(u1, ie, i1, rowI, csrI, vecs, hi, flag);
  agg2attn_kernel<<<U_ / 4, 256, 0, stream>>>(i1, ue, u1, rowU, csrU, vecs, hu, flag);

  // anchor path (16 users/block, MFMA matvec)
  anchor_kernel<<<U_ / 16, 256, 0, stream>>>(ue, WU, cw, vecs, nbr, anc, flag);

  // contrastive loss (1 block per chunk, MFMA Gram)
  contrast_kernel<<<NCHUNK_, 256, 0, stream>>>(hu, anc, loss);

  // scores
  score_kernel<<<(2 * EP_ * 64) / 256, 256, 0, stream>>>(hu, hi, pu, pi, nu, ni, d_out, flag);
  finalize_kernel<<<1, 1, 0, stream>>>(loss, d_out, flag);
}

// Round 12
// 475.074 us; speedup vs baseline: 1.7321x; 1.0009x over previous
//
#include <hip/hip_runtime.h>
#include <hip/hip_bf16.h>

// ---------------- problem constants ----------------
constexpr int U_  = 51200;
constexpr int I_  = 25600;
constexpr int E_  = 1000000;
constexpr int EP_ = 100000;
constexpr int CB_ = 256;                 // contrastive chunk size
constexpr int NCHUNK_ = U_ / CB_;        // 200
constexpr size_t UD_ = (size_t)U_ * 64;
constexpr size_t ID_ = (size_t)I_ * 64;
constexpr int NBK_ = 200;                // buckets per side
constexpr int CAP_ = 8192;               // record slots per bucket (+45 sigma)
constexpr int TILE_ = 4096;              // edges per Phase-A block
constexpr int NBA_ = (E_ + TILE_ - 1) / TILE_;  // 245

// ---------------- workspace layout (4-byte element offsets) ----------------
constexpr size_t OFF_LOSS  = 0;
constexpr size_t OFF_FLAG  = 1;
constexpr size_t OFF_CURU  = 8;                      // 200 ints (bucket cursors U)
constexpr size_t OFF_CURI  = 208;                    // 200 ints (bucket cursors I)
constexpr size_t MEMSET_BYTES = 408 * 4;             // zero loss/flag/cursors
constexpr size_t OFF_VEC   = 448;                    // 192 floats: Wa | vU1 | vU2
constexpr size_t OFF_BBU   = 640;                    // 201 ints (bucket bases U)
constexpr size_t OFF_BBI   = 848;                    // 201 ints (bucket bases I)
constexpr size_t OFF_ROWU  = 1088;                   // U_+1
constexpr size_t OFF_ROWI  = ((OFF_ROWU + U_ + 1 + 63) / 64) * 64;   // I_+1
constexpr size_t OFF_CSRU  = ((OFF_ROWI + I_ + 1 + 63) / 64) * 64;   // E_
constexpr size_t OFF_CSRI  = OFF_CSRU + E_;          // E_
constexpr size_t OFF_U1    = ((OFF_CSRI + E_ + 63) / 64) * 64;
constexpr size_t OFF_I1    = OFF_U1 + UD_;
constexpr size_t OFF_HU    = OFF_I1 + ID_;           // bufU (NBK_*CAP_ uints) aliases
constexpr size_t OFF_HI    = OFF_HU + UD_;           // bufI aliases (exactly ID_)
constexpr size_t OFF_ANC   = OFF_HI + ID_;
// total ≈ 60.7 MB

#define DEVI static __device__ __forceinline__

typedef _Float16 h2v __attribute__((ext_vector_type(2)));
typedef _Float16 f16x8 __attribute__((ext_vector_type(8)));
typedef float floatx4 __attribute__((ext_vector_type(4)));

DEVI float b2f(__hip_bfloat16 x) { return __bfloat162float(x); }

DEVI float ldf(const void* p, size_t i, int isf32) {
  if (isf32) return ((const float*)p)[i];
  return b2f(((const __hip_bfloat16*)p)[i]);
}

DEVI float frcp(float x) { return __builtin_amdgcn_rcpf(x); }

DEVI int waveInclScan(int v, int lane) {
  #pragma unroll
  for (int off = 1; off < 64; off <<= 1) {
    int t = __shfl_up(v, off, 64);
    if (lane >= off) v += t;
  }
  return v;
}

// ---------------- 0. prep: dtype detection + Wa/vU1/vU2 precompute ----------------
__global__ void prep_kernel(const unsigned short* __restrict__ ueu,
                            const void* __restrict__ W, const void* __restrict__ a,
                            const void* __restrict__ WU, const void* __restrict__ aU,
                            float* __restrict__ vecs, float* __restrict__ flag) {
  int cnt = 0;
  for (int i = 0; i < 256; i++) {
    int e = (ueu[i] >> 7) & 0xFF;
    if (e >= 130) cnt++;
  }
  int isf32 = (cnt >= 8);
  if (threadIdx.x == 0) *flag = isf32 ? 1.0f : 0.0f;
  int d = threadIdx.x;  // 64 threads
  float s = 0.f, t1 = 0.f, t2 = 0.f;
  for (int e = 0; e < 64; e++) {
    s += ldf(W, d * 64 + e, isf32) * ldf(a, e, isf32);
    float wue = ldf(WU, d * 64 + e, isf32);
    t1 += wue * ldf(aU, e, isf32);
    t2 += wue * ldf(aU, 64 + e, isf32);
  }
  vecs[d] = s;          // Wa
  vecs[64 + d] = t1;    // vU1
  vecs[128 + d] = t2;   // vU2
}

// ---------------- 1a. Phase A: both sides, per-bucket contiguous chunks ---------
__global__ __launch_bounds__(256) void bucketA_kernel(
    const int* __restrict__ rs, const int* __restrict__ rd,
    unsigned* __restrict__ bufU, unsigned* __restrict__ bufI,
    int* __restrict__ curU, int* __restrict__ curI) {
  __shared__ int histU[NBK_], histI[NBK_];
  __shared__ int loffU[NBK_ + 1], loffI[NBK_ + 1];
  __shared__ int cbU[NBK_], cbI[NBK_];
  __shared__ int lcU[NBK_], lcI[NBK_];
  __shared__ int wsU[4], wsI[4];
  __shared__ unsigned recsU[TILE_], recsI[TILE_];
  int tid = threadIdx.x;
  int base = blockIdx.x * TILE_;
  for (int i = tid; i < NBK_; i += 256) { histU[i] = 0; histI[i] = 0; }
  __syncthreads();
  int ss[16], dd[16];
  #pragma unroll
  for (int t = 0; t < 16; t++) {
    int e = base + t * 256 + tid;
    bool v = e < E_;
    ss[t] = v ? rs[e] : -1;
    dd[t] = v ? rd[e] : 0;
    if (v) {
      atomicAdd(&histU[ss[t] >> 8], 1);
      atomicAdd(&histI[dd[t] >> 7], 1);
    }
  }
  __syncthreads();
  if (tid < NBK_) {
    int cU = histU[tid];
    cbU[tid] = tid * CAP_ + (cU ? atomicAdd(&curU[tid], cU) : 0);
    int cI = histI[tid];
    cbI[tid] = tid * CAP_ + (cI ? atomicAdd(&curI[tid], cI) : 0);
  }
  int lane = tid & 63, wv = tid >> 6;
  int cvU = (tid < NBK_) ? histU[tid] : 0;
  int cvI = (tid < NBK_) ? histI[tid] : 0;
  int inU = waveInclScan(cvU, lane);
  int inI = waveInclScan(cvI, lane);
  if (lane == 63) { wsU[wv] = inU; wsI[wv] = inI; }
  __syncthreads();
  int woU = 0, woI = 0;
  for (int w = 0; w < wv; w++) { woU += wsU[w]; woI += wsI[w]; }
  if (tid < NBK_) {
    loffU[tid] = woU + inU - cvU;
    loffI[tid] = woI + inI - cvI;
  }
  if (tid == NBK_ - 1) {
    loffU[NBK_] = woU + inU;
    loffI[NBK_] = woI + inI;
  }
  __syncthreads();
  if (tid < NBK_) { lcU[tid] = loffU[tid]; lcI[tid] = loffI[tid]; }
  __syncthreads();
  #pragma unroll
  for (int t = 0; t < 16; t++) {
    if (ss[t] >= 0) {
      int b = ss[t] >> 8;
      int p = atomicAdd(&lcU[b], 1);
      recsU[p] = ((unsigned)(ss[t] & 255) << 17) | (unsigned)dd[t];
      b = dd[t] >> 7;
      p = atomicAdd(&lcI[b], 1);
      recsI[p] = ((unsigned)(dd[t] & 127) << 17) | (unsigned)ss[t];
    }
  }
  __syncthreads();
  int totU = loffU[NBK_];
  for (int p = tid; p < totU; p += 256) {
    int lo = 0, hi = NBK_;
    while (hi - lo > 1) { int mid = (lo + hi) >> 1; if (loffU[mid] <= p) lo = mid; else hi = mid; }
    bufU[cbU[lo] + (p - loffU[lo])] = recsU[p];
  }
  int totI = loffI[NBK_];
  for (int p = tid; p < totI; p += 256) {
    int lo = 0, hi = NBK_;
    while (hi - lo > 1) { int mid = (lo + hi) >> 1; if (loffI[mid] <= p) lo = mid; else hi = mid; }
    bufI[cbI[lo] + (p - loffI[lo])] = recsI[p];
  }
}

// ---------------- 1b. tiny scan: bucket totals -> bucket bases + sentinels ------
__global__ void scanBuckets_kernel(const int* __restrict__ curU,
                                   const int* __restrict__ curI,
                                   int* __restrict__ bbU, int* __restrict__ bbI,
                                   int* __restrict__ rowU, int* __restrict__ rowI) {
  if (threadIdx.x == 0) {
    int run = 0;
    for (int i = 0; i < NBK_; i++) { bbU[i] = run; run += curU[i]; }
    bbU[NBK_] = run;
    run = 0;
    for (int i = 0; i < NBK_; i++) { bbI[i] = run; run += curI[i]; }
    bbI[NBK_] = run;
    rowU[U_] = E_;
    rowI[I_] = E_;
  }
}

// ---------------- 1c. Phase B: contiguous bucket -> rowptr slice + CSR ----------
__global__ __launch_bounds__(256) void bucketB_kernel(
    const unsigned* __restrict__ bufU, const unsigned* __restrict__ bufI,
    const int* __restrict__ curU, const int* __restrict__ curI,
    const int* __restrict__ bbU, const int* __restrict__ bbI,
    int* __restrict__ rowU, int* __restrict__ rowI,
    int* __restrict__ csrU, int* __restrict__ csrI) {
  __shared__ int stage[CAP_];   // 32 KB
  __shared__ int cntk[256], offk[256];
  __shared__ int wsum[4];
  int tid = threadIdx.x, b = blockIdx.x;
  int side = b >= NBK_;
  int bb = side ? b - NBK_ : b;
  const unsigned* src = (side ? bufI : bufU) + (size_t)bb * CAP_;
  int total = side ? curI[bb] : curU[bb];
  int gbase = side ? bbI[bb] : bbU[bb];
  int kpb   = side ? 128 : 256;
  int* rowptr = side ? rowI : rowU;
  int* csr    = side ? csrI : csrU;
  cntk[tid] = 0;
  __syncthreads();
  for (int r = tid; r < total; r += 256) atomicAdd(&cntk[src[r] >> 17], 1);
  __syncthreads();
  int lane = tid & 63, wv = tid >> 6;
  int cv = (tid < kpb) ? cntk[tid] : 0;
  int incl = waveInclScan(cv, lane);
  if (lane == 63) wsum[wv] = incl;
  __syncthreads();
  int wvoff = 0;
  for (int w = 0; w < wv; w++) wvoff += wsum[w];
  int excl = wvoff + incl - cv;
  if (tid < kpb) {
    offk[tid] = excl;
    rowptr[bb * kpb + tid] = gbase + excl;
  }
  __syncthreads();
  for (int r = tid; r < total; r += 256) {
    unsigned rec = src[r];
    int slot = atomicAdd(&offk[rec >> 17], 1);
    if (slot < CAP_) stage[slot] = (int)(rec & 0x1FFFFu);
  }
  __syncthreads();
  for (int s = tid; s < total; s += 256) csr[gbase + s] = stage[s];
}

// ---------------- 2. layer-1 aggregation ----------------
__global__ __launch_bounds__(256) void agg1_kernel(
    const void* __restrict__ src, const int* __restrict__ row,
    const int* __restrict__ csr, float* __restrict__ out,
    const float* __restrict__ flag) {
  int isf32 = *flag > 0.5f;
  int wv = threadIdx.x >> 6, lane = threadIdx.x & 63;
  int r = blockIdx.x * 4 + wv;
  int s0 = row[r], s1 = row[r + 1];
  float acc = 0.f;
  int j = s0;
  for (; j + 4 <= s1; j += 4) {
    int a = csr[j], b = csr[j + 1], c = csr[j + 2], d = csr[j + 3];
    float va = ldf(src, (size_t)a * 64 + lane, isf32);
    float vb = ldf(src, (size_t)b * 64 + lane, isf32);
    float vc = ldf(src, (size_t)c * 64 + lane, isf32);
    float vd = ldf(src, (size_t)d * 64 + lane, isf32);
    acc += (va + vb) + (vc + vd);
  }
  for (; j < s1; j++) acc += ldf(src, (size_t)csr[j] * 64 + lane, isf32);
  out[(size_t)r * 64 + lane] = acc / fmaxf((float)(s1 - s0), 1.0f);
}

// ---------------- 3. layer-2 aggregation + fused layer attention ----------------
__global__ __launch_bounds__(256) void agg2attn_kernel(
    const float* __restrict__ opp1, const void* __restrict__ base,
    const float* __restrict__ own1,
    const int* __restrict__ row, const int* __restrict__ csr,
    const float* __restrict__ Wa, float* __restrict__ h,
    const float* __restrict__ flag) {
  int isf32 = *flag > 0.5f;
  int wv = threadIdx.x >> 6, lane = threadIdx.x & 63;
  int r = blockIdx.x * 4 + wv;
  int s0 = row[r], s1 = row[r + 1];
  float acc = 0.f;
  int j = s0;
  for (; j + 4 <= s1; j += 4) {
    int a = csr[j], b = csr[j + 1], c = csr[j + 2], d = csr[j + 3];
    float va = opp1[(size_t)a * 64 + lane];
    float vb = opp1[(size_t)b * 64 + lane];
    float vc = opp1[(size_t)c * 64 + lane];
    float vd = opp1[(size_t)d * 64 + lane];
    acc += (va + vb) + (vc + vd);
  }
  for (; j < s1; j++) acc += opp1[(size_t)csr[j] * 64 + lane];
  size_t idx = (size_t)r * 64 + lane;
  float t2 = acc / fmaxf((float)(s1 - s0), 1.0f);
  float t0 = ldf(base, idx, isf32);
  float t1 = own1[idx];
  float w = Wa[lane];
  float p0 = t0 * w, p1 = t1 * w, p2 = t2 * w;
  #pragma unroll
  for (int off = 32; off; off >>= 1) {
    p0 += __shfl_xor(p0, off, 64);
    p1 += __shfl_xor(p1, off, 64);
    p2 += __shfl_xor(p2, off, 64);
  }
  float m = fmaxf(p0, fmaxf(p1, p2));
  float e0 = __expf(p0 - m), e1 = __expf(p1 - m), e2 = __expf(p2 - m);
  float inv = 1.0f / (e0 + e1 + e2);
  h[idx] = (t0 * e0 + t1 * e1 + t2 * e2) * inv;
}

// ---------------- 4. anchor: 16 users/block, FFT per wave + batched MFMA matvec --
constexpr int WS_ = 72;  // f16 row stride for WUt/mixS
__global__ __launch_bounds__(256) void anchor_kernel(
    const void* __restrict__ ue, const void* __restrict__ WU,
    const void* __restrict__ cw, const float* __restrict__ vecs,
    const int* __restrict__ nbr, float* __restrict__ out,
    const float* __restrict__ flag) {
  int isf32 = *flag > 0.5f;
  __shared__ __align__(16) _Float16 WUt[64 * WS_];   // 9 KB: WUt[n][k] = WU[k][n]
  __shared__ __align__(16) _Float16 mixS[16 * WS_];  // 2.25 KB
  __shared__ float invSe[16];
  __shared__ int nbrS[128];
  int tid = threadIdx.x;
  int wv = tid >> 6, lane = tid & 63;
  int ublk = blockIdx.x * 16;

  #pragma unroll
  for (int it = 0; it < 16; it++) {
    int k = it * 4 + wv;
    WUt[lane * WS_ + k] = (_Float16)ldf(WU, (size_t)k * 64 + lane, isf32);
  }
  if (tid < 128) nbrS[tid] = nbr[ublk * 8 + tid];
  __syncthreads();

  float cw0 = ldf(cw, (0 * 64 + lane) * 2, isf32);
  float w1r = ldf(cw, (1 * 64 + lane) * 2, isf32), w1i = ldf(cw, (1 * 64 + lane) * 2 + 1, isf32);
  float w2r = ldf(cw, (2 * 64 + lane) * 2, isf32), w2i = ldf(cw, (2 * 64 + lane) * 2 + 1, isf32);
  float w3r = ldf(cw, (3 * 64 + lane) * 2, isf32), w3i = ldf(cw, (3 * 64 + lane) * 2 + 1, isf32);
  float cw4 = ldf(cw, (4 * 64 + lane) * 2, isf32);
  float v1 = vecs[64 + lane], v2 = vecs[128 + lane];
  const float c1 = 0.70710678118654752440f;

  float xc[8], xn[8];
  #pragma unroll
  for (int k = 0; k < 8; k++)
    xc[k] = ldf(ue, (size_t)nbrS[wv * 32 + k] * 64 + lane, isf32);

  for (int u4 = 0; u4 < 4; u4++) {
    int uL = wv * 4 + u4;
    int u = ublk + uL;
    if (u4 < 3) {
      #pragma unroll
      for (int k = 0; k < 8; k++)
        xn[k] = ldf(ue, (size_t)nbrS[wv * 32 + (u4 + 1) * 8 + k] * 64 + lane, isf32);
    }
    float sA = xc[1] - xc[3] - xc[5] + xc[7];
    float sB = xc[1] + xc[3] - xc[5] - xc[7];
    float ev = (xc[0] + xc[4]) + (xc[2] + xc[6]);
    float od = (xc[1] + xc[5]) + (xc[3] + xc[7]);
    float d04 = xc[0] - xc[4], d26 = xc[2] - xc[6];
    float X0r = ev + od;
    float X1r = d04 + c1 * sA;
    float X1i = -d26 - c1 * sB;
    float X2r = (xc[0] + xc[4]) - (xc[2] + xc[6]);
    float X2i = -(xc[1] - xc[3] + xc[5] - xc[7]);
    float X3r = d04 - c1 * sA;
    float X3i = d26 - c1 * sB;
    float X4r = ev - od;
    float Zr0 = X0r * cw0;
    float Zr1 = X1r * w1r - X1i * w1i, Zi1 = X1r * w1i + X1i * w1r;
    float Zr2 = X2r * w2r - X2i * w2i, Zi2 = X2r * w2i + X2i * w2r;
    float Zr3 = X3r * w3r - X3i * w3i, Zi3 = X3r * w3i + X3i * w3r;
    float Zr4 = X4r * cw4;
    float eP = Zr0 + Zr4, eM = Zr0 - Zr4;
    float t1 = c1 * (Zr1 - Zr3), t2 = c1 * (Zi1 + Zi3);
    float y[8];
    y[0] = eP + 2.f * (Zr1 + Zr2 + Zr3);
    y[1] = eM + 2.f * (t1 - t2 - Zi2);
    y[2] = eP + 2.f * (-Zi1 - Zr2 + Zi3);
    y[3] = eM + 2.f * (-t1 - t2 + Zi2);
    y[4] = eP + 2.f * (-Zr1 + Zr2 - Zr3);
    y[5] = eM + 2.f * (-t1 + t2 - Zi2);
    y[6] = eP + 2.f * (Zi1 - Zr2 - Zi3);
    y[7] = eM + 2.f * (t1 + t2 + Zi2);
    #pragma unroll
    for (int k = 0; k < 8; k++) y[k] *= 0.125f;

    float ek[8];
    #pragma unroll
    for (int k = 0; k < 8; k++) ek[k] = y[k] * v1;
    float q = ldf(ue, (size_t)u * 64 + lane, isf32) * v2;
    #pragma unroll
    for (int off = 32; off; off >>= 1) {
      #pragma unroll
      for (int k = 0; k < 8; k++) ek[k] += __shfl_xor(ek[k], off, 64);
      q += __shfl_xor(q, off, 64);
    }
    float m = -1e30f;
    #pragma unroll
    for (int k = 0; k < 8; k++) {
      float v = ek[k] + q;
      v = v > 0.f ? v : 0.1f * v;  // LeakyReLU(0.1)
      ek[k] = v;
      m = fmaxf(m, v);
    }
    float se = 0.f, wexp[8];
    #pragma unroll
    for (int k = 0; k < 8; k++) { wexp[k] = __expf(ek[k] - m); se += wexp[k]; }
    float mix = 0.f;
    #pragma unroll
    for (int k = 0; k < 8; k++) mix += wexp[k] * y[k];
    mixS[uL * WS_ + lane] = (_Float16)mix;
    if (lane == 0) invSe[uL] = frcp(se);
    #pragma unroll
    for (int k = 0; k < 8; k++) xc[k] = xn[k];
  }
  __syncthreads();

  int n = lane & 15, qd = lane >> 4;
  f16x8 A0 = *(const f16x8*)&mixS[(lane & 15) * WS_ + qd * 8];
  f16x8 A1 = *(const f16x8*)&mixS[(lane & 15) * WS_ + 32 + qd * 8];
  f16x8 B0 = *(const f16x8*)&WUt[(wv * 16 + n) * WS_ + qd * 8];
  f16x8 B1 = *(const f16x8*)&WUt[(wv * 16 + n) * WS_ + 32 + qd * 8];
  const floatx4 zero = {0.f, 0.f, 0.f, 0.f};
  floatx4 acc = __builtin_amdgcn_mfma_f32_16x16x32_f16(A0, B0, zero, 0, 0, 0);
  acc = __builtin_amdgcn_mfma_f32_16x16x32_f16(A1, B1, acc, 0, 0, 0);
  #pragma unroll
  for (int r = 0; r < 4; r++) {
    int m = qd * 4 + r;
    out[(size_t)(ublk + m) * 64 + wv * 16 + n] = acc[r] * invSe[m];
  }
}

// ---------------- 5. contrastive loss: 1 block/chunk, 16 waves, MFMA Gram -------
// 1024 threads. Staging: threads 0..255 -> hu rows, 256..511 -> anc rows.
// Compute: wave wv (0..15) owns row-tiles 2wv, 2wv+1 x 32 col-tiles.
// Diag mask only in ct==rtg; label only in ct==rtg^16 (wave-uniform branches).
constexpr int XS_ = 72;  // f16 row stride (144 B: 16B-aligned)
__global__ __launch_bounds__(1024) void contrast_kernel(
    const float* __restrict__ hu, const float* __restrict__ an,
    float* __restrict__ loss_acc) {
  __shared__ __align__(16) _Float16 Xh[512 * XS_];  // 72 KB
  __shared__ float Nn[512];
  int tid = threadIdx.x;
  int c = blockIdx.x;

  if (tid < 512) {
    int row = tid & 255;
    const float* r1 = (tid < 256 ? hu : an) + ((size_t)c * CB_ + row) * 64;
    float4 a4[16];
    float s1 = 0.f;
    #pragma unroll
    for (int t = 0; t < 16; t++) {
      a4[t] = ((const float4*)r1)[t];
      s1 += a4[t].x * a4[t].x + a4[t].y * a4[t].y + a4[t].z * a4[t].z + a4[t].w * a4[t].w;
    }
    float n1 = sqrtf(s1);
    float inv1 = frcp(n1);
    Nn[tid] = n1;
    #pragma unroll
    for (int t = 0; t < 8; t++) {
      f16x8 v;
      v[0] = (_Float16)(a4[2*t].x * inv1);   v[1] = (_Float16)(a4[2*t].y * inv1);
      v[2] = (_Float16)(a4[2*t].z * inv1);   v[3] = (_Float16)(a4[2*t].w * inv1);
      v[4] = (_Float16)(a4[2*t+1].x * inv1); v[5] = (_Float16)(a4[2*t+1].y * inv1);
      v[6] = (_Float16)(a4[2*t+1].z * inv1); v[7] = (_Float16)(a4[2*t+1].w * inv1);
      *(f16x8*)&Xh[tid * XS_ + t * 8] = v;
    }
  }
  __syncthreads();

  int l = tid & 63, wv = tid >> 6;       // wv 0..15
  int n = l & 15, q = l >> 4;
  int rb = wv * 32;                      // 2 row-tiles: rb, rb+16
  f16x8 A[2][2];
  #pragma unroll
  for (int t = 0; t < 2; t++) {
    A[t][0] = *(const f16x8*)&Xh[(rb + t * 16 + n) * XS_ + q * 8];
    A[t][1] = *(const f16x8*)&Xh[(rb + t * 16 + n) * XS_ + 32 + q * 8];
  }
  float NiR[2][4];
  #pragma unroll
  for (int t = 0; t < 2; t++)
    #pragma unroll
    for (int r = 0; r < 4; r++)
      NiR[t][r] = Nn[rb + t * 16 + q * 4 + r];
  float sums[2][4] = {{0,0,0,0},{0,0,0,0}};
  float labs2[2] = {0, 0};
  int selfn = q * 4;
  const floatx4 zero = {0.f, 0.f, 0.f, 0.f};
  for (int ct = 0; ct < 32; ct++) {
    f16x8 B0 = *(const f16x8*)&Xh[(ct * 16 + n) * XS_ + q * 8];
    f16x8 B1 = *(const f16x8*)&Xh[(ct * 16 + n) * XS_ + 32 + q * 8];
    float Nj = Nn[ct * 16 + n];
    #pragma unroll
    for (int t = 0; t < 2; t++) {
      floatx4 acc = __builtin_amdgcn_mfma_f32_16x16x32_f16(A[t][0], B0, zero, 0, 0, 0);
      acc = __builtin_amdgcn_mfma_f32_16x16x32_f16(A[t][1], B1, acc, 0, 0, 0);
      int rtg = wv * 2 + t;
      if (ct == (rtg ^ 16)) {
        #pragma unroll
        for (int r = 0; r < 4; r++) {
          float p = NiR[t][r] * Nj;
          float s = 5.0f * acc[r] * p * frcp(p + 1e-6f);
          sums[t][r] += __expf(s);
          if (n == selfn + r) labs2[t] += s;
        }
      } else if (ct == rtg) {
        #pragma unroll
        for (int r = 0; r < 4; r++) {
          float p = NiR[t][r] * Nj;
          float s = 5.0f * acc[r] * p * frcp(p + 1e-6f);
          float e = (n == selfn + r) ? 0.f : __expf(s);
          sums[t][r] += e;
        }
      } else {
        #pragma unroll
        for (int r = 0; r < 4; r++) {
          float p = NiR[t][r] * Nj;
          float s = 5.0f * acc[r] * p * frcp(p + 1e-6f);
          sums[t][r] += __expf(s);
        }
      }
    }
  }
  #pragma unroll
  for (int off = 1; off <= 8; off <<= 1) {
    #pragma unroll
    for (int t = 0; t < 2; t++) {
      #pragma unroll
      for (int r = 0; r < 4; r++) sums[t][r] += __shfl_xor(sums[t][r], off, 64);
      labs2[t] += __shfl_xor(labs2[t], off, 64);
    }
  }
  float part = 0.f;
  if (n == 0) {
    #pragma unroll
    for (int t = 0; t < 2; t++) {
      float lt = 0.f;
      #pragma unroll
      for (int r = 0; r < 4; r++) lt += __logf(sums[t][r]);
      part += lt - labs2[t];
    }
  }
  #pragma unroll
  for (int off = 1; off < 64; off <<= 1) part += __shfl_xor(part, off, 64);
  if (l == 0) atomicAdd(loss_acc, part);
}

// ---------------- 6. scores ----------------
__global__ __launch_bounds__(256) void score_kernel(
    const float* __restrict__ hu, const float* __restrict__ hi,
    const int* __restrict__ pu, const int* __restrict__ pi,
    const int* __restrict__ nu, const int* __restrict__ ni,
    void* __restrict__ out, const float* __restrict__ flag) {
  int isf32 = *flag > 0.5f;
  int w = (blockIdx.x * 256 + threadIdx.x) >> 6;
  int lane = threadIdx.x & 63;
  int uu, ii;
  if (w < EP_) { uu = pu[w]; ii = pi[w]; }
  else         { uu = nu[w - EP_]; ii = ni[w - EP_]; }
  float p = hu[(size_t)uu * 64 + lane] * hi[(size_t)ii * 64 + lane];
  #pragma unroll
  for (int off = 32; off; off >>= 1) p += __shfl_xor(p, off, 64);
  if (lane == 0) {
    if (isf32) ((float*)out)[w] = p;
    else       ((__hip_bfloat16*)out)[w] = __float2bfloat16(p);
  }
}

__global__ void finalize_kernel(const float* __restrict__ loss_acc,
                                void* __restrict__ out,
                                const float* __restrict__ flag) {
  float v = loss_acc[0] * (1.0f / (float)(2 * CB_ * NCHUNK_));
  if (*flag > 0.5f) ((float*)out)[2 * EP_] = v;
  else              ((__hip_bfloat16*)out)[2 * EP_] = __float2bfloat16(v);
}

// ---------------- launch ----------------
extern "C" void kernel_launch(void* const* d_in, const int* in_sizes, int n_in,
                              void* d_out, int out_size, void* d_ws, size_t ws_size,
                              hipStream_t stream) {
  const void* ue  = d_in[0];
  const void* ie  = d_in[1];
  const void* W   = d_in[2];
  const void* a   = d_in[3];
  const void* WU  = d_in[4];
  const void* aU  = d_in[5];
  const void* cw  = d_in[6];
  const int* rs  = (const int*)d_in[7];
  const int* rd  = (const int*)d_in[8];
  const int* pu  = (const int*)d_in[9];
  const int* pi  = (const int*)d_in[10];
  const int* nu  = (const int*)d_in[11];
  const int* ni  = (const int*)d_in[12];
  const int* nbr = (const int*)d_in[13];

  float* wsf  = (float*)d_ws;
  int*   wsi  = (int*)d_ws;
  float* loss = wsf + OFF_LOSS;
  float* flag = wsf + OFF_FLAG;
  int* curU   = wsi + OFF_CURU;
  int* curI   = wsi + OFF_CURI;
  float* vecs = wsf + OFF_VEC;
  int* bbU    = wsi + OFF_BBU;
  int* bbI    = wsi + OFF_BBI;
  int* rowU   = wsi + OFF_ROWU;
  int* rowI   = wsi + OFF_ROWI;
  int* csrU   = wsi + OFF_CSRU;
  int* csrI   = wsi + OFF_CSRI;
  float* u1   = wsf + OFF_U1;
  float* i1   = wsf + OFF_I1;
  float* hu   = wsf + OFF_HU;
  float* hi   = wsf + OFF_HI;
  float* anc  = wsf + OFF_ANC;
  unsigned* bufU = (unsigned*)(wsf + OFF_HU);
  unsigned* bufI = (unsigned*)(wsf + OFF_HI);

  hipMemsetAsync(d_ws, 0, MEMSET_BYTES, stream);
  prep_kernel<<<1, 64, 0, stream>>>((const unsigned short*)ue, W, a, WU, aU, vecs, flag);

  // CSR build: fused Phase A, tiny scan, fused Phase B
  bucketA_kernel<<<NBA_, 256, 0, stream>>>(rs, rd, bufU, bufI, curU, curI);
  scanBuckets_kernel<<<1, 64, 0, stream>>>(curU, curI, bbU, bbI, rowU, rowI);
  bucketB_kernel<<<2 * NBK_, 256, 0, stream>>>(bufU, bufI, curU, curI, bbU, bbI,
                                               rowU, rowI, csrU, csrI);

  // layer-1 aggregation (gather)
  agg1_kernel<<<I_ / 4, 256, 0, stream>>>(ue, rowI, csrI, i1, flag);
  agg1_kernel<<<U_ / 4, 256, 0, stream>>>(ie, rowU, csrU, u1, flag);

  // layer-2 aggregation + fused layer attention
  agg2attn_kernel<<<I_ / 4, 256, 0, stream>>>(u1, ie, i1, rowI, csrI, vecs, hi, flag);
  agg2attn_kernel<<<U_ / 4, 256, 0, stream>>>(i1, ue, u1, rowU, csrU, vecs, hu, flag);

  // anchor path (16 users/block, MFMA matvec)
  anchor_kernel<<<U_ / 16, 256, 0, stream>>>(ue, WU, cw, vecs, nbr, anc, flag);

  // contrastive loss (1 block/chunk, 16 waves, MFMA Gram)
  contrast_kernel<<<NCHUNK_, 1024, 0, stream>>>(hu, anc, loss);

  // scores
  score_kernel<<<(2 * EP_ * 64) / 256, 256, 0, stream>>>(hu, hi, pu, pi, nu, ni, d_out, flag);
  finalize_kernel<<<1, 1, 0, stream>>>(loss, d_out, flag);
}

// Round 13
// 461.901 us; speedup vs baseline: 1.7815x; 1.0285x over previous
//
#include <hip/hip_runtime.h>
#include <hip/hip_bf16.h>

// ---------------- problem constants ----------------
constexpr int U_  = 51200;
constexpr int I_  = 25600;
constexpr int E_  = 1000000;
constexpr int EP_ = 100000;
constexpr int CB_ = 256;                 // contrastive chunk size
constexpr int NCHUNK_ = U_ / CB_;        // 200
constexpr size_t UD_ = (size_t)U_ * 64;
constexpr size_t ID_ = (size_t)I_ * 64;
constexpr int NBK_ = 200;                // buckets per side
constexpr int CAP_ = 8192;               // record slots per bucket (+45 sigma)
constexpr int TILE_ = 4096;              // edges per Phase-A block
constexpr int NBA_ = (E_ + TILE_ - 1) / TILE_;  // 245

// ---------------- workspace layout (4-byte element offsets) ----------------
constexpr size_t OFF_LOSS  = 0;
constexpr size_t OFF_FLAG  = 1;
constexpr size_t OFF_CURU  = 8;                      // 200 ints (bucket cursors U)
constexpr size_t OFF_CURI  = 208;                    // 200 ints (bucket cursors I)
constexpr size_t MEMSET_BYTES = 408 * 4;             // zero loss/flag/cursors
constexpr size_t OFF_VEC   = 448;                    // 192 floats: Wa | vU1 | vU2
constexpr size_t OFF_BBU   = 640;                    // 201 ints (bucket bases U)
constexpr size_t OFF_BBI   = 848;                    // 201 ints (bucket bases I)
constexpr size_t OFF_ROWU  = 1088;                   // U_+1
constexpr size_t OFF_ROWI  = ((OFF_ROWU + U_ + 1 + 63) / 64) * 64;   // I_+1
constexpr size_t OFF_CSRU  = ((OFF_ROWI + I_ + 1 + 63) / 64) * 64;   // E_
constexpr size_t OFF_CSRI  = OFF_CSRU + E_;          // E_
constexpr size_t OFF_U1    = ((OFF_CSRI + E_ + 63) / 64) * 64;       // UD_ (bf16 inside)
constexpr size_t OFF_I1    = OFF_U1 + UD_;
constexpr size_t OFF_HU    = OFF_I1 + ID_;           // bufU (NBK_*CAP_ uints) aliases
constexpr size_t OFF_HI    = OFF_HU + UD_;           // bufI aliases (exactly ID_)
constexpr size_t OFF_ANC   = OFF_HI + ID_;
// total ≈ 60.7 MB

#define DEVI static __device__ __forceinline__

typedef _Float16 h2v __attribute__((ext_vector_type(2)));
typedef _Float16 f16x8 __attribute__((ext_vector_type(8)));
typedef float floatx4 __attribute__((ext_vector_type(4)));

DEVI float b2f(__hip_bfloat16 x) { return __bfloat162float(x); }

DEVI float ldf(const void* p, size_t i, int isf32) {
  if (isf32) return ((const float*)p)[i];
  return b2f(((const __hip_bfloat16*)p)[i]);
}

DEVI float frcp(float x) { return __builtin_amdgcn_rcpf(x); }

DEVI float fexp2(float x) {
#if __has_builtin(__builtin_amdgcn_exp2f)
  return __builtin_amdgcn_exp2f(x);
#else
  return exp2f(x);
#endif
}

DEVI int waveInclScan(int v, int lane) {
  #pragma unroll
  for (int off = 1; off < 64; off <<= 1) {
    int t = __shfl_up(v, off, 64);
    if (lane >= off) v += t;
  }
  return v;
}

// ---------------- 0. prep: dtype detection + Wa/vU1/vU2 precompute ----------------
__global__ void prep_kernel(const unsigned short* __restrict__ ueu,
                            const void* __restrict__ W, const void* __restrict__ a,
                            const void* __restrict__ WU, const void* __restrict__ aU,
                            float* __restrict__ vecs, float* __restrict__ flag) {
  int cnt = 0;
  for (int i = 0; i < 256; i++) {
    int e = (ueu[i] >> 7) & 0xFF;
    if (e >= 130) cnt++;
  }
  int isf32 = (cnt >= 8);
  if (threadIdx.x == 0) *flag = isf32 ? 1.0f : 0.0f;
  int d = threadIdx.x;  // 64 threads
  float s = 0.f, t1 = 0.f, t2 = 0.f;
  for (int e = 0; e < 64; e++) {
    s += ldf(W, d * 64 + e, isf32) * ldf(a, e, isf32);
    float wue = ldf(WU, d * 64 + e, isf32);
    t1 += wue * ldf(aU, e, isf32);
    t2 += wue * ldf(aU, 64 + e, isf32);
  }
  vecs[d] = s;          // Wa
  vecs[64 + d] = t1;    // vU1
  vecs[128 + d] = t2;   // vU2
}

// ---------------- 1a. Phase A: both sides, per-bucket contiguous chunks ---------
__global__ __launch_bounds__(256) void bucketA_kernel(
    const int* __restrict__ rs, const int* __restrict__ rd,
    unsigned* __restrict__ bufU, unsigned* __restrict__ bufI,
    int* __restrict__ curU, int* __restrict__ curI) {
  __shared__ int histU[NBK_], histI[NBK_];
  __shared__ int loffU[NBK_ + 1], loffI[NBK_ + 1];
  __shared__ int cbU[NBK_], cbI[NBK_];
  __shared__ int lcU[NBK_], lcI[NBK_];
  __shared__ int wsU[4], wsI[4];
  __shared__ unsigned recsU[TILE_], recsI[TILE_];
  int tid = threadIdx.x;
  int base = blockIdx.x * TILE_;
  for (int i = tid; i < NBK_; i += 256) { histU[i] = 0; histI[i] = 0; }
  __syncthreads();
  int ss[16], dd[16];
  #pragma unroll
  for (int t = 0; t < 16; t++) {
    int e = base + t * 256 + tid;
    bool v = e < E_;
    ss[t] = v ? rs[e] : -1;
    dd[t] = v ? rd[e] : 0;
    if (v) {
      atomicAdd(&histU[ss[t] >> 8], 1);
      atomicAdd(&histI[dd[t] >> 7], 1);
    }
  }
  __syncthreads();
  if (tid < NBK_) {
    int cU = histU[tid];
    cbU[tid] = tid * CAP_ + (cU ? atomicAdd(&curU[tid], cU) : 0);
    int cI = histI[tid];
    cbI[tid] = tid * CAP_ + (cI ? atomicAdd(&curI[tid], cI) : 0);
  }
  int lane = tid & 63, wv = tid >> 6;
  int cvU = (tid < NBK_) ? histU[tid] : 0;
  int cvI = (tid < NBK_) ? histI[tid] : 0;
  int inU = waveInclScan(cvU, lane);
  int inI = waveInclScan(cvI, lane);
  if (lane == 63) { wsU[wv] = inU; wsI[wv] = inI; }
  __syncthreads();
  int woU = 0, woI = 0;
  for (int w = 0; w < wv; w++) { woU += wsU[w]; woI += wsI[w]; }
  if (tid < NBK_) {
    loffU[tid] = woU + inU - cvU;
    loffI[tid] = woI + inI - cvI;
  }
  if (tid == NBK_ - 1) {
    loffU[NBK_] = woU + inU;
    loffI[NBK_] = woI + inI;
  }
  __syncthreads();
  if (tid < NBK_) { lcU[tid] = loffU[tid]; lcI[tid] = loffI[tid]; }
  __syncthreads();
  #pragma unroll
  for (int t = 0; t < 16; t++) {
    if (ss[t] >= 0) {
      int b = ss[t] >> 8;
      int p = atomicAdd(&lcU[b], 1);
      recsU[p] = ((unsigned)(ss[t] & 255) << 17) | (unsigned)dd[t];
      b = dd[t] >> 7;
      p = atomicAdd(&lcI[b], 1);
      recsI[p] = ((unsigned)(dd[t] & 127) << 17) | (unsigned)ss[t];
    }
  }
  __syncthreads();
  int totU = loffU[NBK_];
  for (int p = tid; p < totU; p += 256) {
    int lo = 0, hi = NBK_;
    while (hi - lo > 1) { int mid = (lo + hi) >> 1; if (loffU[mid] <= p) lo = mid; else hi = mid; }
    bufU[cbU[lo] + (p - loffU[lo])] = recsU[p];
  }
  int totI = loffI[NBK_];
  for (int p = tid; p < totI; p += 256) {
    int lo = 0, hi = NBK_;
    while (hi - lo > 1) { int mid = (lo + hi) >> 1; if (loffI[mid] <= p) lo = mid; else hi = mid; }
    bufI[cbI[lo] + (p - loffI[lo])] = recsI[p];
  }
}

// ---------------- 1b. tiny scan: bucket totals -> bucket bases + sentinels ------
__global__ void scanBuckets_kernel(const int* __restrict__ curU,
                                   const int* __restrict__ curI,
                                   int* __restrict__ bbU, int* __restrict__ bbI,
                                   int* __restrict__ rowU, int* __restrict__ rowI) {
  if (threadIdx.x == 0) {
    int run = 0;
    for (int i = 0; i < NBK_; i++) { bbU[i] = run; run += curU[i]; }
    bbU[NBK_] = run;
    run = 0;
    for (int i = 0; i < NBK_; i++) { bbI[i] = run; run += curI[i]; }
    bbI[NBK_] = run;
    rowU[U_] = E_;
    rowI[I_] = E_;
  }
}

// ---------------- 1c. Phase B: contiguous bucket -> rowptr slice + CSR ----------
__global__ __launch_bounds__(256) void bucketB_kernel(
    const unsigned* __restrict__ bufU, const unsigned* __restrict__ bufI,
    const int* __restrict__ curU, const int* __restrict__ curI,
    const int* __restrict__ bbU, const int* __restrict__ bbI,
    int* __restrict__ rowU, int* __restrict__ rowI,
    int* __restrict__ csrU, int* __restrict__ csrI) {
  __shared__ int stage[CAP_];   // 32 KB
  __shared__ int cntk[256], offk[256];
  __shared__ int wsum[4];
  int tid = threadIdx.x, b = blockIdx.x;
  int side = b >= NBK_;
  int bb = side ? b - NBK_ : b;
  const unsigned* src = (side ? bufI : bufU) + (size_t)bb * CAP_;
  int total = side ? curI[bb] : curU[bb];
  int gbase = side ? bbI[bb] : bbU[bb];
  int kpb   = side ? 128 : 256;
  int* rowptr = side ? rowI : rowU;
  int* csr    = side ? csrI : csrU;
  cntk[tid] = 0;
  __syncthreads();
  for (int r = tid; r < total; r += 256) atomicAdd(&cntk[src[r] >> 17], 1);
  __syncthreads();
  int lane = tid & 63, wv = tid >> 6;
  int cv = (tid < kpb) ? cntk[tid] : 0;
  int incl = waveInclScan(cv, lane);
  if (lane == 63) wsum[wv] = incl;
  __syncthreads();
  int wvoff = 0;
  for (int w = 0; w < wv; w++) wvoff += wsum[w];
  int excl = wvoff + incl - cv;
  if (tid < kpb) {
    offk[tid] = excl;
    rowptr[bb * kpb + tid] = gbase + excl;
  }
  __syncthreads();
  for (int r = tid; r < total; r += 256) {
    unsigned rec = src[r];
    int slot = atomicAdd(&offk[rec >> 17], 1);
    if (slot < CAP_) stage[slot] = (int)(rec & 0x1FFFFu);
  }
  __syncthreads();
  for (int s = tid; s < total; s += 256) csr[gbase + s] = stage[s];
}

// ---------------- 2. layer-1 aggregation (bf16 output) ----------------
__global__ __launch_bounds__(256) void agg1_kernel(
    const void* __restrict__ src, const int* __restrict__ row,
    const int* __restrict__ csr, __hip_bfloat16* __restrict__ out,
    const float* __restrict__ flag) {
  int isf32 = *flag > 0.5f;
  int wv = threadIdx.x >> 6, lane = threadIdx.x & 63;
  int r = blockIdx.x * 4 + wv;
  int s0 = row[r], s1 = row[r + 1];
  float acc = 0.f;
  int j = s0;
  for (; j + 4 <= s1; j += 4) {
    int a = csr[j], b = csr[j + 1], c = csr[j + 2], d = csr[j + 3];
    float va = ldf(src, (size_t)a * 64 + lane, isf32);
    float vb = ldf(src, (size_t)b * 64 + lane, isf32);
    float vc = ldf(src, (size_t)c * 64 + lane, isf32);
    float vd = ldf(src, (size_t)d * 64 + lane, isf32);
    acc += (va + vb) + (vc + vd);
  }
  for (; j < s1; j++) acc += ldf(src, (size_t)csr[j] * 64 + lane, isf32);
  out[(size_t)r * 64 + lane] = __float2bfloat16(acc / fmaxf((float)(s1 - s0), 1.0f));
}

// ---------------- 3. layer-2 aggregation + fused layer attention (bf16 l1) ------
__global__ __launch_bounds__(256) void agg2attn_kernel(
    const __hip_bfloat16* __restrict__ opp1, const void* __restrict__ base,
    const __hip_bfloat16* __restrict__ own1,
    const int* __restrict__ row, const int* __restrict__ csr,
    const float* __restrict__ Wa, float* __restrict__ h,
    const float* __restrict__ flag) {
  int isf32 = *flag > 0.5f;
  int wv = threadIdx.x >> 6, lane = threadIdx.x & 63;
  int r = blockIdx.x * 4 + wv;
  int s0 = row[r], s1 = row[r + 1];
  float acc = 0.f;
  int j = s0;
  for (; j + 4 <= s1; j += 4) {
    int a = csr[j], b = csr[j + 1], c = csr[j + 2], d = csr[j + 3];
    float va = b2f(opp1[(size_t)a * 64 + lane]);
    float vb = b2f(opp1[(size_t)b * 64 + lane]);
    float vc = b2f(opp1[(size_t)c * 64 + lane]);
    float vd = b2f(opp1[(size_t)d * 64 + lane]);
    acc += (va + vb) + (vc + vd);
  }
  for (; j < s1; j++) acc += b2f(opp1[(size_t)csr[j] * 64 + lane]);
  size_t idx = (size_t)r * 64 + lane;
  float t2 = acc / fmaxf((float)(s1 - s0), 1.0f);
  float t0 = ldf(base, idx, isf32);
  float t1 = b2f(own1[idx]);
  float w = Wa[lane];
  float p0 = t0 * w, p1 = t1 * w, p2 = t2 * w;
  #pragma unroll
  for (int off = 32; off; off >>= 1) {
    p0 += __shfl_xor(p0, off, 64);
    p1 += __shfl_xor(p1, off, 64);
    p2 += __shfl_xor(p2, off, 64);
  }
  float m = fmaxf(p0, fmaxf(p1, p2));
  float e0 = __expf(p0 - m), e1 = __expf(p1 - m), e2 = __expf(p2 - m);
  float inv = 1.0f / (e0 + e1 + e2);
  h[idx] = (t0 * e0 + t1 * e1 + t2 * e2) * inv;
}

// ---------------- 4. anchor: 16 users/block, FFT per wave + batched MFMA matvec --
constexpr int WS_ = 72;  // f16 row stride for WUt/mixS
__global__ __launch_bounds__(256) void anchor_kernel(
    const void* __restrict__ ue, const void* __restrict__ WU,
    const void* __restrict__ cw, const float* __restrict__ vecs,
    const int* __restrict__ nbr, float* __restrict__ out,
    const float* __restrict__ flag) {
  int isf32 = *flag > 0.5f;
  __shared__ __align__(16) _Float16 WUt[64 * WS_];   // 9 KB: WUt[n][k] = WU[k][n]
  __shared__ __align__(16) _Float16 mixS[16 * WS_];  // 2.25 KB
  __shared__ float invSe[16];
  __shared__ int nbrS[128];
  int tid = threadIdx.x;
  int wv = tid >> 6, lane = tid & 63;
  int ublk = blockIdx.x * 16;

  #pragma unroll
  for (int it = 0; it < 16; it++) {
    int k = it * 4 + wv;
    WUt[lane * WS_ + k] = (_Float16)ldf(WU, (size_t)k * 64 + lane, isf32);
  }
  if (tid < 128) nbrS[tid] = nbr[ublk * 8 + tid];
  __syncthreads();

  float cw0 = ldf(cw, (0 * 64 + lane) * 2, isf32);
  float w1r = ldf(cw, (1 * 64 + lane) * 2, isf32), w1i = ldf(cw, (1 * 64 + lane) * 2 + 1, isf32);
  float w2r = ldf(cw, (2 * 64 + lane) * 2, isf32), w2i = ldf(cw, (2 * 64 + lane) * 2 + 1, isf32);
  float w3r = ldf(cw, (3 * 64 + lane) * 2, isf32), w3i = ldf(cw, (3 * 64 + lane) * 2 + 1, isf32);
  float cw4 = ldf(cw, (4 * 64 + lane) * 2, isf32);
  float v1 = vecs[64 + lane], v2 = vecs[128 + lane];
  const float c1 = 0.70710678118654752440f;

  float xc[8], xn[8];
  #pragma unroll
  for (int k = 0; k < 8; k++)
    xc[k] = ldf(ue, (size_t)nbrS[wv * 32 + k] * 64 + lane, isf32);

  for (int u4 = 0; u4 < 4; u4++) {
    int uL = wv * 4 + u4;
    int u = ublk + uL;
    if (u4 < 3) {
      #pragma unroll
      for (int k = 0; k < 8; k++)
        xn[k] = ldf(ue, (size_t)nbrS[wv * 32 + (u4 + 1) * 8 + k] * 64 + lane, isf32);
    }
    float sA = xc[1] - xc[3] - xc[5] + xc[7];
    float sB = xc[1] + xc[3] - xc[5] - xc[7];
    float ev = (xc[0] + xc[4]) + (xc[2] + xc[6]);
    float od = (xc[1] + xc[5]) + (xc[3] + xc[7]);
    float d04 = xc[0] - xc[4], d26 = xc[2] - xc[6];
    float X0r = ev + od;
    float X1r = d04 + c1 * sA;
    float X1i = -d26 - c1 * sB;
    float X2r = (xc[0] + xc[4]) - (xc[2] + xc[6]);
    float X2i = -(xc[1] - xc[3] + xc[5] - xc[7]);
    float X3r = d04 - c1 * sA;
    float X3i = d26 - c1 * sB;
    float X4r = ev - od;
    float Zr0 = X0r * cw0;
    float Zr1 = X1r * w1r - X1i * w1i, Zi1 = X1r * w1i + X1i * w1r;
    float Zr2 = X2r * w2r - X2i * w2i, Zi2 = X2r * w2i + X2i * w2r;
    float Zr3 = X3r * w3r - X3i * w3i, Zi3 = X3r * w3i + X3i * w3r;
    float Zr4 = X4r * cw4;
    float eP = Zr0 + Zr4, eM = Zr0 - Zr4;
    float t1 = c1 * (Zr1 - Zr3), t2 = c1 * (Zi1 + Zi3);
    float y[8];
    y[0] = eP + 2.f * (Zr1 + Zr2 + Zr3);
    y[1] = eM + 2.f * (t1 - t2 - Zi2);
    y[2] = eP + 2.f * (-Zi1 - Zr2 + Zi3);
    y[3] = eM + 2.f * (-t1 - t2 + Zi2);
    y[4] = eP + 2.f * (-Zr1 + Zr2 - Zr3);
    y[5] = eM + 2.f * (-t1 + t2 - Zi2);
    y[6] = eP + 2.f * (Zi1 - Zr2 - Zi3);
    y[7] = eM + 2.f * (t1 + t2 + Zi2);
    #pragma unroll
    for (int k = 0; k < 8; k++) y[k] *= 0.125f;

    float ek[8];
    #pragma unroll
    for (int k = 0; k < 8; k++) ek[k] = y[k] * v1;
    float q = ldf(ue, (size_t)u * 64 + lane, isf32) * v2;
    #pragma unroll
    for (int off = 32; off; off >>= 1) {
      #pragma unroll
      for (int k = 0; k < 8; k++) ek[k] += __shfl_xor(ek[k], off, 64);
      q += __shfl_xor(q, off, 64);
    }
    float m = -1e30f;
    #pragma unroll
    for (int k = 0; k < 8; k++) {
      float v = ek[k] + q;
      v = v > 0.f ? v : 0.1f * v;  // LeakyReLU(0.1)
      ek[k] = v;
      m = fmaxf(m, v);
    }
    float se = 0.f, wexp[8];
    #pragma unroll
    for (int k = 0; k < 8; k++) { wexp[k] = __expf(ek[k] - m); se += wexp[k]; }
    float mix = 0.f;
    #pragma unroll
    for (int k = 0; k < 8; k++) mix += wexp[k] * y[k];
    mixS[uL * WS_ + lane] = (_Float16)mix;
    if (lane == 0) invSe[uL] = frcp(se);
    #pragma unroll
    for (int k = 0; k < 8; k++) xc[k] = xn[k];
  }
  __syncthreads();

  int n = lane & 15, qd = lane >> 4;
  f16x8 A0 = *(const f16x8*)&mixS[(lane & 15) * WS_ + qd * 8];
  f16x8 A1 = *(const f16x8*)&mixS[(lane & 15) * WS_ + 32 + qd * 8];
  f16x8 B0 = *(const f16x8*)&WUt[(wv * 16 + n) * WS_ + qd * 8];
  f16x8 B1 = *(const f16x8*)&WUt[(wv * 16 + n) * WS_ + 32 + qd * 8];
  const floatx4 zero = {0.f, 0.f, 0.f, 0.f};
  floatx4 acc = __builtin_amdgcn_mfma_f32_16x16x32_f16(A0, B0, zero, 0, 0, 0);
  acc = __builtin_amdgcn_mfma_f32_16x16x32_f16(A1, B1, acc, 0, 0, 0);
  #pragma unroll
  for (int r = 0; r < 4; r++) {
    int m = qd * 4 + r;
    out[(size_t)(ublk + m) * 64 + wv * 16 + n] = acc[r] * invSe[m];
  }
}

// ---------------- 5. contrastive loss: slim epilogue MFMA Gram ----------
// Rows stored scaled by invN*sqrt(5*log2e) -> MFMA G = 5*log2e*cos.
// s2 = G - G*(eps*invNi)*invNj (1st-order eps correction; eps/p<=4e-3).
// exp2(s2) accumulated; labels in exp2-domain, converted once by ln2.
constexpr int XS_ = 72;                   // f16 row stride (144 B)
constexpr float SC_  = 2.6857914f;        // sqrt(5*log2(e))
constexpr float EPS_ = 1e-6f;
constexpr float LN2_ = 0.6931471805599453f;
__global__ __launch_bounds__(1024) void contrast_kernel(
    const float* __restrict__ hu, const float* __restrict__ an,
    float* __restrict__ loss_acc) {
  __shared__ __align__(16) _Float16 Xh[512 * XS_];  // 72 KB
  __shared__ float iN[512];
  int tid = threadIdx.x;
  int c = blockIdx.x;

  if (tid < 512) {
    int row = tid & 255;
    const float* r1 = (tid < 256 ? hu : an) + ((size_t)c * CB_ + row) * 64;
    float4 a4[16];
    float s1 = 0.f;
    #pragma unroll
    for (int t = 0; t < 16; t++) {
      a4[t] = ((const float4*)r1)[t];
      s1 += a4[t].x * a4[t].x + a4[t].y * a4[t].y + a4[t].z * a4[t].z + a4[t].w * a4[t].w;
    }
    float inv = frcp(sqrtf(s1));
    iN[tid] = inv;
    float sc = inv * SC_;
    #pragma unroll
    for (int t = 0; t < 8; t++) {
      f16x8 v;
      v[0] = (_Float16)(a4[2*t].x * sc);   v[1] = (_Float16)(a4[2*t].y * sc);
      v[2] = (_Float16)(a4[2*t].z * sc);   v[3] = (_Float16)(a4[2*t].w * sc);
      v[4] = (_Float16)(a4[2*t+1].x * sc); v[5] = (_Float16)(a4[2*t+1].y * sc);
      v[6] = (_Float16)(a4[2*t+1].z * sc); v[7] = (_Float16)(a4[2*t+1].w * sc);
      *(f16x8*)&Xh[tid * XS_ + t * 8] = v;
    }
  }
  __syncthreads();

  int l = tid & 63, wv = tid >> 6;       // wv 0..15
  int n = l & 15, q = l >> 4;
  int rb = wv * 32;                      // 2 row-tiles: rb, rb+16
  f16x8 A[2][2];
  #pragma unroll
  for (int t = 0; t < 2; t++) {
    A[t][0] = *(const f16x8*)&Xh[(rb + t * 16 + n) * XS_ + q * 8];
    A[t][1] = *(const f16x8*)&Xh[(rb + t * 16 + n) * XS_ + 32 + q * 8];
  }
  float eNiR[2][4];                      // eps * invN(row)
  #pragma unroll
  for (int t = 0; t < 2; t++)
    #pragma unroll
    for (int r = 0; r < 4; r++)
      eNiR[t][r] = EPS_ * iN[rb + t * 16 + q * 4 + r];
  float sums[2][4] = {{0,0,0,0},{0,0,0,0}};
  float labs2[2] = {0, 0};
  int selfn = q * 4;
  const floatx4 zero = {0.f, 0.f, 0.f, 0.f};
  for (int ct = 0; ct < 32; ct++) {
    f16x8 B0 = *(const f16x8*)&Xh[(ct * 16 + n) * XS_ + q * 8];
    f16x8 B1 = *(const f16x8*)&Xh[(ct * 16 + n) * XS_ + 32 + q * 8];
    float iNj = iN[ct * 16 + n];
    #pragma unroll
    for (int t = 0; t < 2; t++) {
      floatx4 acc = __builtin_amdgcn_mfma_f32_16x16x32_f16(A[t][0], B0, zero, 0, 0, 0);
      acc = __builtin_amdgcn_mfma_f32_16x16x32_f16(A[t][1], B1, acc, 0, 0, 0);
      int rtg = wv * 2 + t;
      if (ct == (rtg ^ 16)) {
        #pragma unroll
        for (int r = 0; r < 4; r++) {
          float G = acc[r];
          float u = eNiR[t][r] * iNj;
          float s2 = __builtin_fmaf(G, -u, G);
          sums[t][r] += fexp2(s2);
          if (n == selfn + r) labs2[t] += s2;
        }
      } else if (ct == rtg) {
        #pragma unroll
        for (int r = 0; r < 4; r++) {
          float G = acc[r];
          float u = eNiR[t][r] * iNj;
          float s2 = __builtin_fmaf(G, -u, G);
          float e = (n == selfn + r) ? 0.f : fexp2(s2);
          sums[t][r] += e;
        }
      } else {
        #pragma unroll
        for (int r = 0; r < 4; r++) {
          float G = acc[r];
          float u = eNiR[t][r] * iNj;
          float s2 = __builtin_fmaf(G, -u, G);
          sums[t][r] += fexp2(s2);
        }
      }
    }
  }
  #pragma unroll
  for (int off = 1; off <= 8; off <<= 1) {
    #pragma unroll
    for (int t = 0; t < 2; t++) {
      #pragma unroll
      for (int r = 0; r < 4; r++) sums[t][r] += __shfl_xor(sums[t][r], off, 64);
      labs2[t] += __shfl_xor(labs2[t], off, 64);
    }
  }
  float part = 0.f;
  if (n == 0) {
    #pragma unroll
    for (int t = 0; t < 2; t++) {
      float lt = 0.f;
      #pragma unroll
      for (int r = 0; r < 4; r++) lt += __logf(sums[t][r]);
      part += lt - labs2[t] * LN2_;
    }
  }
  #pragma unroll
  for (int off = 1; off < 64; off <<= 1) part += __shfl_xor(part, off, 64);
  if (l == 0) atomicAdd(loss_acc, part);
}

// ---------------- 6. scores ----------------
__global__ __launch_bounds__(256) void score_kernel(
    const float* __restrict__ hu, const float* __restrict__ hi,
    const int* __restrict__ pu, const int* __restrict__ pi,
    const int* __restrict__ nu, const int* __restrict__ ni,
    void* __restrict__ out, const float* __restrict__ flag) {
  int isf32 = *flag > 0.5f;
  int w = (blockIdx.x * 256 + threadIdx.x) >> 6;
  int lane = threadIdx.x & 63;
  int uu, ii;
  if (w < EP_) { uu = pu[w]; ii = pi[w]; }
  else         { uu = nu[w - EP_]; ii = ni[w - EP_]; }
  float p = hu[(size_t)uu * 64 + lane] * hi[(size_t)ii * 64 + lane];
  #pragma unroll
  for (int off = 32; off; off >>= 1) p += __shfl_xor(p, off, 64);
  if (lane == 0) {
    if (isf32) ((float*)out)[w] = p;
    else       ((__hip_bfloat16*)out)[w] = __float2bfloat16(p);
  }
}

__global__ void finalize_kernel(const float* __restrict__ loss_acc,
                                void* __restrict__ out,
                                const float* __restrict__ flag) {
  float v = loss_acc[0] * (1.0f / (float)(2 * CB_ * NCHUNK_));
  if (*flag > 0.5f) ((float*)out)[2 * EP_] = v;
  else              ((__hip_bfloat16*)out)[2 * EP_] = __float2bfloat16(v);
}

// ---------------- launch ----------------
extern "C" void kernel_launch(void* const* d_in, const int* in_sizes, int n_in,
                              void* d_out, int out_size, void* d_ws, size_t ws_size,
                              hipStream_t stream) {
  const void* ue  = d_in[0];
  const void* ie  = d_in[1];
  const void* W   = d_in[2];
  const void* a   = d_in[3];
  const void* WU  = d_in[4];
  const void* aU  = d_in[5];
  const void* cw  = d_in[6];
  const int* rs  = (const int*)d_in[7];
  const int* rd  = (const int*)d_in[8];
  const int* pu  = (const int*)d_in[9];
  const int* pi  = (const int*)d_in[10];
  const int* nu  = (const int*)d_in[11];
  const int* ni  = (const int*)d_in[12];
  const int* nbr = (const int*)d_in[13];

  float* wsf  = (float*)d_ws;
  int*   wsi  = (int*)d_ws;
  float* loss = wsf + OFF_LOSS;
  float* flag = wsf + OFF_FLAG;
  int* curU   = wsi + OFF_CURU;
  int* curI   = wsi + OFF_CURI;
  float* vecs = wsf + OFF_VEC;
  int* bbU    = wsi + OFF_BBU;
  int* bbI    = wsi + OFF_BBI;
  int* rowU   = wsi + OFF_ROWU;
  int* rowI   = wsi + OFF_ROWI;
  int* csrU   = wsi + OFF_CSRU;
  int* csrI   = wsi + OFF_CSRI;
  __hip_bfloat16* u1 = (__hip_bfloat16*)(wsf + OFF_U1);
  __hip_bfloat16* i1 = (__hip_bfloat16*)(wsf + OFF_I1);
  float* hu   = wsf + OFF_HU;
  float* hi   = wsf + OFF_HI;
  float* anc  = wsf + OFF_ANC;
  unsigned* bufU = (unsigned*)(wsf + OFF_HU);
  unsigned* bufI = (unsigned*)(wsf + OFF_HI);

  hipMemsetAsync(d_ws, 0, MEMSET_BYTES, stream);
  prep_kernel<<<1, 64, 0, stream>>>((const unsigned short*)ue, W, a, WU, aU, vecs, flag);

  // CSR build: fused Phase A, tiny scan, fused Phase B
  bucketA_kernel<<<NBA_, 256, 0, stream>>>(rs, rd, bufU, bufI, curU, curI);
  scanBuckets_kernel<<<1, 64, 0, stream>>>(curU, curI, bbU, bbI, rowU, rowI);
  bucketB_kernel<<<2 * NBK_, 256, 0, stream>>>(bufU, bufI, curU, curI, bbU, bbI,
                                               rowU, rowI, csrU, csrI);

  // layer-1 aggregation (gather, bf16 out)
  agg1_kernel<<<I_ / 4, 256, 0, stream>>>(ue, rowI, csrI, i1, flag);
  agg1_kernel<<<U_ / 4, 256, 0, stream>>>(ie, rowU, csrU, u1, flag);

  // layer-2 aggregation + fused layer attention (bf16 l1 in)
  agg2attn_kernel<<<I_ / 4, 256, 0, stream>>>(u1, ie, i1, rowI, csrI, vecs, hi, flag);
  agg2attn_kernel<<<U_ / 4, 256, 0, stream>>>(i1, ue, u1, rowU, csrU, vecs, hu, flag);

  // anchor path (16 users/block, MFMA matvec)
  anchor_kernel<<<U_ / 16, 256, 0, stream>>>(ue, WU, cw, vecs, nbr, anc, flag);

  // contrastive loss (1 block/chunk, 16 waves, slim MFMA Gram)
  contrast_kernel<<<NCHUNK_, 1024, 0, stream>>>(hu, anc, loss);

  // scores
  score_kernel<<<(2 * EP_ * 64) / 256, 256, 0, stream>>>(hu, hi, pu, pi, nu, ni, d_out, flag);
  finalize_kernel<<<1, 1, 0, stream>>>(loss, d_out, flag);
}

// Round 14
// 454.063 us; speedup vs baseline: 1.8122x; 1.0173x over previous
//
#include <hip/hip_runtime.h>
#include <hip/hip_bf16.h>

// ---------------- problem constants ----------------
constexpr int U_  = 51200;
constexpr int I_  = 25600;
constexpr int E_  = 1000000;
constexpr int EP_ = 100000;
constexpr int CB_ = 256;                 // contrastive chunk size
constexpr int NCHUNK_ = U_ / CB_;        // 200
constexpr size_t UD_ = (size_t)U_ * 64;
constexpr size_t ID_ = (size_t)I_ * 64;
constexpr int NBK_ = 200;                // buckets per side
constexpr int CAP_ = 8192;               // record slots per bucket (+45 sigma)
constexpr int TILE_ = 4096;              // edges per Phase-A block
constexpr int NBA_ = (E_ + TILE_ - 1) / TILE_;  // 245
constexpr int NSCORE_ = 2 * EP_ / 16;    // 12500 score blocks (16 waves each)

// ---------------- workspace layout (4-byte element offsets) ----------------
constexpr size_t OFF_LOSS  = 0;
constexpr size_t OFF_FLAG  = 1;
constexpr size_t OFF_CURU  = 8;                      // 200 ints
constexpr size_t OFF_CURI  = 208;                    // 200 ints
constexpr size_t MEMSET_BYTES = 408 * 4;
constexpr size_t OFF_VEC   = 448;                    // 192 floats: Wa | vU1 | vU2
constexpr size_t OFF_BBU   = 640;                    // 201 ints
constexpr size_t OFF_BBI   = 848;                    // 201 ints
constexpr size_t OFF_ROWU  = 1088;                   // U_+1
constexpr size_t OFF_ROWI  = ((OFF_ROWU + U_ + 1 + 63) / 64) * 64;   // I_+1
constexpr size_t OFF_CSRU  = ((OFF_ROWI + I_ + 1 + 63) / 64) * 64;   // E_
constexpr size_t OFF_CSRI  = OFF_CSRU + E_;          // E_
constexpr size_t OFF_U1    = ((OFF_CSRI + E_ + 63) / 64) * 64;       // UD_ (bf16)
constexpr size_t OFF_I1    = OFF_U1 + UD_;
constexpr size_t OFF_HU    = OFF_I1 + ID_;           // bufU aliases
constexpr size_t OFF_HI    = OFF_HU + UD_;           // bufI aliases
constexpr size_t OFF_ANC   = OFF_HI + ID_;
// total ≈ 60.7 MB

#define DEVI static __device__ __forceinline__

typedef _Float16 h2v __attribute__((ext_vector_type(2)));
typedef _Float16 f16x8 __attribute__((ext_vector_type(8)));
typedef float floatx4 __attribute__((ext_vector_type(4)));

DEVI float b2f(__hip_bfloat16 x) { return __bfloat162float(x); }

DEVI float ldf(const void* p, size_t i, int isf32) {
  if (isf32) return ((const float*)p)[i];
  return b2f(((const __hip_bfloat16*)p)[i]);
}

DEVI float frcp(float x) { return __builtin_amdgcn_rcpf(x); }

DEVI float fexp2(float x) {
#if __has_builtin(__builtin_amdgcn_exp2f)
  return __builtin_amdgcn_exp2f(x);
#else
  return exp2f(x);
#endif
}

DEVI int waveInclScan(int v, int lane) {
  #pragma unroll
  for (int off = 1; off < 64; off <<= 1) {
    int t = __shfl_up(v, off, 64);
    if (lane >= off) v += t;
  }
  return v;
}

// ---------------- 0. prep ----------------
__global__ void prep_kernel(const unsigned short* __restrict__ ueu,
                            const void* __restrict__ W, const void* __restrict__ a,
                            const void* __restrict__ WU, const void* __restrict__ aU,
                            float* __restrict__ vecs, float* __restrict__ flag) {
  int cnt = 0;
  for (int i = 0; i < 256; i++) {
    int e = (ueu[i] >> 7) & 0xFF;
    if (e >= 130) cnt++;
  }
  int isf32 = (cnt >= 8);
  if (threadIdx.x == 0) *flag = isf32 ? 1.0f : 0.0f;
  int d = threadIdx.x;
  float s = 0.f, t1 = 0.f, t2 = 0.f;
  for (int e = 0; e < 64; e++) {
    s += ldf(W, d * 64 + e, isf32) * ldf(a, e, isf32);
    float wue = ldf(WU, d * 64 + e, isf32);
    t1 += wue * ldf(aU, e, isf32);
    t2 += wue * ldf(aU, 64 + e, isf32);
  }
  vecs[d] = s;
  vecs[64 + d] = t1;
  vecs[128 + d] = t2;
}

// ---------------- fused A: bucketA (blocks 0..244) + anchor (rest) -------------
struct BktSmem {
  int histU[NBK_], histI[NBK_];
  int loffU[NBK_ + 1], loffI[NBK_ + 1];
  int cbU[NBK_], cbI[NBK_];
  int lcU[NBK_], lcI[NBK_];
  int wsU[4], wsI[4];
  unsigned recsU[TILE_], recsI[TILE_];
};
constexpr int WS_ = 72;  // f16 row stride for WUt/mixS
struct AncSmem {
  _Float16 WUt[64 * WS_];
  _Float16 mixS[16 * WS_];
  float invSe[16];
  int nbrS[128];
};
constexpr size_t FSA_SMEM = sizeof(BktSmem) > sizeof(AncSmem) ? sizeof(BktSmem) : sizeof(AncSmem);

DEVI void bucketA_body(char* smemRaw, int blk,
    const int* __restrict__ rs, const int* __restrict__ rd,
    unsigned* __restrict__ bufU, unsigned* __restrict__ bufI,
    int* __restrict__ curU, int* __restrict__ curI) {
  BktSmem& S = *(BktSmem*)smemRaw;
  int tid = threadIdx.x;
  int base = blk * TILE_;
  for (int i = tid; i < NBK_; i += 256) { S.histU[i] = 0; S.histI[i] = 0; }
  __syncthreads();
  int ss[16], dd[16];
  #pragma unroll
  for (int t = 0; t < 16; t++) {
    int e = base + t * 256 + tid;
    bool v = e < E_;
    ss[t] = v ? rs[e] : -1;
    dd[t] = v ? rd[e] : 0;
    if (v) {
      atomicAdd(&S.histU[ss[t] >> 8], 1);
      atomicAdd(&S.histI[dd[t] >> 7], 1);
    }
  }
  __syncthreads();
  if (tid < NBK_) {
    int cU = S.histU[tid];
    S.cbU[tid] = tid * CAP_ + (cU ? atomicAdd(&curU[tid], cU) : 0);
    int cI = S.histI[tid];
    S.cbI[tid] = tid * CAP_ + (cI ? atomicAdd(&curI[tid], cI) : 0);
  }
  int lane = tid & 63, wv = tid >> 6;
  int cvU = (tid < NBK_) ? S.histU[tid] : 0;
  int cvI = (tid < NBK_) ? S.histI[tid] : 0;
  int inU = waveInclScan(cvU, lane);
  int inI = waveInclScan(cvI, lane);
  if (lane == 63) { S.wsU[wv] = inU; S.wsI[wv] = inI; }
  __syncthreads();
  int woU = 0, woI = 0;
  for (int w = 0; w < wv; w++) { woU += S.wsU[w]; woI += S.wsI[w]; }
  if (tid < NBK_) {
    S.loffU[tid] = woU + inU - cvU;
    S.loffI[tid] = woI + inI - cvI;
  }
  if (tid == NBK_ - 1) {
    S.loffU[NBK_] = woU + inU;
    S.loffI[NBK_] = woI + inI;
  }
  __syncthreads();
  if (tid < NBK_) { S.lcU[tid] = S.loffU[tid]; S.lcI[tid] = S.loffI[tid]; }
  __syncthreads();
  #pragma unroll
  for (int t = 0; t < 16; t++) {
    if (ss[t] >= 0) {
      int b = ss[t] >> 8;
      int p = atomicAdd(&S.lcU[b], 1);
      S.recsU[p] = ((unsigned)(ss[t] & 255) << 17) | (unsigned)dd[t];
      b = dd[t] >> 7;
      p = atomicAdd(&S.lcI[b], 1);
      S.recsI[p] = ((unsigned)(dd[t] & 127) << 17) | (unsigned)ss[t];
    }
  }
  __syncthreads();
  int totU = S.loffU[NBK_];
  for (int p = tid; p < totU; p += 256) {
    int lo = 0, hi = NBK_;
    while (hi - lo > 1) { int mid = (lo + hi) >> 1; if (S.loffU[mid] <= p) lo = mid; else hi = mid; }
    bufU[S.cbU[lo] + (p - S.loffU[lo])] = S.recsU[p];
  }
  int totI = S.loffI[NBK_];
  for (int p = tid; p < totI; p += 256) {
    int lo = 0, hi = NBK_;
    while (hi - lo > 1) { int mid = (lo + hi) >> 1; if (S.loffI[mid] <= p) lo = mid; else hi = mid; }
    bufI[S.cbI[lo] + (p - S.loffI[lo])] = S.recsI[p];
  }
}

DEVI void anchor_body(char* smemRaw, int blk,
    const void* __restrict__ ue, const void* __restrict__ WU,
    const void* __restrict__ cw, const float* __restrict__ vecs,
    const int* __restrict__ nbr, float* __restrict__ out, int isf32) {
  AncSmem& S = *(AncSmem*)smemRaw;
  int tid = threadIdx.x;
  int wv = tid >> 6, lane = tid & 63;
  int ublk = blk * 16;

  #pragma unroll
  for (int it = 0; it < 16; it++) {
    int k = it * 4 + wv;
    S.WUt[lane * WS_ + k] = (_Float16)ldf(WU, (size_t)k * 64 + lane, isf32);
  }
  if (tid < 128) S.nbrS[tid] = nbr[ublk * 8 + tid];
  __syncthreads();

  float cw0 = ldf(cw, (0 * 64 + lane) * 2, isf32);
  float w1r = ldf(cw, (1 * 64 + lane) * 2, isf32), w1i = ldf(cw, (1 * 64 + lane) * 2 + 1, isf32);
  float w2r = ldf(cw, (2 * 64 + lane) * 2, isf32), w2i = ldf(cw, (2 * 64 + lane) * 2 + 1, isf32);
  float w3r = ldf(cw, (3 * 64 + lane) * 2, isf32), w3i = ldf(cw, (3 * 64 + lane) * 2 + 1, isf32);
  float cw4 = ldf(cw, (4 * 64 + lane) * 2, isf32);
  float v1 = vecs[64 + lane], v2 = vecs[128 + lane];
  const float c1 = 0.70710678118654752440f;

  float xc[8], xn[8];
  #pragma unroll
  for (int k = 0; k < 8; k++)
    xc[k] = ldf(ue, (size_t)S.nbrS[wv * 32 + k] * 64 + lane, isf32);

  for (int u4 = 0; u4 < 4; u4++) {
    int uL = wv * 4 + u4;
    int u = ublk + uL;
    if (u4 < 3) {
      #pragma unroll
      for (int k = 0; k < 8; k++)
        xn[k] = ldf(ue, (size_t)S.nbrS[wv * 32 + (u4 + 1) * 8 + k] * 64 + lane, isf32);
    }
    float sA = xc[1] - xc[3] - xc[5] + xc[7];
    float sB = xc[1] + xc[3] - xc[5] - xc[7];
    float ev = (xc[0] + xc[4]) + (xc[2] + xc[6]);
    float od = (xc[1] + xc[5]) + (xc[3] + xc[7]);
    float d04 = xc[0] - xc[4], d26 = xc[2] - xc[6];
    float X0r = ev + od;
    float X1r = d04 + c1 * sA;
    float X1i = -d26 - c1 * sB;
    float X2r = (xc[0] + xc[4]) - (xc[2] + xc[6]);
    float X2i = -(xc[1] - xc[3] + xc[5] - xc[7]);
    float X3r = d04 - c1 * sA;
    float X3i = d26 - c1 * sB;
    float X4r = ev - od;
    float Zr0 = X0r * cw0;
    float Zr1 = X1r * w1r - X1i * w1i, Zi1 = X1r * w1i + X1i * w1r;
    float Zr2 = X2r * w2r - X2i * w2i, Zi2 = X2r * w2i + X2i * w2r;
    float Zr3 = X3r * w3r - X3i * w3i, Zi3 = X3r * w3i + X3i * w3r;
    float Zr4 = X4r * cw4;
    float eP = Zr0 + Zr4, eM = Zr0 - Zr4;
    float t1 = c1 * (Zr1 - Zr3), t2 = c1 * (Zi1 + Zi3);
    float y[8];
    y[0] = eP + 2.f * (Zr1 + Zr2 + Zr3);
    y[1] = eM + 2.f * (t1 - t2 - Zi2);
    y[2] = eP + 2.f * (-Zi1 - Zr2 + Zi3);
    y[3] = eM + 2.f * (-t1 - t2 + Zi2);
    y[4] = eP + 2.f * (-Zr1 + Zr2 - Zr3);
    y[5] = eM + 2.f * (-t1 + t2 - Zi2);
    y[6] = eP + 2.f * (Zi1 - Zr2 - Zi3);
    y[7] = eM + 2.f * (t1 + t2 + Zi2);
    #pragma unroll
    for (int k = 0; k < 8; k++) y[k] *= 0.125f;

    float ek[8];
    #pragma unroll
    for (int k = 0; k < 8; k++) ek[k] = y[k] * v1;
    float q = ldf(ue, (size_t)u * 64 + lane, isf32) * v2;
    #pragma unroll
    for (int off = 32; off; off >>= 1) {
      #pragma unroll
      for (int k = 0; k < 8; k++) ek[k] += __shfl_xor(ek[k], off, 64);
      q += __shfl_xor(q, off, 64);
    }
    float m = -1e30f;
    #pragma unroll
    for (int k = 0; k < 8; k++) {
      float v = ek[k] + q;
      v = v > 0.f ? v : 0.1f * v;  // LeakyReLU(0.1)
      ek[k] = v;
      m = fmaxf(m, v);
    }
    float se = 0.f, wexp[8];
    #pragma unroll
    for (int k = 0; k < 8; k++) { wexp[k] = __expf(ek[k] - m); se += wexp[k]; }
    float mix = 0.f;
    #pragma unroll
    for (int k = 0; k < 8; k++) mix += wexp[k] * y[k];
    S.mixS[uL * WS_ + lane] = (_Float16)mix;
    if (lane == 0) S.invSe[uL] = frcp(se);
    #pragma unroll
    for (int k = 0; k < 8; k++) xc[k] = xn[k];
  }
  __syncthreads();

  int n = lane & 15, qd = lane >> 4;
  f16x8 A0 = *(const f16x8*)&S.mixS[(lane & 15) * WS_ + qd * 8];
  f16x8 A1 = *(const f16x8*)&S.mixS[(lane & 15) * WS_ + 32 + qd * 8];
  f16x8 B0 = *(const f16x8*)&S.WUt[(wv * 16 + n) * WS_ + qd * 8];
  f16x8 B1 = *(const f16x8*)&S.WUt[(wv * 16 + n) * WS_ + 32 + qd * 8];
  const floatx4 zero = {0.f, 0.f, 0.f, 0.f};
  floatx4 acc = __builtin_amdgcn_mfma_f32_16x16x32_f16(A0, B0, zero, 0, 0, 0);
  acc = __builtin_amdgcn_mfma_f32_16x16x32_f16(A1, B1, acc, 0, 0, 0);
  #pragma unroll
  for (int r = 0; r < 4; r++) {
    int m = qd * 4 + r;
    out[(size_t)(ublk + m) * 64 + wv * 16 + n] = acc[r] * S.invSe[m];
  }
}

__global__ __launch_bounds__(256) void fusedA_kernel(
    const int* __restrict__ rs, const int* __restrict__ rd,
    unsigned* __restrict__ bufU, unsigned* __restrict__ bufI,
    int* __restrict__ curU, int* __restrict__ curI,
    const void* __restrict__ ue, const void* __restrict__ WU,
    const void* __restrict__ cw, const float* __restrict__ vecs,
    const int* __restrict__ nbr, float* __restrict__ anc,
    const float* __restrict__ flag) {
  __shared__ __align__(16) char smem[FSA_SMEM];
  if (blockIdx.x < NBA_) {
    bucketA_body(smem, blockIdx.x, rs, rd, bufU, bufI, curU, curI);
  } else {
    anchor_body(smem, blockIdx.x - NBA_, ue, WU, cw, vecs, nbr, anc, *flag > 0.5f);
  }
}

// ---------------- 1b. tiny scan ----------------
__global__ void scanBuckets_kernel(const int* __restrict__ curU,
                                   const int* __restrict__ curI,
                                   int* __restrict__ bbU, int* __restrict__ bbI,
                                   int* __restrict__ rowU, int* __restrict__ rowI) {
  if (threadIdx.x == 0) {
    int run = 0;
    for (int i = 0; i < NBK_; i++) { bbU[i] = run; run += curU[i]; }
    bbU[NBK_] = run;
    run = 0;
    for (int i = 0; i < NBK_; i++) { bbI[i] = run; run += curI[i]; }
    bbI[NBK_] = run;
    rowU[U_] = E_;
    rowI[I_] = E_;
  }
}

// ---------------- 1c. Phase B ----------------
__global__ __launch_bounds__(256) void bucketB_kernel(
    const unsigned* __restrict__ bufU, const unsigned* __restrict__ bufI,
    const int* __restrict__ curU, const int* __restrict__ curI,
    const int* __restrict__ bbU, const int* __restrict__ bbI,
    int* __restrict__ rowU, int* __restrict__ rowI,
    int* __restrict__ csrU, int* __restrict__ csrI) {
  __shared__ int stage[CAP_];
  __shared__ int cntk[256], offk[256];
  __shared__ int wsum[4];
  int tid = threadIdx.x, b = blockIdx.x;
  int side = b >= NBK_;
  int bb = side ? b - NBK_ : b;
  const unsigned* src = (side ? bufI : bufU) + (size_t)bb * CAP_;
  int total = side ? curI[bb] : curU[bb];
  int gbase = side ? bbI[bb] : bbU[bb];
  int kpb   = side ? 128 : 256;
  int* rowptr = side ? rowI : rowU;
  int* csr    = side ? csrI : csrU;
  cntk[tid] = 0;
  __syncthreads();
  for (int r = tid; r < total; r += 256) atomicAdd(&cntk[src[r] >> 17], 1);
  __syncthreads();
  int lane = tid & 63, wv = tid >> 6;
  int cv = (tid < kpb) ? cntk[tid] : 0;
  int incl = waveInclScan(cv, lane);
  if (lane == 63) wsum[wv] = incl;
  __syncthreads();
  int wvoff = 0;
  for (int w = 0; w < wv; w++) wvoff += wsum[w];
  int excl = wvoff + incl - cv;
  if (tid < kpb) {
    offk[tid] = excl;
    rowptr[bb * kpb + tid] = gbase + excl;
  }
  __syncthreads();
  for (int r = tid; r < total; r += 256) {
    unsigned rec = src[r];
    int slot = atomicAdd(&offk[rec >> 17], 1);
    if (slot < CAP_) stage[slot] = (int)(rec & 0x1FFFFu);
  }
  __syncthreads();
  for (int s = tid; s < total; s += 256) csr[gbase + s] = stage[s];
}

// ---------------- 2. fused layer-1 aggregation (both sides, bf16 out) -----------
__global__ __launch_bounds__(256) void agg1_kernel(
    const void* __restrict__ ue, const void* __restrict__ ie,
    const int* __restrict__ rowU, const int* __restrict__ rowI,
    const int* __restrict__ csrU, const int* __restrict__ csrI,
    __hip_bfloat16* __restrict__ u1, __hip_bfloat16* __restrict__ i1,
    const float* __restrict__ flag) {
  int isf32 = *flag > 0.5f;
  int wv = threadIdx.x >> 6, lane = threadIdx.x & 63;
  int side = blockIdx.x >= I_ / 4;          // 0: item rows (gather ue), 1: user rows
  int blk = side ? blockIdx.x - I_ / 4 : blockIdx.x;
  int r = blk * 4 + wv;
  const int* row = side ? rowU : rowI;
  const int* csr = side ? csrU : csrI;
  const void* src = side ? ie : ue;
  __hip_bfloat16* out = side ? u1 : i1;
  int s0 = row[r], s1 = row[r + 1];
  float acc = 0.f;
  int j = s0;
  for (; j + 4 <= s1; j += 4) {
    int a = csr[j], b = csr[j + 1], c = csr[j + 2], d = csr[j + 3];
    float va = ldf(src, (size_t)a * 64 + lane, isf32);
    float vb = ldf(src, (size_t)b * 64 + lane, isf32);
    float vc = ldf(src, (size_t)c * 64 + lane, isf32);
    float vd = ldf(src, (size_t)d * 64 + lane, isf32);
    acc += (va + vb) + (vc + vd);
  }
  for (; j < s1; j++) acc += ldf(src, (size_t)csr[j] * 64 + lane, isf32);
  out[(size_t)r * 64 + lane] = __float2bfloat16(acc / fmaxf((float)(s1 - s0), 1.0f));
}

// ---------------- 3. fused layer-2 aggregation + attention (both sides) ---------
__global__ __launch_bounds__(256) void agg2attn_kernel(
    const __hip_bfloat16* __restrict__ u1, const __hip_bfloat16* __restrict__ i1,
    const void* __restrict__ ue, const void* __restrict__ ie,
    const int* __restrict__ rowU, const int* __restrict__ rowI,
    const int* __restrict__ csrU, const int* __restrict__ csrI,
    const float* __restrict__ vecs, float* __restrict__ hu, float* __restrict__ hi,
    const float* __restrict__ flag) {
  int isf32 = *flag > 0.5f;
  int wv = threadIdx.x >> 6, lane = threadIdx.x & 63;
  int side = blockIdx.x >= I_ / 4;          // 0: item rows, 1: user rows
  int blk = side ? blockIdx.x - I_ / 4 : blockIdx.x;
  int r = blk * 4 + wv;
  const int* row = side ? rowU : rowI;
  const int* csr = side ? csrU : csrI;
  const __hip_bfloat16* opp1 = side ? i1 : u1;
  const __hip_bfloat16* own1 = side ? u1 : i1;
  const void* base = side ? ue : ie;
  float* h = side ? hu : hi;
  int s0 = row[r], s1 = row[r + 1];
  float acc = 0.f;
  int j = s0;
  for (; j + 4 <= s1; j += 4) {
    int a = csr[j], b = csr[j + 1], c = csr[j + 2], d = csr[j + 3];
    float va = b2f(opp1[(size_t)a * 64 + lane]);
    float vb = b2f(opp1[(size_t)b * 64 + lane]);
    float vc = b2f(opp1[(size_t)c * 64 + lane]);
    float vd = b2f(opp1[(size_t)d * 64 + lane]);
    acc += (va + vb) + (vc + vd);
  }
  for (; j < s1; j++) acc += b2f(opp1[(size_t)csr[j] * 64 + lane]);
  size_t idx = (size_t)r * 64 + lane;
  float t2 = acc / fmaxf((float)(s1 - s0), 1.0f);
  float t0 = ldf(base, idx, isf32);
  float t1 = b2f(own1[idx]);
  float w = vecs[lane];   // Wa
  float p0 = t0 * w, p1 = t1 * w, p2 = t2 * w;
  #pragma unroll
  for (int off = 32; off; off >>= 1) {
    p0 += __shfl_xor(p0, off, 64);
    p1 += __shfl_xor(p1, off, 64);
    p2 += __shfl_xor(p2, off, 64);
  }
  float m = fmaxf(p0, fmaxf(p1, p2));
  float e0 = __expf(p0 - m), e1 = __expf(p1 - m), e2 = __expf(p2 - m);
  float inv = 1.0f / (e0 + e1 + e2);
  h[idx] = (t0 * e0 + t1 * e1 + t2 * e2) * inv;
}

// ---------------- fused loss: contrast (blocks 0..199) + score (rest) ----------
constexpr int XS_ = 72;                   // f16 row stride (144 B)
constexpr float SC_  = 2.6857914f;        // sqrt(5*log2(e))
constexpr float EPS_ = 1e-6f;
constexpr float LN2_ = 0.6931471805599453f;
struct CtrSmem {
  _Float16 Xh[512 * XS_];
  float iN[512];
};

DEVI void contrast_body(char* smemRaw, int c,
    const float* __restrict__ hu, const float* __restrict__ an,
    float* __restrict__ loss_acc) {
  CtrSmem& S = *(CtrSmem*)smemRaw;
  int tid = threadIdx.x;
  if (tid < 512) {
    int row = tid & 255;
    const float* r1 = (tid < 256 ? hu : an) + ((size_t)c * CB_ + row) * 64;
    float4 a4[16];
    float s1 = 0.f;
    #pragma unroll
    for (int t = 0; t < 16; t++) {
      a4[t] = ((const float4*)r1)[t];
      s1 += a4[t].x * a4[t].x + a4[t].y * a4[t].y + a4[t].z * a4[t].z + a4[t].w * a4[t].w;
    }
    float inv = frcp(sqrtf(s1));
    S.iN[tid] = inv;
    float sc = inv * SC_;
    #pragma unroll
    for (int t = 0; t < 8; t++) {
      f16x8 v;
      v[0] = (_Float16)(a4[2*t].x * sc);   v[1] = (_Float16)(a4[2*t].y * sc);
      v[2] = (_Float16)(a4[2*t].z * sc);   v[3] = (_Float16)(a4[2*t].w * sc);
      v[4] = (_Float16)(a4[2*t+1].x * sc); v[5] = (_Float16)(a4[2*t+1].y * sc);
      v[6] = (_Float16)(a4[2*t+1].z * sc); v[7] = (_Float16)(a4[2*t+1].w * sc);
      *(f16x8*)&S.Xh[tid * XS_ + t * 8] = v;
    }
  }
  __syncthreads();

  int l = tid & 63, wv = tid >> 6;       // wv 0..15
  int n = l & 15, q = l >> 4;
  int rb = wv * 32;
  f16x8 A[2][2];
  #pragma unroll
  for (int t = 0; t < 2; t++) {
    A[t][0] = *(const f16x8*)&S.Xh[(rb + t * 16 + n) * XS_ + q * 8];
    A[t][1] = *(const f16x8*)&S.Xh[(rb + t * 16 + n) * XS_ + 32 + q * 8];
  }
  float eNiR[2][4];
  #pragma unroll
  for (int t = 0; t < 2; t++)
    #pragma unroll
    for (int r = 0; r < 4; r++)
      eNiR[t][r] = EPS_ * S.iN[rb + t * 16 + q * 4 + r];
  float sums[2][4] = {{0,0,0,0},{0,0,0,0}};
  float labs2[2] = {0, 0};
  int selfn = q * 4;
  const floatx4 zero = {0.f, 0.f, 0.f, 0.f};
  for (int ct = 0; ct < 32; ct++) {
    f16x8 B0 = *(const f16x8*)&S.Xh[(ct * 16 + n) * XS_ + q * 8];
    f16x8 B1 = *(const f16x8*)&S.Xh[(ct * 16 + n) * XS_ + 32 + q * 8];
    float iNj = S.iN[ct * 16 + n];
    #pragma unroll
    for (int t = 0; t < 2; t++) {
      floatx4 acc = __builtin_amdgcn_mfma_f32_16x16x32_f16(A[t][0], B0, zero, 0, 0, 0);
      acc = __builtin_amdgcn_mfma_f32_16x16x32_f16(A[t][1], B1, acc, 0, 0, 0);
      int rtg = wv * 2 + t;
      if (ct == (rtg ^ 16)) {
        #pragma unroll
        for (int r = 0; r < 4; r++) {
          float G = acc[r];
          float u = eNiR[t][r] * iNj;
          float s2 = __builtin_fmaf(G, -u, G);
          sums[t][r] += fexp2(s2);
          if (n == selfn + r) labs2[t] += s2;
        }
      } else if (ct == rtg) {
        #pragma unroll
        for (int r = 0; r < 4; r++) {
          float G = acc[r];
          float u = eNiR[t][r] * iNj;
          float s2 = __builtin_fmaf(G, -u, G);
          float e = (n == selfn + r) ? 0.f : fexp2(s2);
          sums[t][r] += e;
        }
      } else {
        #pragma unroll
        for (int r = 0; r < 4; r++) {
          float G = acc[r];
          float u = eNiR[t][r] * iNj;
          float s2 = __builtin_fmaf(G, -u, G);
          sums[t][r] += fexp2(s2);
        }
      }
    }
  }
  #pragma unroll
  for (int off = 1; off <= 8; off <<= 1) {
    #pragma unroll
    for (int t = 0; t < 2; t++) {
      #pragma unroll
      for (int r = 0; r < 4; r++) sums[t][r] += __shfl_xor(sums[t][r], off, 64);
      labs2[t] += __shfl_xor(labs2[t], off, 64);
    }
  }
  float part = 0.f;
  if (n == 0) {
    #pragma unroll
    for (int t = 0; t < 2; t++) {
      float lt = 0.f;
      #pragma unroll
      for (int r = 0; r < 4; r++) lt += __logf(sums[t][r]);
      part += lt - labs2[t] * LN2_;
    }
  }
  #pragma unroll
  for (int off = 1; off < 64; off <<= 1) part += __shfl_xor(part, off, 64);
  if (l == 0) atomicAdd(loss_acc, part);
}

__global__ __launch_bounds__(1024) void fusedLoss_kernel(
    const float* __restrict__ hu, const float* __restrict__ hi,
    const float* __restrict__ an, float* __restrict__ loss_acc,
    const int* __restrict__ pu, const int* __restrict__ pi,
    const int* __restrict__ nu, const int* __restrict__ ni,
    void* __restrict__ out, const float* __restrict__ flag) {
  __shared__ __align__(16) char smem[sizeof(CtrSmem)];
  if (blockIdx.x < NCHUNK_) {
    contrast_body(smem, blockIdx.x, hu, an, loss_acc);
  } else {
    int isf32 = *flag > 0.5f;
    int w = (blockIdx.x - NCHUNK_) * 16 + (threadIdx.x >> 6);  // wave -> edge
    int lane = threadIdx.x & 63;
    int uu, ii;
    if (w < EP_) { uu = pu[w]; ii = pi[w]; }
    else         { uu = nu[w - EP_]; ii = ni[w - EP_]; }
    float p = hu[(size_t)uu * 64 + lane] * hi[(size_t)ii * 64 + lane];
    #pragma unroll
    for (int off = 32; off; off >>= 1) p += __shfl_xor(p, off, 64);
    if (lane == 0) {
      if (isf32) ((float*)out)[w] = p;
      else       ((__hip_bfloat16*)out)[w] = __float2bfloat16(p);
    }
  }
}

__global__ void finalize_kernel(const float* __restrict__ loss_acc,
                                void* __restrict__ out,
                                const float* __restrict__ flag) {
  float v = loss_acc[0] * (1.0f / (float)(2 * CB_ * NCHUNK_));
  if (*flag > 0.5f) ((float*)out)[2 * EP_] = v;
  else              ((__hip_bfloat16*)out)[2 * EP_] = __float2bfloat16(v);
}

// ---------------- launch ----------------
extern "C" void kernel_launch(void* const* d_in, const int* in_sizes, int n_in,
                              void* d_out, int out_size, void* d_ws, size_t ws_size,
                              hipStream_t stream) {
  const void* ue  = d_in[0];
  const void* ie  = d_in[1];
  const void* W   = d_in[2];
  const void* a   = d_in[3];
  const void* WU  = d_in[4];
  const void* aU  = d_in[5];
  const void* cw  = d_in[6];
  const int* rs  = (const int*)d_in[7];
  const int* rd  = (const int*)d_in[8];
  const int* pu  = (const int*)d_in[9];
  const int* pi  = (const int*)d_in[10];
  const int* nu  = (const int*)d_in[11];
  const int* ni  = (const int*)d_in[12];
  const int* nbr = (const int*)d_in[13];

  float* wsf  = (float*)d_ws;
  int*   wsi  = (int*)d_ws;
  float* loss = wsf + OFF_LOSS;
  float* flag = wsf + OFF_FLAG;
  int* curU   = wsi + OFF_CURU;
  int* curI   = wsi + OFF_CURI;
  float* vecs = wsf + OFF_VEC;
  int* bbU    = wsi + OFF_BBU;
  int* bbI    = wsi + OFF_BBI;
  int* rowU   = wsi + OFF_ROWU;
  int* rowI   = wsi + OFF_ROWI;
  int* csrU   = wsi + OFF_CSRU;
  int* csrI   = wsi + OFF_CSRI;
  __hip_bfloat16* u1 = (__hip_bfloat16*)(wsf + OFF_U1);
  __hip_bfloat16* i1 = (__hip_bfloat16*)(wsf + OFF_I1);
  float* hu   = wsf + OFF_HU;
  float* hi   = wsf + OFF_HI;
  float* anc  = wsf + OFF_ANC;
  unsigned* bufU = (unsigned*)(wsf + OFF_HU);
  unsigned* bufI = (unsigned*)(wsf + OFF_HI);

  hipMemsetAsync(d_ws, 0, MEMSET_BYTES, stream);
  prep_kernel<<<1, 64, 0, stream>>>((const unsigned short*)ue, W, a, WU, aU, vecs, flag);

  // fused: CSR Phase A + anchor (independent)
  fusedA_kernel<<<NBA_ + U_ / 16, 256, 0, stream>>>(
      rs, rd, bufU, bufI, curU, curI, ue, WU, cw, vecs, nbr, anc, flag);
  scanBuckets_kernel<<<1, 64, 0, stream>>>(curU, curI, bbU, bbI, rowU, rowI);
  bucketB_kernel<<<2 * NBK_, 256, 0, stream>>>(bufU, bufI, curU, curI, bbU, bbI,
                                               rowU, rowI, csrU, csrI);

  // fused layer-1 aggregation (both sides)
  agg1_kernel<<<(I_ + U_) / 4, 256, 0, stream>>>(ue, ie, rowU, rowI, csrU, csrI,
                                                 u1, i1, flag);
  // fused layer-2 aggregation + attention (both sides)
  agg2attn_kernel<<<(I_ + U_) / 4, 256, 0, stream>>>(u1, i1, ue, ie, rowU, rowI,
                                                     csrU, csrI, vecs, hu, hi, flag);

  // fused: contrast + score
  fusedLoss_kernel<<<NCHUNK_ + NSCORE_, 1024, 0, stream>>>(
      hu, hi, anc, loss, pu, pi, nu, ni, d_out, flag);
  finalize_kernel<<<1, 1, 0, stream>>>(loss, d_out, flag);
}

// Round 15
// 431.889 us; speedup vs baseline: 1.9053x; 1.0513x over previous
//
#include <hip/hip_runtime.h>
#include <hip/hip_bf16.h>

// ---------------- problem constants ----------------
constexpr int U_  = 51200;
constexpr int I_  = 25600;
constexpr int E_  = 1000000;
constexpr int EP_ = 100000;
constexpr int CB_ = 256;                 // contrastive chunk size
constexpr int NCHUNK_ = U_ / CB_;        // 200
constexpr size_t UD_ = (size_t)U_ * 64;
constexpr size_t ID_ = (size_t)I_ * 64;
constexpr int NBK_ = 200;                // buckets per side
constexpr int CAP_ = 8192;               // record slots per bucket (+45 sigma)
constexpr int TILE_ = 4096;              // edges per Phase-A block
constexpr int NBA_ = (E_ + TILE_ - 1) / TILE_;  // 245

// ---------------- workspace layout (4-byte element offsets) ----------------
constexpr size_t OFF_LOSS  = 0;
constexpr size_t OFF_FLAG  = 1;
constexpr size_t OFF_CURU  = 8;                      // 200 ints
constexpr size_t OFF_CURI  = 208;                    // 200 ints
constexpr size_t MEMSET_BYTES = 408 * 4;
constexpr size_t OFF_VEC   = 448;                    // 192 floats: Wa | vU1 | vU2
constexpr size_t OFF_BBU   = 640;                    // 201 ints
constexpr size_t OFF_BBI   = 848;                    // 201 ints
constexpr size_t OFF_ROWU  = 1088;                   // U_+1
constexpr size_t OFF_ROWI  = ((OFF_ROWU + U_ + 1 + 63) / 64) * 64;   // I_+1
constexpr size_t OFF_CSRU  = ((OFF_ROWI + I_ + 1 + 63) / 64) * 64;   // E_
constexpr size_t OFF_CSRI  = OFF_CSRU + E_;          // E_
constexpr size_t OFF_U1    = ((OFF_CSRI + E_ + 63) / 64) * 64;       // UD_ (bf16)
constexpr size_t OFF_I1    = OFF_U1 + UD_;
constexpr size_t OFF_HU    = OFF_I1 + ID_;           // bufU aliases
constexpr size_t OFF_HI    = OFF_HU + UD_;           // bufI aliases
constexpr size_t OFF_ANC   = OFF_HI + ID_;
// total ≈ 60.7 MB

#define DEVI static __device__ __forceinline__

typedef _Float16 h2v __attribute__((ext_vector_type(2)));
typedef _Float16 f16x8 __attribute__((ext_vector_type(8)));
typedef float floatx4 __attribute__((ext_vector_type(4)));

DEVI float b2f(__hip_bfloat16 x) { return __bfloat162float(x); }

DEVI float ldf(const void* p, size_t i, int isf32) {
  if (isf32) return ((const float*)p)[i];
  return b2f(((const __hip_bfloat16*)p)[i]);
}

DEVI float frcp(float x) { return __builtin_amdgcn_rcpf(x); }

DEVI float fexp2(float x) {
#if __has_builtin(__builtin_amdgcn_exp2f)
  return __builtin_amdgcn_exp2f(x);
#else
  return exp2f(x);
#endif
}

DEVI int waveInclScan(int v, int lane) {
  #pragma unroll
  for (int off = 1; off < 64; off <<= 1) {
    int t = __shfl_up(v, off, 64);
    if (lane >= off) v += t;
  }
  return v;
}

// ---------------- 0. prep ----------------
__global__ void prep_kernel(const unsigned short* __restrict__ ueu,
                            const void* __restrict__ W, const void* __restrict__ a,
                            const void* __restrict__ WU, const void* __restrict__ aU,
                            float* __restrict__ vecs, float* __restrict__ flag) {
  int cnt = 0;
  for (int i = 0; i < 256; i++) {
    int e = (ueu[i] >> 7) & 0xFF;
    if (e >= 130) cnt++;
  }
  int isf32 = (cnt >= 8);
  if (threadIdx.x == 0) *flag = isf32 ? 1.0f : 0.0f;
  int d = threadIdx.x;
  float s = 0.f, t1 = 0.f, t2 = 0.f;
  for (int e = 0; e < 64; e++) {
    s += ldf(W, d * 64 + e, isf32) * ldf(a, e, isf32);
    float wue = ldf(WU, d * 64 + e, isf32);
    t1 += wue * ldf(aU, e, isf32);
    t2 += wue * ldf(aU, 64 + e, isf32);
  }
  vecs[d] = s;
  vecs[64 + d] = t1;
  vecs[128 + d] = t2;
}

// ---------------- fused A: bucketA (blocks 0..244) + anchor (rest) -------------
struct BktSmem {
  int histU[NBK_], histI[NBK_];
  int loffU[NBK_ + 1], loffI[NBK_ + 1];
  int cbU[NBK_], cbI[NBK_];
  int lcU[NBK_], lcI[NBK_];
  int wsU[4], wsI[4];
  unsigned recsU[TILE_], recsI[TILE_];
};
constexpr int WS_ = 72;  // f16 row stride for WUt/mixS
struct AncSmem {
  _Float16 WUt[64 * WS_];
  _Float16 mixS[16 * WS_];
  float invSe[16];
  int nbrS[128];
};
constexpr size_t FSA_SMEM = sizeof(BktSmem) > sizeof(AncSmem) ? sizeof(BktSmem) : sizeof(AncSmem);

DEVI void bucketA_body(char* smemRaw, int blk,
    const int* __restrict__ rs, const int* __restrict__ rd,
    unsigned* __restrict__ bufU, unsigned* __restrict__ bufI,
    int* __restrict__ curU, int* __restrict__ curI) {
  BktSmem& S = *(BktSmem*)smemRaw;
  int tid = threadIdx.x;
  int base = blk * TILE_;
  for (int i = tid; i < NBK_; i += 256) { S.histU[i] = 0; S.histI[i] = 0; }
  __syncthreads();
  int ss[16], dd[16];
  #pragma unroll
  for (int t = 0; t < 16; t++) {
    int e = base + t * 256 + tid;
    bool v = e < E_;
    ss[t] = v ? rs[e] : -1;
    dd[t] = v ? rd[e] : 0;
    if (v) {
      atomicAdd(&S.histU[ss[t] >> 8], 1);
      atomicAdd(&S.histI[dd[t] >> 7], 1);
    }
  }
  __syncthreads();
  if (tid < NBK_) {
    int cU = S.histU[tid];
    S.cbU[tid] = tid * CAP_ + (cU ? atomicAdd(&curU[tid], cU) : 0);
    int cI = S.histI[tid];
    S.cbI[tid] = tid * CAP_ + (cI ? atomicAdd(&curI[tid], cI) : 0);
  }
  int lane = tid & 63, wv = tid >> 6;
  int cvU = (tid < NBK_) ? S.histU[tid] : 0;
  int cvI = (tid < NBK_) ? S.histI[tid] : 0;
  int inU = waveInclScan(cvU, lane);
  int inI = waveInclScan(cvI, lane);
  if (lane == 63) { S.wsU[wv] = inU; S.wsI[wv] = inI; }
  __syncthreads();
  int woU = 0, woI = 0;
  for (int w = 0; w < wv; w++) { woU += S.wsU[w]; woI += S.wsI[w]; }
  if (tid < NBK_) {
    S.loffU[tid] = woU + inU - cvU;
    S.loffI[tid] = woI + inI - cvI;
  }
  if (tid == NBK_ - 1) {
    S.loffU[NBK_] = woU + inU;
    S.loffI[NBK_] = woI + inI;
  }
  __syncthreads();
  if (tid < NBK_) { S.lcU[tid] = S.loffU[tid]; S.lcI[tid] = S.loffI[tid]; }
  __syncthreads();
  #pragma unroll
  for (int t = 0; t < 16; t++) {
    if (ss[t] >= 0) {
      int b = ss[t] >> 8;
      int p = atomicAdd(&S.lcU[b], 1);
      S.recsU[p] = ((unsigned)(ss[t] & 255) << 17) | (unsigned)dd[t];
      b = dd[t] >> 7;
      p = atomicAdd(&S.lcI[b], 1);
      S.recsI[p] = ((unsigned)(dd[t] & 127) << 17) | (unsigned)ss[t];
    }
  }
  __syncthreads();
  int totU = S.loffU[NBK_];
  for (int p = tid; p < totU; p += 256) {
    int lo = 0, hi = NBK_;
    while (hi - lo > 1) { int mid = (lo + hi) >> 1; if (S.loffU[mid] <= p) lo = mid; else hi = mid; }
    bufU[S.cbU[lo] + (p - S.loffU[lo])] = S.recsU[p];
  }
  int totI = S.loffI[NBK_];
  for (int p = tid; p < totI; p += 256) {
    int lo = 0, hi = NBK_;
    while (hi - lo > 1) { int mid = (lo + hi) >> 1; if (S.loffI[mid] <= p) lo = mid; else hi = mid; }
    bufI[S.cbI[lo] + (p - S.loffI[lo])] = S.recsI[p];
  }
}

DEVI void anchor_body(char* smemRaw, int blk,
    const void* __restrict__ ue, const void* __restrict__ WU,
    const void* __restrict__ cw, const float* __restrict__ vecs,
    const int* __restrict__ nbr, float* __restrict__ out, int isf32) {
  AncSmem& S = *(AncSmem*)smemRaw;
  int tid = threadIdx.x;
  int wv = tid >> 6, lane = tid & 63;
  int ublk = blk * 16;

  #pragma unroll
  for (int it = 0; it < 16; it++) {
    int k = it * 4 + wv;
    S.WUt[lane * WS_ + k] = (_Float16)ldf(WU, (size_t)k * 64 + lane, isf32);
  }
  if (tid < 128) S.nbrS[tid] = nbr[ublk * 8 + tid];
  __syncthreads();

  float cw0 = ldf(cw, (0 * 64 + lane) * 2, isf32);
  float w1r = ldf(cw, (1 * 64 + lane) * 2, isf32), w1i = ldf(cw, (1 * 64 + lane) * 2 + 1, isf32);
  float w2r = ldf(cw, (2 * 64 + lane) * 2, isf32), w2i = ldf(cw, (2 * 64 + lane) * 2 + 1, isf32);
  float w3r = ldf(cw, (3 * 64 + lane) * 2, isf32), w3i = ldf(cw, (3 * 64 + lane) * 2 + 1, isf32);
  float cw4 = ldf(cw, (4 * 64 + lane) * 2, isf32);
  float v1 = vecs[64 + lane], v2 = vecs[128 + lane];
  const float c1 = 0.70710678118654752440f;

  float xc[8], xn[8];
  #pragma unroll
  for (int k = 0; k < 8; k++)
    xc[k] = ldf(ue, (size_t)S.nbrS[wv * 32 + k] * 64 + lane, isf32);

  for (int u4 = 0; u4 < 4; u4++) {
    int uL = wv * 4 + u4;
    int u = ublk + uL;
    if (u4 < 3) {
      #pragma unroll
      for (int k = 0; k < 8; k++)
        xn[k] = ldf(ue, (size_t)S.nbrS[wv * 32 + (u4 + 1) * 8 + k] * 64 + lane, isf32);
    }
    float sA = xc[1] - xc[3] - xc[5] + xc[7];
    float sB = xc[1] + xc[3] - xc[5] - xc[7];
    float ev = (xc[0] + xc[4]) + (xc[2] + xc[6]);
    float od = (xc[1] + xc[5]) + (xc[3] + xc[7]);
    float d04 = xc[0] - xc[4], d26 = xc[2] - xc[6];
    float X0r = ev + od;
    float X1r = d04 + c1 * sA;
    float X1i = -d26 - c1 * sB;
    float X2r = (xc[0] + xc[4]) - (xc[2] + xc[6]);
    float X2i = -(xc[1] - xc[3] + xc[5] - xc[7]);
    float X3r = d04 - c1 * sA;
    float X3i = d26 - c1 * sB;
    float X4r = ev - od;
    float Zr0 = X0r * cw0;
    float Zr1 = X1r * w1r - X1i * w1i, Zi1 = X1r * w1i + X1i * w1r;
    float Zr2 = X2r * w2r - X2i * w2i, Zi2 = X2r * w2i + X2i * w2r;
    float Zr3 = X3r * w3r - X3i * w3i, Zi3 = X3r * w3i + X3i * w3r;
    float Zr4 = X4r * cw4;
    float eP = Zr0 + Zr4, eM = Zr0 - Zr4;
    float t1 = c1 * (Zr1 - Zr3), t2 = c1 * (Zi1 + Zi3);
    float y[8];
    y[0] = eP + 2.f * (Zr1 + Zr2 + Zr3);
    y[1] = eM + 2.f * (t1 - t2 - Zi2);
    y[2] = eP + 2.f * (-Zi1 - Zr2 + Zi3);
    y[3] = eM + 2.f * (-t1 - t2 + Zi2);
    y[4] = eP + 2.f * (-Zr1 + Zr2 - Zr3);
    y[5] = eM + 2.f * (-t1 + t2 - Zi2);
    y[6] = eP + 2.f * (Zi1 - Zr2 - Zi3);
    y[7] = eM + 2.f * (t1 + t2 + Zi2);
    #pragma unroll
    for (int k = 0; k < 8; k++) y[k] *= 0.125f;

    float ek[8];
    #pragma unroll
    for (int k = 0; k < 8; k++) ek[k] = y[k] * v1;
    float q = ldf(ue, (size_t)u * 64 + lane, isf32) * v2;
    #pragma unroll
    for (int off = 32; off; off >>= 1) {
      #pragma unroll
      for (int k = 0; k < 8; k++) ek[k] += __shfl_xor(ek[k], off, 64);
      q += __shfl_xor(q, off, 64);
    }
    float m = -1e30f;
    #pragma unroll
    for (int k = 0; k < 8; k++) {
      float v = ek[k] + q;
      v = v > 0.f ? v : 0.1f * v;  // LeakyReLU(0.1)
      ek[k] = v;
      m = fmaxf(m, v);
    }
    float se = 0.f, wexp[8];
    #pragma unroll
    for (int k = 0; k < 8; k++) { wexp[k] = __expf(ek[k] - m); se += wexp[k]; }
    float mix = 0.f;
    #pragma unroll
    for (int k = 0; k < 8; k++) mix += wexp[k] * y[k];
    S.mixS[uL * WS_ + lane] = (_Float16)mix;
    if (lane == 0) S.invSe[uL] = frcp(se);
    #pragma unroll
    for (int k = 0; k < 8; k++) xc[k] = xn[k];
  }
  __syncthreads();

  int n = lane & 15, qd = lane >> 4;
  f16x8 A0 = *(const f16x8*)&S.mixS[(lane & 15) * WS_ + qd * 8];
  f16x8 A1 = *(const f16x8*)&S.mixS[(lane & 15) * WS_ + 32 + qd * 8];
  f16x8 B0 = *(const f16x8*)&S.WUt[(wv * 16 + n) * WS_ + qd * 8];
  f16x8 B1 = *(const f16x8*)&S.WUt[(wv * 16 + n) * WS_ + 32 + qd * 8];
  const floatx4 zero = {0.f, 0.f, 0.f, 0.f};
  floatx4 acc = __builtin_amdgcn_mfma_f32_16x16x32_f16(A0, B0, zero, 0, 0, 0);
  acc = __builtin_amdgcn_mfma_f32_16x16x32_f16(A1, B1, acc, 0, 0, 0);
  #pragma unroll
  for (int r = 0; r < 4; r++) {
    int m = qd * 4 + r;
    out[(size_t)(ublk + m) * 64 + wv * 16 + n] = acc[r] * S.invSe[m];
  }
}

__global__ __launch_bounds__(256) void fusedA_kernel(
    const int* __restrict__ rs, const int* __restrict__ rd,
    unsigned* __restrict__ bufU, unsigned* __restrict__ bufI,
    int* __restrict__ curU, int* __restrict__ curI,
    const void* __restrict__ ue, const void* __restrict__ WU,
    const void* __restrict__ cw, const float* __restrict__ vecs,
    const int* __restrict__ nbr, float* __restrict__ anc,
    const float* __restrict__ flag) {
  __shared__ __align__(16) char smem[FSA_SMEM];
  if (blockIdx.x < NBA_) {
    bucketA_body(smem, blockIdx.x, rs, rd, bufU, bufI, curU, curI);
  } else {
    anchor_body(smem, blockIdx.x - NBA_, ue, WU, cw, vecs, nbr, anc, *flag > 0.5f);
  }
}

// ---------------- 1b. tiny scan ----------------
__global__ void scanBuckets_kernel(const int* __restrict__ curU,
                                   const int* __restrict__ curI,
                                   int* __restrict__ bbU, int* __restrict__ bbI,
                                   int* __restrict__ rowU, int* __restrict__ rowI) {
  if (threadIdx.x == 0) {
    int run = 0;
    for (int i = 0; i < NBK_; i++) { bbU[i] = run; run += curU[i]; }
    bbU[NBK_] = run;
    run = 0;
    for (int i = 0; i < NBK_; i++) { bbI[i] = run; run += curI[i]; }
    bbI[NBK_] = run;
    rowU[U_] = E_;
    rowI[I_] = E_;
  }
}

// ---------------- 1c. Phase B ----------------
__global__ __launch_bounds__(256) void bucketB_kernel(
    const unsigned* __restrict__ bufU, const unsigned* __restrict__ bufI,
    const int* __restrict__ curU, const int* __restrict__ curI,
    const int* __restrict__ bbU, const int* __restrict__ bbI,
    int* __restrict__ rowU, int* __restrict__ rowI,
    int* __restrict__ csrU, int* __restrict__ csrI) {
  __shared__ int stage[CAP_];
  __shared__ int cntk[256], offk[256];
  __shared__ int wsum[4];
  int tid = threadIdx.x, b = blockIdx.x;
  int side = b >= NBK_;
  int bb = side ? b - NBK_ : b;
  const unsigned* src = (side ? bufI : bufU) + (size_t)bb * CAP_;
  int total = side ? curI[bb] : curU[bb];
  int gbase = side ? bbI[bb] : bbU[bb];
  int kpb   = side ? 128 : 256;
  int* rowptr = side ? rowI : rowU;
  int* csr    = side ? csrI : csrU;
  cntk[tid] = 0;
  __syncthreads();
  for (int r = tid; r < total; r += 256) atomicAdd(&cntk[src[r] >> 17], 1);
  __syncthreads();
  int lane = tid & 63, wv = tid >> 6;
  int cv = (tid < kpb) ? cntk[tid] : 0;
  int incl = waveInclScan(cv, lane);
  if (lane == 63) wsum[wv] = incl;
  __syncthreads();
  int wvoff = 0;
  for (int w = 0; w < wv; w++) wvoff += wsum[w];
  int excl = wvoff + incl - cv;
  if (tid < kpb) {
    offk[tid] = excl;
    rowptr[bb * kpb + tid] = gbase + excl;
  }
  __syncthreads();
  for (int r = tid; r < total; r += 256) {
    unsigned rec = src[r];
    int slot = atomicAdd(&offk[rec >> 17], 1);
    if (slot < CAP_) stage[slot] = (int)(rec & 0x1FFFFu);
  }
  __syncthreads();
  for (int s = tid; s < total; s += 256) csr[gbase + s] = stage[s];
}

// ---------------- 2. fused layer-1 aggregation (both sides, bf16 out) -----------
__global__ __launch_bounds__(256) void agg1_kernel(
    const void* __restrict__ ue, const void* __restrict__ ie,
    const int* __restrict__ rowU, const int* __restrict__ rowI,
    const int* __restrict__ csrU, const int* __restrict__ csrI,
    __hip_bfloat16* __restrict__ u1, __hip_bfloat16* __restrict__ i1,
    const float* __restrict__ flag) {
  int isf32 = *flag > 0.5f;
  int wv = threadIdx.x >> 6, lane = threadIdx.x & 63;
  int side = blockIdx.x >= I_ / 4;
  int blk = side ? blockIdx.x - I_ / 4 : blockIdx.x;
  int r = blk * 4 + wv;
  const int* row = side ? rowU : rowI;
  const int* csr = side ? csrU : csrI;
  const void* src = side ? ie : ue;
  __hip_bfloat16* out = side ? u1 : i1;
  int s0 = row[r], s1 = row[r + 1];
  float acc = 0.f;
  int j = s0;
  for (; j + 4 <= s1; j += 4) {
    int a = csr[j], b = csr[j + 1], c = csr[j + 2], d = csr[j + 3];
    float va = ldf(src, (size_t)a * 64 + lane, isf32);
    float vb = ldf(src, (size_t)b * 64 + lane, isf32);
    float vc = ldf(src, (size_t)c * 64 + lane, isf32);
    float vd = ldf(src, (size_t)d * 64 + lane, isf32);
    acc += (va + vb) + (vc + vd);
  }
  for (; j < s1; j++) acc += ldf(src, (size_t)csr[j] * 64 + lane, isf32);
  out[(size_t)r * 64 + lane] = __float2bfloat16(acc / fmaxf((float)(s1 - s0), 1.0f));
}

// ---------------- 3. fused layer-2 aggregation + attention (both sides) ---------
__global__ __launch_bounds__(256) void agg2attn_kernel(
    const __hip_bfloat16* __restrict__ u1, const __hip_bfloat16* __restrict__ i1,
    const void* __restrict__ ue, const void* __restrict__ ie,
    const int* __restrict__ rowU, const int* __restrict__ rowI,
    const int* __restrict__ csrU, const int* __restrict__ csrI,
    const float* __restrict__ vecs, float* __restrict__ hu, float* __restrict__ hi,
    const float* __restrict__ flag) {
  int isf32 = *flag > 0.5f;
  int wv = threadIdx.x >> 6, lane = threadIdx.x & 63;
  int side = blockIdx.x >= I_ / 4;
  int blk = side ? blockIdx.x - I_ / 4 : blockIdx.x;
  int r = blk * 4 + wv;
  const int* row = side ? rowU : rowI;
  const int* csr = side ? csrU : csrI;
  const __hip_bfloat16* opp1 = side ? i1 : u1;
  const __hip_bfloat16* own1 = side ? u1 : i1;
  const void* base = side ? ue : ie;
  float* h = side ? hu : hi;
  int s0 = row[r], s1 = row[r + 1];
  float acc = 0.f;
  int j = s0;
  for (; j + 4 <= s1; j += 4) {
    int a = csr[j], b = csr[j + 1], c = csr[j + 2], d = csr[j + 3];
    float va = b2f(opp1[(size_t)a * 64 + lane]);
    float vb = b2f(opp1[(size_t)b * 64 + lane]);
    float vc = b2f(opp1[(size_t)c * 64 + lane]);
    float vd = b2f(opp1[(size_t)d * 64 + lane]);
    acc += (va + vb) + (vc + vd);
  }
  for (; j < s1; j++) acc += b2f(opp1[(size_t)csr[j] * 64 + lane]);
  size_t idx = (size_t)r * 64 + lane;
  float t2 = acc / fmaxf((float)(s1 - s0), 1.0f);
  float t0 = ldf(base, idx, isf32);
  float t1 = b2f(own1[idx]);
  float w = vecs[lane];   // Wa
  float p0 = t0 * w, p1 = t1 * w, p2 = t2 * w;
  #pragma unroll
  for (int off = 32; off; off >>= 1) {
    p0 += __shfl_xor(p0, off, 64);
    p1 += __shfl_xor(p1, off, 64);
    p2 += __shfl_xor(p2, off, 64);
  }
  float m = fmaxf(p0, fmaxf(p1, p2));
  float e0 = __expf(p0 - m), e1 = __expf(p1 - m), e2 = __expf(p2 - m);
  float inv = 1.0f / (e0 + e1 + e2);
  h[idx] = (t0 * e0 + t1 * e1 + t2 * e2) * inv;
}

// ---------------- 5. contrastive loss: slim epilogue MFMA Gram ----------
constexpr int XS_ = 72;                   // f16 row stride (144 B)
constexpr float SC_  = 2.6857914f;        // sqrt(5*log2(e))
constexpr float EPS_ = 1e-6f;
constexpr float LN2_ = 0.6931471805599453f;
__global__ __launch_bounds__(1024) void contrast_kernel(
    const float* __restrict__ hu, const float* __restrict__ an,
    float* __restrict__ loss_acc) {
  __shared__ __align__(16) _Float16 Xh[512 * XS_];  // 72 KB
  __shared__ float iN[512];
  int tid = threadIdx.x;
  int c = blockIdx.x;

  if (tid < 512) {
    int row = tid & 255;
    const float* r1 = (tid < 256 ? hu : an) + ((size_t)c * CB_ + row) * 64;
    float4 a4[16];
    float s1 = 0.f;
    #pragma unroll
    for (int t = 0; t < 16; t++) {
      a4[t] = ((const float4*)r1)[t];
      s1 += a4[t].x * a4[t].x + a4[t].y * a4[t].y + a4[t].z * a4[t].z + a4[t].w * a4[t].w;
    }
    float inv = frcp(sqrtf(s1));
    iN[tid] = inv;
    float sc = inv * SC_;
    #pragma unroll
    for (int t = 0; t < 8; t++) {
      f16x8 v;
      v[0] = (_Float16)(a4[2*t].x * sc);   v[1] = (_Float16)(a4[2*t].y * sc);
      v[2] = (_Float16)(a4[2*t].z * sc);   v[3] = (_Float16)(a4[2*t].w * sc);
      v[4] = (_Float16)(a4[2*t+1].x * sc); v[5] = (_Float16)(a4[2*t+1].y * sc);
      v[6] = (_Float16)(a4[2*t+1].z * sc); v[7] = (_Float16)(a4[2*t+1].w * sc);
      *(f16x8*)&Xh[tid * XS_ + t * 8] = v;
    }
  }
  __syncthreads();

  int l = tid & 63, wv = tid >> 6;       // wv 0..15
  int n = l & 15, q = l >> 4;
  int rb = wv * 32;
  f16x8 A[2][2];
  #pragma unroll
  for (int t = 0; t < 2; t++) {
    A[t][0] = *(const f16x8*)&Xh[(rb + t * 16 + n) * XS_ + q * 8];
    A[t][1] = *(const f16x8*)&Xh[(rb + t * 16 + n) * XS_ + 32 + q * 8];
  }
  float eNiR[2][4];
  #pragma unroll
  for (int t = 0; t < 2; t++)
    #pragma unroll
    for (int r = 0; r < 4; r++)
      eNiR[t][r] = EPS_ * iN[rb + t * 16 + q * 4 + r];
  float sums[2][4] = {{0,0,0,0},{0,0,0,0}};
  float labs2[2] = {0, 0};
  int selfn = q * 4;
  const floatx4 zero = {0.f, 0.f, 0.f, 0.f};
  for (int ct = 0; ct < 32; ct++) {
    f16x8 B0 = *(const f16x8*)&Xh[(ct * 16 + n) * XS_ + q * 8];
    f16x8 B1 = *(const f16x8*)&Xh[(ct * 16 + n) * XS_ + 32 + q * 8];
    float iNj = iN[ct * 16 + n];
    #pragma unroll
    for (int t = 0; t < 2; t++) {
      floatx4 acc = __builtin_amdgcn_mfma_f32_16x16x32_f16(A[t][0], B0, zero, 0, 0, 0);
      acc = __builtin_amdgcn_mfma_f32_16x16x32_f16(A[t][1], B1, acc, 0, 0, 0);
      int rtg = wv * 2 + t;
      if (ct == (rtg ^ 16)) {
        #pragma unroll
        for (int r = 0; r < 4; r++) {
          float G = acc[r];
          float u = eNiR[t][r] * iNj;
          float s2 = __builtin_fmaf(G, -u, G);
          sums[t][r] += fexp2(s2);
          if (n == selfn + r) labs2[t] += s2;
        }
      } else if (ct == rtg) {
        #pragma unroll
        for (int r = 0; r < 4; r++) {
          float G = acc[r];
          float u = eNiR[t][r] * iNj;
          float s2 = __builtin_fmaf(G, -u, G);
          float e = (n == selfn + r) ? 0.f : fexp2(s2);
          sums[t][r] += e;
        }
      } else {
        #pragma unroll
        for (int r = 0; r < 4; r++) {
          float G = acc[r];
          float u = eNiR[t][r] * iNj;
          float s2 = __builtin_fmaf(G, -u, G);
          sums[t][r] += fexp2(s2);
        }
      }
    }
  }
  #pragma unroll
  for (int off = 1; off <= 8; off <<= 1) {
    #pragma unroll
    for (int t = 0; t < 2; t++) {
      #pragma unroll
      for (int r = 0; r < 4; r++) sums[t][r] += __shfl_xor(sums[t][r], off, 64);
      labs2[t] += __shfl_xor(labs2[t], off, 64);
    }
  }
  float part = 0.f;
  if (n == 0) {
    #pragma unroll
    for (int t = 0; t < 2; t++) {
      float lt = 0.f;
      #pragma unroll
      for (int r = 0; r < 4; r++) lt += __logf(sums[t][r]);
      part += lt - labs2[t] * LN2_;
    }
  }
  #pragma unroll
  for (int off = 1; off < 64; off <<= 1) part += __shfl_xor(part, off, 64);
  if (l == 0) atomicAdd(loss_acc, part);
}

// ---------------- 6. scores (no LDS, 256 threads) ----------------
__global__ __launch_bounds__(256) void score_kernel(
    const float* __restrict__ hu, const float* __restrict__ hi,
    const int* __restrict__ pu, const int* __restrict__ pi,
    const int* __restrict__ nu, const int* __restrict__ ni,
    void* __restrict__ out, const float* __restrict__ flag) {
  int isf32 = *flag > 0.5f;
  int w = (blockIdx.x * 256 + threadIdx.x) >> 6;
  int lane = threadIdx.x & 63;
  int uu, ii;
  if (w < EP_) { uu = pu[w]; ii = pi[w]; }
  else         { uu = nu[w - EP_]; ii = ni[w - EP_]; }
  float p = hu[(size_t)uu * 64 + lane] * hi[(size_t)ii * 64 + lane];
  #pragma unroll
  for (int off = 32; off; off >>= 1) p += __shfl_xor(p, off, 64);
  if (lane == 0) {
    if (isf32) ((float*)out)[w] = p;
    else       ((__hip_bfloat16*)out)[w] = __float2bfloat16(p);
  }
}

__global__ void finalize_kernel(const float* __restrict__ loss_acc,
                                void* __restrict__ out,
                                const float* __restrict__ flag) {
  float v = loss_acc[0] * (1.0f / (float)(2 * CB_ * NCHUNK_));
  if (*flag > 0.5f) ((float*)out)[2 * EP_] = v;
  else              ((__hip_bfloat16*)out)[2 * EP_] = __float2bfloat16(v);
}

// ---------------- launch ----------------
extern "C" void kernel_launch(void* const* d_in, const int* in_sizes, int n_in,
                              void* d_out, int out_size, void* d_ws, size_t ws_size,
                              hipStream_t stream) {
  const void* ue  = d_in[0];
  const void* ie  = d_in[1];
  const void* W   = d_in[2];
  const void* a   = d_in[3];
  const void* WU  = d_in[4];
  const void* aU  = d_in[5];
  const void* cw  = d_in[6];
  const int* rs  = (const int*)d_in[7];
  const int* rd  = (const int*)d_in[8];
  const int* pu  = (const int*)d_in[9];
  const int* pi  = (const int*)d_in[10];
  const int* nu  = (const int*)d_in[11];
  const int* ni  = (const int*)d_in[12];
  const int* nbr = (const int*)d_in[13];

  float* wsf  = (float*)d_ws;
  int*   wsi  = (int*)d_ws;
  float* loss = wsf + OFF_LOSS;
  float* flag = wsf + OFF_FLAG;
  int* curU   = wsi + OFF_CURU;
  int* curI   = wsi + OFF_CURI;
  float* vecs = wsf + OFF_VEC;
  int* bbU    = wsi + OFF_BBU;
  int* bbI    = wsi + OFF_BBI;
  int* rowU   = wsi + OFF_ROWU;
  int* rowI   = wsi + OFF_ROWI;
  int* csrU   = wsi + OFF_CSRU;
  int* csrI   = wsi + OFF_CSRI;
  __hip_bfloat16* u1 = (__hip_bfloat16*)(wsf + OFF_U1);
  __hip_bfloat16* i1 = (__hip_bfloat16*)(wsf + OFF_I1);
  float* hu   = wsf + OFF_HU;
  float* hi   = wsf + OFF_HI;
  float* anc  = wsf + OFF_ANC;
  unsigned* bufU = (unsigned*)(wsf + OFF_HU);
  unsigned* bufI = (unsigned*)(wsf + OFF_HI);

  hipMemsetAsync(d_ws, 0, MEMSET_BYTES, stream);
  prep_kernel<<<1, 64, 0, stream>>>((const unsigned short*)ue, W, a, WU, aU, vecs, flag);

  // fused: CSR Phase A + anchor (independent)
  fusedA_kernel<<<NBA_ + U_ / 16, 256, 0, stream>>>(
      rs, rd, bufU, bufI, curU, curI, ue, WU, cw, vecs, nbr, anc, flag);
  scanBuckets_kernel<<<1, 64, 0, stream>>>(curU, curI, bbU, bbI, rowU, rowI);
  bucketB_kernel<<<2 * NBK_, 256, 0, stream>>>(bufU, bufI, curU, curI, bbU, bbI,
                                               rowU, rowI, csrU, csrI);

  // fused layer-1 aggregation (both sides)
  agg1_kernel<<<(I_ + U_) / 4, 256, 0, stream>>>(ue, ie, rowU, rowI, csrU, csrI,
                                                 u1, i1, flag);
  // fused layer-2 aggregation + attention (both sides)
  agg2attn_kernel<<<(I_ + U_) / 4, 256, 0, stream>>>(u1, i1, ue, ie, rowU, rowI,
                                                     csrU, csrI, vecs, hu, hi, flag);

  // contrastive loss (1 block/chunk, 16 waves, slim MFMA Gram)
  contrast_kernel<<<NCHUNK_, 1024, 0, stream>>>(hu, anc, loss);

  // scores (no LDS)
  score_kernel<<<(2 * EP_ * 64) / 256, 256, 0, stream>>>(hu, hi, pu, pi, nu, ni, d_out, flag);
  finalize_kernel<<<1, 1, 0, stream>>>(loss, d_out, flag);
}

// Round 16
// 406.489 us; speedup vs baseline: 2.0243x; 1.0625x over previous
//
#include <hip/hip_runtime.h>
#include <hip/hip_bf16.h>

// ---------------- problem constants ----------------
constexpr int U_  = 51200;
constexpr int I_  = 25600;
constexpr int E_  = 1000000;
constexpr int EP_ = 100000;
constexpr int CB_ = 256;                 // contrastive chunk size
constexpr int NCHUNK_ = U_ / CB_;        // 200
constexpr size_t UD_ = (size_t)U_ * 64;
constexpr size_t ID_ = (size_t)I_ * 64;
constexpr int NBK_ = 200;                // buckets per side
constexpr int CAP_ = 8192;               // record slots per bucket
constexpr int TILE_ = 4096;              // edges per Phase-A block
constexpr int NBA_ = (E_ + TILE_ - 1) / TILE_;  // 245
constexpr int NANC_ = U_ / 16;           // 3200 anchor blocks
constexpr int NCVT_ = (int)((UD_ + ID_) / 512);  // 9600 convert blocks

// fp8 scaling (values sit in e4m3 sweet range)
constexpr float SCALE_E_  = 16.f;   // raw embeddings ~0.1
constexpr float ISCALE_E_ = 1.f / 16.f;
constexpr float SCALE_1_  = 64.f;   // layer-1 aggregates ~0.02
constexpr float ISCALE_1_ = 1.f / 64.f;

// ---------------- workspace layout (4-byte element offsets) ----------------
constexpr size_t OFF_LOSS  = 0;
constexpr size_t OFF_FLAG  = 1;
constexpr size_t OFF_CURU  = 8;                      // 200 ints
constexpr size_t OFF_CURI  = 208;                    // 200 ints
constexpr size_t MEMSET_BYTES = 408 * 4;
constexpr size_t OFF_VEC   = 448;                    // 192 floats
constexpr size_t OFF_BBU   = 640;                    // 201 ints
constexpr size_t OFF_BBI   = 848;                    // 201 ints
constexpr size_t OFF_ROWU  = 1088;                   // U_+1
constexpr size_t OFF_ROWI  = ((OFF_ROWU + U_ + 1 + 63) / 64) * 64;   // I_+1
constexpr size_t OFF_CSRU  = ((OFF_ROWI + I_ + 1 + 63) / 64) * 64;   // E_
constexpr size_t OFF_CSRI  = OFF_CSRU + E_;          // E_
constexpr size_t OFF_U1    = ((OFF_CSRI + E_ + 63) / 64) * 64;       // UD_ (bf16)
constexpr size_t OFF_I1    = OFF_U1 + UD_;
constexpr size_t OFF_HU    = OFF_I1 + ID_;           // bufU aliases
constexpr size_t OFF_HI    = OFF_HU + UD_;           // bufI aliases
constexpr size_t OFF_ANC   = OFF_HI + ID_;
constexpr size_t OFF_UE8   = OFF_ANC + UD_;          // UD_ bytes (fp8)
constexpr size_t OFF_IE8   = OFF_UE8 + UD_ / 4;
constexpr size_t OFF_U18   = OFF_IE8 + ID_ / 4;
constexpr size_t OFF_I18   = OFF_U18 + UD_ / 4;
// total ≈ 65.6 MB

#define DEVI static __device__ __forceinline__

typedef _Float16 h2v __attribute__((ext_vector_type(2)));
typedef _Float16 f16x8 __attribute__((ext_vector_type(8)));
typedef float floatx4 __attribute__((ext_vector_type(4)));

DEVI float b2f(__hip_bfloat16 x) { return __bfloat162float(x); }

DEVI float ldf(const void* p, size_t i, int isf32) {
  if (isf32) return ((const float*)p)[i];
  return b2f(((const __hip_bfloat16*)p)[i]);
}

DEVI float frcp(float x) { return __builtin_amdgcn_rcpf(x); }

DEVI float fexp2(float x) {
#if __has_builtin(__builtin_amdgcn_exp2f)
  return __builtin_amdgcn_exp2f(x);
#else
  return exp2f(x);
#endif
}

// fp8 e4m3 (OCP) decode/encode
DEVI float fp8_dec(unsigned v) {
#if __has_builtin(__builtin_amdgcn_cvt_f32_fp8)
  return __builtin_amdgcn_cvt_f32_fp8(v, 0);
#else
  unsigned b = v & 0xFF;
  if (!(b & 0x78)) return 0.f;  // flush subnormals (negligible at our scales)
  unsigned short h = (unsigned short)(((b & 0x80) << 8) | (((b & 0x7f) + (8 << 3)) << 7));
  _Float16 hf; __builtin_memcpy(&hf, &h, 2);
  return (float)hf;
#endif
}
DEVI unsigned fp8_enc_pk(float a, float b) {
#if __has_builtin(__builtin_amdgcn_cvt_pk_fp8_f32)
  return __builtin_amdgcn_cvt_pk_fp8_f32(a, b, 0u, false);
#else
  auto enc1 = [](float f) -> unsigned {
    _Float16 hf = (_Float16)f; unsigned short hb; __builtin_memcpy(&hb, &hf, 2);
    int s = hb >> 15, e = (hb >> 10) & 31, m = hb & 1023;
    int e8 = e - 15 + 7;
    int m3 = (m + ((1 << 6) + ((m >> 7) & 1))) >> 7;
    if (m3 > 7) { m3 = 0; e8++; }
    if (e8 <= 0) return (unsigned)(s << 7);
    if (e8 > 15) { e8 = 15; m3 = 6; }
    return (unsigned)((s << 7) | (e8 << 3) | m3);
  };
  return enc1(a) | (enc1(b) << 8);
#endif
}

DEVI int waveInclScan(int v, int lane) {
  #pragma unroll
  for (int off = 1; off < 64; off <<= 1) {
    int t = __shfl_up(v, off, 64);
    if (lane >= off) v += t;
  }
  return v;
}

// ---------------- 0. prep ----------------
__global__ void prep_kernel(const unsigned short* __restrict__ ueu,
                            const void* __restrict__ W, const void* __restrict__ a,
                            const void* __restrict__ WU, const void* __restrict__ aU,
                            float* __restrict__ vecs, float* __restrict__ flag) {
  int cnt = 0;
  for (int i = 0; i < 256; i++) {
    int e = (ueu[i] >> 7) & 0xFF;
    if (e >= 130) cnt++;
  }
  int isf32 = (cnt >= 8);
  if (threadIdx.x == 0) *flag = isf32 ? 1.0f : 0.0f;
  int d = threadIdx.x;
  float s = 0.f, t1 = 0.f, t2 = 0.f;
  for (int e = 0; e < 64; e++) {
    s += ldf(W, d * 64 + e, isf32) * ldf(a, e, isf32);
    float wue = ldf(WU, d * 64 + e, isf32);
    t1 += wue * ldf(aU, e, isf32);
    t2 += wue * ldf(aU, 64 + e, isf32);
  }
  vecs[d] = s;
  vecs[64 + d] = t1;
  vecs[128 + d] = t2;
}

// ---------------- fused A: bucketA + anchor + fp8-convert -------------
struct BktSmem {
  int histU[NBK_], histI[NBK_];
  int loffU[NBK_ + 1], loffI[NBK_ + 1];
  int cbU[NBK_], cbI[NBK_];
  int lcU[NBK_], lcI[NBK_];
  int wsU[4], wsI[4];
  unsigned recsU[TILE_], recsI[TILE_];
};
constexpr int WS_ = 72;
struct AncSmem {
  _Float16 WUt[64 * WS_];
  _Float16 mixS[16 * WS_];
  float invSe[16];
  int nbrS[128];
};
constexpr size_t FSA_SMEM = sizeof(BktSmem) > sizeof(AncSmem) ? sizeof(BktSmem) : sizeof(AncSmem);

DEVI void bucketA_body(char* smemRaw, int blk,
    const int* __restrict__ rs, const int* __restrict__ rd,
    unsigned* __restrict__ bufU, unsigned* __restrict__ bufI,
    int* __restrict__ curU, int* __restrict__ curI) {
  BktSmem& S = *(BktSmem*)smemRaw;
  int tid = threadIdx.x;
  int base = blk * TILE_;
  for (int i = tid; i < NBK_; i += 256) { S.histU[i] = 0; S.histI[i] = 0; }
  __syncthreads();
  int ss[16], dd[16];
  #pragma unroll
  for (int t = 0; t < 16; t++) {
    int e = base + t * 256 + tid;
    bool v = e < E_;
    ss[t] = v ? rs[e] : -1;
    dd[t] = v ? rd[e] : 0;
    if (v) {
      atomicAdd(&S.histU[ss[t] >> 8], 1);
      atomicAdd(&S.histI[dd[t] >> 7], 1);
    }
  }
  __syncthreads();
  if (tid < NBK_) {
    int cU = S.histU[tid];
    S.cbU[tid] = tid * CAP_ + (cU ? atomicAdd(&curU[tid], cU) : 0);
    int cI = S.histI[tid];
    S.cbI[tid] = tid * CAP_ + (cI ? atomicAdd(&curI[tid], cI) : 0);
  }
  int lane = tid & 63, wv = tid >> 6;
  int cvU = (tid < NBK_) ? S.histU[tid] : 0;
  int cvI = (tid < NBK_) ? S.histI[tid] : 0;
  int inU = waveInclScan(cvU, lane);
  int inI = waveInclScan(cvI, lane);
  if (lane == 63) { S.wsU[wv] = inU; S.wsI[wv] = inI; }
  __syncthreads();
  int woU = 0, woI = 0;
  for (int w = 0; w < wv; w++) { woU += S.wsU[w]; woI += S.wsI[w]; }
  if (tid < NBK_) {
    S.loffU[tid] = woU + inU - cvU;
    S.loffI[tid] = woI + inI - cvI;
  }
  if (tid == NBK_ - 1) {
    S.loffU[NBK_] = woU + inU;
    S.loffI[NBK_] = woI + inI;
  }
  __syncthreads();
  if (tid < NBK_) { S.lcU[tid] = S.loffU[tid]; S.lcI[tid] = S.loffI[tid]; }
  __syncthreads();
  #pragma unroll
  for (int t = 0; t < 16; t++) {
    if (ss[t] >= 0) {
      int b = ss[t] >> 8;
      int p = atomicAdd(&S.lcU[b], 1);
      S.recsU[p] = ((unsigned)(ss[t] & 255) << 17) | (unsigned)dd[t];
      b = dd[t] >> 7;
      p = atomicAdd(&S.lcI[b], 1);
      S.recsI[p] = ((unsigned)(dd[t] & 127) << 17) | (unsigned)ss[t];
    }
  }
  __syncthreads();
  int totU = S.loffU[NBK_];
  for (int p = tid; p < totU; p += 256) {
    int lo = 0, hi = NBK_;
    while (hi - lo > 1) { int mid = (lo + hi) >> 1; if (S.loffU[mid] <= p) lo = mid; else hi = mid; }
    bufU[S.cbU[lo] + (p - S.loffU[lo])] = S.recsU[p];
  }
  int totI = S.loffI[NBK_];
  for (int p = tid; p < totI; p += 256) {
    int lo = 0, hi = NBK_;
    while (hi - lo > 1) { int mid = (lo + hi) >> 1; if (S.loffI[mid] <= p) lo = mid; else hi = mid; }
    bufI[S.cbI[lo] + (p - S.loffI[lo])] = S.recsI[p];
  }
}

DEVI void anchor_body(char* smemRaw, int blk,
    const void* __restrict__ ue, const void* __restrict__ WU,
    const void* __restrict__ cw, const float* __restrict__ vecs,
    const int* __restrict__ nbr, float* __restrict__ out, int isf32) {
  AncSmem& S = *(AncSmem*)smemRaw;
  int tid = threadIdx.x;
  int wv = tid >> 6, lane = tid & 63;
  int ublk = blk * 16;

  #pragma unroll
  for (int it = 0; it < 16; it++) {
    int k = it * 4 + wv;
    S.WUt[lane * WS_ + k] = (_Float16)ldf(WU, (size_t)k * 64 + lane, isf32);
  }
  if (tid < 128) S.nbrS[tid] = nbr[ublk * 8 + tid];
  __syncthreads();

  float cw0 = ldf(cw, (0 * 64 + lane) * 2, isf32);
  float w1r = ldf(cw, (1 * 64 + lane) * 2, isf32), w1i = ldf(cw, (1 * 64 + lane) * 2 + 1, isf32);
  float w2r = ldf(cw, (2 * 64 + lane) * 2, isf32), w2i = ldf(cw, (2 * 64 + lane) * 2 + 1, isf32);
  float w3r = ldf(cw, (3 * 64 + lane) * 2, isf32), w3i = ldf(cw, (3 * 64 + lane) * 2 + 1, isf32);
  float cw4 = ldf(cw, (4 * 64 + lane) * 2, isf32);
  float v1 = vecs[64 + lane], v2 = vecs[128 + lane];
  const float c1 = 0.70710678118654752440f;

  float xc[8], xn[8];
  #pragma unroll
  for (int k = 0; k < 8; k++)
    xc[k] = ldf(ue, (size_t)S.nbrS[wv * 32 + k] * 64 + lane, isf32);

  for (int u4 = 0; u4 < 4; u4++) {
    int uL = wv * 4 + u4;
    int u = ublk + uL;
    if (u4 < 3) {
      #pragma unroll
      for (int k = 0; k < 8; k++)
        xn[k] = ldf(ue, (size_t)S.nbrS[wv * 32 + (u4 + 1) * 8 + k] * 64 + lane, isf32);
    }
    float sA = xc[1] - xc[3] - xc[5] + xc[7];
    float sB = xc[1] + xc[3] - xc[5] - xc[7];
    float ev = (xc[0] + xc[4]) + (xc[2] + xc[6]);
    float od = (xc[1] + xc[5]) + (xc[3] + xc[7]);
    float d04 = xc[0] - xc[4], d26 = xc[2] - xc[6];
    float X0r = ev + od;
    float X1r = d04 + c1 * sA;
    float X1i = -d26 - c1 * sB;
    float X2r = (xc[0] + xc[4]) - (xc[2] + xc[6]);
    float X2i = -(xc[1] - xc[3] + xc[5] - xc[7]);
    float X3r = d04 - c1 * sA;
    float X3i = d26 - c1 * sB;
    float X4r = ev - od;
    float Zr0 = X0r * cw0;
    float Zr1 = X1r * w1r - X1i * w1i, Zi1 = X1r * w1i + X1i * w1r;
    float Zr2 = X2r * w2r - X2i * w2i, Zi2 = X2r * w2i + X2i * w2r;
    float Zr3 = X3r * w3r - X3i * w3i, Zi3 = X3r * w3i + X3i * w3r;
    float Zr4 = X4r * cw4;
    float eP = Zr0 + Zr4, eM = Zr0 - Zr4;
    float t1 = c1 * (Zr1 - Zr3), t2 = c1 * (Zi1 + Zi3);
    float y[8];
    y[0] = eP + 2.f * (Zr1 + Zr2 + Zr3);
    y[1] = eM + 2.f * (t1 - t2 - Zi2);
    y[2] = eP + 2.f * (-Zi1 - Zr2 + Zi3);
    y[3] = eM + 2.f * (-t1 - t2 + Zi2);
    y[4] = eP + 2.f * (-Zr1 + Zr2 - Zr3);
    y[5] = eM + 2.f * (-t1 + t2 - Zi2);
    y[6] = eP + 2.f * (Zi1 - Zr2 - Zi3);
    y[7] = eM + 2.f * (t1 + t2 + Zi2);
    #pragma unroll
    for (int k = 0; k < 8; k++) y[k] *= 0.125f;

    float ek[8];
    #pragma unroll
    for (int k = 0; k < 8; k++) ek[k] = y[k] * v1;
    float q = ldf(ue, (size_t)u * 64 + lane, isf32) * v2;
    #pragma unroll
    for (int off = 32; off; off >>= 1) {
      #pragma unroll
      for (int k = 0; k < 8; k++) ek[k] += __shfl_xor(ek[k], off, 64);
      q += __shfl_xor(q, off, 64);
    }
    float m = -1e30f;
    #pragma unroll
    for (int k = 0; k < 8; k++) {
      float v = ek[k] + q;
      v = v > 0.f ? v : 0.1f * v;  // LeakyReLU(0.1)
      ek[k] = v;
      m = fmaxf(m, v);
    }
    float se = 0.f, wexp[8];
    #pragma unroll
    for (int k = 0; k < 8; k++) { wexp[k] = __expf(ek[k] - m); se += wexp[k]; }
    float mix = 0.f;
    #pragma unroll
    for (int k = 0; k < 8; k++) mix += wexp[k] * y[k];
    S.mixS[uL * WS_ + lane] = (_Float16)mix;
    if (lane == 0) S.invSe[uL] = frcp(se);
    #pragma unroll
    for (int k = 0; k < 8; k++) xc[k] = xn[k];
  }
  __syncthreads();

  int n = lane & 15, qd = lane >> 4;
  f16x8 A0 = *(const f16x8*)&S.mixS[(lane & 15) * WS_ + qd * 8];
  f16x8 A1 = *(const f16x8*)&S.mixS[(lane & 15) * WS_ + 32 + qd * 8];
  f16x8 B0 = *(const f16x8*)&S.WUt[(wv * 16 + n) * WS_ + qd * 8];
  f16x8 B1 = *(const f16x8*)&S.WUt[(wv * 16 + n) * WS_ + 32 + qd * 8];
  const floatx4 zero = {0.f, 0.f, 0.f, 0.f};
  floatx4 acc = __builtin_amdgcn_mfma_f32_16x16x32_f16(A0, B0, zero, 0, 0, 0);
  acc = __builtin_amdgcn_mfma_f32_16x16x32_f16(A1, B1, acc, 0, 0, 0);
  #pragma unroll
  for (int r = 0; r < 4; r++) {
    int m = qd * 4 + r;
    out[(size_t)(ublk + m) * 64 + wv * 16 + n] = acc[r] * S.invSe[m];
  }
}

DEVI void convert_body(int blk, const void* __restrict__ ue, const void* __restrict__ ie,
                       unsigned char* __restrict__ ue8, unsigned char* __restrict__ ie8,
                       int isf32) {
  size_t t = (size_t)blk * 256 + threadIdx.x;   // element-pair index
  float a, b; unsigned short* dst; size_t o;
  if (t < UD_ / 2) {
    a = ldf(ue, 2 * t, isf32); b = ldf(ue, 2 * t + 1, isf32);
    dst = (unsigned short*)ue8; o = t;
  } else {
    size_t s = t - UD_ / 2;
    a = ldf(ie, 2 * s, isf32); b = ldf(ie, 2 * s + 1, isf32);
    dst = (unsigned short*)ie8; o = s;
  }
  unsigned p = fp8_enc_pk(a * SCALE_E_, b * SCALE_E_);
  dst[o] = (unsigned short)(p & 0xFFFF);
}

__global__ __launch_bounds__(256) void fusedA_kernel(
    const int* __restrict__ rs, const int* __restrict__ rd,
    unsigned* __restrict__ bufU, unsigned* __restrict__ bufI,
    int* __restrict__ curU, int* __restrict__ curI,
    const void* __restrict__ ue, const void* __restrict__ ie,
    const void* __restrict__ WU, const void* __restrict__ cw,
    const float* __restrict__ vecs, const int* __restrict__ nbr,
    float* __restrict__ anc, unsigned char* __restrict__ ue8,
    unsigned char* __restrict__ ie8, const float* __restrict__ flag) {
  __shared__ __align__(16) char smem[FSA_SMEM];
  if (blockIdx.x < NBA_) {
    bucketA_body(smem, blockIdx.x, rs, rd, bufU, bufI, curU, curI);
  } else if (blockIdx.x < NBA_ + NANC_) {
    anchor_body(smem, blockIdx.x - NBA_, ue, WU, cw, vecs, nbr, anc, *flag > 0.5f);
  } else {
    convert_body(blockIdx.x - NBA_ - NANC_, ue, ie, ue8, ie8, *flag > 0.5f);
  }
}

// ---------------- 1b. tiny scan ----------------
__global__ void scanBuckets_kernel(const int* __restrict__ curU,
                                   const int* __restrict__ curI,
                                   int* __restrict__ bbU, int* __restrict__ bbI,
                                   int* __restrict__ rowU, int* __restrict__ rowI) {
  if (threadIdx.x == 0) {
    int run = 0;
    for (int i = 0; i < NBK_; i++) { bbU[i] = run; run += curU[i]; }
    bbU[NBK_] = run;
    run = 0;
    for (int i = 0; i < NBK_; i++) { bbI[i] = run; run += curI[i]; }
    bbI[NBK_] = run;
    rowU[U_] = E_;
    rowI[I_] = E_;
  }
}

// ---------------- 1c. Phase B ----------------
__global__ __launch_bounds__(256) void bucketB_kernel(
    const unsigned* __restrict__ bufU, const unsigned* __restrict__ bufI,
    const int* __restrict__ curU, const int* __restrict__ curI,
    const int* __restrict__ bbU, const int* __restrict__ bbI,
    int* __restrict__ rowU, int* __restrict__ rowI,
    int* __restrict__ csrU, int* __restrict__ csrI) {
  __shared__ int stage[CAP_];
  __shared__ int cntk[256], offk[256];
  __shared__ int wsum[4];
  int tid = threadIdx.x, b = blockIdx.x;
  int side = b >= NBK_;
  int bb = side ? b - NBK_ : b;
  const unsigned* src = (side ? bufI : bufU) + (size_t)bb * CAP_;
  int total = side ? curI[bb] : curU[bb];
  int gbase = side ? bbI[bb] : bbU[bb];
  int kpb   = side ? 128 : 256;
  int* rowptr = side ? rowI : rowU;
  int* csr    = side ? csrI : csrU;
  cntk[tid] = 0;
  __syncthreads();
  for (int r = tid; r < total; r += 256) atomicAdd(&cntk[src[r] >> 17], 1);
  __syncthreads();
  int lane = tid & 63, wv = tid >> 6;
  int cv = (tid < kpb) ? cntk[tid] : 0;
  int incl = waveInclScan(cv, lane);
  if (lane == 63) wsum[wv] = incl;
  __syncthreads();
  int wvoff = 0;
  for (int w = 0; w < wv; w++) wvoff += wsum[w];
  int excl = wvoff + incl - cv;
  if (tid < kpb) {
    offk[tid] = excl;
    rowptr[bb * kpb + tid] = gbase + excl;
  }
  __syncthreads();
  for (int r = tid; r < total; r += 256) {
    unsigned rec = src[r];
    int slot = atomicAdd(&offk[rec >> 17], 1);
    if (slot < CAP_) stage[slot] = (int)(rec & 0x1FFFFu);
  }
  __syncthreads();
  for (int s = tid; s < total; s += 256) csr[gbase + s] = stage[s];
}

// ---------------- 2. fused layer-1 aggregation (fp8 gather, bf16+fp8 out) -------
__global__ __launch_bounds__(256) void agg1_kernel(
    const unsigned char* __restrict__ ue8, const unsigned char* __restrict__ ie8,
    const int* __restrict__ rowU, const int* __restrict__ rowI,
    const int* __restrict__ csrU, const int* __restrict__ csrI,
    __hip_bfloat16* __restrict__ u1, __hip_bfloat16* __restrict__ i1,
    unsigned char* __restrict__ u18, unsigned char* __restrict__ i18) {
  int wv = threadIdx.x >> 6, lane = threadIdx.x & 63;
  int side = blockIdx.x >= I_ / 4;          // 0: item rows (gather ue8), 1: user rows
  int blk = side ? blockIdx.x - I_ / 4 : blockIdx.x;
  int r = blk * 4 + wv;
  const int* row = side ? rowU : rowI;
  const int* csr = side ? csrU : csrI;
  const unsigned char* src = side ? ie8 : ue8;
  __hip_bfloat16* out = side ? u1 : i1;
  unsigned char* out8 = side ? u18 : i18;
  int s0 = row[r], s1 = row[r + 1];
  float acc = 0.f;
  int j = s0;
  for (; j + 4 <= s1; j += 4) {
    int a = csr[j], b = csr[j + 1], c = csr[j + 2], d = csr[j + 3];
    float va = fp8_dec(src[(size_t)a * 64 + lane]);
    float vb = fp8_dec(src[(size_t)b * 64 + lane]);
    float vc = fp8_dec(src[(size_t)c * 64 + lane]);
    float vd = fp8_dec(src[(size_t)d * 64 + lane]);
    acc += (va + vb) + (vc + vd);
  }
  for (; j < s1; j++) acc += fp8_dec(src[(size_t)csr[j] * 64 + lane]);
  float val = acc * ISCALE_E_ * frcp(fmaxf((float)(s1 - s0), 1.0f));
  size_t idx = (size_t)r * 64 + lane;
  out[idx] = __float2bfloat16(val);
  unsigned p = fp8_enc_pk(val * SCALE_1_, val * SCALE_1_);
  out8[idx] = (unsigned char)(p & 0xFF);
}

// ---------------- 3. fused layer-2 aggregation + attention (fp8 gather) ---------
__global__ __launch_bounds__(256) void agg2attn_kernel(
    const unsigned char* __restrict__ u18, const unsigned char* __restrict__ i18,
    const __hip_bfloat16* __restrict__ u1, const __hip_bfloat16* __restrict__ i1,
    const void* __restrict__ ue, const void* __restrict__ ie,
    const int* __restrict__ rowU, const int* __restrict__ rowI,
    const int* __restrict__ csrU, const int* __restrict__ csrI,
    const float* __restrict__ vecs, float* __restrict__ hu, float* __restrict__ hi,
    const float* __restrict__ flag) {
  int isf32 = *flag > 0.5f;
  int wv = threadIdx.x >> 6, lane = threadIdx.x & 63;
  int side = blockIdx.x >= I_ / 4;          // 0: item rows, 1: user rows
  int blk = side ? blockIdx.x - I_ / 4 : blockIdx.x;
  int r = blk * 4 + wv;
  const int* row = side ? rowU : rowI;
  const int* csr = side ? csrU : csrI;
  const unsigned char* opp8 = side ? i18 : u18;
  const __hip_bfloat16* own1 = side ? u1 : i1;
  const void* base = side ? ue : ie;
  float* h = side ? hu : hi;
  int s0 = row[r], s1 = row[r + 1];
  float acc = 0.f;
  int j = s0;
  for (; j + 4 <= s1; j += 4) {
    int a = csr[j], b = csr[j + 1], c = csr[j + 2], d = csr[j + 3];
    float va = fp8_dec(opp8[(size_t)a * 64 + lane]);
    float vb = fp8_dec(opp8[(size_t)b * 64 + lane]);
    float vc = fp8_dec(opp8[(size_t)c * 64 + lane]);
    float vd = fp8_dec(opp8[(size_t)d * 64 + lane]);
    acc += (va + vb) + (vc + vd);
  }
  for (; j < s1; j++) acc += fp8_dec(opp8[(size_t)csr[j] * 64 + lane]);
  size_t idx = (size_t)r * 64 + lane;
  float t2 = acc * ISCALE_1_ * frcp(fmaxf((float)(s1 - s0), 1.0f));
  float t0 = ldf(base, idx, isf32);
  float t1 = b2f(own1[idx]);
  float w = vecs[lane];   // Wa
  float p0 = t0 * w, p1 = t1 * w, p2 = t2 * w;
  #pragma unroll
  for (int off = 32; off; off >>= 1) {
    p0 += __shfl_xor(p0, off, 64);
    p1 += __shfl_xor(p1, off, 64);
    p2 += __shfl_xor(p2, off, 64);
  }
  float m = fmaxf(p0, fmaxf(p1, p2));
  float e0 = __expf(p0 - m), e1 = __expf(p1 - m), e2 = __expf(p2 - m);
  float inv = 1.0f / (e0 + e1 + e2);
  h[idx] = (t0 * e0 + t1 * e1 + t2 * e2) * inv;
}

// ---------------- 5. contrastive loss: slim epilogue MFMA Gram ----------
constexpr int XS_ = 72;                   // f16 row stride (144 B)
constexpr float SC_  = 2.6857914f;        // sqrt(5*log2(e))
constexpr float EPS_ = 1e-6f;
constexpr float LN2_ = 0.6931471805599453f;
__global__ __launch_bounds__(1024) void contrast_kernel(
    const float* __restrict__ hu, const float* __restrict__ an,
    float* __restrict__ loss_acc) {
  __shared__ __align__(16) _Float16 Xh[512 * XS_];  // 72 KB
  __shared__ float iN[512];
  int tid = threadIdx.x;
  int c = blockIdx.x;

  if (tid < 512) {
    int row = tid & 255;
    const float* r1 = (tid < 256 ? hu : an) + ((size_t)c * CB_ + row) * 64;
    float4 a4[16];
    float s1 = 0.f;
    #pragma unroll
    for (int t = 0; t < 16; t++) {
      a4[t] = ((const float4*)r1)[t];
      s1 += a4[t].x * a4[t].x + a4[t].y * a4[t].y + a4[t].z * a4[t].z + a4[t].w * a4[t].w;
    }
    float inv = frcp(sqrtf(s1));
    iN[tid] = inv;
    float sc = inv * SC_;
    #pragma unroll
    for (int t = 0; t < 8; t++) {
      f16x8 v;
      v[0] = (_Float16)(a4[2*t].x * sc);   v[1] = (_Float16)(a4[2*t].y * sc);
      v[2] = (_Float16)(a4[2*t].z * sc);   v[3] = (_Float16)(a4[2*t].w * sc);
      v[4] = (_Float16)(a4[2*t+1].x * sc); v[5] = (_Float16)(a4[2*t+1].y * sc);
      v[6] = (_Float16)(a4[2*t+1].z * sc); v[7] = (_Float16)(a4[2*t+1].w * sc);
      *(f16x8*)&Xh[tid * XS_ + t * 8] = v;
    }
  }
  __syncthreads();

  int l = tid & 63, wv = tid >> 6;       // wv 0..15
  int n = l & 15, q = l >> 4;
  int rb = wv * 32;
  f16x8 A[2][2];
  #pragma unroll
  for (int t = 0; t < 2; t++) {
    A[t][0] = *(const f16x8*)&Xh[(rb + t * 16 + n) * XS_ + q * 8];
    A[t][1] = *(const f16x8*)&Xh[(rb + t * 16 + n) * XS_ + 32 + q * 8];
  }
  float eNiR[2][4];
  #pragma unroll
  for (int t = 0; t < 2; t++)
    #pragma unroll
    for (int r = 0; r < 4; r++)
      eNiR[t][r] = EPS_ * iN[rb + t * 16 + q * 4 + r];
  float sums[2][4] = {{0,0,0,0},{0,0,0,0}};
  float labs2[2] = {0, 0};
  int selfn = q * 4;
  const floatx4 zero = {0.f, 0.f, 0.f, 0.f};
  for (int ct = 0; ct < 32; ct++) {
    f16x8 B0 = *(const f16x8*)&Xh[(ct * 16 + n) * XS_ + q * 8];
    f16x8 B1 = *(const f16x8*)&Xh[(ct * 16 + n) * XS_ + 32 + q * 8];
    float iNj = iN[ct * 16 + n];
    #pragma unroll
    for (int t = 0; t < 2; t++) {
      floatx4 acc = __builtin_amdgcn_mfma_f32_16x16x32_f16(A[t][0], B0, zero, 0, 0, 0);
      acc = __builtin_amdgcn_mfma_f32_16x16x32_f16(A[t][1], B1, acc, 0, 0, 0);
      int rtg = wv * 2 + t;
      if (ct == (rtg ^ 16)) {
        #pragma unroll
        for (int r = 0; r < 4; r++) {
          float G = acc[r];
          float u = eNiR[t][r] * iNj;
          float s2 = __builtin_fmaf(G, -u, G);
          sums[t][r] += fexp2(s2);
          if (n == selfn + r) labs2[t] += s2;
        }
      } else if (ct == rtg) {
        #pragma unroll
        for (int r = 0; r < 4; r++) {
          float G = acc[r];
          float u = eNiR[t][r] * iNj;
          float s2 = __builtin_fmaf(G, -u, G);
          float e = (n == selfn + r) ? 0.f : fexp2(s2);
          sums[t][r] += e;
        }
      } else {
        #pragma unroll
        for (int r = 0; r < 4; r++) {
          float G = acc[r];
          float u = eNiR[t][r] * iNj;
          float s2 = __builtin_fmaf(G, -u, G);
          sums[t][r] += fexp2(s2);
        }
      }
    }
  }
  #pragma unroll
  for (int off = 1; off <= 8; off <<= 1) {
    #pragma unroll
    for (int t = 0; t < 2; t++) {
      #pragma unroll
      for (int r = 0; r < 4; r++) sums[t][r] += __shfl_xor(sums[t][r], off, 64);
      labs2[t] += __shfl_xor(labs2[t], off, 64);
    }
  }
  float part = 0.f;
  if (n == 0) {
    #pragma unroll
    for (int t = 0; t < 2; t++) {
      float lt = 0.f;
      #pragma unroll
      for (int r = 0; r < 4; r++) lt += __logf(sums[t][r]);
      part += lt - labs2[t] * LN2_;
    }
  }
  #pragma unroll
  for (int off = 1; off < 64; off <<= 1) part += __shfl_xor(part, off, 64);
  if (l == 0) atomicAdd(loss_acc, part);
}

// ---------------- 6. scores ----------------
__global__ __launch_bounds__(256) void score_kernel(
    const float* __restrict__ hu, const float* __restrict__ hi,
    const int* __restrict__ pu, const int* __restrict__ pi,
    const int* __restrict__ nu, const int* __restrict__ ni,
    void* __restrict__ out, const float* __restrict__ flag) {
  int isf32 = *flag > 0.5f;
  int w = (blockIdx.x * 256 + threadIdx.x) >> 6;
  int lane = threadIdx.x & 63;
  int uu, ii;
  if (w < EP_) { uu = pu[w]; ii = pi[w]; }
  else         { uu = nu[w - EP_]; ii = ni[w - EP_]; }
  float p = hu[(size_t)uu * 64 + lane] * hi[(size_t)ii * 64 + lane];
  #pragma unroll
  for (int off = 32; off; off >>= 1) p += __shfl_xor(p, off, 64);
  if (lane == 0) {
    if (isf32) ((float*)out)[w] = p;
    else       ((__hip_bfloat16*)out)[w] = __float2bfloat16(p);
  }
}

__global__ void finalize_kernel(const float* __restrict__ loss_acc,
                                void* __restrict__ out,
                                const float* __restrict__ flag) {
  float v = loss_acc[0] * (1.0f / (float)(2 * CB_ * NCHUNK_));
  if (*flag > 0.5f) ((float*)out)[2 * EP_] = v;
  else              ((__hip_bfloat16*)out)[2 * EP_] = __float2bfloat16(v);
}

// ---------------- launch ----------------
extern "C" void kernel_launch(void* const* d_in, const int* in_sizes, int n_in,
                              void* d_out, int out_size, void* d_ws, size_t ws_size,
                              hipStream_t stream) {
  const void* ue  = d_in[0];
  const void* ie  = d_in[1];
  const void* W   = d_in[2];
  const void* a   = d_in[3];
  const void* WU  = d_in[4];
  const void* aU  = d_in[5];
  const void* cw  = d_in[6];
  const int* rs  = (const int*)d_in[7];
  const int* rd  = (const int*)d_in[8];
  const int* pu  = (const int*)d_in[9];
  const int* pi  = (const int*)d_in[10];
  const int* nu  = (const int*)d_in[11];
  const int* ni  = (const int*)d_in[12];
  const int* nbr = (const int*)d_in[13];

  float* wsf  = (float*)d_ws;
  int*   wsi  = (int*)d_ws;
  float* loss = wsf + OFF_LOSS;
  float* flag = wsf + OFF_FLAG;
  int* curU   = wsi + OFF_CURU;
  int* curI   = wsi + OFF_CURI;
  float* vecs = wsf + OFF_VEC;
  int* bbU    = wsi + OFF_BBU;
  int* bbI    = wsi + OFF_BBI;
  int* rowU   = wsi + OFF_ROWU;
  int* rowI   = wsi + OFF_ROWI;
  int* csrU   = wsi + OFF_CSRU;
  int* csrI   = wsi + OFF_CSRI;
  __hip_bfloat16* u1 = (__hip_bfloat16*)(wsf + OFF_U1);
  __hip_bfloat16* i1 = (__hip_bfloat16*)(wsf + OFF_I1);
  float* hu   = wsf + OFF_HU;
  float* hi   = wsf + OFF_HI;
  float* anc  = wsf + OFF_ANC;
  unsigned char* ue8 = (unsigned char*)(wsf + OFF_UE8);
  unsigned char* ie8 = (unsigned char*)(wsf + OFF_IE8);
  unsigned char* u18 = (unsigned char*)(wsf + OFF_U18);
  unsigned char* i18 = (unsigned char*)(wsf + OFF_I18);
  unsigned* bufU = (unsigned*)(wsf + OFF_HU);
  unsigned* bufI = (unsigned*)(wsf + OFF_HI);

  hipMemsetAsync(d_ws, 0, MEMSET_BYTES, stream);
  prep_kernel<<<1, 64, 0, stream>>>((const unsigned short*)ue, W, a, WU, aU, vecs, flag);

  // fused: CSR Phase A + anchor + fp8 convert (all independent)
  fusedA_kernel<<<NBA_ + NANC_ + NCVT_, 256, 0, stream>>>(
      rs, rd, bufU, bufI, curU, curI, ue, ie, WU, cw, vecs, nbr, anc, ue8, ie8, flag);
  scanBuckets_kernel<<<1, 64, 0, stream>>>(curU, curI, bbU, bbI, rowU, rowI);
  bucketB_kernel<<<2 * NBK_, 256, 0, stream>>>(bufU, bufI, curU, curI, bbU, bbI,
                                               rowU, rowI, csrU, csrI);

  // fused layer-1 aggregation (fp8 gather, both sides)
  agg1_kernel<<<(I_ + U_) / 4, 256, 0, stream>>>(ue8, ie8, rowU, rowI, csrU, csrI,
                                                 u1, i1, u18, i18);
  // fused layer-2 aggregation + attention (fp8 gather, both sides)
  agg2attn_kernel<<<(I_ + U_) / 4, 256, 0, stream>>>(u18, i18, u1, i1, ue, ie,
                                                     rowU, rowI, csrU, csrI,
                                                     vecs, hu, hi, flag);

  // contrastive loss
  contrast_kernel<<<NCHUNK_, 1024, 0, stream>>>(hu, anc, loss);

  // scores
  score_kernel<<<(2 * EP_ * 64) / 256, 256, 0, stream>>>(hu, hi, pu, pi, nu, ni, d_out, flag);
  finalize_kernel<<<1, 1, 0, stream>>>(loss, d_out, flag);
}